// Round 8
// baseline (422.644 us; speedup 1.0000x reference)
//
#include <hip/hip_runtime.h>
#include <cstdint>

#define DEV __device__ __forceinline__

typedef __attribute__((ext_vector_type(8))) short bf16x8;
typedef __attribute__((ext_vector_type(4))) float f32x4;

DEV unsigned short f2bf(float x){
  union { float f; unsigned u; } c; c.f = x;
  unsigned r = c.u + 0x7fffu + ((c.u >> 16) & 1u);
  return (unsigned short)(r >> 16);
}
DEV float bf2f(unsigned short h){
  union { unsigned u; float f; } c; c.u = ((unsigned)h) << 16;
  return c.f;
}
DEV float gelu_f(float x){ return 0.5f * x * (1.f + erff(x * 0.70710678118654752440f)); }

DEV f32x4 mfma16(bf16x8 a, bf16x8 b, f32x4 c){
  return __builtin_amdgcn_mfma_f32_16x16x32_bf16(a, b, c, 0, 0, 0);
}

// block_sum: 256 threads (4 waves)
DEV float block_sum(float v, float* red, int tid){
  #pragma unroll
  for (int o = 32; o > 0; o >>= 1) v += __shfl_down(v, o);
  if ((tid & 63) == 0) red[tid >> 6] = v;
  __syncthreads();
  float s = red[0] + red[1] + red[2] + red[3];
  __syncthreads();
  return s;
}

// ---------------- constants ----------------
// B=16 N=64 D=256 CI=256 H=W=64 P=36 HEADS=8 HD=32 HID=1024 TOTAL=66832 T=1024
// params3 blocked layout: element n of token t lives at
//   params3[(n>>6)*65536 + t*64 + (n&63)]   (nc-major, then token, then off)

// ---------------- kernel 1: per-token prep ----------------
__global__ __launch_bounds__(256) void k_prep(
    const float* __restrict__ embed, const float* __restrict__ roi,
    const float* __restrict__ g_adj, const float* __restrict__ b_adj, const float* __restrict__ w_adj,
    const float* __restrict__ g_off, const float* __restrict__ b_off, const float* __restrict__ w_off,
    const float* __restrict__ off_bias,
    const float* __restrict__ g_pg, const float* __restrict__ b_pg,
    const float* __restrict__ w_pg1, const float* __restrict__ b_pg1,
    float* __restrict__ pts, float* __restrict__ hbuf)
{
  __shared__ float red[4];
  __shared__ float xln[256];
  __shared__ float offs[72];
  __shared__ float lg[4];
  __shared__ float stat[8];
  const int t = blockIdx.x, tid = threadIdx.x;
  float e = embed[t * 256 + tid];
  float mean = block_sum(e, red, tid) * (1.f / 256.f);
  float dv = e - mean;
  float var = block_sum(dv * dv, red, tid) * (1.f / 256.f);
  xln[tid] = dv * rsqrtf(var + 1e-5f);
  __syncthreads();
  if (tid < 4){
    float a0 = 0.f, a1 = 0.f, a2 = 0.f, a3 = 0.f;
    #pragma unroll 4
    for (int c = 0; c < 256; c += 4){
      a0 += (xln[c+0] * g_adj[c+0] + b_adj[c+0]) * w_adj[(c+0) * 4 + tid];
      a1 += (xln[c+1] * g_adj[c+1] + b_adj[c+1]) * w_adj[(c+1) * 4 + tid];
      a2 += (xln[c+2] * g_adj[c+2] + b_adj[c+2]) * w_adj[(c+2) * 4 + tid];
      a3 += (xln[c+3] * g_adj[c+3] + b_adj[c+3]) * w_adj[(c+3) * 4 + tid];
    }
    lg[tid] = (a0 + a1) + (a2 + a3);
  } else if (tid < 76){
    int j = tid - 4;
    float a0 = 0.f, a1 = 0.f, a2 = 0.f, a3 = 0.f;
    #pragma unroll 4
    for (int c = 0; c < 256; c += 4){
      a0 += (xln[c+0] * g_off[c+0] + b_off[c+0]) * w_off[(c+0) * 72 + j];
      a1 += (xln[c+1] * g_off[c+1] + b_off[c+1]) * w_off[(c+1) * 72 + j];
      a2 += (xln[c+2] * g_off[c+2] + b_off[c+2]) * w_off[(c+2) * 72 + j];
      a3 += (xln[c+3] * g_off[c+3] + b_off[c+3]) * w_off[(c+3) * 72 + j];
    }
    offs[j] = (a0 + a1) + (a2 + a3) + off_bias[j];
  } else if (tid < 140){
    int j = tid - 76;
    float a0 = 0.f, a1 = 0.f, a2 = 0.f, a3 = 0.f;
    #pragma unroll 4
    for (int c = 0; c < 256; c += 4){
      a0 += (xln[c+0] * g_pg[c+0] + b_pg[c+0]) * w_pg1[(c+0) * 64 + j];
      a1 += (xln[c+1] * g_pg[c+1] + b_pg[c+1]) * w_pg1[(c+1) * 64 + j];
      a2 += (xln[c+2] * g_pg[c+2] + b_pg[c+2]) * w_pg1[(c+2) * 64 + j];
      a3 += (xln[c+3] * g_pg[c+3] + b_pg[c+3]) * w_pg1[(c+3) * 64 + j];
    }
    hbuf[t * 64 + j] = (a0 + a1) + (a2 + a3) + b_pg1[j];
  }
  __syncthreads();
  if (tid == 0){
    float x0 = roi[t*4+0], y0 = roi[t*4+1], x1 = roi[t*4+2], y1 = roi[t*4+3];
    float cx = (x0 + x1) * 0.5f, cy = (y0 + y1) * 0.5f;
    float w = fabsf(x1 - x0), hh = fabsf(y1 - y0);
    cx += lg[0] * w; cy += lg[1] * hh;
    w *= expf(lg[2]); hh *= expf(lg[3]);
    stat[0] = cx; stat[1] = cy; stat[2] = w; stat[3] = hh;
  }
  if (tid < 2){
    float mu = 0.f;
    for (int p = 0; p < 36; ++p) mu += offs[p*2 + tid];
    mu *= (1.f / 36.f);
    float v2 = 0.f;
    for (int p = 0; p < 36; ++p){ float d = offs[p*2 + tid] - mu; v2 += d * d; }
    float sd = sqrtf(v2 * (1.f / 35.f)) + 1e-7f;   // ddof=1
    stat[4 + tid] = mu; stat[6 + tid] = 1.f / (3.f * sd);
  }
  __syncthreads();
  if (tid < 72){
    int c = tid & 1;
    pts[t * 72 + tid] = stat[c] + (offs[tid] - stat[4 + c]) * stat[6 + c] * stat[2 + c];
  }
}

// ---------------- kernel 2: img [B,C,H,W] f32 -> [B,H,W,C] bf16 ----------------
__global__ __launch_bounds__(256) void k_transpose(const float* __restrict__ img,
                                                   unsigned short* __restrict__ imgT)
{
  __shared__ float tile[128][65];
  const int blk = blockIdx.x, tid = threadIdx.x;
  const int b = blk >> 6, y = blk & 63;
  for (int half = 0; half < 2; ++half){
    int c_loc = tid >> 1, x0 = (tid & 1) * 32;
    const float* src = img + (((size_t)(b * 256 + half * 128 + c_loc)) * 64 + y) * 64 + x0;
    #pragma unroll
    for (int i = 0; i < 32; ++i) tile[c_loc][x0 + i] = src[i];
    __syncthreads();
    int c = tid & 127, xh = tid >> 7;
    size_t obase = ((size_t)(b * 64 + y)) * 64 * 256 + half * 128 + c;
    for (int xx = 0; xx < 64; xx += 2){
      int x = xx + xh;
      imgT[obase + (size_t)x * 256] = f2bf(tile[c][x]);
    }
    __syncthreads();
  }
}

// ---------------- kernel 3: bilinear sample -> sampled [T,36,256] bf16 ----------------
__global__ __launch_bounds__(256) void k_sample(const unsigned short* __restrict__ imgT,
                                                const float* __restrict__ pts,
                                                unsigned short* __restrict__ sampled)
{
  __shared__ float lpts[72];
  const int t = blockIdx.x, tid = threadIdx.x;
  const int b = t >> 6;
  if (tid < 72) lpts[tid] = pts[t * 72 + tid];
  __syncthreads();
  for (int p = 0; p < 36; ++p){
    float fx = lpts[p*2]   * 64.f - 0.5f;
    float fy = lpts[p*2+1] * 64.f - 0.5f;
    float x0f = floorf(fx), y0f = floorf(fy);
    float wx = fx - x0f, wy = fy - y0f;
    int x0 = (int)x0f, y0 = (int)y0f;
    float acc = 0.f;
    #pragma unroll
    for (int dy = 0; dy < 2; ++dy){
      #pragma unroll
      for (int dx = 0; dx < 2; ++dx){
        int xi = x0 + dx, yi = y0 + dy;
        bool valid = (xi >= 0) & (xi < 64) & (yi >= 0) & (yi < 64);
        int xc = min(max(xi, 0), 63), yc = min(max(yi, 0), 63);
        float w = (dx ? wx : 1.f - wx) * (dy ? wy : 1.f - wy);
        float v = bf2f(imgT[(((size_t)(b * 64 + yc)) * 64 + xc) * 256 + tid]);
        acc += v * (valid ? w : 0.f);
      }
    }
    sampled[(size_t)t * 9216 + p * 256 + tid] = f2bf(acc);
  }
}

// ---------------- kernel 4: params3 = blocked(h @ pg_w2 + pg_b2), ONE TILE PER BLOCK
// grid (1045, 16): block (nc, mt) computes 64 tokens x 64 cols. No loop, 2 barriers,
// final stores are never drained by a barrier (kernel ends).
__global__ __launch_bounds__(256) void k_params(
    const float* __restrict__ hbuf, const float* __restrict__ w2,
    const float* __restrict__ b2, unsigned short* __restrict__ params3)
{
  __shared__ __align__(16) unsigned short Bs[64][72];  // [n][k^swz]
  __shared__ __align__(16) unsigned short As[64][72];  // [m][k]
  __shared__ __align__(16) unsigned short Os[64][72];  // output staging [m][n]
  const int tid = threadIdx.x, lane = tid & 63, wave = tid >> 6;
  const int wm = wave >> 1, wn = wave & 1;
  const int nc = blockIdx.x, n0 = nc * 64;
  const int m0 = blockIdx.y * 64;
  {
    int k = tid >> 2, nb = (tid & 3) * 16;
    #pragma unroll
    for (int i = 0; i < 16; ++i){
      int n = nb + i, gn = n0 + n;
      float v = (gn < 66832) ? w2[(size_t)k * 66832 + gn] : 0.f;
      Bs[n][k ^ (((n >> 3) & 7) << 3)] = f2bf(v);
    }
  }
  { int m = tid >> 2, kb4 = (tid & 3) * 16;
    const float* hp = hbuf + (m0 + m) * 64 + kb4;
    #pragma unroll
    for (int i = 0; i < 16; ++i) As[m][kb4 + i] = f2bf(hp[i]);
  }
  float bv[2];
  #pragma unroll
  for (int j = 0; j < 2; ++j){
    int col = n0 + wn*32 + j*16 + (lane & 15);
    bv[j] = (col < 66832) ? b2[col] : 0.f;
  }
  __syncthreads();
  f32x4 acc[2][2] = {};
  #pragma unroll
  for (int ks = 0; ks < 2; ++ks){
    int kb = ks * 32 + (lane >> 4) * 8;
    bf16x8 a[2], bb[2];
    #pragma unroll
    for (int i = 0; i < 2; ++i) a[i] = *(const bf16x8*)&As[wm*32 + i*16 + (lane & 15)][kb];
    #pragma unroll
    for (int j = 0; j < 2; ++j){
      int n = wn*32 + j*16 + (lane & 15);
      bb[j] = *(const bf16x8*)&Bs[n][kb ^ (((n >> 3) & 7) << 3)];
    }
    #pragma unroll
    for (int i = 0; i < 2; ++i)
      #pragma unroll
      for (int j = 0; j < 2; ++j) acc[i][j] = mfma16(a[i], bb[j], acc[i][j]);
  }
  #pragma unroll
  for (int i = 0; i < 2; ++i)
    #pragma unroll
    for (int j = 0; j < 2; ++j){
      int cl = wn*32 + j*16 + (lane & 15);
      #pragma unroll
      for (int r = 0; r < 4; ++r){
        int rl = wm*32 + i*16 + (lane >> 4) * 4 + r;
        Os[rl][cl] = f2bf(acc[i][j][r] + bv[j]);
      }
    }
  __syncthreads();
  {
    int rl = tid >> 2, c0 = (tid & 3) * 16;
    size_t gbase = ((size_t)nc * 1024 + m0 + rl) * 64 + c0;
    *(bf16x8*)(params3 + gbase)     = *(const bf16x8*)&Os[rl][c0];
    *(bf16x8*)(params3 + gbase + 8) = *(const bf16x8*)&Os[rl][c0 + 8];
  }
}

// ---------------- kernel 5: per-token adaptive mixing ----------------
// Single-barrier-per-cc double-buffered pipeline:
//   prefetch cc+1 (64B contiguous per lane) AFTER the barrier -> drain-free barriers;
//   LDS writes use d-dependent XOR swizzle (<=2-way conflicts).
// LDS (shorts): phase1: Ss[36][264]@0 (9504) + Cs[2][256][40]@9504 (20480) = 29984
//               phase2: O1T[256][72]@0 (18432) + Sm[48][72]@18432 (3456)
__global__ __launch_bounds__(256) void k_mixtoken(
    const unsigned short* __restrict__ sampled,
    const unsigned short* __restrict__ params3,
    const float* __restrict__ m_beta, const float* __restrict__ s_beta,
    unsigned short* __restrict__ out2)
{
  __shared__ __align__(16) unsigned short smem[29984];
  const int t = blockIdx.x, tid = threadIdx.x, lane = tid & 63, wave = tid >> 6;
  const int l15 = lane & 15, kb = (lane >> 4) * 8;
  unsigned short (*Ss)[264] = (unsigned short (*)[264])smem;
  // staging decomposition: thread -> (c_loc = tid&31, g = tid>>5); per v: d = g*32+v*8..+7
  const int c31  = tid & 31;
  const int g    = tid >> 5;
  const int goff = (g & 1) * 32;
  const int colw = c31 ^ ((g & 3) << 3);   // write swizzle; (d>>5)&3 == g&3 for all 8 d
  const unsigned short* ptok = params3 + (size_t)t * 64;
  bf16x8 rv[4];
  // prefetch cc=0 (lane reads 64B contiguous; wave = 32 fully-used 128B lines)
  {
    const unsigned short* src = ptok + ((size_t)(c31 * 4 + (g >> 1)) << 16) + goff;
    #pragma unroll
    for (int v = 0; v < 4; ++v) rv[v] = *(const bf16x8*)(src + v * 8);
  }
  // Sm tail into registers (written to LDS at phase-2 start)
  unsigned short rSm[14];
  #pragma unroll
  for (int k = 0; k < 14; ++k){
    int idx = tid + k * 256;
    unsigned short v = 0;
    if (idx < 3456){
      int o = idx / 72, p = idx % 72;
      if (o < 36 && p < 36){
        int n = 65536 + o * 36 + p;
        v = params3[(size_t)(n >> 6) * 65536 + (size_t)t * 64 + (n & 63)];
      }
    }
    rSm[k] = v;
  }
  // stage Ss rows 0..35
  const unsigned short* sp = sampled + (size_t)t * 9216;
  #pragma unroll
  for (int it = 0; it < 5; ++it){
    int slot = it * 256 + tid;
    if (slot < 1152){
      int p = slot >> 5, c8 = (slot & 31) << 3;
      *(bf16x8*)&Ss[p][c8] = *(const bf16x8*)(sp + p * 256 + c8);
    }
  }
  __syncthreads();
  f32x4 acc[3][4] = {};
  int cur = 0;
  for (int cc = 0; cc < 8; ++cc){
    unsigned short (*C)[40] = (unsigned short (*)[40])(smem + 9504 + cur * 10240);
    #pragma unroll
    for (int v = 0; v < 4; ++v){
      int dbase = g * 32 + v * 8;
      #pragma unroll
      for (int j = 0; j < 8; ++j) C[dbase + j][colw] = ((unsigned short*)&rv[v])[j];
    }
    __syncthreads();   // Cs[cur] ready; no global loads pending (rv consumed above)
    if (cc < 7){
      const unsigned short* src = ptok + ((size_t)((cc + 1) * 128 + c31 * 4 + (g >> 1)) << 16) + goff;
      #pragma unroll
      for (int v = 0; v < 4; ++v) rv[v] = *(const bf16x8*)(src + v * 8);
    }
    bf16x8 a[3], bfr[4];
    a[0] = *(const bf16x8*)&Ss[l15][cc * 32 + kb];
    a[1] = *(const bf16x8*)&Ss[16 + l15][cc * 32 + kb];
    a[2] = bf16x8{};
    if (l15 < 4) a[2] = *(const bf16x8*)&Ss[32 + l15][cc * 32 + kb];  // rows 36..47 are zero
    #pragma unroll
    for (int j = 0; j < 4; ++j){
      int d = wave * 64 + j * 16 + l15;
      bfr[j] = *(const bf16x8*)&C[d][kb ^ (((d >> 5) & 3) << 3)];
    }
    #pragma unroll
    for (int i = 0; i < 3; ++i)
      #pragma unroll
      for (int j = 0; j < 4; ++j) acc[i][j] = mfma16(a[i], bfr[j], acc[i][j]);
    cur ^= 1;   // single barrier per cc is safe: write(buf) and stale reads of the
                // same buf are separated by two barriers in the chain
  }
  __syncthreads();
  // repurpose smem: zero O1T [256][72] and write Sm from registers
  {
    const bf16x8 z = {};
    #pragma unroll
    for (int i = 0; i < 9; ++i)
      *(bf16x8*)&smem[(i * 256 + tid) * 8] = z;
    #pragma unroll
    for (int k = 0; k < 14; ++k){
      int idx = tid + k * 256;
      if (idx < 3456) smem[18432 + idx] = rSm[k];
    }
  }
  __syncthreads();
  unsigned short (*O1T)[72] = (unsigned short (*)[72])smem;
  unsigned short (*Sm)[72]  = (unsigned short (*)[72])(smem + 18432);
  #pragma unroll
  for (int i = 0; i < 3; ++i){
    int p = i * 16 + ((lane >> 4) << 2);
    if (p < 36){
      #pragma unroll
      for (int j = 0; j < 4; ++j){
        int d = wave * 64 + j * 16 + l15;
        float mb = m_beta[d];
        unsigned short* dst = &O1T[d][p];
        #pragma unroll
        for (int r = 0; r < 4; ++r) dst[r] = f2bf(gelu_f(acc[i][j][r] + mb));
      }
    }
  }
  __syncthreads();
  // ---- phase 2: out2 = sm @ out1 ----
  f32x4 acc2[3][4] = {};
  #pragma unroll
  for (int ks = 0; ks < 2; ++ks){
    int kb2 = ks * 32 + (lane >> 4) * 8;
    bf16x8 a2[3], bf2[4];
    #pragma unroll
    for (int i = 0; i < 3; ++i) a2[i] = *(const bf16x8*)&Sm[i*16 + l15][kb2];
    #pragma unroll
    for (int j = 0; j < 4; ++j) bf2[j] = *(const bf16x8*)&O1T[wave*64 + j*16 + l15][kb2];
    #pragma unroll
    for (int i = 0; i < 3; ++i)
      #pragma unroll
      for (int j = 0; j < 4; ++j) acc2[i][j] = mfma16(a2[i], bf2[j], acc2[i][j]);
  }
  unsigned short* o2 = out2 + (size_t)t * 9216;
  #pragma unroll
  for (int i = 0; i < 3; ++i){
    int ob = i*16 + ((lane >> 4) << 2);
    #pragma unroll
    for (int j = 0; j < 4; ++j){
      int d = wave*64 + j*16 + l15;
      #pragma unroll
      for (int r = 0; r < 4; ++r){
        int o = ob + r;
        if (o < 36) o2[o * 256 + d] = f2bf(gelu_f(acc2[i][j][r] + s_beta[o]));
      }
    }
  }
}

// ---------------- generic GEMM: C = act(A @ W + bias) (+resid) ----------------
template<int AK, int ACT, int RES, int OUTB>
__global__ __launch_bounds__(256) void k_gemm(
    const void* __restrict__ Ap, const float* __restrict__ W,
    const float* __restrict__ bias, const float* __restrict__ resid,
    void* __restrict__ Cp, int M, int N, int K)
{
  __shared__ __align__(16) unsigned short As[64][40];  // [m][k]
  __shared__ __align__(16) unsigned short Bs[64][40];  // [n][k^swz]
  const int tid = threadIdx.x, lane = tid & 63, wave = tid >> 6;
  const int wm = wave >> 1, wn = wave & 1;
  const int n0 = blockIdx.x * 64, m0 = blockIdx.y * 64;
  f32x4 acc[2][2] = {};
  for (int kk = 0; kk < K; kk += 32){
    { int m = tid >> 2, k4 = (tid & 3) * 8;
      if (AK == 0){
        const float* ap = (const float*)Ap + (size_t)(m0 + m) * K + kk + k4;
        #pragma unroll
        for (int i = 0; i < 8; ++i) As[m][k4 + i] = f2bf(ap[i]);
      } else {
        const unsigned short* ap = (const unsigned short*)Ap + (size_t)(m0 + m) * K + kk + k4;
        *(bf16x8*)&As[m][k4] = *(const bf16x8*)ap;
      }
    }
    { int kq = tid >> 3, n8 = (tid & 7) * 8;
      const float* wp = W + (size_t)(kk + kq) * N + n0 + n8;
      #pragma unroll
      for (int i = 0; i < 8; ++i){
        int n = n8 + i;
        Bs[n][kq ^ (((n >> 3) & 3) << 3)] = f2bf(wp[i]);
      }
    }
    __syncthreads();
    const int kb = (lane >> 4) * 8;
    bf16x8 a[2], bfr[2];
    #pragma unroll
    for (int i = 0; i < 2; ++i) a[i] = *(const bf16x8*)&As[wm*32 + i*16 + (lane & 15)][kb];
    #pragma unroll
    for (int j = 0; j < 2; ++j){
      int n = wn*32 + j*16 + (lane & 15);
      bfr[j] = *(const bf16x8*)&Bs[n][kb ^ (((n >> 3) & 3) << 3)];
    }
    #pragma unroll
    for (int i = 0; i < 2; ++i)
      #pragma unroll
      for (int j = 0; j < 2; ++j) acc[i][j] = mfma16(a[i], bfr[j], acc[i][j]);
    __syncthreads();
  }
  #pragma unroll
  for (int i = 0; i < 2; ++i)
    #pragma unroll
    for (int j = 0; j < 2; ++j){
      int col = n0 + wn*32 + j*16 + (lane & 15);
      float bv = bias[col];
      #pragma unroll
      for (int r = 0; r < 4; ++r){
        int row = m0 + wm*32 + i*16 + (lane >> 4) * 4 + r;
        float v = acc[i][j][r] + bv;
        if (ACT == 1) v = gelu_f(v);
        if (RES) v += resid[(size_t)row * N + col];
        if (OUTB) ((unsigned short*)Cp)[(size_t)row * N + col] = f2bf(v);
        else      ((float*)Cp)[(size_t)row * N + col] = v;
      }
    }
}

// ---------------- split-K GEMM: part[z][M][N] = A[:, z*KS:(z+1)*KS] @ W[z*KS:...] ----
template<int AK>
__global__ __launch_bounds__(256) void k_gemm_sk(
    const void* __restrict__ Ap, const float* __restrict__ W,
    float* __restrict__ part, int M, int N, int K, int KS)
{
  __shared__ __align__(16) unsigned short As[64][40];  // [m][k]
  __shared__ __align__(16) unsigned short Bs[64][40];  // [n][k^swz]
  const int tid = threadIdx.x, lane = tid & 63, wave = tid >> 6;
  const int wm = wave >> 1, wn = wave & 1;
  const int n0 = blockIdx.x * 64, m0 = blockIdx.y * 64;
  const int kbase = blockIdx.z * KS;
  f32x4 acc[2][2] = {};
  for (int kq = 0; kq < KS; kq += 32){
    int kk = kbase + kq;
    { int m = tid >> 2, k4 = (tid & 3) * 8;
      if (AK == 0){
        const float* ap = (const float*)Ap + (size_t)(m0 + m) * K + kk + k4;
        #pragma unroll
        for (int i = 0; i < 8; ++i) As[m][k4 + i] = f2bf(ap[i]);
      } else {
        const unsigned short* ap = (const unsigned short*)Ap + (size_t)(m0 + m) * K + kk + k4;
        *(bf16x8*)&As[m][k4] = *(const bf16x8*)ap;
      }
    }
    { int kr = tid >> 3, n8 = (tid & 7) * 8;
      const float* wp = W + (size_t)(kk + kr) * N + n0 + n8;
      #pragma unroll
      for (int i = 0; i < 8; ++i){
        int n = n8 + i;
        Bs[n][kr ^ (((n >> 3) & 3) << 3)] = f2bf(wp[i]);
      }
    }
    __syncthreads();
    const int kb = (lane >> 4) * 8;
    bf16x8 a[2], bfr[2];
    #pragma unroll
    for (int i = 0; i < 2; ++i) a[i] = *(const bf16x8*)&As[wm*32 + i*16 + (lane & 15)][kb];
    #pragma unroll
    for (int j = 0; j < 2; ++j){
      int n = wn*32 + j*16 + (lane & 15);
      bfr[j] = *(const bf16x8*)&Bs[n][kb ^ (((n >> 3) & 3) << 3)];
    }
    #pragma unroll
    for (int i = 0; i < 2; ++i)
      #pragma unroll
      for (int j = 0; j < 2; ++j) acc[i][j] = mfma16(a[i], bfr[j], acc[i][j]);
    __syncthreads();
  }
  float* pz = part + (size_t)blockIdx.z * M * N;
  #pragma unroll
  for (int i = 0; i < 2; ++i)
    #pragma unroll
    for (int j = 0; j < 2; ++j){
      int col = n0 + wn*32 + j*16 + (lane & 15);
      #pragma unroll
      for (int r = 0; r < 4; ++r){
        int row = m0 + wm*32 + i*16 + (lane >> 4) * 4 + r;
        pz[(size_t)row * N + col] = acc[i][j][r];
      }
    }
}

// ---------------- split-K reduce: out = sum_z part[z] + bias (+resid) ----------------
template<int RES>
__global__ __launch_bounds__(256) void k_reduce(
    const float* __restrict__ part, const float* __restrict__ bias,
    const float* __restrict__ resid, float* __restrict__ out,
    int total, int N, int SK)
{
  int i = blockIdx.x * 256 + threadIdx.x;
  if (i >= total) return;
  float s = 0.f;
  for (int z = 0; z < SK; ++z) s += part[(size_t)z * total + i];
  s += bias[i % N];
  if (RES) s += resid[i];
  out[i] = s;
}

// ---------------- fused split-K reduce + residual + LayerNorm ----------------
__global__ __launch_bounds__(256) void k_reduce_ln(
    const float* __restrict__ part, const float* __restrict__ bias,
    const float* __restrict__ resid,
    const float* __restrict__ g, const float* __restrict__ bb,
    float* __restrict__ emb_out, unsigned short* __restrict__ ln_out, int SK)
{
  __shared__ float red[4];
  const int t = blockIdx.x, tid = threadIdx.x;
  const int i = t * 256 + tid;
  float s = 0.f;
  for (int z = 0; z < SK; ++z) s += part[(size_t)z * 262144 + i];
  s += bias[tid] + resid[i];
  emb_out[i] = s;
  float mean = block_sum(s, red, tid) * (1.f / 256.f);
  float d = s - mean;
  float var = block_sum(d * d, red, tid) * (1.f / 256.f);
  ln_out[i] = f2bf(d * rsqrtf(var + 1e-5f) * g[tid] + bb[tid]);
}

// ---------------- attention: one (b,h) per block ----------------
__global__ __launch_bounds__(64) void k_attn(const float* __restrict__ qkv,
                                             float* __restrict__ attno)
{
  __shared__ float qs[64][33], ksm[64][33], vsm[64][33];
  const int blk = blockIdx.x, lane = threadIdx.x;
  const int b = blk >> 3, h = blk & 7;
  for (int idx = lane; idx < 2048; idx += 64){
    int row = idx >> 5, d = idx & 31;
    const float* base = qkv + (size_t)(b * 64 + row) * 768 + h * 32 + d;
    qs[row][d] = base[0]; ksm[row][d] = base[256]; vsm[row][d] = base[512];
  }
  __syncthreads();
  float qr[32];
  #pragma unroll
  for (int d = 0; d < 32; ++d) qr[d] = qs[lane][d];
  float s[64]; float mx = -1e30f;
  for (int m = 0; m < 64; ++m){
    float dot = 0.f;
    #pragma unroll
    for (int d = 0; d < 32; ++d) dot += qr[d] * ksm[m][d];
    dot *= 0.17677669529663687f;  // 32^-0.5
    s[m] = dot; mx = fmaxf(mx, dot);
  }
  float sum = 0.f;
  for (int m = 0; m < 64; ++m){ s[m] = expf(s[m] - mx); sum += s[m]; }
  float inv = 1.f / sum;
  float o[32] = {};
  for (int m = 0; m < 64; ++m){
    float p = s[m] * inv;
    #pragma unroll
    for (int d = 0; d < 32; ++d) o[d] += p * vsm[m][d];
  }
  float* dst = attno + (size_t)(b * 64 + lane) * 256 + h * 32;
  #pragma unroll
  for (int d = 0; d < 32; ++d) dst[d] = o[d];
}

__global__ void k_fill(float* p, int n, float v){
  int i = blockIdx.x * 256 + threadIdx.x;
  if (i < n) p[i] = v;
}

// ---------------- launch ----------------
extern "C" void kernel_launch(void* const* d_in, const int* in_sizes, int n_in,
                              void* d_out, int out_size, void* d_ws, size_t ws_size,
                              hipStream_t stream)
{
  const float* img      = (const float*)d_in[0];
  const float* embed    = (const float*)d_in[1];
  const float* roi      = (const float*)d_in[2];
  const float* ln_adj_g = (const float*)d_in[3];
  const float* ln_adj_b = (const float*)d_in[4];
  const float* w_adj    = (const float*)d_in[5];
  const float* ln_off_g = (const float*)d_in[6];
  const float* ln_off_b = (const float*)d_in[7];
  const float* w_off    = (const float*)d_in[8];
  const float* off_bias = (const float*)d_in[9];
  const float* pg_ln_g  = (const float*)d_in[10];
  const float* pg_ln_b  = (const float*)d_in[11];
  const float* pg_w1    = (const float*)d_in[12];
  const float* pg_b1    = (const float*)d_in[13];
  const float* pg_w2    = (const float*)d_in[14];
  const float* pg_b2    = (const float*)d_in[15];
  const float* m_beta   = (const float*)d_in[16];
  const float* s_beta   = (const float*)d_in[17];
  const float* mix_w    = (const float*)d_in[18];
  const float* mix_b    = (const float*)d_in[19];
  const float* ln1_g    = (const float*)d_in[20];
  const float* ln1_b    = (const float*)d_in[21];
  const float* qkv_w    = (const float*)d_in[22];
  const float* qkv_b    = (const float*)d_in[23];
  const float* proj_w   = (const float*)d_in[24];
  const float* proj_b   = (const float*)d_in[25];
  const float* ln2_g    = (const float*)d_in[26];
  const float* ln2_b    = (const float*)d_in[27];
  const float* fc1_w    = (const float*)d_in[28];
  const float* fc1_b    = (const float*)d_in[29];
  const float* fc2_w    = (const float*)d_in[30];
  const float* fc2_b    = (const float*)d_in[31];

  char* ws = (char*)d_ws;
  float*          pts     = (float*)         (ws + 0);          //   294912
  float*          hbuf    = (float*)         (ws + 294912);     //   262144
  unsigned short* imgT    = (unsigned short*)(ws + 557056);     // 33554432
  unsigned short* sampled = (unsigned short*)(ws + 34111488);   // 18874368
  unsigned short* params3 = (unsigned short*)(ws + 52985856);   // 136970240 (1045*65536*2)
  unsigned short* out2    = (unsigned short*)(ws + 189956096);  // 18874368
  float*          embed1  = (float*)         (ws + 208830464);  //  1048576
  float*          embed2  = (float*)         (ws + 209879040);  //  1048576
  unsigned short* xln1    = (unsigned short*)(ws + 210927616);  //   524288
  unsigned short* xln2    = (unsigned short*)(ws + 211451904);  //   524288
  float*          qkvb    = (float*)         (ws + 211976192);  //  3145728
  float*          attno   = (float*)         (ws + 215121920);  //  1048576
  // aliased into the params3 region (dead after k_mixtoken):
  float*          part_mix  = (float*)(ws + 52985856);             // 16 MB (16 slabs)
  float*          part_smll = (float*)(ws + 52985856 + 16777216);  //  4 MB (4 slabs)
  unsigned short* h1        = (unsigned short*)(ws + 52985856 + 20971520); // 2 MB
  const size_t WS_NEEDED = 216170496;
  if (ws_size < WS_NEEDED){
    k_fill<<<(out_size + 255) / 256, 256, 0, stream>>>((float*)d_out, out_size, 12345.0f);
    return;
  }

  float* out = (float*)d_out;

  k_prep<<<1024, 256, 0, stream>>>(embed, roi, ln_adj_g, ln_adj_b, w_adj,
                                   ln_off_g, ln_off_b, w_off, off_bias,
                                   pg_ln_g, pg_ln_b, pg_w1, pg_b1, pts, hbuf);
  k_transpose<<<1024, 256, 0, stream>>>(img, imgT);
  k_sample<<<1024, 256, 0, stream>>>(imgT, pts, sampled);
  k_params<<<dim3(1045, 16), 256, 0, stream>>>(hbuf, pg_w2, pg_b2, params3);
  k_mixtoken<<<1024, 256, 0, stream>>>(sampled, params3, m_beta, s_beta, out2);
  // embed1 = embed + out2 @ mix_w + mix_b   (split-K: 9216 = 16 x 576), fused LN1
  k_gemm_sk<1><<<dim3(4,16,16), 256, 0, stream>>>(out2, mix_w, part_mix, 1024, 256, 9216, 576);
  k_reduce_ln<<<1024, 256, 0, stream>>>(part_mix, mix_b, embed, ln1_g, ln1_b, embed1, xln1, 16);
  k_gemm<1,0,0,0><<<dim3(12,16), 256, 0, stream>>>(xln1, qkv_w, qkv_b, nullptr, qkvb, 1024, 768, 256);
  k_attn<<<128, 64, 0, stream>>>(qkvb, attno);
  // embed2 = embed1 + attno @ proj_w + proj_b (split-K: 256 = 4 x 64), fused LN2
  k_gemm_sk<0><<<dim3(4,16,4), 256, 0, stream>>>(attno, proj_w, part_smll, 1024, 256, 256, 64);
  k_reduce_ln<<<1024, 256, 0, stream>>>(part_smll, proj_b, embed1, ln2_g, ln2_b, embed2, xln2, 4);
  k_gemm<1,1,0,1><<<dim3(16,16), 256, 0, stream>>>(xln2, fc1_w, fc1_b, nullptr, h1, 1024, 1024, 256);
  // out = embed2 + h1 @ fc2_w + fc2_b   (split-K: 1024 = 4 x 256)
  k_gemm_sk<1><<<dim3(4,16,4), 256, 0, stream>>>(h1, fc2_w, part_smll, 1024, 256, 1024, 256);
  k_reduce<1><<<1024, 256, 0, stream>>>(part_smll, fc2_b, embed2, out, 262144, 256, 4);
}

// Round 9
// 279.924 us; speedup vs baseline: 1.5099x; 1.5099x over previous
//
#include <hip/hip_runtime.h>
#include <cstdint>

#define DEV __device__ __forceinline__

typedef __attribute__((ext_vector_type(8))) short bf16x8;
typedef __attribute__((ext_vector_type(4))) float f32x4;

DEV unsigned short f2bf(float x){
  union { float f; unsigned u; } c; c.f = x;
  unsigned r = c.u + 0x7fffu + ((c.u >> 16) & 1u);
  return (unsigned short)(r >> 16);
}
DEV float bf2f(unsigned short h){
  union { unsigned u; float f; } c; c.u = ((unsigned)h) << 16;
  return c.f;
}
DEV float gelu_f(float x){ return 0.5f * x * (1.f + erff(x * 0.70710678118654752440f)); }

DEV f32x4 mfma16(bf16x8 a, bf16x8 b, f32x4 c){
  return __builtin_amdgcn_mfma_f32_16x16x32_bf16(a, b, c, 0, 0, 0);
}

// block_sum: 256 threads (4 waves)
DEV float block_sum(float v, float* red, int tid){
  #pragma unroll
  for (int o = 32; o > 0; o >>= 1) v += __shfl_down(v, o);
  if ((tid & 63) == 0) red[tid >> 6] = v;
  __syncthreads();
  float s = red[0] + red[1] + red[2] + red[3];
  __syncthreads();
  return s;
}

// ---------------- constants ----------------
// B=16 N=64 D=256 CI=256 H=W=64 P=36 HEADS=8 HD=32 HID=1024 TOTAL=66832 T=1024
// params3 blocked layout: element n of token t lives at
//   params3[(n>>6)*65536 + t*64 + (n&63)]   (nc-major, then token, then off)

// ---------------- kernel 1: per-token prep ----------------
__global__ __launch_bounds__(256) void k_prep(
    const float* __restrict__ embed, const float* __restrict__ roi,
    const float* __restrict__ g_adj, const float* __restrict__ b_adj, const float* __restrict__ w_adj,
    const float* __restrict__ g_off, const float* __restrict__ b_off, const float* __restrict__ w_off,
    const float* __restrict__ off_bias,
    const float* __restrict__ g_pg, const float* __restrict__ b_pg,
    const float* __restrict__ w_pg1, const float* __restrict__ b_pg1,
    float* __restrict__ pts, float* __restrict__ hbuf)
{
  __shared__ float red[4];
  __shared__ float xln[256];
  __shared__ float offs[72];
  __shared__ float lg[4];
  __shared__ float stat[8];
  const int t = blockIdx.x, tid = threadIdx.x;
  float e = embed[t * 256 + tid];
  float mean = block_sum(e, red, tid) * (1.f / 256.f);
  float dv = e - mean;
  float var = block_sum(dv * dv, red, tid) * (1.f / 256.f);
  xln[tid] = dv * rsqrtf(var + 1e-5f);
  __syncthreads();
  if (tid < 4){
    float a0 = 0.f, a1 = 0.f, a2 = 0.f, a3 = 0.f;
    #pragma unroll 4
    for (int c = 0; c < 256; c += 4){
      a0 += (xln[c+0] * g_adj[c+0] + b_adj[c+0]) * w_adj[(c+0) * 4 + tid];
      a1 += (xln[c+1] * g_adj[c+1] + b_adj[c+1]) * w_adj[(c+1) * 4 + tid];
      a2 += (xln[c+2] * g_adj[c+2] + b_adj[c+2]) * w_adj[(c+2) * 4 + tid];
      a3 += (xln[c+3] * g_adj[c+3] + b_adj[c+3]) * w_adj[(c+3) * 4 + tid];
    }
    lg[tid] = (a0 + a1) + (a2 + a3);
  } else if (tid < 76){
    int j = tid - 4;
    float a0 = 0.f, a1 = 0.f, a2 = 0.f, a3 = 0.f;
    #pragma unroll 4
    for (int c = 0; c < 256; c += 4){
      a0 += (xln[c+0] * g_off[c+0] + b_off[c+0]) * w_off[(c+0) * 72 + j];
      a1 += (xln[c+1] * g_off[c+1] + b_off[c+1]) * w_off[(c+1) * 72 + j];
      a2 += (xln[c+2] * g_off[c+2] + b_off[c+2]) * w_off[(c+2) * 72 + j];
      a3 += (xln[c+3] * g_off[c+3] + b_off[c+3]) * w_off[(c+3) * 72 + j];
    }
    offs[j] = (a0 + a1) + (a2 + a3) + off_bias[j];
  } else if (tid < 140){
    int j = tid - 76;
    float a0 = 0.f, a1 = 0.f, a2 = 0.f, a3 = 0.f;
    #pragma unroll 4
    for (int c = 0; c < 256; c += 4){
      a0 += (xln[c+0] * g_pg[c+0] + b_pg[c+0]) * w_pg1[(c+0) * 64 + j];
      a1 += (xln[c+1] * g_pg[c+1] + b_pg[c+1]) * w_pg1[(c+1) * 64 + j];
      a2 += (xln[c+2] * g_pg[c+2] + b_pg[c+2]) * w_pg1[(c+2) * 64 + j];
      a3 += (xln[c+3] * g_pg[c+3] + b_pg[c+3]) * w_pg1[(c+3) * 64 + j];
    }
    hbuf[t * 64 + j] = (a0 + a1) + (a2 + a3) + b_pg1[j];
  }
  __syncthreads();
  if (tid == 0){
    float x0 = roi[t*4+0], y0 = roi[t*4+1], x1 = roi[t*4+2], y1 = roi[t*4+3];
    float cx = (x0 + x1) * 0.5f, cy = (y0 + y1) * 0.5f;
    float w = fabsf(x1 - x0), hh = fabsf(y1 - y0);
    cx += lg[0] * w; cy += lg[1] * hh;
    w *= expf(lg[2]); hh *= expf(lg[3]);
    stat[0] = cx; stat[1] = cy; stat[2] = w; stat[3] = hh;
  }
  if (tid < 2){
    float mu = 0.f;
    for (int p = 0; p < 36; ++p) mu += offs[p*2 + tid];
    mu *= (1.f / 36.f);
    float v2 = 0.f;
    for (int p = 0; p < 36; ++p){ float d = offs[p*2 + tid] - mu; v2 += d * d; }
    float sd = sqrtf(v2 * (1.f / 35.f)) + 1e-7f;   // ddof=1
    stat[4 + tid] = mu; stat[6 + tid] = 1.f / (3.f * sd);
  }
  __syncthreads();
  if (tid < 72){
    int c = tid & 1;
    pts[t * 72 + tid] = stat[c] + (offs[tid] - stat[4 + c]) * stat[6 + c] * stat[2 + c];
  }
}

// ---------------- kernel 2: img [B,C,H,W] f32 -> [B,H,W,C] bf16 ----------------
// Output now fully vectorized: each thread owns (x, 32 consecutive c) and emits
// 4x bf16x8 (64B contiguous); block writes 16KB-contiguous rows.
__global__ __launch_bounds__(256) void k_transpose(const float* __restrict__ img,
                                                   unsigned short* __restrict__ imgT)
{
  __shared__ float tile[128][65];
  const int blk = blockIdx.x, tid = threadIdx.x;
  const int b = blk >> 6, y = blk & 63;
  for (int half = 0; half < 2; ++half){
    int c_loc = tid >> 1, x0 = (tid & 1) * 32;
    const float* src = img + (((size_t)(b * 256 + half * 128 + c_loc)) * 64 + y) * 64 + x0;
    #pragma unroll
    for (int i = 0; i < 32; ++i) tile[c_loc][x0 + i] = src[i];
    __syncthreads();
    {
      int x = tid >> 2, c0 = (tid & 3) * 32;
      size_t obase = (((size_t)(b * 64 + y)) * 64 + x) * 256 + half * 128 + c0;
      #pragma unroll
      for (int cb = 0; cb < 32; cb += 8){
        unsigned short tmp[8];
        #pragma unroll
        for (int j = 0; j < 8; ++j) tmp[j] = f2bf(tile[c0 + cb + j][x]);
        *(bf16x8*)(imgT + obase + cb) = *(const bf16x8*)tmp;
      }
    }
    __syncthreads();
  }
}

// ---------------- kernel 3: bilinear sample -> sampled [T,36,256] bf16 ----------------
__global__ __launch_bounds__(256) void k_sample(const unsigned short* __restrict__ imgT,
                                                const float* __restrict__ pts,
                                                unsigned short* __restrict__ sampled)
{
  __shared__ float lpts[72];
  const int t = blockIdx.x, tid = threadIdx.x;
  const int b = t >> 6;
  if (tid < 72) lpts[tid] = pts[t * 72 + tid];
  __syncthreads();
  for (int p = 0; p < 36; ++p){
    float fx = lpts[p*2]   * 64.f - 0.5f;
    float fy = lpts[p*2+1] * 64.f - 0.5f;
    float x0f = floorf(fx), y0f = floorf(fy);
    float wx = fx - x0f, wy = fy - y0f;
    int x0 = (int)x0f, y0 = (int)y0f;
    float acc = 0.f;
    #pragma unroll
    for (int dy = 0; dy < 2; ++dy){
      #pragma unroll
      for (int dx = 0; dx < 2; ++dx){
        int xi = x0 + dx, yi = y0 + dy;
        bool valid = (xi >= 0) & (xi < 64) & (yi >= 0) & (yi < 64);
        int xc = min(max(xi, 0), 63), yc = min(max(yi, 0), 63);
        float w = (dx ? wx : 1.f - wx) * (dy ? wy : 1.f - wy);
        float v = bf2f(imgT[(((size_t)(b * 64 + yc)) * 64 + xc) * 256 + tid]);
        acc += v * (valid ? w : 0.f);
      }
    }
    sampled[(size_t)t * 9216 + p * 256 + tid] = f2bf(acc);
  }
}

// ---------------- kernel 4: params3 = blocked(h @ pg_w2 + pg_b2)  (M=1024,K=64,N=66832)
// grid (1045); block nc computes all 1024 tokens for its 64-wide n-chunk.
// Writes are a single contiguous 128KB window per block. (r4 version: proven ~72us,
// at the ~2 TB/s wall this pipeline shape sustains.)
__global__ __launch_bounds__(256) void k_params(
    const float* __restrict__ hbuf, const float* __restrict__ w2,
    const float* __restrict__ b2, unsigned short* __restrict__ params3)
{
  __shared__ __align__(16) unsigned short Bs[64][72];  // [n][k^swz]
  __shared__ __align__(16) unsigned short As[64][72];  // [m][k]
  __shared__ __align__(16) unsigned short Os[64][72];  // output staging [m][n]
  const int tid = threadIdx.x, lane = tid & 63, wave = tid >> 6;
  const int wm = wave >> 1, wn = wave & 1;
  const int nc = blockIdx.x, n0 = nc * 64;
  {
    int k = tid >> 2, nb = (tid & 3) * 16;
    #pragma unroll
    for (int i = 0; i < 16; ++i){
      int n = nb + i, gn = n0 + n;
      float v = (gn < 66832) ? w2[(size_t)k * 66832 + gn] : 0.f;
      Bs[n][k ^ (((n >> 3) & 7) << 3)] = f2bf(v);
    }
  }
  float bv[2];
  #pragma unroll
  for (int j = 0; j < 2; ++j){
    int col = n0 + wn*32 + j*16 + (lane & 15);
    bv[j] = (col < 66832) ? b2[col] : 0.f;
  }
  __syncthreads();
  for (int mt = 0; mt < 16; ++mt){
    int m0 = mt * 64;
    { int m = tid >> 2, kb4 = (tid & 3) * 16;
      const float* hp = hbuf + (m0 + m) * 64 + kb4;
      #pragma unroll
      for (int i = 0; i < 16; ++i) As[m][kb4 + i] = f2bf(hp[i]);
    }
    __syncthreads();
    f32x4 acc[2][2] = {};
    #pragma unroll
    for (int ks = 0; ks < 2; ++ks){
      int kb = ks * 32 + (lane >> 4) * 8;
      bf16x8 a[2], bb[2];
      #pragma unroll
      for (int i = 0; i < 2; ++i) a[i] = *(const bf16x8*)&As[wm*32 + i*16 + (lane & 15)][kb];
      #pragma unroll
      for (int j = 0; j < 2; ++j){
        int n = wn*32 + j*16 + (lane & 15);
        bb[j] = *(const bf16x8*)&Bs[n][kb ^ (((n >> 3) & 7) << 3)];
      }
      #pragma unroll
      for (int i = 0; i < 2; ++i)
        #pragma unroll
        for (int j = 0; j < 2; ++j) acc[i][j] = mfma16(a[i], bb[j], acc[i][j]);
    }
    // stage tile in LDS: Os[m][n]
    #pragma unroll
    for (int i = 0; i < 2; ++i)
      #pragma unroll
      for (int j = 0; j < 2; ++j){
        int cl = wn*32 + j*16 + (lane & 15);
        #pragma unroll
        for (int r = 0; r < 4; ++r){
          int rl = wm*32 + i*16 + (lane >> 4) * 4 + r;
          Os[rl][cl] = f2bf(acc[i][j][r] + bv[j]);
        }
      }
    __syncthreads();
    // contiguous store: 8KB dense per tile, appended across the m-loop
    {
      int rl = tid >> 2, c0 = (tid & 3) * 16;
      size_t gbase = ((size_t)nc * 1024 + m0 + rl) * 64 + c0;
      *(bf16x8*)(params3 + gbase)     = *(const bf16x8*)&Os[rl][c0];
      *(bf16x8*)(params3 + gbase + 8) = *(const bf16x8*)&Os[rl][c0 + 8];
    }
    __syncthreads();
  }
}

// ---------------- kernel 5: per-token adaptive mixing ----------------
// Single-barrier-per-cc double-buffered pipeline (r8 version, ~71us):
//   prefetch cc+1 (64B contiguous per lane) AFTER the barrier;
//   LDS writes use d-dependent XOR swizzle.
__global__ __launch_bounds__(256) void k_mixtoken(
    const unsigned short* __restrict__ sampled,
    const unsigned short* __restrict__ params3,
    const float* __restrict__ m_beta, const float* __restrict__ s_beta,
    unsigned short* __restrict__ out2)
{
  __shared__ __align__(16) unsigned short smem[29984];
  const int t = blockIdx.x, tid = threadIdx.x, lane = tid & 63, wave = tid >> 6;
  const int l15 = lane & 15, kb = (lane >> 4) * 8;
  unsigned short (*Ss)[264] = (unsigned short (*)[264])smem;
  const int c31  = tid & 31;
  const int g    = tid >> 5;
  const int goff = (g & 1) * 32;
  const int colw = c31 ^ ((g & 3) << 3);
  const unsigned short* ptok = params3 + (size_t)t * 64;
  bf16x8 rv[4];
  {
    const unsigned short* src = ptok + ((size_t)(c31 * 4 + (g >> 1)) << 16) + goff;
    #pragma unroll
    for (int v = 0; v < 4; ++v) rv[v] = *(const bf16x8*)(src + v * 8);
  }
  unsigned short rSm[14];
  #pragma unroll
  for (int k = 0; k < 14; ++k){
    int idx = tid + k * 256;
    unsigned short v = 0;
    if (idx < 3456){
      int o = idx / 72, p = idx % 72;
      if (o < 36 && p < 36){
        int n = 65536 + o * 36 + p;
        v = params3[(size_t)(n >> 6) * 65536 + (size_t)t * 64 + (n & 63)];
      }
    }
    rSm[k] = v;
  }
  const unsigned short* sp = sampled + (size_t)t * 9216;
  #pragma unroll
  for (int it = 0; it < 5; ++it){
    int slot = it * 256 + tid;
    if (slot < 1152){
      int p = slot >> 5, c8 = (slot & 31) << 3;
      *(bf16x8*)&Ss[p][c8] = *(const bf16x8*)(sp + p * 256 + c8);
    }
  }
  __syncthreads();
  f32x4 acc[3][4] = {};
  int cur = 0;
  for (int cc = 0; cc < 8; ++cc){
    unsigned short (*C)[40] = (unsigned short (*)[40])(smem + 9504 + cur * 10240);
    #pragma unroll
    for (int v = 0; v < 4; ++v){
      int dbase = g * 32 + v * 8;
      #pragma unroll
      for (int j = 0; j < 8; ++j) C[dbase + j][colw] = ((unsigned short*)&rv[v])[j];
    }
    __syncthreads();
    if (cc < 7){
      const unsigned short* src = ptok + ((size_t)((cc + 1) * 128 + c31 * 4 + (g >> 1)) << 16) + goff;
      #pragma unroll
      for (int v = 0; v < 4; ++v) rv[v] = *(const bf16x8*)(src + v * 8);
    }
    bf16x8 a[3], bfr[4];
    a[0] = *(const bf16x8*)&Ss[l15][cc * 32 + kb];
    a[1] = *(const bf16x8*)&Ss[16 + l15][cc * 32 + kb];
    a[2] = bf16x8{};
    if (l15 < 4) a[2] = *(const bf16x8*)&Ss[32 + l15][cc * 32 + kb];
    #pragma unroll
    for (int j = 0; j < 4; ++j){
      int d = wave * 64 + j * 16 + l15;
      bfr[j] = *(const bf16x8*)&C[d][kb ^ (((d >> 5) & 3) << 3)];
    }
    #pragma unroll
    for (int i = 0; i < 3; ++i)
      #pragma unroll
      for (int j = 0; j < 4; ++j) acc[i][j] = mfma16(a[i], bfr[j], acc[i][j]);
    cur ^= 1;
  }
  __syncthreads();
  {
    const bf16x8 z = {};
    #pragma unroll
    for (int i = 0; i < 9; ++i)
      *(bf16x8*)&smem[(i * 256 + tid) * 8] = z;
    #pragma unroll
    for (int k = 0; k < 14; ++k){
      int idx = tid + k * 256;
      if (idx < 3456) smem[18432 + idx] = rSm[k];
    }
  }
  __syncthreads();
  unsigned short (*O1T)[72] = (unsigned short (*)[72])smem;
  unsigned short (*Sm)[72]  = (unsigned short (*)[72])(smem + 18432);
  #pragma unroll
  for (int i = 0; i < 3; ++i){
    int p = i * 16 + ((lane >> 4) << 2);
    if (p < 36){
      #pragma unroll
      for (int j = 0; j < 4; ++j){
        int d = wave * 64 + j * 16 + l15;
        float mb = m_beta[d];
        unsigned short* dst = &O1T[d][p];
        #pragma unroll
        for (int r = 0; r < 4; ++r) dst[r] = f2bf(gelu_f(acc[i][j][r] + mb));
      }
    }
  }
  __syncthreads();
  f32x4 acc2[3][4] = {};
  #pragma unroll
  for (int ks = 0; ks < 2; ++ks){
    int kb2 = ks * 32 + (lane >> 4) * 8;
    bf16x8 a2[3], bf2[4];
    #pragma unroll
    for (int i = 0; i < 3; ++i) a2[i] = *(const bf16x8*)&Sm[i*16 + l15][kb2];
    #pragma unroll
    for (int j = 0; j < 4; ++j) bf2[j] = *(const bf16x8*)&O1T[wave*64 + j*16 + l15][kb2];
    #pragma unroll
    for (int i = 0; i < 3; ++i)
      #pragma unroll
      for (int j = 0; j < 4; ++j) acc2[i][j] = mfma16(a2[i], bf2[j], acc2[i][j]);
  }
  unsigned short* o2 = out2 + (size_t)t * 9216;
  #pragma unroll
  for (int i = 0; i < 3; ++i){
    int ob = i*16 + ((lane >> 4) << 2);
    #pragma unroll
    for (int j = 0; j < 4; ++j){
      int d = wave*64 + j*16 + l15;
      #pragma unroll
      for (int r = 0; r < 4; ++r){
        int o = ob + r;
        if (o < 36) o2[o * 256 + d] = f2bf(gelu_f(acc2[i][j][r] + s_beta[o]));
      }
    }
  }
}

// ---------------- generic GEMM: C = act(A @ W + bias) (+resid) ----------------
template<int AK, int ACT, int RES, int OUTB>
__global__ __launch_bounds__(256) void k_gemm(
    const void* __restrict__ Ap, const float* __restrict__ W,
    const float* __restrict__ bias, const float* __restrict__ resid,
    void* __restrict__ Cp, int M, int N, int K)
{
  __shared__ __align__(16) unsigned short As[64][40];  // [m][k]
  __shared__ __align__(16) unsigned short Bs[64][40];  // [n][k^swz]
  const int tid = threadIdx.x, lane = tid & 63, wave = tid >> 6;
  const int wm = wave >> 1, wn = wave & 1;
  const int n0 = blockIdx.x * 64, m0 = blockIdx.y * 64;
  f32x4 acc[2][2] = {};
  for (int kk = 0; kk < K; kk += 32){
    { int m = tid >> 2, k4 = (tid & 3) * 8;
      if (AK == 0){
        const float* ap = (const float*)Ap + (size_t)(m0 + m) * K + kk + k4;
        #pragma unroll
        for (int i = 0; i < 8; ++i) As[m][k4 + i] = f2bf(ap[i]);
      } else {
        const unsigned short* ap = (const unsigned short*)Ap + (size_t)(m0 + m) * K + kk + k4;
        *(bf16x8*)&As[m][k4] = *(const bf16x8*)ap;
      }
    }
    { int kq = tid >> 3, n8 = (tid & 7) * 8;
      const float* wp = W + (size_t)(kk + kq) * N + n0 + n8;
      #pragma unroll
      for (int i = 0; i < 8; ++i){
        int n = n8 + i;
        Bs[n][kq ^ (((n >> 3) & 3) << 3)] = f2bf(wp[i]);
      }
    }
    __syncthreads();
    const int kb = (lane >> 4) * 8;
    bf16x8 a[2], bfr[2];
    #pragma unroll
    for (int i = 0; i < 2; ++i) a[i] = *(const bf16x8*)&As[wm*32 + i*16 + (lane & 15)][kb];
    #pragma unroll
    for (int j = 0; j < 2; ++j){
      int n = wn*32 + j*16 + (lane & 15);
      bfr[j] = *(const bf16x8*)&Bs[n][kb ^ (((n >> 3) & 3) << 3)];
    }
    #pragma unroll
    for (int i = 0; i < 2; ++i)
      #pragma unroll
      for (int j = 0; j < 2; ++j) acc[i][j] = mfma16(a[i], bfr[j], acc[i][j]);
    __syncthreads();
  }
  #pragma unroll
  for (int i = 0; i < 2; ++i)
    #pragma unroll
    for (int j = 0; j < 2; ++j){
      int col = n0 + wn*32 + j*16 + (lane & 15);
      float bv = bias[col];
      #pragma unroll
      for (int r = 0; r < 4; ++r){
        int row = m0 + wm*32 + i*16 + (lane >> 4) * 4 + r;
        float v = acc[i][j][r] + bv;
        if (ACT == 1) v = gelu_f(v);
        if (RES) v += resid[(size_t)row * N + col];
        if (OUTB) ((unsigned short*)Cp)[(size_t)row * N + col] = f2bf(v);
        else      ((float*)Cp)[(size_t)row * N + col] = v;
      }
    }
}

// ---------------- split-K GEMM: part[z][M][N] = A[:, z*KS:(z+1)*KS] @ W[z*KS:...] ----
template<int AK>
__global__ __launch_bounds__(256) void k_gemm_sk(
    const void* __restrict__ Ap, const float* __restrict__ W,
    float* __restrict__ part, int M, int N, int K, int KS)
{
  __shared__ __align__(16) unsigned short As[64][40];  // [m][k]
  __shared__ __align__(16) unsigned short Bs[64][40];  // [n][k^swz]
  const int tid = threadIdx.x, lane = tid & 63, wave = tid >> 6;
  const int wm = wave >> 1, wn = wave & 1;
  const int n0 = blockIdx.x * 64, m0 = blockIdx.y * 64;
  const int kbase = blockIdx.z * KS;
  f32x4 acc[2][2] = {};
  for (int kq = 0; kq < KS; kq += 32){
    int kk = kbase + kq;
    { int m = tid >> 2, k4 = (tid & 3) * 8;
      if (AK == 0){
        const float* ap = (const float*)Ap + (size_t)(m0 + m) * K + kk + k4;
        #pragma unroll
        for (int i = 0; i < 8; ++i) As[m][k4 + i] = f2bf(ap[i]);
      } else {
        const unsigned short* ap = (const unsigned short*)Ap + (size_t)(m0 + m) * K + kk + k4;
        *(bf16x8*)&As[m][k4] = *(const bf16x8*)ap;
      }
    }
    { int kr = tid >> 3, n8 = (tid & 7) * 8;
      const float* wp = W + (size_t)(kk + kr) * N + n0 + n8;
      #pragma unroll
      for (int i = 0; i < 8; ++i){
        int n = n8 + i;
        Bs[n][kr ^ (((n >> 3) & 3) << 3)] = f2bf(wp[i]);
      }
    }
    __syncthreads();
    const int kb = (lane >> 4) * 8;
    bf16x8 a[2], bfr[2];
    #pragma unroll
    for (int i = 0; i < 2; ++i) a[i] = *(const bf16x8*)&As[wm*32 + i*16 + (lane & 15)][kb];
    #pragma unroll
    for (int j = 0; j < 2; ++j){
      int n = wn*32 + j*16 + (lane & 15);
      bfr[j] = *(const bf16x8*)&Bs[n][kb ^ (((n >> 3) & 3) << 3)];
    }
    #pragma unroll
    for (int i = 0; i < 2; ++i)
      #pragma unroll
      for (int j = 0; j < 2; ++j) acc[i][j] = mfma16(a[i], bfr[j], acc[i][j]);
    __syncthreads();
  }
  float* pz = part + (size_t)blockIdx.z * M * N;
  #pragma unroll
  for (int i = 0; i < 2; ++i)
    #pragma unroll
    for (int j = 0; j < 2; ++j){
      int col = n0 + wn*32 + j*16 + (lane & 15);
      #pragma unroll
      for (int r = 0; r < 4; ++r){
        int row = m0 + wm*32 + i*16 + (lane >> 4) * 4 + r;
        pz[(size_t)row * N + col] = acc[i][j][r];
      }
    }
}

// ---------------- split-K reduce: out = sum_z part[z] + bias (+resid) ----------------
template<int RES>
__global__ __launch_bounds__(256) void k_reduce(
    const float* __restrict__ part, const float* __restrict__ bias,
    const float* __restrict__ resid, float* __restrict__ out,
    int total, int N, int SK)
{
  int i = blockIdx.x * 256 + threadIdx.x;
  if (i >= total) return;
  float s = 0.f;
  for (int z = 0; z < SK; ++z) s += part[(size_t)z * total + i];
  s += bias[i % N];
  if (RES) s += resid[i];
  out[i] = s;
}

// ---------------- fused split-K reduce + residual + LayerNorm ----------------
__global__ __launch_bounds__(256) void k_reduce_ln(
    const float* __restrict__ part, const float* __restrict__ bias,
    const float* __restrict__ resid,
    const float* __restrict__ g, const float* __restrict__ bb,
    float* __restrict__ emb_out, unsigned short* __restrict__ ln_out, int SK)
{
  __shared__ float red[4];
  const int t = blockIdx.x, tid = threadIdx.x;
  const int i = t * 256 + tid;
  float s = 0.f;
  for (int z = 0; z < SK; ++z) s += part[(size_t)z * 262144 + i];
  s += bias[tid] + resid[i];
  emb_out[i] = s;
  float mean = block_sum(s, red, tid) * (1.f / 256.f);
  float d = s - mean;
  float var = block_sum(d * d, red, tid) * (1.f / 256.f);
  ln_out[i] = f2bf(d * rsqrtf(var + 1e-5f) * g[tid] + bb[tid]);
}

// ---------------- attention: one (b,h) per block ----------------
__global__ __launch_bounds__(64) void k_attn(const float* __restrict__ qkv,
                                             float* __restrict__ attno)
{
  __shared__ float qs[64][33], ksm[64][33], vsm[64][33];
  const int blk = blockIdx.x, lane = threadIdx.x;
  const int b = blk >> 3, h = blk & 7;
  for (int idx = lane; idx < 2048; idx += 64){
    int row = idx >> 5, d = idx & 31;
    const float* base = qkv + (size_t)(b * 64 + row) * 768 + h * 32 + d;
    qs[row][d] = base[0]; ksm[row][d] = base[256]; vsm[row][d] = base[512];
  }
  __syncthreads();
  float qr[32];
  #pragma unroll
  for (int d = 0; d < 32; ++d) qr[d] = qs[lane][d];
  float s[64]; float mx = -1e30f;
  for (int m = 0; m < 64; ++m){
    float dot = 0.f;
    #pragma unroll
    for (int d = 0; d < 32; ++d) dot += qr[d] * ksm[m][d];
    dot *= 0.17677669529663687f;  // 32^-0.5
    s[m] = dot; mx = fmaxf(mx, dot);
  }
  float sum = 0.f;
  for (int m = 0; m < 64; ++m){ s[m] = expf(s[m] - mx); sum += s[m]; }
  float inv = 1.f / sum;
  float o[32] = {};
  for (int m = 0; m < 64; ++m){
    float p = s[m] * inv;
    #pragma unroll
    for (int d = 0; d < 32; ++d) o[d] += p * vsm[m][d];
  }
  float* dst = attno + (size_t)(b * 64 + lane) * 256 + h * 32;
  #pragma unroll
  for (int d = 0; d < 32; ++d) dst[d] = o[d];
}

__global__ void k_fill(float* p, int n, float v){
  int i = blockIdx.x * 256 + threadIdx.x;
  if (i < n) p[i] = v;
}

// ---------------- launch ----------------
extern "C" void kernel_launch(void* const* d_in, const int* in_sizes, int n_in,
                              void* d_out, int out_size, void* d_ws, size_t ws_size,
                              hipStream_t stream)
{
  const float* img      = (const float*)d_in[0];
  const float* embed    = (const float*)d_in[1];
  const float* roi      = (const float*)d_in[2];
  const float* ln_adj_g = (const float*)d_in[3];
  const float* ln_adj_b = (const float*)d_in[4];
  const float* w_adj    = (const float*)d_in[5];
  const float* ln_off_g = (const float*)d_in[6];
  const float* ln_off_b = (const float*)d_in[7];
  const float* w_off    = (const float*)d_in[8];
  const float* off_bias = (const float*)d_in[9];
  const float* pg_ln_g  = (const float*)d_in[10];
  const float* pg_ln_b  = (const float*)d_in[11];
  const float* pg_w1    = (const float*)d_in[12];
  const float* pg_b1    = (const float*)d_in[13];
  const float* pg_w2    = (const float*)d_in[14];
  const float* pg_b2    = (const float*)d_in[15];
  const float* m_beta   = (const float*)d_in[16];
  const float* s_beta   = (const float*)d_in[17];
  const float* mix_w    = (const float*)d_in[18];
  const float* mix_b    = (const float*)d_in[19];
  const float* ln1_g    = (const float*)d_in[20];
  const float* ln1_b    = (const float*)d_in[21];
  const float* qkv_w    = (const float*)d_in[22];
  const float* qkv_b    = (const float*)d_in[23];
  const float* proj_w   = (const float*)d_in[24];
  const float* proj_b   = (const float*)d_in[25];
  const float* ln2_g    = (const float*)d_in[26];
  const float* ln2_b    = (const float*)d_in[27];
  const float* fc1_w    = (const float*)d_in[28];
  const float* fc1_b    = (const float*)d_in[29];
  const float* fc2_w    = (const float*)d_in[30];
  const float* fc2_b    = (const float*)d_in[31];

  char* ws = (char*)d_ws;
  float*          pts     = (float*)         (ws + 0);          //   294912
  float*          hbuf    = (float*)         (ws + 294912);     //   262144
  unsigned short* imgT    = (unsigned short*)(ws + 557056);     // 33554432
  unsigned short* sampled = (unsigned short*)(ws + 34111488);   // 18874368
  unsigned short* params3 = (unsigned short*)(ws + 52985856);   // 136970240 (1045*65536*2)
  unsigned short* out2    = (unsigned short*)(ws + 189956096);  // 18874368
  float*          embed1  = (float*)         (ws + 208830464);  //  1048576
  float*          embed2  = (float*)         (ws + 209879040);  //  1048576
  unsigned short* xln1    = (unsigned short*)(ws + 210927616);  //   524288
  unsigned short* xln2    = (unsigned short*)(ws + 211451904);  //   524288
  float*          qkvb    = (float*)         (ws + 211976192);  //  3145728
  float*          attno   = (float*)         (ws + 215121920);  //  1048576
  // aliased into the params3 region (dead after k_mixtoken):
  float*          part_mix  = (float*)(ws + 52985856);             // 16 MB (16 slabs)
  float*          part_smll = (float*)(ws + 52985856 + 16777216);  //  4 MB (4 slabs)
  unsigned short* h1        = (unsigned short*)(ws + 52985856 + 20971520); // 2 MB
  const size_t WS_NEEDED = 216170496;
  if (ws_size < WS_NEEDED){
    k_fill<<<(out_size + 255) / 256, 256, 0, stream>>>((float*)d_out, out_size, 12345.0f);
    return;
  }

  float* out = (float*)d_out;

  k_prep<<<1024, 256, 0, stream>>>(embed, roi, ln_adj_g, ln_adj_b, w_adj,
                                   ln_off_g, ln_off_b, w_off, off_bias,
                                   pg_ln_g, pg_ln_b, pg_w1, pg_b1, pts, hbuf);
  k_transpose<<<1024, 256, 0, stream>>>(img, imgT);
  k_sample<<<1024, 256, 0, stream>>>(imgT, pts, sampled);
  k_params<<<1045, 256, 0, stream>>>(hbuf, pg_w2, pg_b2, params3);
  k_mixtoken<<<1024, 256, 0, stream>>>(sampled, params3, m_beta, s_beta, out2);
  // embed1 = embed + out2 @ mix_w + mix_b   (split-K: 9216 = 16 x 576), fused LN1
  k_gemm_sk<1><<<dim3(4,16,16), 256, 0, stream>>>(out2, mix_w, part_mix, 1024, 256, 9216, 576);
  k_reduce_ln<<<1024, 256, 0, stream>>>(part_mix, mix_b, embed, ln1_g, ln1_b, embed1, xln1, 16);
  k_gemm<1,0,0,0><<<dim3(12,16), 256, 0, stream>>>(xln1, qkv_w, qkv_b, nullptr, qkvb, 1024, 768, 256);
  k_attn<<<128, 64, 0, stream>>>(qkvb, attno);
  // embed2 = embed1 + attno @ proj_w + proj_b (split-K: 256 = 4 x 64), fused LN2
  k_gemm_sk<0><<<dim3(4,16,4), 256, 0, stream>>>(attno, proj_w, part_smll, 1024, 256, 256, 64);
  k_reduce_ln<<<1024, 256, 0, stream>>>(part_smll, proj_b, embed1, ln2_g, ln2_b, embed2, xln2, 4);
  k_gemm<1,1,0,1><<<dim3(16,16), 256, 0, stream>>>(xln2, fc1_w, fc1_b, nullptr, h1, 1024, 1024, 256);
  // out = embed2 + h1 @ fc2_w + fc2_b   (split-K: 1024 = 4 x 256)
  k_gemm_sk<1><<<dim3(4,16,4), 256, 0, stream>>>(h1, fc2_w, part_smll, 1024, 256, 1024, 256);
  k_reduce<1><<<1024, 256, 0, stream>>>(part_smll, fc2_b, embed2, out, 262144, 256, 4);
}

// Round 10
// 269.081 us; speedup vs baseline: 1.5707x; 1.0403x over previous
//
#include <hip/hip_runtime.h>
#include <cstdint>

#define DEV __device__ __forceinline__

typedef __attribute__((ext_vector_type(8))) short bf16x8;
typedef __attribute__((ext_vector_type(8))) _Float16 f16x8;
typedef __attribute__((ext_vector_type(4))) float f32x4;

DEV unsigned short f2bf(float x){
  union { float f; unsigned u; } c; c.f = x;
  unsigned r = c.u + 0x7fffu + ((c.u >> 16) & 1u);
  return (unsigned short)(r >> 16);
}
DEV float bf2f(unsigned short h){
  union { unsigned u; float f; } c; c.u = ((unsigned)h) << 16;
  return c.f;
}
DEV unsigned short f2h(float x){
  union { unsigned short u; _Float16 h; } c;
  c.h = (_Float16)x;
  return c.u;
}
// f32 -> e4m3 (OCP), RNE, saturate to +-448. Denormals handled via rintf path.
DEV unsigned char f2fp8(float x){
  union { float f; unsigned u; } c; c.f = x;
  unsigned s = (c.u >> 24) & 0x80u;
  float a = fabsf(x);
  a = fminf(a, 448.f);
  unsigned n;
  if (a < 0.015625f){
    n = (unsigned)(int)rintf(a * 512.f);       // 0..8, RNE; 8 == 2^-6 normal
  } else {
    union { float f; unsigned u; } d; d.f = a;
    unsigned u2 = d.u + 0x7FFFFu + ((d.u >> 20) & 1u);
    n = (((u2 >> 23) - 120u) << 3) | ((u2 >> 20) & 7u);
  }
  return (unsigned char)(s | n);
}
// e4m3 -> f16 bits, exact: place exp/man in f16 fields, scale by 2^8.
DEV unsigned short fp82h(unsigned b){
  union { unsigned short u; _Float16 h; } c;
  c.u = (unsigned short)(((b & 0x80u) << 8) | ((b & 0x7Fu) << 7));
  c.h = c.h * (_Float16)256.0f;
  return c.u;
}

DEV float gelu_f(float x){ return 0.5f * x * (1.f + erff(x * 0.70710678118654752440f)); }

DEV f32x4 mfma16(bf16x8 a, bf16x8 b, f32x4 c){
  return __builtin_amdgcn_mfma_f32_16x16x32_bf16(a, b, c, 0, 0, 0);
}
DEV f32x4 mfma16h(f16x8 a, f16x8 b, f32x4 c){
  return __builtin_amdgcn_mfma_f32_16x16x32_f16(a, b, c, 0, 0, 0);
}

// block_sum: 256 threads (4 waves)
DEV float block_sum(float v, float* red, int tid){
  #pragma unroll
  for (int o = 32; o > 0; o >>= 1) v += __shfl_down(v, o);
  if ((tid & 63) == 0) red[tid >> 6] = v;
  __syncthreads();
  float s = red[0] + red[1] + red[2] + red[3];
  __syncthreads();
  return s;
}

// ---------------- constants ----------------
// B=16 N=64 D=256 CI=256 H=W=64 P=36 HEADS=8 HD=32 HID=1024 TOTAL=66832 T=1024
// cm (n<65536) stored fp8 e4m3, blocked: params8[(n>>6)*65536 + t*64 + (n&63)] bytes
// sm tail (n>=65536) stored f16, blocked: sm16[((n>>6)-1024)*65536 + t*64 + (n&63)]

// ---------------- kernel 1: per-token prep ----------------
__global__ __launch_bounds__(256) void k_prep(
    const float* __restrict__ embed, const float* __restrict__ roi,
    const float* __restrict__ g_adj, const float* __restrict__ b_adj, const float* __restrict__ w_adj,
    const float* __restrict__ g_off, const float* __restrict__ b_off, const float* __restrict__ w_off,
    const float* __restrict__ off_bias,
    const float* __restrict__ g_pg, const float* __restrict__ b_pg,
    const float* __restrict__ w_pg1, const float* __restrict__ b_pg1,
    float* __restrict__ pts, float* __restrict__ hbuf)
{
  __shared__ float red[4];
  __shared__ float xln[256];
  __shared__ float offs[72];
  __shared__ float lg[4];
  __shared__ float stat[8];
  const int t = blockIdx.x, tid = threadIdx.x;
  float e = embed[t * 256 + tid];
  float mean = block_sum(e, red, tid) * (1.f / 256.f);
  float dv = e - mean;
  float var = block_sum(dv * dv, red, tid) * (1.f / 256.f);
  xln[tid] = dv * rsqrtf(var + 1e-5f);
  __syncthreads();
  if (tid < 4){
    float a0 = 0.f, a1 = 0.f, a2 = 0.f, a3 = 0.f;
    #pragma unroll 4
    for (int c = 0; c < 256; c += 4){
      a0 += (xln[c+0] * g_adj[c+0] + b_adj[c+0]) * w_adj[(c+0) * 4 + tid];
      a1 += (xln[c+1] * g_adj[c+1] + b_adj[c+1]) * w_adj[(c+1) * 4 + tid];
      a2 += (xln[c+2] * g_adj[c+2] + b_adj[c+2]) * w_adj[(c+2) * 4 + tid];
      a3 += (xln[c+3] * g_adj[c+3] + b_adj[c+3]) * w_adj[(c+3) * 4 + tid];
    }
    lg[tid] = (a0 + a1) + (a2 + a3);
  } else if (tid < 76){
    int j = tid - 4;
    float a0 = 0.f, a1 = 0.f, a2 = 0.f, a3 = 0.f;
    #pragma unroll 4
    for (int c = 0; c < 256; c += 4){
      a0 += (xln[c+0] * g_off[c+0] + b_off[c+0]) * w_off[(c+0) * 72 + j];
      a1 += (xln[c+1] * g_off[c+1] + b_off[c+1]) * w_off[(c+1) * 72 + j];
      a2 += (xln[c+2] * g_off[c+2] + b_off[c+2]) * w_off[(c+2) * 72 + j];
      a3 += (xln[c+3] * g_off[c+3] + b_off[c+3]) * w_off[(c+3) * 72 + j];
    }
    offs[j] = (a0 + a1) + (a2 + a3) + off_bias[j];
  } else if (tid < 140){
    int j = tid - 76;
    float a0 = 0.f, a1 = 0.f, a2 = 0.f, a3 = 0.f;
    #pragma unroll 4
    for (int c = 0; c < 256; c += 4){
      a0 += (xln[c+0] * g_pg[c+0] + b_pg[c+0]) * w_pg1[(c+0) * 64 + j];
      a1 += (xln[c+1] * g_pg[c+1] + b_pg[c+1]) * w_pg1[(c+1) * 64 + j];
      a2 += (xln[c+2] * g_pg[c+2] + b_pg[c+2]) * w_pg1[(c+2) * 64 + j];
      a3 += (xln[c+3] * g_pg[c+3] + b_pg[c+3]) * w_pg1[(c+3) * 64 + j];
    }
    hbuf[t * 64 + j] = (a0 + a1) + (a2 + a3) + b_pg1[j];
  }
  __syncthreads();
  if (tid == 0){
    float x0 = roi[t*4+0], y0 = roi[t*4+1], x1 = roi[t*4+2], y1 = roi[t*4+3];
    float cx = (x0 + x1) * 0.5f, cy = (y0 + y1) * 0.5f;
    float w = fabsf(x1 - x0), hh = fabsf(y1 - y0);
    cx += lg[0] * w; cy += lg[1] * hh;
    w *= expf(lg[2]); hh *= expf(lg[3]);
    stat[0] = cx; stat[1] = cy; stat[2] = w; stat[3] = hh;
  }
  if (tid < 2){
    float mu = 0.f;
    for (int p = 0; p < 36; ++p) mu += offs[p*2 + tid];
    mu *= (1.f / 36.f);
    float v2 = 0.f;
    for (int p = 0; p < 36; ++p){ float d = offs[p*2 + tid] - mu; v2 += d * d; }
    float sd = sqrtf(v2 * (1.f / 35.f)) + 1e-7f;   // ddof=1
    stat[4 + tid] = mu; stat[6 + tid] = 1.f / (3.f * sd);
  }
  __syncthreads();
  if (tid < 72){
    int c = tid & 1;
    pts[t * 72 + tid] = stat[c] + (offs[tid] - stat[4 + c]) * stat[6 + c] * stat[2 + c];
  }
}

// ---------------- kernel 2: img [B,C,H,W] f32 -> [B,H,W,C] bf16 ----------------
__global__ __launch_bounds__(256) void k_transpose(const float* __restrict__ img,
                                                   unsigned short* __restrict__ imgT)
{
  __shared__ float tile[128][65];
  const int blk = blockIdx.x, tid = threadIdx.x;
  const int b = blk >> 6, y = blk & 63;
  for (int half = 0; half < 2; ++half){
    int c_loc = tid >> 1, x0 = (tid & 1) * 32;
    const float* src = img + (((size_t)(b * 256 + half * 128 + c_loc)) * 64 + y) * 64 + x0;
    #pragma unroll
    for (int i = 0; i < 32; ++i) tile[c_loc][x0 + i] = src[i];
    __syncthreads();
    {
      int x = tid >> 2, c0 = (tid & 3) * 32;
      size_t obase = (((size_t)(b * 64 + y)) * 64 + x) * 256 + half * 128 + c0;
      #pragma unroll
      for (int cb = 0; cb < 32; cb += 8){
        unsigned short tmp[8];
        #pragma unroll
        for (int j = 0; j < 8; ++j) tmp[j] = f2bf(tile[c0 + cb + j][x]);
        *(bf16x8*)(imgT + obase + cb) = *(const bf16x8*)tmp;
      }
    }
    __syncthreads();
  }
}

// ---------------- kernel 3: bilinear sample -> sampled [T,36,256] f16 ----------------
__global__ __launch_bounds__(256) void k_sample(const unsigned short* __restrict__ imgT,
                                                const float* __restrict__ pts,
                                                unsigned short* __restrict__ sampled)
{
  __shared__ float lpts[72];
  const int t = blockIdx.x, tid = threadIdx.x;
  const int b = t >> 6;
  if (tid < 72) lpts[tid] = pts[t * 72 + tid];
  __syncthreads();
  for (int p = 0; p < 36; ++p){
    float fx = lpts[p*2]   * 64.f - 0.5f;
    float fy = lpts[p*2+1] * 64.f - 0.5f;
    float x0f = floorf(fx), y0f = floorf(fy);
    float wx = fx - x0f, wy = fy - y0f;
    int x0 = (int)x0f, y0 = (int)y0f;
    float acc = 0.f;
    #pragma unroll
    for (int dy = 0; dy < 2; ++dy){
      #pragma unroll
      for (int dx = 0; dx < 2; ++dx){
        int xi = x0 + dx, yi = y0 + dy;
        bool valid = (xi >= 0) & (xi < 64) & (yi >= 0) & (yi < 64);
        int xc = min(max(xi, 0), 63), yc = min(max(yi, 0), 63);
        float w = (dx ? wx : 1.f - wx) * (dy ? wy : 1.f - wy);
        float v = bf2f(imgT[(((size_t)(b * 64 + yc)) * 64 + xc) * 256 + tid]);
        acc += v * (valid ? w : 0.f);
      }
    }
    sampled[(size_t)t * 9216 + p * 256 + tid] = f2h(acc);
  }
}

// ---------------- kernel 4: params = h @ pg_w2 + pg_b2 (M=1024,K=64,N=66832)
// cm chunks (nc<1024) -> fp8 e4m3; sm tail (nc>=1024) -> f16. Blocked layouts.
__global__ __launch_bounds__(256) void k_params(
    const float* __restrict__ hbuf, const float* __restrict__ w2,
    const float* __restrict__ b2, unsigned char* __restrict__ params8,
    unsigned short* __restrict__ sm16)
{
  __shared__ __align__(16) unsigned short Bs[64][72];  // [n][k^swz]
  __shared__ __align__(16) unsigned short As[64][72];  // [m][k]
  __shared__ __align__(16) unsigned short Os[64][72];  // f16 staging (sm path)
  __shared__ __align__(16) unsigned char  Os8[64][72]; // fp8 staging (cm path)
  const int tid = threadIdx.x, lane = tid & 63, wave = tid >> 6;
  const int wm = wave >> 1, wn = wave & 1;
  const int nc = blockIdx.x, n0 = nc * 64;
  const bool cm = (nc < 1024);
  {
    int k = tid >> 2, nb = (tid & 3) * 16;
    #pragma unroll
    for (int i = 0; i < 16; ++i){
      int n = nb + i, gn = n0 + n;
      float v = (gn < 66832) ? w2[(size_t)k * 66832 + gn] : 0.f;
      Bs[n][k ^ (((n >> 3) & 7) << 3)] = f2bf(v);
    }
  }
  float bv[2];
  #pragma unroll
  for (int j = 0; j < 2; ++j){
    int col = n0 + wn*32 + j*16 + (lane & 15);
    bv[j] = (col < 66832) ? b2[col] : 0.f;
  }
  __syncthreads();
  for (int mt = 0; mt < 16; ++mt){
    int m0 = mt * 64;
    { int m = tid >> 2, kb4 = (tid & 3) * 16;
      const float* hp = hbuf + (m0 + m) * 64 + kb4;
      #pragma unroll
      for (int i = 0; i < 16; ++i) As[m][kb4 + i] = f2bf(hp[i]);
    }
    __syncthreads();
    f32x4 acc[2][2] = {};
    #pragma unroll
    for (int ks = 0; ks < 2; ++ks){
      int kb = ks * 32 + (lane >> 4) * 8;
      bf16x8 a[2], bb[2];
      #pragma unroll
      for (int i = 0; i < 2; ++i) a[i] = *(const bf16x8*)&As[wm*32 + i*16 + (lane & 15)][kb];
      #pragma unroll
      for (int j = 0; j < 2; ++j){
        int n = wn*32 + j*16 + (lane & 15);
        bb[j] = *(const bf16x8*)&Bs[n][kb ^ (((n >> 3) & 7) << 3)];
      }
      #pragma unroll
      for (int i = 0; i < 2; ++i)
        #pragma unroll
        for (int j = 0; j < 2; ++j) acc[i][j] = mfma16(a[i], bb[j], acc[i][j]);
    }
    if (cm){
      #pragma unroll
      for (int i = 0; i < 2; ++i)
        #pragma unroll
        for (int j = 0; j < 2; ++j){
          int cl = wn*32 + j*16 + (lane & 15);
          #pragma unroll
          for (int r = 0; r < 4; ++r){
            int rl = wm*32 + i*16 + (lane >> 4) * 4 + r;
            Os8[rl][cl] = f2fp8(acc[i][j][r] + bv[j]);
          }
        }
      __syncthreads();
      {
        int rl = tid >> 2, c0 = (tid & 3) * 16;
        uint2 lo = *(const uint2*)&Os8[rl][c0];
        uint2 hi = *(const uint2*)&Os8[rl][c0 + 8];
        uint4 val; val.x = lo.x; val.y = lo.y; val.z = hi.x; val.w = hi.y;
        *(uint4*)(params8 + ((size_t)nc * 1024 + m0 + rl) * 64 + c0) = val;
      }
    } else {
      #pragma unroll
      for (int i = 0; i < 2; ++i)
        #pragma unroll
        for (int j = 0; j < 2; ++j){
          int cl = wn*32 + j*16 + (lane & 15);
          #pragma unroll
          for (int r = 0; r < 4; ++r){
            int rl = wm*32 + i*16 + (lane >> 4) * 4 + r;
            Os[rl][cl] = f2h(acc[i][j][r] + bv[j]);
          }
        }
      __syncthreads();
      {
        int rl = tid >> 2, c0 = (tid & 3) * 16;
        size_t gbase = ((size_t)(nc - 1024) * 1024 + m0 + rl) * 64 + c0;
        *(bf16x8*)(sm16 + gbase)     = *(const bf16x8*)&Os[rl][c0];
        *(bf16x8*)(sm16 + gbase + 8) = *(const bf16x8*)&Os[rl][c0 + 8];
      }
    }
    __syncthreads();
  }
}

// ---------------- kernel 5: per-token adaptive mixing (fp8 cm, f16 pipeline) ----
__global__ __launch_bounds__(256) void k_mixtoken(
    const unsigned short* __restrict__ sampled,   // f16
    const unsigned char*  __restrict__ params8,   // fp8 cm
    const unsigned short* __restrict__ sm16,      // f16 sm tail
    const float* __restrict__ m_beta, const float* __restrict__ s_beta,
    unsigned short* __restrict__ out2)            // bf16
{
  __shared__ __align__(16) unsigned short smem[29984];
  const int t = blockIdx.x, tid = threadIdx.x, lane = tid & 63, wave = tid >> 6;
  const int l15 = lane & 15, kb = (lane >> 4) * 8;
  unsigned short (*Ss)[264] = (unsigned short (*)[264])smem;
  const int c31  = tid & 31;
  const int g    = tid >> 5;
  const int goff = (g & 1) * 32;
  const int colw = c31 ^ ((g & 3) << 3);
  const unsigned char* ptok8 = params8 + (size_t)t * 64;
  uint4 rv8[2];
  {
    const unsigned char* src = ptok8 + ((size_t)(c31 * 4 + (g >> 1)) << 16) + goff;
    rv8[0] = *(const uint4*)src;
    rv8[1] = *(const uint4*)(src + 16);
  }
  unsigned short rSm[14];
  #pragma unroll
  for (int k = 0; k < 14; ++k){
    int idx = tid + k * 256;
    unsigned short v = 0;
    if (idx < 3456){
      int o = idx / 72, p = idx % 72;
      if (o < 36 && p < 36){
        int n = 65536 + o * 36 + p;
        v = sm16[(size_t)((n >> 6) - 1024) * 65536 + (size_t)t * 64 + (n & 63)];
      }
    }
    rSm[k] = v;
  }
  const unsigned short* sp = sampled + (size_t)t * 9216;
  #pragma unroll
  for (int it = 0; it < 5; ++it){
    int slot = it * 256 + tid;
    if (slot < 1152){
      int p = slot >> 5, c8 = (slot & 31) << 3;
      *(bf16x8*)&Ss[p][c8] = *(const bf16x8*)(sp + p * 256 + c8);
    }
  }
  __syncthreads();
  f32x4 acc[3][4] = {};
  int cur = 0;
  for (int cc = 0; cc < 8; ++cc){
    unsigned short (*C)[40] = (unsigned short (*)[40])(smem + 9504 + cur * 10240);
    #pragma unroll
    for (int v = 0; v < 2; ++v){
      #pragma unroll
      for (int w = 0; w < 4; ++w){
        unsigned dw = ((const unsigned*)&rv8[v])[w];
        int d0 = g * 32 + v * 16 + w * 4;
        C[d0 + 0][colw] = fp82h(dw & 0xFFu);
        C[d0 + 1][colw] = fp82h((dw >> 8) & 0xFFu);
        C[d0 + 2][colw] = fp82h((dw >> 16) & 0xFFu);
        C[d0 + 3][colw] = fp82h(dw >> 24);
      }
    }
    __syncthreads();   // C[cur] ready
    if (cc < 7){
      const unsigned char* src = ptok8 + ((size_t)((cc + 1) * 128 + c31 * 4 + (g >> 1)) << 16) + goff;
      rv8[0] = *(const uint4*)src;
      rv8[1] = *(const uint4*)(src + 16);
    }
    f16x8 a[3], bfr[4];
    a[0] = *(const f16x8*)&Ss[l15][cc * 32 + kb];
    a[1] = *(const f16x8*)&Ss[16 + l15][cc * 32 + kb];
    a[2] = f16x8{};
    if (l15 < 4) a[2] = *(const f16x8*)&Ss[32 + l15][cc * 32 + kb];
    #pragma unroll
    for (int j = 0; j < 4; ++j){
      int d = wave * 64 + j * 16 + l15;
      bfr[j] = *(const f16x8*)&C[d][kb ^ (((d >> 5) & 3) << 3)];
    }
    #pragma unroll
    for (int i = 0; i < 3; ++i)
      #pragma unroll
      for (int j = 0; j < 4; ++j) acc[i][j] = mfma16h(a[i], bfr[j], acc[i][j]);
    cur ^= 1;
  }
  __syncthreads();
  {
    const bf16x8 z = {};
    #pragma unroll
    for (int i = 0; i < 9; ++i)
      *(bf16x8*)&smem[(i * 256 + tid) * 8] = z;
    #pragma unroll
    for (int k = 0; k < 14; ++k){
      int idx = tid + k * 256;
      if (idx < 3456) smem[18432 + idx] = rSm[k];
    }
  }
  __syncthreads();
  unsigned short (*O1T)[72] = (unsigned short (*)[72])smem;
  unsigned short (*Sm)[72]  = (unsigned short (*)[72])(smem + 18432);
  #pragma unroll
  for (int i = 0; i < 3; ++i){
    int p = i * 16 + ((lane >> 4) << 2);
    if (p < 36){
      #pragma unroll
      for (int j = 0; j < 4; ++j){
        int d = wave * 64 + j * 16 + l15;
        float mb = m_beta[d];
        unsigned short* dst = &O1T[d][p];
        #pragma unroll
        for (int r = 0; r < 4; ++r) dst[r] = f2h(gelu_f(acc[i][j][r] + mb));
      }
    }
  }
  __syncthreads();
  f32x4 acc2[3][4] = {};
  #pragma unroll
  for (int ks = 0; ks < 2; ++ks){
    int kb2 = ks * 32 + (lane >> 4) * 8;
    f16x8 a2[3], bf2[4];
    #pragma unroll
    for (int i = 0; i < 3; ++i) a2[i] = *(const f16x8*)&Sm[i*16 + l15][kb2];
    #pragma unroll
    for (int j = 0; j < 4; ++j) bf2[j] = *(const f16x8*)&O1T[wave*64 + j*16 + l15][kb2];
    #pragma unroll
    for (int i = 0; i < 3; ++i)
      #pragma unroll
      for (int j = 0; j < 4; ++j) acc2[i][j] = mfma16h(a2[i], bf2[j], acc2[i][j]);
  }
  unsigned short* o2 = out2 + (size_t)t * 9216;
  #pragma unroll
  for (int i = 0; i < 3; ++i){
    int ob = i*16 + ((lane >> 4) << 2);
    #pragma unroll
    for (int j = 0; j < 4; ++j){
      int d = wave*64 + j*16 + l15;
      #pragma unroll
      for (int r = 0; r < 4; ++r){
        int o = ob + r;
        if (o < 36) o2[o * 256 + d] = f2bf(gelu_f(acc2[i][j][r] + s_beta[o]));
      }
    }
  }
}

// ---------------- generic GEMM: C = act(A @ W + bias) (+resid) ----------------
template<int AK, int ACT, int RES, int OUTB>
__global__ __launch_bounds__(256) void k_gemm(
    const void* __restrict__ Ap, const float* __restrict__ W,
    const float* __restrict__ bias, const float* __restrict__ resid,
    void* __restrict__ Cp, int M, int N, int K)
{
  __shared__ __align__(16) unsigned short As[64][40];  // [m][k]
  __shared__ __align__(16) unsigned short Bs[64][40];  // [n][k^swz]
  const int tid = threadIdx.x, lane = tid & 63, wave = tid >> 6;
  const int wm = wave >> 1, wn = wave & 1;
  const int n0 = blockIdx.x * 64, m0 = blockIdx.y * 64;
  f32x4 acc[2][2] = {};
  for (int kk = 0; kk < K; kk += 32){
    { int m = tid >> 2, k4 = (tid & 3) * 8;
      if (AK == 0){
        const float* ap = (const float*)Ap + (size_t)(m0 + m) * K + kk + k4;
        #pragma unroll
        for (int i = 0; i < 8; ++i) As[m][k4 + i] = f2bf(ap[i]);
      } else {
        const unsigned short* ap = (const unsigned short*)Ap + (size_t)(m0 + m) * K + kk + k4;
        *(bf16x8*)&As[m][k4] = *(const bf16x8*)ap;
      }
    }
    { int kq = tid >> 3, n8 = (tid & 7) * 8;
      const float* wp = W + (size_t)(kk + kq) * N + n0 + n8;
      #pragma unroll
      for (int i = 0; i < 8; ++i){
        int n = n8 + i;
        Bs[n][kq ^ (((n >> 3) & 3) << 3)] = f2bf(wp[i]);
      }
    }
    __syncthreads();
    const int kb = (lane >> 4) * 8;
    bf16x8 a[2], bfr[2];
    #pragma unroll
    for (int i = 0; i < 2; ++i) a[i] = *(const bf16x8*)&As[wm*32 + i*16 + (lane & 15)][kb];
    #pragma unroll
    for (int j = 0; j < 2; ++j){
      int n = wn*32 + j*16 + (lane & 15);
      bfr[j] = *(const bf16x8*)&Bs[n][kb ^ (((n >> 3) & 3) << 3)];
    }
    #pragma unroll
    for (int i = 0; i < 2; ++i)
      #pragma unroll
      for (int j = 0; j < 2; ++j) acc[i][j] = mfma16(a[i], bfr[j], acc[i][j]);
    __syncthreads();
  }
  #pragma unroll
  for (int i = 0; i < 2; ++i)
    #pragma unroll
    for (int j = 0; j < 2; ++j){
      int col = n0 + wn*32 + j*16 + (lane & 15);
      float bv = bias[col];
      #pragma unroll
      for (int r = 0; r < 4; ++r){
        int row = m0 + wm*32 + i*16 + (lane >> 4) * 4 + r;
        float v = acc[i][j][r] + bv;
        if (ACT == 1) v = gelu_f(v);
        if (RES) v += resid[(size_t)row * N + col];
        if (OUTB) ((unsigned short*)Cp)[(size_t)row * N + col] = f2bf(v);
        else      ((float*)Cp)[(size_t)row * N + col] = v;
      }
    }
}

// ---------------- split-K GEMM: part[z][M][N] = A[:, z*KS:(z+1)*KS] @ W[z*KS:...] ----
template<int AK>
__global__ __launch_bounds__(256) void k_gemm_sk(
    const void* __restrict__ Ap, const float* __restrict__ W,
    float* __restrict__ part, int M, int N, int K, int KS)
{
  __shared__ __align__(16) unsigned short As[64][40];  // [m][k]
  __shared__ __align__(16) unsigned short Bs[64][40];  // [n][k^swz]
  const int tid = threadIdx.x, lane = tid & 63, wave = tid >> 6;
  const int wm = wave >> 1, wn = wave & 1;
  const int n0 = blockIdx.x * 64, m0 = blockIdx.y * 64;
  const int kbase = blockIdx.z * KS;
  f32x4 acc[2][2] = {};
  for (int kq = 0; kq < KS; kq += 32){
    int kk = kbase + kq;
    { int m = tid >> 2, k4 = (tid & 3) * 8;
      if (AK == 0){
        const float* ap = (const float*)Ap + (size_t)(m0 + m) * K + kk + k4;
        #pragma unroll
        for (int i = 0; i < 8; ++i) As[m][k4 + i] = f2bf(ap[i]);
      } else {
        const unsigned short* ap = (const unsigned short*)Ap + (size_t)(m0 + m) * K + kk + k4;
        *(bf16x8*)&As[m][k4] = *(const bf16x8*)ap;
      }
    }
    { int kr = tid >> 3, n8 = (tid & 7) * 8;
      const float* wp = W + (size_t)(kk + kr) * N + n0 + n8;
      #pragma unroll
      for (int i = 0; i < 8; ++i){
        int n = n8 + i;
        Bs[n][kr ^ (((n >> 3) & 3) << 3)] = f2bf(wp[i]);
      }
    }
    __syncthreads();
    const int kb = (lane >> 4) * 8;
    bf16x8 a[2], bfr[2];
    #pragma unroll
    for (int i = 0; i < 2; ++i) a[i] = *(const bf16x8*)&As[wm*32 + i*16 + (lane & 15)][kb];
    #pragma unroll
    for (int j = 0; j < 2; ++j){
      int n = wn*32 + j*16 + (lane & 15);
      bfr[j] = *(const bf16x8*)&Bs[n][kb ^ (((n >> 3) & 3) << 3)];
    }
    #pragma unroll
    for (int i = 0; i < 2; ++i)
      #pragma unroll
      for (int j = 0; j < 2; ++j) acc[i][j] = mfma16(a[i], bfr[j], acc[i][j]);
    __syncthreads();
  }
  float* pz = part + (size_t)blockIdx.z * M * N;
  #pragma unroll
  for (int i = 0; i < 2; ++i)
    #pragma unroll
    for (int j = 0; j < 2; ++j){
      int col = n0 + wn*32 + j*16 + (lane & 15);
      #pragma unroll
      for (int r = 0; r < 4; ++r){
        int row = m0 + wm*32 + i*16 + (lane >> 4) * 4 + r;
        pz[(size_t)row * N + col] = acc[i][j][r];
      }
    }
}

// ---------------- split-K reduce: out = sum_z part[z] + bias (+resid) ----------------
template<int RES>
__global__ __launch_bounds__(256) void k_reduce(
    const float* __restrict__ part, const float* __restrict__ bias,
    const float* __restrict__ resid, float* __restrict__ out,
    int total, int N, int SK)
{
  int i = blockIdx.x * 256 + threadIdx.x;
  if (i >= total) return;
  float s = 0.f;
  for (int z = 0; z < SK; ++z) s += part[(size_t)z * total + i];
  s += bias[i % N];
  if (RES) s += resid[i];
  out[i] = s;
}

// ---------------- fused split-K reduce + residual + LayerNorm ----------------
__global__ __launch_bounds__(256) void k_reduce_ln(
    const float* __restrict__ part, const float* __restrict__ bias,
    const float* __restrict__ resid,
    const float* __restrict__ g, const float* __restrict__ bb,
    float* __restrict__ emb_out, unsigned short* __restrict__ ln_out, int SK)
{
  __shared__ float red[4];
  const int t = blockIdx.x, tid = threadIdx.x;
  const int i = t * 256 + tid;
  float s = 0.f;
  for (int z = 0; z < SK; ++z) s += part[(size_t)z * 262144 + i];
  s += bias[tid] + resid[i];
  emb_out[i] = s;
  float mean = block_sum(s, red, tid) * (1.f / 256.f);
  float d = s - mean;
  float var = block_sum(d * d, red, tid) * (1.f / 256.f);
  ln_out[i] = f2bf(d * rsqrtf(var + 1e-5f) * g[tid] + bb[tid]);
}

// ---------------- attention: one (b,h) per block ----------------
__global__ __launch_bounds__(64) void k_attn(const float* __restrict__ qkv,
                                             float* __restrict__ attno)
{
  __shared__ float qs[64][33], ksm[64][33], vsm[64][33];
  const int blk = blockIdx.x, lane = threadIdx.x;
  const int b = blk >> 3, h = blk & 7;
  for (int idx = lane; idx < 2048; idx += 64){
    int row = idx >> 5, d = idx & 31;
    const float* base = qkv + (size_t)(b * 64 + row) * 768 + h * 32 + d;
    qs[row][d] = base[0]; ksm[row][d] = base[256]; vsm[row][d] = base[512];
  }
  __syncthreads();
  float qr[32];
  #pragma unroll
  for (int d = 0; d < 32; ++d) qr[d] = qs[lane][d];
  float s[64]; float mx = -1e30f;
  for (int m = 0; m < 64; ++m){
    float dot = 0.f;
    #pragma unroll
    for (int d = 0; d < 32; ++d) dot += qr[d] * ksm[m][d];
    dot *= 0.17677669529663687f;  // 32^-0.5
    s[m] = dot; mx = fmaxf(mx, dot);
  }
  float sum = 0.f;
  for (int m = 0; m < 64; ++m){ s[m] = expf(s[m] - mx); sum += s[m]; }
  float inv = 1.f / sum;
  float o[32] = {};
  for (int m = 0; m < 64; ++m){
    float p = s[m] * inv;
    #pragma unroll
    for (int d = 0; d < 32; ++d) o[d] += p * vsm[m][d];
  }
  float* dst = attno + (size_t)(b * 64 + lane) * 256 + h * 32;
  #pragma unroll
  for (int d = 0; d < 32; ++d) dst[d] = o[d];
}

__global__ void k_fill(float* p, int n, float v){
  int i = blockIdx.x * 256 + threadIdx.x;
  if (i < n) p[i] = v;
}

// ---------------- launch ----------------
extern "C" void kernel_launch(void* const* d_in, const int* in_sizes, int n_in,
                              void* d_out, int out_size, void* d_ws, size_t ws_size,
                              hipStream_t stream)
{
  const float* img      = (const float*)d_in[0];
  const float* embed    = (const float*)d_in[1];
  const float* roi      = (const float*)d_in[2];
  const float* ln_adj_g = (const float*)d_in[3];
  const float* ln_adj_b = (const float*)d_in[4];
  const float* w_adj    = (const float*)d_in[5];
  const float* ln_off_g = (const float*)d_in[6];
  const float* ln_off_b = (const float*)d_in[7];
  const float* w_off    = (const float*)d_in[8];
  const float* off_bias = (const float*)d_in[9];
  const float* pg_ln_g  = (const float*)d_in[10];
  const float* pg_ln_b  = (const float*)d_in[11];
  const float* pg_w1    = (const float*)d_in[12];
  const float* pg_b1    = (const float*)d_in[13];
  const float* pg_w2    = (const float*)d_in[14];
  const float* pg_b2    = (const float*)d_in[15];
  const float* m_beta   = (const float*)d_in[16];
  const float* s_beta   = (const float*)d_in[17];
  const float* mix_w    = (const float*)d_in[18];
  const float* mix_b    = (const float*)d_in[19];
  const float* ln1_g    = (const float*)d_in[20];
  const float* ln1_b    = (const float*)d_in[21];
  const float* qkv_w    = (const float*)d_in[22];
  const float* qkv_b    = (const float*)d_in[23];
  const float* proj_w   = (const float*)d_in[24];
  const float* proj_b   = (const float*)d_in[25];
  const float* ln2_g    = (const float*)d_in[26];
  const float* ln2_b    = (const float*)d_in[27];
  const float* fc1_w    = (const float*)d_in[28];
  const float* fc1_b    = (const float*)d_in[29];
  const float* fc2_w    = (const float*)d_in[30];
  const float* fc2_b    = (const float*)d_in[31];

  char* ws = (char*)d_ws;
  float*          pts     = (float*)         (ws + 0);          //   294912
  float*          hbuf    = (float*)         (ws + 294912);     //   262144
  unsigned short* imgT    = (unsigned short*)(ws + 557056);     // 33554432
  unsigned short* sampled = (unsigned short*)(ws + 34111488);   // 18874368 (f16)
  unsigned char*  params8 = (unsigned char*) (ws + 52985856);   // 67108864 (fp8 cm)
  unsigned short* sm16    = (unsigned short*)(ws + 120094720);  //  2752512 (f16 sm)
  unsigned short* out2    = (unsigned short*)(ws + 122847232);  // 18874368 (bf16)
  float*          embed1  = (float*)         (ws + 141721600);  //  1048576
  float*          embed2  = (float*)         (ws + 142770176);  //  1048576
  unsigned short* xln1    = (unsigned short*)(ws + 143818752);  //   524288
  unsigned short* xln2    = (unsigned short*)(ws + 144343040);  //   524288
  float*          qkvb    = (float*)         (ws + 144867328);  //  3145728
  float*          attno   = (float*)         (ws + 148013056);  //  1048576
  // aliased into the params8 region (dead after k_mixtoken):
  float*          part_mix  = (float*)(ws + 52985856);             // 16 MB (16 slabs)
  float*          part_smll = (float*)(ws + 52985856 + 16777216);  //  4 MB (4 slabs)
  unsigned short* h1        = (unsigned short*)(ws + 52985856 + 20971520); // 2 MB
  const size_t WS_NEEDED = 149061632;
  if (ws_size < WS_NEEDED){
    k_fill<<<(out_size + 255) / 256, 256, 0, stream>>>((float*)d_out, out_size, 12345.0f);
    return;
  }

  float* out = (float*)d_out;

  k_prep<<<1024, 256, 0, stream>>>(embed, roi, ln_adj_g, ln_adj_b, w_adj,
                                   ln_off_g, ln_off_b, w_off, off_bias,
                                   pg_ln_g, pg_ln_b, pg_w1, pg_b1, pts, hbuf);
  k_transpose<<<1024, 256, 0, stream>>>(img, imgT);
  k_sample<<<1024, 256, 0, stream>>>(imgT, pts, sampled);
  k_params<<<1045, 256, 0, stream>>>(hbuf, pg_w2, pg_b2, params8, sm16);
  k_mixtoken<<<1024, 256, 0, stream>>>(sampled, params8, sm16, m_beta, s_beta, out2);
  // embed1 = embed + out2 @ mix_w + mix_b   (split-K: 9216 = 16 x 576), fused LN1
  k_gemm_sk<1><<<dim3(4,16,16), 256, 0, stream>>>(out2, mix_w, part_mix, 1024, 256, 9216, 576);
  k_reduce_ln<<<1024, 256, 0, stream>>>(part_mix, mix_b, embed, ln1_g, ln1_b, embed1, xln1, 16);
  k_gemm<1,0,0,0><<<dim3(12,16), 256, 0, stream>>>(xln1, qkv_w, qkv_b, nullptr, qkvb, 1024, 768, 256);
  k_attn<<<128, 64, 0, stream>>>(qkvb, attno);
  // embed2 = embed1 + attno @ proj_w + proj_b (split-K: 256 = 4 x 64), fused LN2
  k_gemm_sk<0><<<dim3(4,16,4), 256, 0, stream>>>(attno, proj_w, part_smll, 1024, 256, 256, 64);
  k_reduce_ln<<<1024, 256, 0, stream>>>(part_smll, proj_b, embed1, ln2_g, ln2_b, embed2, xln2, 4);
  k_gemm<1,1,0,1><<<dim3(16,16), 256, 0, stream>>>(xln2, fc1_w, fc1_b, nullptr, h1, 1024, 1024, 256);
  // out = embed2 + h1 @ fc2_w + fc2_b   (split-K: 1024 = 4 x 256)
  k_gemm_sk<1><<<dim3(4,16,4), 256, 0, stream>>>(h1, fc2_w, part_smll, 1024, 256, 1024, 256);
  k_reduce<1><<<1024, 256, 0, stream>>>(part_smll, fc2_b, embed2, out, 262144, 256, 4);
}

// Round 11
// 255.298 us; speedup vs baseline: 1.6555x; 1.0540x over previous
//
#include <hip/hip_runtime.h>
#include <cstdint>

#define DEV __device__ __forceinline__

typedef __attribute__((ext_vector_type(8))) short bf16x8;
typedef __attribute__((ext_vector_type(8))) _Float16 f16x8;
typedef __attribute__((ext_vector_type(4))) float f32x4;

DEV unsigned short f2bf(float x){
  union { float f; unsigned u; } c; c.f = x;
  unsigned r = c.u + 0x7fffu + ((c.u >> 16) & 1u);
  return (unsigned short)(r >> 16);
}
DEV float bf2f(unsigned short h){
  union { unsigned u; float f; } c; c.u = ((unsigned)h) << 16;
  return c.f;
}
DEV unsigned short f2h(float x){
  union { unsigned short u; _Float16 h; } c;
  c.h = (_Float16)x;
  return c.u;
}
// f32 -> e4m3 (OCP), RNE, saturate to +-448. Software fallback path.
DEV unsigned char f2fp8(float x){
  union { float f; unsigned u; } c; c.f = x;
  unsigned s = (c.u >> 24) & 0x80u;
  float a = fabsf(x);
  a = fminf(a, 448.f);
  unsigned n;
  if (a < 0.015625f){
    n = (unsigned)(int)rintf(a * 512.f);       // 0..8, RNE; 8 == 2^-6 normal
  } else {
    union { float f; unsigned u; } d; d.f = a;
    unsigned u2 = d.u + 0x7FFFFu + ((d.u >> 20) & 1u);
    n = (((u2 >> 23) - 120u) << 3) | ((u2 >> 20) & 7u);
  }
  return (unsigned char)(s | n);
}
// pack 2 f32 -> 2 e4m3 bytes (byte0 = a, byte1 = b); HW instr on gfx950
DEV unsigned pk_fp8(float a, float b){
#if defined(__has_builtin)
#if __has_builtin(__builtin_amdgcn_cvt_pk_fp8_f32)
  return (unsigned)__builtin_amdgcn_cvt_pk_fp8_f32(a, b, 0, false);
#else
  return (unsigned)f2fp8(a) | ((unsigned)f2fp8(b) << 8);
#endif
#else
  return (unsigned)f2fp8(a) | ((unsigned)f2fp8(b) << 8);
#endif
}
// e4m3 -> f16 bits, exact: place exp/man in f16 fields, scale by 2^8.
DEV unsigned short fp82h(unsigned b){
  union { unsigned short u; _Float16 h; } c;
  c.u = (unsigned short)(((b & 0x80u) << 8) | ((b & 0x7Fu) << 7));
  c.h = c.h * (_Float16)256.0f;
  return c.u;
}

DEV float gelu_f(float x){ return 0.5f * x * (1.f + erff(x * 0.70710678118654752440f)); }

DEV f32x4 mfma16(bf16x8 a, bf16x8 b, f32x4 c){
  return __builtin_amdgcn_mfma_f32_16x16x32_bf16(a, b, c, 0, 0, 0);
}
DEV f32x4 mfma16h(f16x8 a, f16x8 b, f32x4 c){
  return __builtin_amdgcn_mfma_f32_16x16x32_f16(a, b, c, 0, 0, 0);
}

// block_sum: 256 threads (4 waves)
DEV float block_sum(float v, float* red, int tid){
  #pragma unroll
  for (int o = 32; o > 0; o >>= 1) v += __shfl_down(v, o);
  if ((tid & 63) == 0) red[tid >> 6] = v;
  __syncthreads();
  float s = red[0] + red[1] + red[2] + red[3];
  __syncthreads();
  return s;
}

// ---------------- constants ----------------
// B=16 N=64 D=256 CI=256 H=W=64 P=36 HEADS=8 HD=32 HID=1024 TOTAL=66832 T=1024
// cm (n<65536) stored fp8 e4m3, blocked: params8[(n>>6)*65536 + t*64 + (n&63)] bytes
// sm tail (n>=65536) stored f16, blocked: sm16[((n>>6)-1024)*65536 + t*64 + (n&63)]
// hbuf is stored bf16 (identical value to the consumer-side f2bf it replaced).

// ---------------- kernel 1: per-token prep ----------------
__global__ __launch_bounds__(256) void k_prep(
    const float* __restrict__ embed, const float* __restrict__ roi,
    const float* __restrict__ g_adj, const float* __restrict__ b_adj, const float* __restrict__ w_adj,
    const float* __restrict__ g_off, const float* __restrict__ b_off, const float* __restrict__ w_off,
    const float* __restrict__ off_bias,
    const float* __restrict__ g_pg, const float* __restrict__ b_pg,
    const float* __restrict__ w_pg1, const float* __restrict__ b_pg1,
    float* __restrict__ pts, unsigned short* __restrict__ hbuf)
{
  __shared__ float red[4];
  __shared__ float xln[256];
  __shared__ float offs[72];
  __shared__ float lg[4];
  __shared__ float stat[8];
  const int t = blockIdx.x, tid = threadIdx.x;
  float e = embed[t * 256 + tid];
  float mean = block_sum(e, red, tid) * (1.f / 256.f);
  float dv = e - mean;
  float var = block_sum(dv * dv, red, tid) * (1.f / 256.f);
  xln[tid] = dv * rsqrtf(var + 1e-5f);
  __syncthreads();
  if (tid < 4){
    float a0 = 0.f, a1 = 0.f, a2 = 0.f, a3 = 0.f;
    #pragma unroll 4
    for (int c = 0; c < 256; c += 4){
      a0 += (xln[c+0] * g_adj[c+0] + b_adj[c+0]) * w_adj[(c+0) * 4 + tid];
      a1 += (xln[c+1] * g_adj[c+1] + b_adj[c+1]) * w_adj[(c+1) * 4 + tid];
      a2 += (xln[c+2] * g_adj[c+2] + b_adj[c+2]) * w_adj[(c+2) * 4 + tid];
      a3 += (xln[c+3] * g_adj[c+3] + b_adj[c+3]) * w_adj[(c+3) * 4 + tid];
    }
    lg[tid] = (a0 + a1) + (a2 + a3);
  } else if (tid < 76){
    int j = tid - 4;
    float a0 = 0.f, a1 = 0.f, a2 = 0.f, a3 = 0.f;
    #pragma unroll 4
    for (int c = 0; c < 256; c += 4){
      a0 += (xln[c+0] * g_off[c+0] + b_off[c+0]) * w_off[(c+0) * 72 + j];
      a1 += (xln[c+1] * g_off[c+1] + b_off[c+1]) * w_off[(c+1) * 72 + j];
      a2 += (xln[c+2] * g_off[c+2] + b_off[c+2]) * w_off[(c+2) * 72 + j];
      a3 += (xln[c+3] * g_off[c+3] + b_off[c+3]) * w_off[(c+3) * 72 + j];
    }
    offs[j] = (a0 + a1) + (a2 + a3) + off_bias[j];
  } else if (tid < 140){
    int j = tid - 76;
    float a0 = 0.f, a1 = 0.f, a2 = 0.f, a3 = 0.f;
    #pragma unroll 4
    for (int c = 0; c < 256; c += 4){
      a0 += (xln[c+0] * g_pg[c+0] + b_pg[c+0]) * w_pg1[(c+0) * 64 + j];
      a1 += (xln[c+1] * g_pg[c+1] + b_pg[c+1]) * w_pg1[(c+1) * 64 + j];
      a2 += (xln[c+2] * g_pg[c+2] + b_pg[c+2]) * w_pg1[(c+2) * 64 + j];
      a3 += (xln[c+3] * g_pg[c+3] + b_pg[c+3]) * w_pg1[(c+3) * 64 + j];
    }
    hbuf[t * 64 + j] = f2bf((a0 + a1) + (a2 + a3) + b_pg1[j]);
  }
  __syncthreads();
  if (tid == 0){
    float x0 = roi[t*4+0], y0 = roi[t*4+1], x1 = roi[t*4+2], y1 = roi[t*4+3];
    float cx = (x0 + x1) * 0.5f, cy = (y0 + y1) * 0.5f;
    float w = fabsf(x1 - x0), hh = fabsf(y1 - y0);
    cx += lg[0] * w; cy += lg[1] * hh;
    w *= expf(lg[2]); hh *= expf(lg[3]);
    stat[0] = cx; stat[1] = cy; stat[2] = w; stat[3] = hh;
  }
  if (tid < 2){
    float mu = 0.f;
    for (int p = 0; p < 36; ++p) mu += offs[p*2 + tid];
    mu *= (1.f / 36.f);
    float v2 = 0.f;
    for (int p = 0; p < 36; ++p){ float d = offs[p*2 + tid] - mu; v2 += d * d; }
    float sd = sqrtf(v2 * (1.f / 35.f)) + 1e-7f;   // ddof=1
    stat[4 + tid] = mu; stat[6 + tid] = 1.f / (3.f * sd);
  }
  __syncthreads();
  if (tid < 72){
    int c = tid & 1;
    pts[t * 72 + tid] = stat[c] + (offs[tid] - stat[4 + c]) * stat[6 + c] * stat[2 + c];
  }
}

// ---------------- kernel 2: img [B,C,H,W] f32 -> [B,H,W,C] bf16 ----------------
__global__ __launch_bounds__(256) void k_transpose(const float* __restrict__ img,
                                                   unsigned short* __restrict__ imgT)
{
  __shared__ float tile[128][65];
  const int blk = blockIdx.x, tid = threadIdx.x;
  const int b = blk >> 6, y = blk & 63;
  for (int half = 0; half < 2; ++half){
    int c_loc = tid >> 1, x0 = (tid & 1) * 32;
    const float* src = img + (((size_t)(b * 256 + half * 128 + c_loc)) * 64 + y) * 64 + x0;
    #pragma unroll
    for (int i = 0; i < 32; ++i) tile[c_loc][x0 + i] = src[i];
    __syncthreads();
    {
      int x = tid >> 2, c0 = (tid & 3) * 32;
      size_t obase = (((size_t)(b * 64 + y)) * 64 + x) * 256 + half * 128 + c0;
      #pragma unroll
      for (int cb = 0; cb < 32; cb += 8){
        unsigned short tmp[8];
        #pragma unroll
        for (int j = 0; j < 8; ++j) tmp[j] = f2bf(tile[c0 + cb + j][x]);
        *(bf16x8*)(imgT + obase + cb) = *(const bf16x8*)tmp;
      }
    }
    __syncthreads();
  }
}

// ---------------- kernel 3: bilinear sample -> sampled [T,36,256] f16 ----------------
__global__ __launch_bounds__(256) void k_sample(const unsigned short* __restrict__ imgT,
                                                const float* __restrict__ pts,
                                                unsigned short* __restrict__ sampled)
{
  __shared__ float lpts[72];
  const int t = blockIdx.x, tid = threadIdx.x;
  const int b = t >> 6;
  if (tid < 72) lpts[tid] = pts[t * 72 + tid];
  __syncthreads();
  for (int p = 0; p < 36; ++p){
    float fx = lpts[p*2]   * 64.f - 0.5f;
    float fy = lpts[p*2+1] * 64.f - 0.5f;
    float x0f = floorf(fx), y0f = floorf(fy);
    float wx = fx - x0f, wy = fy - y0f;
    int x0 = (int)x0f, y0 = (int)y0f;
    float acc = 0.f;
    #pragma unroll
    for (int dy = 0; dy < 2; ++dy){
      #pragma unroll
      for (int dx = 0; dx < 2; ++dx){
        int xi = x0 + dx, yi = y0 + dy;
        bool valid = (xi >= 0) & (xi < 64) & (yi >= 0) & (yi < 64);
        int xc = min(max(xi, 0), 63), yc = min(max(yi, 0), 63);
        float w = (dx ? wx : 1.f - wx) * (dy ? wy : 1.f - wy);
        float v = bf2f(imgT[(((size_t)(b * 64 + yc)) * 64 + xc) * 256 + tid]);
        acc += v * (valid ? w : 0.f);
      }
    }
    sampled[(size_t)t * 9216 + p * 256 + tid] = f2h(acc);
  }
}

// ---------------- kernel 4: params = h @ pg_w2 + pg_b2 (M=1024,K=64,N=66832)
// cm chunks (nc<1024) -> fp8 e4m3 via HW cvt_pk; sm tail (nc>=1024) -> f16.
__global__ __launch_bounds__(256) void k_params(
    const unsigned short* __restrict__ hbuf, const float* __restrict__ w2,
    const float* __restrict__ b2, unsigned char* __restrict__ params8,
    unsigned short* __restrict__ sm16)
{
  __shared__ __align__(16) unsigned short Bs[64][72];  // [n][k^swz]
  __shared__ __align__(16) unsigned short As[64][72];  // [m][k]
  __shared__ __align__(16) unsigned short Os[64][72];  // f16 staging (sm path)
  __shared__ __align__(16) unsigned char  Os8[64][72]; // fp8 staging (cm path)
  const int tid = threadIdx.x, lane = tid & 63, wave = tid >> 6;
  const int wm = wave >> 1, wn = wave & 1;
  const int nc = blockIdx.x, n0 = nc * 64;
  const bool cm = (nc < 1024);
  {
    int k = tid >> 2, nb = (tid & 3) * 16;
    #pragma unroll
    for (int i = 0; i < 16; ++i){
      int n = nb + i, gn = n0 + n;
      float v = (gn < 66832) ? w2[(size_t)k * 66832 + gn] : 0.f;
      Bs[n][k ^ (((n >> 3) & 7) << 3)] = f2bf(v);
    }
  }
  float bv[2];
  #pragma unroll
  for (int j = 0; j < 2; ++j){
    int col = n0 + wn*32 + j*16 + (lane & 15);
    bv[j] = (col < 66832) ? b2[col] : 0.f;
  }
  __syncthreads();
  for (int mt = 0; mt < 16; ++mt){
    int m0 = mt * 64;
    { int m = tid >> 2, kb4 = (tid & 3) * 16;
      const unsigned short* hp = hbuf + (m0 + m) * 64 + kb4;
      *(bf16x8*)&As[m][kb4]     = *(const bf16x8*)hp;
      *(bf16x8*)&As[m][kb4 + 8] = *(const bf16x8*)(hp + 8);
    }
    __syncthreads();
    f32x4 acc[2][2] = {};
    #pragma unroll
    for (int ks = 0; ks < 2; ++ks){
      int kb = ks * 32 + (lane >> 4) * 8;
      bf16x8 a[2], bb[2];
      #pragma unroll
      for (int i = 0; i < 2; ++i) a[i] = *(const bf16x8*)&As[wm*32 + i*16 + (lane & 15)][kb];
      #pragma unroll
      for (int j = 0; j < 2; ++j){
        int n = wn*32 + j*16 + (lane & 15);
        bb[j] = *(const bf16x8*)&Bs[n][kb ^ (((n >> 3) & 7) << 3)];
      }
      #pragma unroll
      for (int i = 0; i < 2; ++i)
        #pragma unroll
        for (int j = 0; j < 2; ++j) acc[i][j] = mfma16(a[i], bb[j], acc[i][j]);
    }
    if (cm){
      #pragma unroll
      for (int i = 0; i < 2; ++i)
        #pragma unroll
        for (int j = 0; j < 2; ++j){
          int cl = wn*32 + j*16 + (lane & 15);
          int rl = wm*32 + i*16 + (lane >> 4) * 4;
          unsigned p01 = pk_fp8(acc[i][j][0] + bv[j], acc[i][j][1] + bv[j]);
          unsigned p23 = pk_fp8(acc[i][j][2] + bv[j], acc[i][j][3] + bv[j]);
          Os8[rl + 0][cl] = (unsigned char)(p01 & 0xFFu);
          Os8[rl + 1][cl] = (unsigned char)((p01 >> 8) & 0xFFu);
          Os8[rl + 2][cl] = (unsigned char)(p23 & 0xFFu);
          Os8[rl + 3][cl] = (unsigned char)((p23 >> 8) & 0xFFu);
        }
      __syncthreads();
      {
        int rl = tid >> 2, c0 = (tid & 3) * 16;
        uint2 lo = *(const uint2*)&Os8[rl][c0];
        uint2 hi = *(const uint2*)&Os8[rl][c0 + 8];
        uint4 val; val.x = lo.x; val.y = lo.y; val.z = hi.x; val.w = hi.y;
        *(uint4*)(params8 + ((size_t)nc * 1024 + m0 + rl) * 64 + c0) = val;
      }
    } else {
      #pragma unroll
      for (int i = 0; i < 2; ++i)
        #pragma unroll
        for (int j = 0; j < 2; ++j){
          int cl = wn*32 + j*16 + (lane & 15);
          #pragma unroll
          for (int r = 0; r < 4; ++r){
            int rl = wm*32 + i*16 + (lane >> 4) * 4 + r;
            Os[rl][cl] = f2h(acc[i][j][r] + bv[j]);
          }
        }
      __syncthreads();
      {
        int rl = tid >> 2, c0 = (tid & 3) * 16;
        size_t gbase = ((size_t)(nc - 1024) * 1024 + m0 + rl) * 64 + c0;
        *(bf16x8*)(sm16 + gbase)     = *(const bf16x8*)&Os[rl][c0];
        *(bf16x8*)(sm16 + gbase + 8) = *(const bf16x8*)&Os[rl][c0 + 8];
      }
    }
    __syncthreads();
  }
}

// ---------------- kernel 5: per-token adaptive mixing (fp8 cm, f16 pipeline) ----
__global__ __launch_bounds__(256) void k_mixtoken(
    const unsigned short* __restrict__ sampled,   // f16
    const unsigned char*  __restrict__ params8,   // fp8 cm
    const unsigned short* __restrict__ sm16,      // f16 sm tail
    const float* __restrict__ m_beta, const float* __restrict__ s_beta,
    unsigned short* __restrict__ out2)            // bf16
{
  __shared__ __align__(16) unsigned short smem[29984];
  const int t = blockIdx.x, tid = threadIdx.x, lane = tid & 63, wave = tid >> 6;
  const int l15 = lane & 15, kb = (lane >> 4) * 8;
  unsigned short (*Ss)[264] = (unsigned short (*)[264])smem;
  const int c31  = tid & 31;
  const int g    = tid >> 5;
  const int goff = (g & 1) * 32;
  const int colw = c31 ^ ((g & 3) << 3);
  const unsigned char* ptok8 = params8 + (size_t)t * 64;
  uint4 rv8[2];
  {
    const unsigned char* src = ptok8 + ((size_t)(c31 * 4 + (g >> 1)) << 16) + goff;
    rv8[0] = *(const uint4*)src;
    rv8[1] = *(const uint4*)(src + 16);
  }
  unsigned short rSm[14];
  #pragma unroll
  for (int k = 0; k < 14; ++k){
    int idx = tid + k * 256;
    unsigned short v = 0;
    if (idx < 3456){
      int o = idx / 72, p = idx % 72;
      if (o < 36 && p < 36){
        int n = 65536 + o * 36 + p;
        v = sm16[(size_t)((n >> 6) - 1024) * 65536 + (size_t)t * 64 + (n & 63)];
      }
    }
    rSm[k] = v;
  }
  const unsigned short* sp = sampled + (size_t)t * 9216;
  #pragma unroll
  for (int it = 0; it < 5; ++it){
    int slot = it * 256 + tid;
    if (slot < 1152){
      int p = slot >> 5, c8 = (slot & 31) << 3;
      *(bf16x8*)&Ss[p][c8] = *(const bf16x8*)(sp + p * 256 + c8);
    }
  }
  __syncthreads();
  f32x4 acc[3][4] = {};
  int cur = 0;
  for (int cc = 0; cc < 8; ++cc){
    unsigned short (*C)[40] = (unsigned short (*)[40])(smem + 9504 + cur * 10240);
    #pragma unroll
    for (int v = 0; v < 2; ++v){
      #pragma unroll
      for (int w = 0; w < 4; ++w){
        unsigned dw = ((const unsigned*)&rv8[v])[w];
        int d0 = g * 32 + v * 16 + w * 4;
        C[d0 + 0][colw] = fp82h(dw & 0xFFu);
        C[d0 + 1][colw] = fp82h((dw >> 8) & 0xFFu);
        C[d0 + 2][colw] = fp82h((dw >> 16) & 0xFFu);
        C[d0 + 3][colw] = fp82h(dw >> 24);
      }
    }
    __syncthreads();   // C[cur] ready
    if (cc < 7){
      const unsigned char* src = ptok8 + ((size_t)((cc + 1) * 128 + c31 * 4 + (g >> 1)) << 16) + goff;
      rv8[0] = *(const uint4*)src;
      rv8[1] = *(const uint4*)(src + 16);
    }
    f16x8 a[3], bfr[4];
    a[0] = *(const f16x8*)&Ss[l15][cc * 32 + kb];
    a[1] = *(const f16x8*)&Ss[16 + l15][cc * 32 + kb];
    a[2] = f16x8{};
    if (l15 < 4) a[2] = *(const f16x8*)&Ss[32 + l15][cc * 32 + kb];
    #pragma unroll
    for (int j = 0; j < 4; ++j){
      int d = wave * 64 + j * 16 + l15;
      bfr[j] = *(const f16x8*)&C[d][kb ^ (((d >> 5) & 3) << 3)];
    }
    #pragma unroll
    for (int i = 0; i < 3; ++i)
      #pragma unroll
      for (int j = 0; j < 4; ++j) acc[i][j] = mfma16h(a[i], bfr[j], acc[i][j]);
    cur ^= 1;
  }
  __syncthreads();
  {
    const bf16x8 z = {};
    #pragma unroll
    for (int i = 0; i < 9; ++i)
      *(bf16x8*)&smem[(i * 256 + tid) * 8] = z;
    #pragma unroll
    for (int k = 0; k < 14; ++k){
      int idx = tid + k * 256;
      if (idx < 3456) smem[18432 + idx] = rSm[k];
    }
  }
  __syncthreads();
  unsigned short (*O1T)[72] = (unsigned short (*)[72])smem;
  unsigned short (*Sm)[72]  = (unsigned short (*)[72])(smem + 18432);
  #pragma unroll
  for (int i = 0; i < 3; ++i){
    int p = i * 16 + ((lane >> 4) << 2);
    if (p < 36){
      #pragma unroll
      for (int j = 0; j < 4; ++j){
        int d = wave * 64 + j * 16 + l15;
        float mb = m_beta[d];
        unsigned short* dst = &O1T[d][p];
        #pragma unroll
        for (int r = 0; r < 4; ++r) dst[r] = f2h(gelu_f(acc[i][j][r] + mb));
      }
    }
  }
  __syncthreads();
  f32x4 acc2[3][4] = {};
  #pragma unroll
  for (int ks = 0; ks < 2; ++ks){
    int kb2 = ks * 32 + (lane >> 4) * 8;
    f16x8 a2[3], bf2[4];
    #pragma unroll
    for (int i = 0; i < 3; ++i) a2[i] = *(const f16x8*)&Sm[i*16 + l15][kb2];
    #pragma unroll
    for (int j = 0; j < 4; ++j) bf2[j] = *(const f16x8*)&O1T[wave*64 + j*16 + l15][kb2];
    #pragma unroll
    for (int i = 0; i < 3; ++i)
      #pragma unroll
      for (int j = 0; j < 4; ++j) acc2[i][j] = mfma16h(a2[i], bf2[j], acc2[i][j]);
  }
  unsigned short* o2 = out2 + (size_t)t * 9216;
  #pragma unroll
  for (int i = 0; i < 3; ++i){
    int ob = i*16 + ((lane >> 4) << 2);
    #pragma unroll
    for (int j = 0; j < 4; ++j){
      int d = wave*64 + j*16 + l15;
      #pragma unroll
      for (int r = 0; r < 4; ++r){
        int o = ob + r;
        if (o < 36) o2[o * 256 + d] = f2bf(gelu_f(acc2[i][j][r] + s_beta[o]));
      }
    }
  }
}

// ---------------- generic GEMM: C = act(A @ W + bias) (+resid) ----------------
template<int AK, int ACT, int RES, int OUTB>
__global__ __launch_bounds__(256) void k_gemm(
    const void* __restrict__ Ap, const float* __restrict__ W,
    const float* __restrict__ bias, const float* __restrict__ resid,
    void* __restrict__ Cp, int M, int N, int K)
{
  __shared__ __align__(16) unsigned short As[64][40];  // [m][k]
  __shared__ __align__(16) unsigned short Bs[64][40];  // [n][k^swz]
  const int tid = threadIdx.x, lane = tid & 63, wave = tid >> 6;
  const int wm = wave >> 1, wn = wave & 1;
  const int n0 = blockIdx.x * 64, m0 = blockIdx.y * 64;
  f32x4 acc[2][2] = {};
  for (int kk = 0; kk < K; kk += 32){
    { int m = tid >> 2, k4 = (tid & 3) * 8;
      if (AK == 0){
        const float* ap = (const float*)Ap + (size_t)(m0 + m) * K + kk + k4;
        #pragma unroll
        for (int i = 0; i < 8; ++i) As[m][k4 + i] = f2bf(ap[i]);
      } else {
        const unsigned short* ap = (const unsigned short*)Ap + (size_t)(m0 + m) * K + kk + k4;
        *(bf16x8*)&As[m][k4] = *(const bf16x8*)ap;
      }
    }
    { int kq = tid >> 3, n8 = (tid & 7) * 8;
      const float* wp = W + (size_t)(kk + kq) * N + n0 + n8;
      #pragma unroll
      for (int i = 0; i < 8; ++i){
        int n = n8 + i;
        Bs[n][kq ^ (((n >> 3) & 3) << 3)] = f2bf(wp[i]);
      }
    }
    __syncthreads();
    const int kb = (lane >> 4) * 8;
    bf16x8 a[2], bfr[2];
    #pragma unroll
    for (int i = 0; i < 2; ++i) a[i] = *(const bf16x8*)&As[wm*32 + i*16 + (lane & 15)][kb];
    #pragma unroll
    for (int j = 0; j < 2; ++j){
      int n = wn*32 + j*16 + (lane & 15);
      bfr[j] = *(const bf16x8*)&Bs[n][kb ^ (((n >> 3) & 3) << 3)];
    }
    #pragma unroll
    for (int i = 0; i < 2; ++i)
      #pragma unroll
      for (int j = 0; j < 2; ++j) acc[i][j] = mfma16(a[i], bfr[j], acc[i][j]);
    __syncthreads();
  }
  #pragma unroll
  for (int i = 0; i < 2; ++i)
    #pragma unroll
    for (int j = 0; j < 2; ++j){
      int col = n0 + wn*32 + j*16 + (lane & 15);
      float bv = bias[col];
      #pragma unroll
      for (int r = 0; r < 4; ++r){
        int row = m0 + wm*32 + i*16 + (lane >> 4) * 4 + r;
        float v = acc[i][j][r] + bv;
        if (ACT == 1) v = gelu_f(v);
        if (RES) v += resid[(size_t)row * N + col];
        if (OUTB) ((unsigned short*)Cp)[(size_t)row * N + col] = f2bf(v);
        else      ((float*)Cp)[(size_t)row * N + col] = v;
      }
    }
}

// ---------------- split-K GEMM: part[z][M][N] = A[:, z*KS:(z+1)*KS] @ W[z*KS:...] ----
template<int AK>
__global__ __launch_bounds__(256) void k_gemm_sk(
    const void* __restrict__ Ap, const float* __restrict__ W,
    float* __restrict__ part, int M, int N, int K, int KS)
{
  __shared__ __align__(16) unsigned short As[64][40];  // [m][k]
  __shared__ __align__(16) unsigned short Bs[64][40];  // [n][k^swz]
  const int tid = threadIdx.x, lane = tid & 63, wave = tid >> 6;
  const int wm = wave >> 1, wn = wave & 1;
  const int n0 = blockIdx.x * 64, m0 = blockIdx.y * 64;
  const int kbase = blockIdx.z * KS;
  f32x4 acc[2][2] = {};
  for (int kq = 0; kq < KS; kq += 32){
    int kk = kbase + kq;
    { int m = tid >> 2, k4 = (tid & 3) * 8;
      if (AK == 0){
        const float* ap = (const float*)Ap + (size_t)(m0 + m) * K + kk + k4;
        #pragma unroll
        for (int i = 0; i < 8; ++i) As[m][k4 + i] = f2bf(ap[i]);
      } else {
        const unsigned short* ap = (const unsigned short*)Ap + (size_t)(m0 + m) * K + kk + k4;
        *(bf16x8*)&As[m][k4] = *(const bf16x8*)ap;
      }
    }
    { int kr = tid >> 3, n8 = (tid & 7) * 8;
      const float* wp = W + (size_t)(kk + kr) * N + n0 + n8;
      #pragma unroll
      for (int i = 0; i < 8; ++i){
        int n = n8 + i;
        Bs[n][kr ^ (((n >> 3) & 3) << 3)] = f2bf(wp[i]);
      }
    }
    __syncthreads();
    const int kb = (lane >> 4) * 8;
    bf16x8 a[2], bfr[2];
    #pragma unroll
    for (int i = 0; i < 2; ++i) a[i] = *(const bf16x8*)&As[wm*32 + i*16 + (lane & 15)][kb];
    #pragma unroll
    for (int j = 0; j < 2; ++j){
      int n = wn*32 + j*16 + (lane & 15);
      bfr[j] = *(const bf16x8*)&Bs[n][kb ^ (((n >> 3) & 3) << 3)];
    }
    #pragma unroll
    for (int i = 0; i < 2; ++i)
      #pragma unroll
      for (int j = 0; j < 2; ++j) acc[i][j] = mfma16(a[i], bfr[j], acc[i][j]);
    __syncthreads();
  }
  float* pz = part + (size_t)blockIdx.z * M * N;
  #pragma unroll
  for (int i = 0; i < 2; ++i)
    #pragma unroll
    for (int j = 0; j < 2; ++j){
      int col = n0 + wn*32 + j*16 + (lane & 15);
      #pragma unroll
      for (int r = 0; r < 4; ++r){
        int row = m0 + wm*32 + i*16 + (lane >> 4) * 4 + r;
        pz[(size_t)row * N + col] = acc[i][j][r];
      }
    }
}

// ---------------- split-K reduce: out = sum_z part[z] + bias (+resid) ----------------
template<int RES>
__global__ __launch_bounds__(256) void k_reduce(
    const float* __restrict__ part, const float* __restrict__ bias,
    const float* __restrict__ resid, float* __restrict__ out,
    int total, int N, int SK)
{
  int i = blockIdx.x * 256 + threadIdx.x;
  if (i >= total) return;
  float s = 0.f;
  for (int z = 0; z < SK; ++z) s += part[(size_t)z * total + i];
  s += bias[i % N];
  if (RES) s += resid[i];
  out[i] = s;
}

// ---------------- fused split-K reduce + residual + LayerNorm ----------------
__global__ __launch_bounds__(256) void k_reduce_ln(
    const float* __restrict__ part, const float* __restrict__ bias,
    const float* __restrict__ resid,
    const float* __restrict__ g, const float* __restrict__ bb,
    float* __restrict__ emb_out, unsigned short* __restrict__ ln_out, int SK)
{
  __shared__ float red[4];
  const int t = blockIdx.x, tid = threadIdx.x;
  const int i = t * 256 + tid;
  float s = 0.f;
  for (int z = 0; z < SK; ++z) s += part[(size_t)z * 262144 + i];
  s += bias[tid] + resid[i];
  emb_out[i] = s;
  float mean = block_sum(s, red, tid) * (1.f / 256.f);
  float d = s - mean;
  float var = block_sum(d * d, red, tid) * (1.f / 256.f);
  ln_out[i] = f2bf(d * rsqrtf(var + 1e-5f) * g[tid] + bb[tid]);
}

// ---------------- attention: one (b,h) per block ----------------
__global__ __launch_bounds__(64) void k_attn(const float* __restrict__ qkv,
                                             float* __restrict__ attno)
{
  __shared__ float qs[64][33], ksm[64][33], vsm[64][33];
  const int blk = blockIdx.x, lane = threadIdx.x;
  const int b = blk >> 3, h = blk & 7;
  for (int idx = lane; idx < 2048; idx += 64){
    int row = idx >> 5, d = idx & 31;
    const float* base = qkv + (size_t)(b * 64 + row) * 768 + h * 32 + d;
    qs[row][d] = base[0]; ksm[row][d] = base[256]; vsm[row][d] = base[512];
  }
  __syncthreads();
  float qr[32];
  #pragma unroll
  for (int d = 0; d < 32; ++d) qr[d] = qs[lane][d];
  float s[64]; float mx = -1e30f;
  for (int m = 0; m < 64; ++m){
    float dot = 0.f;
    #pragma unroll
    for (int d = 0; d < 32; ++d) dot += qr[d] * ksm[m][d];
    dot *= 0.17677669529663687f;  // 32^-0.5
    s[m] = dot; mx = fmaxf(mx, dot);
  }
  float sum = 0.f;
  for (int m = 0; m < 64; ++m){ s[m] = expf(s[m] - mx); sum += s[m]; }
  float inv = 1.f / sum;
  float o[32] = {};
  for (int m = 0; m < 64; ++m){
    float p = s[m] * inv;
    #pragma unroll
    for (int d = 0; d < 32; ++d) o[d] += p * vsm[m][d];
  }
  float* dst = attno + (size_t)(b * 64 + lane) * 256 + h * 32;
  #pragma unroll
  for (int d = 0; d < 32; ++d) dst[d] = o[d];
}

__global__ void k_fill(float* p, int n, float v){
  int i = blockIdx.x * 256 + threadIdx.x;
  if (i < n) p[i] = v;
}

// ---------------- launch ----------------
extern "C" void kernel_launch(void* const* d_in, const int* in_sizes, int n_in,
                              void* d_out, int out_size, void* d_ws, size_t ws_size,
                              hipStream_t stream)
{
  const float* img      = (const float*)d_in[0];
  const float* embed    = (const float*)d_in[1];
  const float* roi      = (const float*)d_in[2];
  const float* ln_adj_g = (const float*)d_in[3];
  const float* ln_adj_b = (const float*)d_in[4];
  const float* w_adj    = (const float*)d_in[5];
  const float* ln_off_g = (const float*)d_in[6];
  const float* ln_off_b = (const float*)d_in[7];
  const float* w_off    = (const float*)d_in[8];
  const float* off_bias = (const float*)d_in[9];
  const float* pg_ln_g  = (const float*)d_in[10];
  const float* pg_ln_b  = (const float*)d_in[11];
  const float* pg_w1    = (const float*)d_in[12];
  const float* pg_b1    = (const float*)d_in[13];
  const float* pg_w2    = (const float*)d_in[14];
  const float* pg_b2    = (const float*)d_in[15];
  const float* m_beta   = (const float*)d_in[16];
  const float* s_beta   = (const float*)d_in[17];
  const float* mix_w    = (const float*)d_in[18];
  const float* mix_b    = (const float*)d_in[19];
  const float* ln1_g    = (const float*)d_in[20];
  const float* ln1_b    = (const float*)d_in[21];
  const float* qkv_w    = (const float*)d_in[22];
  const float* qkv_b    = (const float*)d_in[23];
  const float* proj_w   = (const float*)d_in[24];
  const float* proj_b   = (const float*)d_in[25];
  const float* ln2_g    = (const float*)d_in[26];
  const float* ln2_b    = (const float*)d_in[27];
  const float* fc1_w    = (const float*)d_in[28];
  const float* fc1_b    = (const float*)d_in[29];
  const float* fc2_w    = (const float*)d_in[30];
  const float* fc2_b    = (const float*)d_in[31];

  char* ws = (char*)d_ws;
  float*          pts     = (float*)         (ws + 0);          //   294912
  unsigned short* hbuf    = (unsigned short*)(ws + 294912);     //   131072 (bf16)
  unsigned short* imgT    = (unsigned short*)(ws + 557056);     // 33554432
  unsigned short* sampled = (unsigned short*)(ws + 34111488);   // 18874368 (f16)
  unsigned char*  params8 = (unsigned char*) (ws + 52985856);   // 67108864 (fp8 cm)
  unsigned short* sm16    = (unsigned short*)(ws + 120094720);  //  2752512 (f16 sm)
  unsigned short* out2    = (unsigned short*)(ws + 122847232);  // 18874368 (bf16)
  float*          embed1  = (float*)         (ws + 141721600);  //  1048576
  float*          embed2  = (float*)         (ws + 142770176);  //  1048576
  unsigned short* xln1    = (unsigned short*)(ws + 143818752);  //   524288
  unsigned short* xln2    = (unsigned short*)(ws + 144343040);  //   524288
  float*          qkvb    = (float*)         (ws + 144867328);  //  3145728
  float*          attno   = (float*)         (ws + 148013056);  //  1048576
  // aliased into the params8 region (dead after k_mixtoken):
  float*          part_mix  = (float*)(ws + 52985856);             // 16 MB (16 slabs)
  float*          part_smll = (float*)(ws + 52985856 + 16777216);  //  4 MB (4 slabs)
  unsigned short* h1        = (unsigned short*)(ws + 52985856 + 20971520); // 2 MB
  const size_t WS_NEEDED = 149061632;
  if (ws_size < WS_NEEDED){
    k_fill<<<(out_size + 255) / 256, 256, 0, stream>>>((float*)d_out, out_size, 12345.0f);
    return;
  }

  float* out = (float*)d_out;

  k_prep<<<1024, 256, 0, stream>>>(embed, roi, ln_adj_g, ln_adj_b, w_adj,
                                   ln_off_g, ln_off_b, w_off, off_bias,
                                   pg_ln_g, pg_ln_b, pg_w1, pg_b1, pts, hbuf);
  k_transpose<<<1024, 256, 0, stream>>>(img, imgT);
  k_sample<<<1024, 256, 0, stream>>>(imgT, pts, sampled);
  k_params<<<1045, 256, 0, stream>>>(hbuf, pg_w2, pg_b2, params8, sm16);
  k_mixtoken<<<1024, 256, 0, stream>>>(sampled, params8, sm16, m_beta, s_beta, out2);
  // embed1 = embed + out2 @ mix_w + mix_b   (split-K: 9216 = 16 x 576), fused LN1
  k_gemm_sk<1><<<dim3(4,16,16), 256, 0, stream>>>(out2, mix_w, part_mix, 1024, 256, 9216, 576);
  k_reduce_ln<<<1024, 256, 0, stream>>>(part_mix, mix_b, embed, ln1_g, ln1_b, embed1, xln1, 16);
  k_gemm<1,0,0,0><<<dim3(12,16), 256, 0, stream>>>(xln1, qkv_w, qkv_b, nullptr, qkvb, 1024, 768, 256);
  k_attn<<<128, 64, 0, stream>>>(qkvb, attno);
  // embed2 = embed1 + attno @ proj_w + proj_b (split-K: 256 = 4 x 64), fused LN2
  k_gemm_sk<0><<<dim3(4,16,4), 256, 0, stream>>>(attno, proj_w, part_smll, 1024, 256, 256, 64);
  k_reduce_ln<<<1024, 256, 0, stream>>>(part_smll, proj_b, embed1, ln2_g, ln2_b, embed2, xln2, 4);
  k_gemm<1,1,0,1><<<dim3(16,16), 256, 0, stream>>>(xln2, fc1_w, fc1_b, nullptr, h1, 1024, 1024, 256);
  // out = embed2 + h1 @ fc2_w + fc2_b   (split-K: 1024 = 4 x 256)
  k_gemm_sk<1><<<dim3(4,16,4), 256, 0, stream>>>(h1, fc2_w, part_smll, 1024, 256, 1024, 256);
  k_reduce<1><<<1024, 256, 0, stream>>>(part_smll, fc2_b, embed2, out, 262144, 256, 4);
}

// Round 13
// 253.481 us; speedup vs baseline: 1.6674x; 1.0072x over previous
//
#include <hip/hip_runtime.h>
#include <cstdint>

#define DEV __device__ __forceinline__

typedef __attribute__((ext_vector_type(8))) short bf16x8;
typedef __attribute__((ext_vector_type(8))) _Float16 f16x8;
typedef __attribute__((ext_vector_type(2))) __fp16 fp16x2;
typedef __attribute__((ext_vector_type(2))) float f32x2;
typedef __attribute__((ext_vector_type(4))) float f32x4;

DEV unsigned short f2bf(float x){
  union { float f; unsigned u; } c; c.f = x;
  unsigned r = c.u + 0x7fffu + ((c.u >> 16) & 1u);
  return (unsigned short)(r >> 16);
}
DEV float bf2f(unsigned short h){
  union { unsigned u; float f; } c; c.u = ((unsigned)h) << 16;
  return c.f;
}
DEV unsigned short f2h(float x){
  union { unsigned short u; _Float16 h; } c;
  c.h = (_Float16)x;
  return c.u;
}
// f32 -> e4m3 (OCP), RNE, saturate to +-448. Software fallback path.
DEV unsigned char f2fp8(float x){
  union { float f; unsigned u; } c; c.f = x;
  unsigned s = (c.u >> 24) & 0x80u;
  float a = fabsf(x);
  a = fminf(a, 448.f);
  unsigned n;
  if (a < 0.015625f){
    n = (unsigned)(int)rintf(a * 512.f);       // 0..8, RNE; 8 == 2^-6 normal
  } else {
    union { float f; unsigned u; } d; d.f = a;
    unsigned u2 = d.u + 0x7FFFFu + ((d.u >> 20) & 1u);
    n = (((u2 >> 23) - 120u) << 3) | ((u2 >> 20) & 7u);
  }
  return (unsigned char)(s | n);
}
// pack 2 f32 -> 2 e4m3 bytes (byte0 = a, byte1 = b); HW instr on gfx950
DEV unsigned pk_fp8(float a, float b){
#if defined(__has_builtin)
#if __has_builtin(__builtin_amdgcn_cvt_pk_fp8_f32)
  return (unsigned)__builtin_amdgcn_cvt_pk_fp8_f32(a, b, 0, false);
#else
  return (unsigned)f2fp8(a) | ((unsigned)f2fp8(b) << 8);
#endif
#else
  return (unsigned)f2fp8(a) | ((unsigned)f2fp8(b) << 8);
#endif
}
// e4m3 -> f16 bits, exact (software fallback).
DEV unsigned short fp82h(unsigned b){
  union { unsigned short u; _Float16 h; } c;
  c.u = (unsigned short)(((b & 0x80u) << 8) | ((b & 0x7Fu) << 7));
  c.h = c.h * (_Float16)256.0f;
  return c.u;
}
// decode 4 fp8 bytes (one dword, consecutive elements) -> 4 f16 (exact)
DEV void dec4_fp8(unsigned dw, unsigned short r[4]){
#if defined(__has_builtin)
#if __has_builtin(__builtin_amdgcn_cvt_pk_f32_fp8)
  f32x2 lo = __builtin_amdgcn_cvt_pk_f32_fp8((int)dw, false);
  f32x2 hi = __builtin_amdgcn_cvt_pk_f32_fp8((int)dw, true);
  union { fp16x2 h; unsigned short u[2]; } a, b;
  a.h = __builtin_amdgcn_cvt_pkrtz(lo.x, lo.y);   // fp8 values exact in f16 -> RTZ lossless
  b.h = __builtin_amdgcn_cvt_pkrtz(hi.x, hi.y);
  r[0] = a.u[0]; r[1] = a.u[1]; r[2] = b.u[0]; r[3] = b.u[1];
#else
  r[0] = fp82h(dw & 0xFFu); r[1] = fp82h((dw >> 8) & 0xFFu);
  r[2] = fp82h((dw >> 16) & 0xFFu); r[3] = fp82h(dw >> 24);
#endif
#else
  r[0] = fp82h(dw & 0xFFu); r[1] = fp82h((dw >> 8) & 0xFFu);
  r[2] = fp82h((dw >> 16) & 0xFFu); r[3] = fp82h(dw >> 24);
#endif
}

DEV float gelu_f(float x){ return 0.5f * x * (1.f + erff(x * 0.70710678118654752440f)); }

DEV f32x4 mfma16(bf16x8 a, bf16x8 b, f32x4 c){
  return __builtin_amdgcn_mfma_f32_16x16x32_bf16(a, b, c, 0, 0, 0);
}
DEV f32x4 mfma16h(f16x8 a, f16x8 b, f32x4 c){
  return __builtin_amdgcn_mfma_f32_16x16x32_f16(a, b, c, 0, 0, 0);
}

// block_sum: 256 threads (4 waves)
DEV float block_sum(float v, float* red, int tid){
  #pragma unroll
  for (int o = 32; o > 0; o >>= 1) v += __shfl_down(v, o);
  if ((tid & 63) == 0) red[tid >> 6] = v;
  __syncthreads();
  float s = red[0] + red[1] + red[2] + red[3];
  __syncthreads();
  return s;
}

// ---------------- constants ----------------
// B=16 N=64 D=256 CI=256 H=W=64 P=36 HEADS=8 HD=32 HID=1024 TOTAL=66832 T=1024
// cm (n<65536) stored fp8 e4m3, blocked: params8[(n>>6)*65536 + t*64 + (n&63)] bytes
// sm tail (n>=65536) stored f16, blocked: sm16[((n>>6)-1024)*65536 + t*64 + (n&63)]
// hbuf is stored bf16.

// ---------------- kernel 1: per-token prep ----------------
__global__ __launch_bounds__(256) void k_prep(
    const float* __restrict__ embed, const float* __restrict__ roi,
    const float* __restrict__ g_adj, const float* __restrict__ b_adj, const float* __restrict__ w_adj,
    const float* __restrict__ g_off, const float* __restrict__ b_off, const float* __restrict__ w_off,
    const float* __restrict__ off_bias,
    const float* __restrict__ g_pg, const float* __restrict__ b_pg,
    const float* __restrict__ w_pg1, const float* __restrict__ b_pg1,
    float* __restrict__ pts, unsigned short* __restrict__ hbuf)
{
  __shared__ float red[4];
  __shared__ float xln[256];
  __shared__ float offs[72];
  __shared__ float lg[4];
  __shared__ float stat[8];
  const int t = blockIdx.x, tid = threadIdx.x;
  float e = embed[t * 256 + tid];
  float mean = block_sum(e, red, tid) * (1.f / 256.f);
  float dv = e - mean;
  float var = block_sum(dv * dv, red, tid) * (1.f / 256.f);
  xln[tid] = dv * rsqrtf(var + 1e-5f);
  __syncthreads();
  if (tid < 4){
    float a0 = 0.f, a1 = 0.f, a2 = 0.f, a3 = 0.f;
    #pragma unroll 4
    for (int c = 0; c < 256; c += 4){
      a0 += (xln[c+0] * g_adj[c+0] + b_adj[c+0]) * w_adj[(c+0) * 4 + tid];
      a1 += (xln[c+1] * g_adj[c+1] + b_adj[c+1]) * w_adj[(c+1) * 4 + tid];
      a2 += (xln[c+2] * g_adj[c+2] + b_adj[c+2]) * w_adj[(c+2) * 4 + tid];
      a3 += (xln[c+3] * g_adj[c+3] + b_adj[c+3]) * w_adj[(c+3) * 4 + tid];
    }
    lg[tid] = (a0 + a1) + (a2 + a3);
  } else if (tid < 76){
    int j = tid - 4;
    float a0 = 0.f, a1 = 0.f, a2 = 0.f, a3 = 0.f;
    #pragma unroll 4
    for (int c = 0; c < 256; c += 4){
      a0 += (xln[c+0] * g_off[c+0] + b_off[c+0]) * w_off[(c+0) * 72 + j];
      a1 += (xln[c+1] * g_off[c+1] + b_off[c+1]) * w_off[(c+1) * 72 + j];
      a2 += (xln[c+2] * g_off[c+2] + b_off[c+2]) * w_off[(c+2) * 72 + j];
      a3 += (xln[c+3] * g_off[c+3] + b_off[c+3]) * w_off[(c+3) * 72 + j];
    }
    offs[j] = (a0 + a1) + (a2 + a3) + off_bias[j];
  } else if (tid < 140){
    int j = tid - 76;
    float a0 = 0.f, a1 = 0.f, a2 = 0.f, a3 = 0.f;
    #pragma unroll 4
    for (int c = 0; c < 256; c += 4){
      a0 += (xln[c+0] * g_pg[c+0] + b_pg[c+0]) * w_pg1[(c+0) * 64 + j];
      a1 += (xln[c+1] * g_pg[c+1] + b_pg[c+1]) * w_pg1[(c+1) * 64 + j];
      a2 += (xln[c+2] * g_pg[c+2] + b_pg[c+2]) * w_pg1[(c+2) * 64 + j];
      a3 += (xln[c+3] * g_pg[c+3] + b_pg[c+3]) * w_pg1[(c+3) * 64 + j];
    }
    hbuf[t * 64 + j] = f2bf((a0 + a1) + (a2 + a3) + b_pg1[j]);
  }
  __syncthreads();
  if (tid == 0){
    float x0 = roi[t*4+0], y0 = roi[t*4+1], x1 = roi[t*4+2], y1 = roi[t*4+3];
    float cx = (x0 + x1) * 0.5f, cy = (y0 + y1) * 0.5f;
    float w = fabsf(x1 - x0), hh = fabsf(y1 - y0);
    cx += lg[0] * w; cy += lg[1] * hh;
    w *= expf(lg[2]); hh *= expf(lg[3]);
    stat[0] = cx; stat[1] = cy; stat[2] = w; stat[3] = hh;
  }
  if (tid < 2){
    float mu = 0.f;
    for (int p = 0; p < 36; ++p) mu += offs[p*2 + tid];
    mu *= (1.f / 36.f);
    float v2 = 0.f;
    for (int p = 0; p < 36; ++p){ float d = offs[p*2 + tid] - mu; v2 += d * d; }
    float sd = sqrtf(v2 * (1.f / 35.f)) + 1e-7f;   // ddof=1
    stat[4 + tid] = mu; stat[6 + tid] = 1.f / (3.f * sd);
  }
  __syncthreads();
  if (tid < 72){
    int c = tid & 1;
    pts[t * 72 + tid] = stat[c] + (offs[tid] - stat[4 + c]) * stat[6 + c] * stat[2 + c];
  }
}

// ---------------- kernel 2: img [B,C,H,W] f32 -> [B,H,W,C] bf16 ----------------
__global__ __launch_bounds__(256) void k_transpose(const float* __restrict__ img,
                                                   unsigned short* __restrict__ imgT)
{
  __shared__ float tile[128][65];
  const int blk = blockIdx.x, tid = threadIdx.x;
  const int b = blk >> 6, y = blk & 63;
  for (int half = 0; half < 2; ++half){
    int c_loc = tid >> 1, x0 = (tid & 1) * 32;
    const float* src = img + (((size_t)(b * 256 + half * 128 + c_loc)) * 64 + y) * 64 + x0;
    #pragma unroll
    for (int i = 0; i < 32; ++i) tile[c_loc][x0 + i] = src[i];
    __syncthreads();
    {
      int x = tid >> 2, c0 = (tid & 3) * 32;
      size_t obase = (((size_t)(b * 64 + y)) * 64 + x) * 256 + half * 128 + c0;
      #pragma unroll
      for (int cb = 0; cb < 32; cb += 8){
        unsigned short tmp[8];
        #pragma unroll
        for (int j = 0; j < 8; ++j) tmp[j] = f2bf(tile[c0 + cb + j][x]);
        *(bf16x8*)(imgT + obase + cb) = *(const bf16x8*)tmp;
      }
    }
    __syncthreads();
  }
}

// ---------------- kernel 3: bilinear sample -> sampled [T,36,256] f16 ----------------
__global__ __launch_bounds__(256) void k_sample(const unsigned short* __restrict__ imgT,
                                                const float* __restrict__ pts,
                                                unsigned short* __restrict__ sampled)
{
  __shared__ float lpts[72];
  const int t = blockIdx.x, tid = threadIdx.x;
  const int b = t >> 6;
  if (tid < 72) lpts[tid] = pts[t * 72 + tid];
  __syncthreads();
  for (int p = 0; p < 36; ++p){
    float fx = lpts[p*2]   * 64.f - 0.5f;
    float fy = lpts[p*2+1] * 64.f - 0.5f;
    float x0f = floorf(fx), y0f = floorf(fy);
    float wx = fx - x0f, wy = fy - y0f;
    int x0 = (int)x0f, y0 = (int)y0f;
    float acc = 0.f;
    #pragma unroll
    for (int dy = 0; dy < 2; ++dy){
      #pragma unroll
      for (int dx = 0; dx < 2; ++dx){
        int xi = x0 + dx, yi = y0 + dy;
        bool valid = (xi >= 0) & (xi < 64) & (yi >= 0) & (yi < 64);
        int xc = min(max(xi, 0), 63), yc = min(max(yi, 0), 63);
        float w = (dx ? wx : 1.f - wx) * (dy ? wy : 1.f - wy);
        float v = bf2f(imgT[(((size_t)(b * 64 + yc)) * 64 + xc) * 256 + tid]);
        acc += v * (valid ? w : 0.f);
      }
    }
    sampled[(size_t)t * 9216 + p * 256 + tid] = f2h(acc);
  }
}

// ---------------- kernel 4: params = h @ pg_w2 + pg_b2 (M=1024,K=64,N=66832)
// cm chunks (nc<1024) -> fp8 e4m3 via HW cvt_pk; sm tail (nc>=1024) -> f16.
__global__ __launch_bounds__(256) void k_params(
    const unsigned short* __restrict__ hbuf, const float* __restrict__ w2,
    const float* __restrict__ b2, unsigned char* __restrict__ params8,
    unsigned short* __restrict__ sm16)
{
  __shared__ __align__(16) unsigned short Bs[64][72];  // [n][k^swz]
  __shared__ __align__(16) unsigned short As[64][72];  // [m][k]
  __shared__ __align__(16) unsigned short Os[64][72];  // f16 staging (sm path)
  __shared__ __align__(16) unsigned char  Os8[64][72]; // fp8 staging (cm path)
  const int tid = threadIdx.x, lane = tid & 63, wave = tid >> 6;
  const int wm = wave >> 1, wn = wave & 1;
  const int nc = blockIdx.x, n0 = nc * 64;
  const bool cm = (nc < 1024);
  {
    int k = tid >> 2, nb = (tid & 3) * 16;
    #pragma unroll
    for (int i = 0; i < 16; ++i){
      int n = nb + i, gn = n0 + n;
      float v = (gn < 66832) ? w2[(size_t)k * 66832 + gn] : 0.f;
      Bs[n][k ^ (((n >> 3) & 7) << 3)] = f2bf(v);
    }
  }
  float bv[2];
  #pragma unroll
  for (int j = 0; j < 2; ++j){
    int col = n0 + wn*32 + j*16 + (lane & 15);
    bv[j] = (col < 66832) ? b2[col] : 0.f;
  }
  __syncthreads();
  for (int mt = 0; mt < 16; ++mt){
    int m0 = mt * 64;
    { int m = tid >> 2, kb4 = (tid & 3) * 16;
      const unsigned short* hp = hbuf + (m0 + m) * 64 + kb4;
      *(bf16x8*)&As[m][kb4]     = *(const bf16x8*)hp;
      *(bf16x8*)&As[m][kb4 + 8] = *(const bf16x8*)(hp + 8);
    }
    __syncthreads();
    f32x4 acc[2][2] = {};
    #pragma unroll
    for (int ks = 0; ks < 2; ++ks){
      int kb = ks * 32 + (lane >> 4) * 8;
      bf16x8 a[2], bb[2];
      #pragma unroll
      for (int i = 0; i < 2; ++i) a[i] = *(const bf16x8*)&As[wm*32 + i*16 + (lane & 15)][kb];
      #pragma unroll
      for (int j = 0; j < 2; ++j){
        int n = wn*32 + j*16 + (lane & 15);
        bb[j] = *(const bf16x8*)&Bs[n][kb ^ (((n >> 3) & 7) << 3)];
      }
      #pragma unroll
      for (int i = 0; i < 2; ++i)
        #pragma unroll
        for (int j = 0; j < 2; ++j) acc[i][j] = mfma16(a[i], bb[j], acc[i][j]);
    }
    if (cm){
      #pragma unroll
      for (int i = 0; i < 2; ++i)
        #pragma unroll
        for (int j = 0; j < 2; ++j){
          int cl = wn*32 + j*16 + (lane & 15);
          int rl = wm*32 + i*16 + (lane >> 4) * 4;
          unsigned p01 = pk_fp8(acc[i][j][0] + bv[j], acc[i][j][1] + bv[j]);
          unsigned p23 = pk_fp8(acc[i][j][2] + bv[j], acc[i][j][3] + bv[j]);
          Os8[rl + 0][cl] = (unsigned char)(p01 & 0xFFu);
          Os8[rl + 1][cl] = (unsigned char)((p01 >> 8) & 0xFFu);
          Os8[rl + 2][cl] = (unsigned char)(p23 & 0xFFu);
          Os8[rl + 3][cl] = (unsigned char)((p23 >> 8) & 0xFFu);
        }
      __syncthreads();
      {
        int rl = tid >> 2, c0 = (tid & 3) * 16;
        uint2 lo = *(const uint2*)&Os8[rl][c0];
        uint2 hi = *(const uint2*)&Os8[rl][c0 + 8];
        uint4 val; val.x = lo.x; val.y = lo.y; val.z = hi.x; val.w = hi.y;
        *(uint4*)(params8 + ((size_t)nc * 1024 + m0 + rl) * 64 + c0) = val;
      }
    } else {
      #pragma unroll
      for (int i = 0; i < 2; ++i)
        #pragma unroll
        for (int j = 0; j < 2; ++j){
          int cl = wn*32 + j*16 + (lane & 15);
          #pragma unroll
          for (int r = 0; r < 4; ++r){
            int rl = wm*32 + i*16 + (lane >> 4) * 4 + r;
            Os[rl][cl] = f2h(acc[i][j][r] + bv[j]);
          }
        }
      __syncthreads();
      {
        int rl = tid >> 2, c0 = (tid & 3) * 16;
        size_t gbase = ((size_t)(nc - 1024) * 1024 + m0 + rl) * 64 + c0;
        *(bf16x8*)(sm16 + gbase)     = *(const bf16x8*)&Os[rl][c0];
        *(bf16x8*)(sm16 + gbase + 8) = *(const bf16x8*)&Os[rl][c0 + 8];
      }
    }
    __syncthreads();
  }
}

// ---------------- kernel 5: per-token adaptive mixing (fp8 cm, f16 pipeline) ----
__global__ __launch_bounds__(256) void k_mixtoken(
    const unsigned short* __restrict__ sampled,   // f16
    const unsigned char*  __restrict__ params8,   // fp8 cm
    const unsigned short* __restrict__ sm16,      // f16 sm tail
    const float* __restrict__ m_beta, const float* __restrict__ s_beta,
    unsigned short* __restrict__ out2)            // bf16
{
  __shared__ __align__(16) unsigned short smem[29984];
  const int t = blockIdx.x, tid = threadIdx.x, lane = tid & 63, wave = tid >> 6;
  const int l15 = lane & 15, kb = (lane >> 4) * 8;
  unsigned short (*Ss)[264] = (unsigned short (*)[264])smem;
  const int c31  = tid & 31;
  const int g    = tid >> 5;
  const int goff = (g & 1) * 32;
  const int colw = c31 ^ ((g & 3) << 3);
  const unsigned char* ptok8 = params8 + (size_t)t * 64;
  uint4 rv8[2];
  {
    const unsigned char* src = ptok8 + ((size_t)(c31 * 4 + (g >> 1)) << 16) + goff;
    rv8[0] = *(const uint4*)src;
    rv8[1] = *(const uint4*)(src + 16);
  }
  unsigned short rSm[14];
  #pragma unroll
  for (int k = 0; k < 14; ++k){
    int idx = tid + k * 256;
    unsigned short v = 0;
    if (idx < 3456){
      int o = idx / 72, p = idx % 72;
      if (o < 36 && p < 36){
        int n = 65536 + o * 36 + p;
        v = sm16[(size_t)((n >> 6) - 1024) * 65536 + (size_t)t * 64 + (n & 63)];
      }
    }
    rSm[k] = v;
  }
  const unsigned short* sp = sampled + (size_t)t * 9216;
  #pragma unroll
  for (int it = 0; it < 5; ++it){
    int slot = it * 256 + tid;
    if (slot < 1152){
      int p = slot >> 5, c8 = (slot & 31) << 3;
      *(bf16x8*)&Ss[p][c8] = *(const bf16x8*)(sp + p * 256 + c8);
    }
  }
  __syncthreads();
  f32x4 acc[3][4] = {};
  int cur = 0;
  for (int cc = 0; cc < 8; ++cc){
    unsigned short (*C)[40] = (unsigned short (*)[40])(smem + 9504 + cur * 10240);
    #pragma unroll
    for (int v = 0; v < 2; ++v){
      #pragma unroll
      for (int w = 0; w < 4; ++w){
        unsigned dw = ((const unsigned*)&rv8[v])[w];
        int d0 = g * 32 + v * 16 + w * 4;
        unsigned short r[4];
        dec4_fp8(dw, r);
        C[d0 + 0][colw] = r[0];
        C[d0 + 1][colw] = r[1];
        C[d0 + 2][colw] = r[2];
        C[d0 + 3][colw] = r[3];
      }
    }
    __syncthreads();   // C[cur] ready
    if (cc < 7){
      const unsigned char* src = ptok8 + ((size_t)((cc + 1) * 128 + c31 * 4 + (g >> 1)) << 16) + goff;
      rv8[0] = *(const uint4*)src;
      rv8[1] = *(const uint4*)(src + 16);
    }
    f16x8 a[3], bfr[4];
    a[0] = *(const f16x8*)&Ss[l15][cc * 32 + kb];
    a[1] = *(const f16x8*)&Ss[16 + l15][cc * 32 + kb];
    a[2] = f16x8{};
    if (l15 < 4) a[2] = *(const f16x8*)&Ss[32 + l15][cc * 32 + kb];
    #pragma unroll
    for (int j = 0; j < 4; ++j){
      int d = wave * 64 + j * 16 + l15;
      bfr[j] = *(const f16x8*)&C[d][kb ^ (((d >> 5) & 3) << 3)];
    }
    #pragma unroll
    for (int i = 0; i < 3; ++i)
      #pragma unroll
      for (int j = 0; j < 4; ++j) acc[i][j] = mfma16h(a[i], bfr[j], acc[i][j]);
    cur ^= 1;
  }
  __syncthreads();
  {
    const bf16x8 z = {};
    #pragma unroll
    for (int i = 0; i < 9; ++i)
      *(bf16x8*)&smem[(i * 256 + tid) * 8] = z;
    #pragma unroll
    for (int k = 0; k < 14; ++k){
      int idx = tid + k * 256;
      if (idx < 3456) smem[18432 + idx] = rSm[k];
    }
  }
  __syncthreads();
  unsigned short (*O1T)[72] = (unsigned short (*)[72])smem;
  unsigned short (*Sm)[72]  = (unsigned short (*)[72])(smem + 18432);
  #pragma unroll
  for (int i = 0; i < 3; ++i){
    int p = i * 16 + ((lane >> 4) << 2);
    if (p < 36){
      #pragma unroll
      for (int j = 0; j < 4; ++j){
        int d = wave * 64 + j * 16 + l15;
        float mb = m_beta[d];
        unsigned short* dst = &O1T[d][p];
        #pragma unroll
        for (int r = 0; r < 4; ++r) dst[r] = f2h(gelu_f(acc[i][j][r] + mb));
      }
    }
  }
  __syncthreads();
  f32x4 acc2[3][4] = {};
  #pragma unroll
  for (int ks = 0; ks < 2; ++ks){
    int kb2 = ks * 32 + (lane >> 4) * 8;
    f16x8 a2[3], bf2[4];
    #pragma unroll
    for (int i = 0; i < 3; ++i) a2[i] = *(const f16x8*)&Sm[i*16 + l15][kb2];
    #pragma unroll
    for (int j = 0; j < 4; ++j) bf2[j] = *(const f16x8*)&O1T[wave*64 + j*16 + l15][kb2];
    #pragma unroll
    for (int i = 0; i < 3; ++i)
      #pragma unroll
      for (int j = 0; j < 4; ++j) acc2[i][j] = mfma16h(a2[i], bf2[j], acc2[i][j]);
  }
  unsigned short* o2 = out2 + (size_t)t * 9216;
  #pragma unroll
  for (int i = 0; i < 3; ++i){
    int ob = i*16 + ((lane >> 4) << 2);
    #pragma unroll
    for (int j = 0; j < 4; ++j){
      int d = wave*64 + j*16 + l15;
      #pragma unroll
      for (int r = 0; r < 4; ++r){
        int o = ob + r;
        if (o < 36) o2[o * 256 + d] = f2bf(gelu_f(acc2[i][j][r] + s_beta[o]));
      }
    }
  }
}

// ---------------- generic GEMM: C = act(A @ W + bias) (+resid) ----------------
template<int AK, int ACT, int RES, int OUTB>
__global__ __launch_bounds__(256) void k_gemm(
    const void* __restrict__ Ap, const float* __restrict__ W,
    const float* __restrict__ bias, const float* __restrict__ resid,
    void* __restrict__ Cp, int M, int N, int K)
{
  __shared__ __align__(16) unsigned short As[64][40];  // [m][k]
  __shared__ __align__(16) unsigned short Bs[64][40];  // [n][k^swz]
  const int tid = threadIdx.x, lane = tid & 63, wave = tid >> 6;
  const int wm = wave >> 1, wn = wave & 1;
  const int n0 = blockIdx.x * 64, m0 = blockIdx.y * 64;
  f32x4 acc[2][2] = {};
  for (int kk = 0; kk < K; kk += 32){
    { int m = tid >> 2, k4 = (tid & 3) * 8;
      if (AK == 0){
        const float* ap = (const float*)Ap + (size_t)(m0 + m) * K + kk + k4;
        #pragma unroll
        for (int i = 0; i < 8; ++i) As[m][k4 + i] = f2bf(ap[i]);
      } else {
        const unsigned short* ap = (const unsigned short*)Ap + (size_t)(m0 + m) * K + kk + k4;
        *(bf16x8*)&As[m][k4] = *(const bf16x8*)ap;
      }
    }
    { int kq = tid >> 3, n8 = (tid & 7) * 8;
      const float* wp = W + (size_t)(kk + kq) * N + n0 + n8;
      #pragma unroll
      for (int i = 0; i < 8; ++i){
        int n = n8 + i;
        Bs[n][kq ^ (((n >> 3) & 3) << 3)] = f2bf(wp[i]);
      }
    }
    __syncthreads();
    const int kb = (lane >> 4) * 8;
    bf16x8 a[2], bfr[2];
    #pragma unroll
    for (int i = 0; i < 2; ++i) a[i] = *(const bf16x8*)&As[wm*32 + i*16 + (lane & 15)][kb];
    #pragma unroll
    for (int j = 0; j < 2; ++j){
      int n = wn*32 + j*16 + (lane & 15);
      bfr[j] = *(const bf16x8*)&Bs[n][kb ^ (((n >> 3) & 3) << 3)];
    }
    #pragma unroll
    for (int i = 0; i < 2; ++i)
      #pragma unroll
      for (int j = 0; j < 2; ++j) acc[i][j] = mfma16(a[i], bfr[j], acc[i][j]);
    __syncthreads();
  }
  #pragma unroll
  for (int i = 0; i < 2; ++i)
    #pragma unroll
    for (int j = 0; j < 2; ++j){
      int col = n0 + wn*32 + j*16 + (lane & 15);
      float bv = bias[col];
      #pragma unroll
      for (int r = 0; r < 4; ++r){
        int row = m0 + wm*32 + i*16 + (lane >> 4) * 4 + r;
        float v = acc[i][j][r] + bv;
        if (ACT == 1) v = gelu_f(v);
        if (RES) v += resid[(size_t)row * N + col];
        if (OUTB) ((unsigned short*)Cp)[(size_t)row * N + col] = f2bf(v);
        else      ((float*)Cp)[(size_t)row * N + col] = v;
      }
    }
}

// ---------------- split-K GEMM: part[z][M][N] = A[:, z*KS:(z+1)*KS] @ W[z*KS:...] ----
template<int AK>
__global__ __launch_bounds__(256) void k_gemm_sk(
    const void* __restrict__ Ap, const float* __restrict__ W,
    float* __restrict__ part, int M, int N, int K, int KS)
{
  __shared__ __align__(16) unsigned short As[64][40];  // [m][k]
  __shared__ __align__(16) unsigned short Bs[64][40];  // [n][k^swz]
  const int tid = threadIdx.x, lane = tid & 63, wave = tid >> 6;
  const int wm = wave >> 1, wn = wave & 1;
  const int n0 = blockIdx.x * 64, m0 = blockIdx.y * 64;
  const int kbase = blockIdx.z * KS;
  f32x4 acc[2][2] = {};
  for (int kq = 0; kq < KS; kq += 32){
    int kk = kbase + kq;
    { int m = tid >> 2, k4 = (tid & 3) * 8;
      if (AK == 0){
        const float* ap = (const float*)Ap + (size_t)(m0 + m) * K + kk + k4;
        #pragma unroll
        for (int i = 0; i < 8; ++i) As[m][k4 + i] = f2bf(ap[i]);
      } else {
        const unsigned short* ap = (const unsigned short*)Ap + (size_t)(m0 + m) * K + kk + k4;
        *(bf16x8*)&As[m][k4] = *(const bf16x8*)ap;
      }
    }
    { int kr = tid >> 3, n8 = (tid & 7) * 8;
      const float* wp = W + (size_t)(kk + kr) * N + n0 + n8;
      #pragma unroll
      for (int i = 0; i < 8; ++i){
        int n = n8 + i;
        Bs[n][kr ^ (((n >> 3) & 3) << 3)] = f2bf(wp[i]);
      }
    }
    __syncthreads();
    const int kb = (lane >> 4) * 8;
    bf16x8 a[2], bfr[2];
    #pragma unroll
    for (int i = 0; i < 2; ++i) a[i] = *(const bf16x8*)&As[wm*32 + i*16 + (lane & 15)][kb];
    #pragma unroll
    for (int j = 0; j < 2; ++j){
      int n = wn*32 + j*16 + (lane & 15);
      bfr[j] = *(const bf16x8*)&Bs[n][kb ^ (((n >> 3) & 3) << 3)];
    }
    #pragma unroll
    for (int i = 0; i < 2; ++i)
      #pragma unroll
      for (int j = 0; j < 2; ++j) acc[i][j] = mfma16(a[i], bfr[j], acc[i][j]);
    __syncthreads();
  }
  float* pz = part + (size_t)blockIdx.z * M * N;
  #pragma unroll
  for (int i = 0; i < 2; ++i)
    #pragma unroll
    for (int j = 0; j < 2; ++j){
      int col = n0 + wn*32 + j*16 + (lane & 15);
      #pragma unroll
      for (int r = 0; r < 4; ++r){
        int row = m0 + wm*32 + i*16 + (lane >> 4) * 4 + r;
        pz[(size_t)row * N + col] = acc[i][j][r];
      }
    }
}

// ---------------- split-K reduce: out = sum_z part[z] + bias (+resid) ----------------
template<int RES>
__global__ __launch_bounds__(256) void k_reduce(
    const float* __restrict__ part, const float* __restrict__ bias,
    const float* __restrict__ resid, float* __restrict__ out,
    int total, int N, int SK)
{
  int i = blockIdx.x * 256 + threadIdx.x;
  if (i >= total) return;
  float s = 0.f;
  for (int z = 0; z < SK; ++z) s += part[(size_t)z * total + i];
  s += bias[i % N];
  if (RES) s += resid[i];
  out[i] = s;
}

// ---------------- fused split-K reduce + residual + LayerNorm ----------------
__global__ __launch_bounds__(256) void k_reduce_ln(
    const float* __restrict__ part, const float* __restrict__ bias,
    const float* __restrict__ resid,
    const float* __restrict__ g, const float* __restrict__ bb,
    float* __restrict__ emb_out, unsigned short* __restrict__ ln_out, int SK)
{
  __shared__ float red[4];
  const int t = blockIdx.x, tid = threadIdx.x;
  const int i = t * 256 + tid;
  float s = 0.f;
  for (int z = 0; z < SK; ++z) s += part[(size_t)z * 262144 + i];
  s += bias[tid] + resid[i];
  emb_out[i] = s;
  float mean = block_sum(s, red, tid) * (1.f / 256.f);
  float d = s - mean;
  float var = block_sum(d * d, red, tid) * (1.f / 256.f);
  ln_out[i] = f2bf(d * rsqrtf(var + 1e-5f) * g[tid] + bb[tid]);
}

// ---------------- attention: one (b,h) per block ----------------
__global__ __launch_bounds__(64) void k_attn(const float* __restrict__ qkv,
                                             float* __restrict__ attno)
{
  __shared__ float qs[64][33], ksm[64][33], vsm[64][33];
  const int blk = blockIdx.x, lane = threadIdx.x;
  const int b = blk >> 3, h = blk & 7;
  for (int idx = lane; idx < 2048; idx += 64){
    int row = idx >> 5, d = idx & 31;
    const float* base = qkv + (size_t)(b * 64 + row) * 768 + h * 32 + d;
    qs[row][d] = base[0]; ksm[row][d] = base[256]; vsm[row][d] = base[512];
  }
  __syncthreads();
  float qr[32];
  #pragma unroll
  for (int d = 0; d < 32; ++d) qr[d] = qs[lane][d];
  float s[64]; float mx = -1e30f;
  for (int m = 0; m < 64; ++m){
    float dot = 0.f;
    #pragma unroll
    for (int d = 0; d < 32; ++d) dot += qr[d] * ksm[m][d];
    dot *= 0.17677669529663687f;  // 32^-0.5
    s[m] = dot; mx = fmaxf(mx, dot);
  }
  float sum = 0.f;
  for (int m = 0; m < 64; ++m){ s[m] = expf(s[m] - mx); sum += s[m]; }
  float inv = 1.f / sum;
  float o[32] = {};
  for (int m = 0; m < 64; ++m){
    float p = s[m] * inv;
    #pragma unroll
    for (int d = 0; d < 32; ++d) o[d] += p * vsm[m][d];
  }
  float* dst = attno + (size_t)(b * 64 + lane) * 256 + h * 32;
  #pragma unroll
  for (int d = 0; d < 32; ++d) dst[d] = o[d];
}

__global__ void k_fill(float* p, int n, float v){
  int i = blockIdx.x * 256 + threadIdx.x;
  if (i < n) p[i] = v;
}

// ---------------- launch ----------------
extern "C" void kernel_launch(void* const* d_in, const int* in_sizes, int n_in,
                              void* d_out, int out_size, void* d_ws, size_t ws_size,
                              hipStream_t stream)
{
  const float* img      = (const float*)d_in[0];
  const float* embed    = (const float*)d_in[1];
  const float* roi      = (const float*)d_in[2];
  const float* ln_adj_g = (const float*)d_in[3];
  const float* ln_adj_b = (const float*)d_in[4];
  const float* w_adj    = (const float*)d_in[5];
  const float* ln_off_g = (const float*)d_in[6];
  const float* ln_off_b = (const float*)d_in[7];
  const float* w_off    = (const float*)d_in[8];
  const float* off_bias = (const float*)d_in[9];
  const float* pg_ln_g  = (const float*)d_in[10];
  const float* pg_ln_b  = (const float*)d_in[11];
  const float* pg_w1    = (const float*)d_in[12];
  const float* pg_b1    = (const float*)d_in[13];
  const float* pg_w2    = (const float*)d_in[14];
  const float* pg_b2    = (const float*)d_in[15];
  const float* m_beta   = (const float*)d_in[16];
  const float* s_beta   = (const float*)d_in[17];
  const float* mix_w    = (const float*)d_in[18];
  const float* mix_b    = (const float*)d_in[19];
  const float* ln1_g    = (const float*)d_in[20];
  const float* ln1_b    = (const float*)d_in[21];
  const float* qkv_w    = (const float*)d_in[22];
  const float* qkv_b    = (const float*)d_in[23];
  const float* proj_w   = (const float*)d_in[24];
  const float* proj_b   = (const float*)d_in[25];
  const float* ln2_g    = (const float*)d_in[26];
  const float* ln2_b    = (const float*)d_in[27];
  const float* fc1_w    = (const float*)d_in[28];
  const float* fc1_b    = (const float*)d_in[29];
  const float* fc2_w    = (const float*)d_in[30];
  const float* fc2_b    = (const float*)d_in[31];

  char* ws = (char*)d_ws;
  float*          pts     = (float*)         (ws + 0);          //   294912
  unsigned short* hbuf    = (unsigned short*)(ws + 294912);     //   131072 (bf16)
  unsigned short* imgT    = (unsigned short*)(ws + 557056);     // 33554432
  unsigned short* sampled = (unsigned short*)(ws + 34111488);   // 18874368 (f16)
  unsigned char*  params8 = (unsigned char*) (ws + 52985856);   // 67108864 (fp8 cm)
  unsigned short* sm16    = (unsigned short*)(ws + 120094720);  //  2752512 (f16 sm)
  unsigned short* out2    = (unsigned short*)(ws + 122847232);  // 18874368 (bf16)
  float*          embed1  = (float*)         (ws + 141721600);  //  1048576
  float*          embed2  = (float*)         (ws + 142770176);  //  1048576
  unsigned short* xln1    = (unsigned short*)(ws + 143818752);  //   524288
  unsigned short* xln2    = (unsigned short*)(ws + 144343040);  //   524288
  float*          qkvb    = (float*)         (ws + 144867328);  //  3145728
  float*          attno   = (float*)         (ws + 148013056);  //  1048576
  // aliased into the params8 region (dead after k_mixtoken):
  float*          part_mix  = (float*)(ws + 52985856);             // 16 MB (16 slabs)
  float*          part_smll = (float*)(ws + 52985856 + 16777216);  //  4 MB (4 slabs)
  unsigned short* h1        = (unsigned short*)(ws + 52985856 + 20971520); // 2 MB
  const size_t WS_NEEDED = 149061632;
  if (ws_size < WS_NEEDED){
    k_fill<<<(out_size + 255) / 256, 256, 0, stream>>>((float*)d_out, out_size, 12345.0f);
    return;
  }

  float* out = (float*)d_out;

  k_prep<<<1024, 256, 0, stream>>>(embed, roi, ln_adj_g, ln_adj_b, w_adj,
                                   ln_off_g, ln_off_b, w_off, off_bias,
                                   pg_ln_g, pg_ln_b, pg_w1, pg_b1, pts, hbuf);
  k_transpose<<<1024, 256, 0, stream>>>(img, imgT);
  k_sample<<<1024, 256, 0, stream>>>(imgT, pts, sampled);
  k_params<<<1045, 256, 0, stream>>>(hbuf, pg_w2, pg_b2, params8, sm16);
  k_mixtoken<<<1024, 256, 0, stream>>>(sampled, params8, sm16, m_beta, s_beta, out2);
  // embed1 = embed + out2 @ mix_w + mix_b   (split-K: 9216 = 16 x 576), fused LN1
  k_gemm_sk<1><<<dim3(4,16,16), 256, 0, stream>>>(out2, mix_w, part_mix, 1024, 256, 9216, 576);
  k_reduce_ln<<<1024, 256, 0, stream>>>(part_mix, mix_b, embed, ln1_g, ln1_b, embed1, xln1, 16);
  k_gemm<1,0,0,0><<<dim3(12,16), 256, 0, stream>>>(xln1, qkv_w, qkv_b, nullptr, qkvb, 1024, 768, 256);
  k_attn<<<128, 64, 0, stream>>>(qkvb, attno);
  // embed2 = embed1 + attno @ proj_w + proj_b (split-K: 256 = 4 x 64), fused LN2
  k_gemm_sk<0><<<dim3(4,16,4), 256, 0, stream>>>(attno, proj_w, part_smll, 1024, 256, 256, 64);
  k_reduce_ln<<<1024, 256, 0, stream>>>(part_smll, proj_b, embed1, ln2_g, ln2_b, embed2, xln2, 4);
  k_gemm<1,1,0,1><<<dim3(16,16), 256, 0, stream>>>(xln2, fc1_w, fc1_b, nullptr, h1, 1024, 1024, 256);
  // out = embed2 + h1 @ fc2_w + fc2_b   (split-K: 1024 = 4 x 256)
  k_gemm_sk<1><<<dim3(4,16,4), 256, 0, stream>>>(h1, fc2_w, part_smll, 1024, 256, 1024, 256);
  k_reduce<1><<<1024, 256, 0, stream>>>(part_smll, fc2_b, embed2, out, 262144, 256, 4);
}

// Round 14
// 246.892 us; speedup vs baseline: 1.7119x; 1.0267x over previous
//
#include <hip/hip_runtime.h>
#include <cstdint>

#define DEV __device__ __forceinline__

typedef __attribute__((ext_vector_type(8))) short bf16x8;
typedef __attribute__((ext_vector_type(8))) _Float16 f16x8;
typedef __attribute__((ext_vector_type(2))) __fp16 fp16x2;
typedef __attribute__((ext_vector_type(2))) float f32x2;
typedef __attribute__((ext_vector_type(4))) float f32x4;

DEV unsigned short f2bf(float x){
  union { float f; unsigned u; } c; c.f = x;
  unsigned r = c.u + 0x7fffu + ((c.u >> 16) & 1u);
  return (unsigned short)(r >> 16);
}
DEV float bf2f(unsigned short h){
  union { unsigned u; float f; } c; c.u = ((unsigned)h) << 16;
  return c.f;
}
DEV unsigned short f2h(float x){
  union { unsigned short u; _Float16 h; } c;
  c.h = (_Float16)x;
  return c.u;
}
// f32 -> e4m3 (OCP), RNE, saturate to +-448. Software fallback path.
DEV unsigned char f2fp8(float x){
  union { float f; unsigned u; } c; c.f = x;
  unsigned s = (c.u >> 24) & 0x80u;
  float a = fabsf(x);
  a = fminf(a, 448.f);
  unsigned n;
  if (a < 0.015625f){
    n = (unsigned)(int)rintf(a * 512.f);       // 0..8, RNE; 8 == 2^-6 normal
  } else {
    union { float f; unsigned u; } d; d.f = a;
    unsigned u2 = d.u + 0x7FFFFu + ((d.u >> 20) & 1u);
    n = (((u2 >> 23) - 120u) << 3) | ((u2 >> 20) & 7u);
  }
  return (unsigned char)(s | n);
}
// pack 2 f32 -> 2 e4m3 bytes (byte0 = a, byte1 = b); HW instr on gfx950
DEV unsigned pk_fp8(float a, float b){
#if defined(__has_builtin)
#if __has_builtin(__builtin_amdgcn_cvt_pk_fp8_f32)
  return (unsigned)__builtin_amdgcn_cvt_pk_fp8_f32(a, b, 0, false);
#else
  return (unsigned)f2fp8(a) | ((unsigned)f2fp8(b) << 8);
#endif
#else
  return (unsigned)f2fp8(a) | ((unsigned)f2fp8(b) << 8);
#endif
}
// e4m3 -> f16 bits, exact (software fallback).
DEV unsigned short fp82h(unsigned b){
  union { unsigned short u; _Float16 h; } c;
  c.u = (unsigned short)(((b & 0x80u) << 8) | ((b & 0x7Fu) << 7));
  c.h = c.h * (_Float16)256.0f;
  return c.u;
}
// decode 4 fp8 bytes (one dword, consecutive elements) -> 4 f16 (exact)
DEV void dec4_fp8(unsigned dw, unsigned short r[4]){
#if defined(__has_builtin)
#if __has_builtin(__builtin_amdgcn_cvt_pk_f32_fp8)
  f32x2 lo = __builtin_amdgcn_cvt_pk_f32_fp8((int)dw, false);
  f32x2 hi = __builtin_amdgcn_cvt_pk_f32_fp8((int)dw, true);
  union { fp16x2 h; unsigned short u[2]; } a, b;
  a.h = __builtin_amdgcn_cvt_pkrtz(lo.x, lo.y);   // fp8 values exact in f16 -> RTZ lossless
  b.h = __builtin_amdgcn_cvt_pkrtz(hi.x, hi.y);
  r[0] = a.u[0]; r[1] = a.u[1]; r[2] = b.u[0]; r[3] = b.u[1];
#else
  r[0] = fp82h(dw & 0xFFu); r[1] = fp82h((dw >> 8) & 0xFFu);
  r[2] = fp82h((dw >> 16) & 0xFFu); r[3] = fp82h(dw >> 24);
#endif
#else
  r[0] = fp82h(dw & 0xFFu); r[1] = fp82h((dw >> 8) & 0xFFu);
  r[2] = fp82h((dw >> 16) & 0xFFu); r[3] = fp82h(dw >> 24);
#endif
}

DEV float gelu_f(float x){ return 0.5f * x * (1.f + erff(x * 0.70710678118654752440f)); }

DEV f32x4 mfma16(bf16x8 a, bf16x8 b, f32x4 c){
  return __builtin_amdgcn_mfma_f32_16x16x32_bf16(a, b, c, 0, 0, 0);
}
DEV f32x4 mfma16h(f16x8 a, f16x8 b, f32x4 c){
  return __builtin_amdgcn_mfma_f32_16x16x32_f16(a, b, c, 0, 0, 0);
}

// block_sum: 256 threads (4 waves)
DEV float block_sum(float v, float* red, int tid){
  #pragma unroll
  for (int o = 32; o > 0; o >>= 1) v += __shfl_down(v, o);
  if ((tid & 63) == 0) red[tid >> 6] = v;
  __syncthreads();
  float s = red[0] + red[1] + red[2] + red[3];
  __syncthreads();
  return s;
}

// ---------------- constants ----------------
// B=16 N=64 D=256 CI=256 H=W=64 P=36 HEADS=8 HD=32 HID=1024 TOTAL=66832 T=1024
// cm (n<65536) stored fp8 e4m3, blocked: params8[(n>>6)*65536 + t*64 + (n&63)] bytes
// sm tail (n>=65536) stored f16, blocked: sm16[((n>>6)-1024)*65536 + t*64 + (n&63)]
// hbuf is stored bf16. k_sample is fused into k_mixtoken (gathers from imgT).

// ---------------- kernel 1: per-token prep ----------------
__global__ __launch_bounds__(256) void k_prep(
    const float* __restrict__ embed, const float* __restrict__ roi,
    const float* __restrict__ g_adj, const float* __restrict__ b_adj, const float* __restrict__ w_adj,
    const float* __restrict__ g_off, const float* __restrict__ b_off, const float* __restrict__ w_off,
    const float* __restrict__ off_bias,
    const float* __restrict__ g_pg, const float* __restrict__ b_pg,
    const float* __restrict__ w_pg1, const float* __restrict__ b_pg1,
    float* __restrict__ pts, unsigned short* __restrict__ hbuf)
{
  __shared__ float red[4];
  __shared__ float xln[256];
  __shared__ float offs[72];
  __shared__ float lg[4];
  __shared__ float stat[8];
  const int t = blockIdx.x, tid = threadIdx.x;
  float e = embed[t * 256 + tid];
  float mean = block_sum(e, red, tid) * (1.f / 256.f);
  float dv = e - mean;
  float var = block_sum(dv * dv, red, tid) * (1.f / 256.f);
  xln[tid] = dv * rsqrtf(var + 1e-5f);
  __syncthreads();
  if (tid < 4){
    float a0 = 0.f, a1 = 0.f, a2 = 0.f, a3 = 0.f;
    #pragma unroll 4
    for (int c = 0; c < 256; c += 4){
      a0 += (xln[c+0] * g_adj[c+0] + b_adj[c+0]) * w_adj[(c+0) * 4 + tid];
      a1 += (xln[c+1] * g_adj[c+1] + b_adj[c+1]) * w_adj[(c+1) * 4 + tid];
      a2 += (xln[c+2] * g_adj[c+2] + b_adj[c+2]) * w_adj[(c+2) * 4 + tid];
      a3 += (xln[c+3] * g_adj[c+3] + b_adj[c+3]) * w_adj[(c+3) * 4 + tid];
    }
    lg[tid] = (a0 + a1) + (a2 + a3);
  } else if (tid < 76){
    int j = tid - 4;
    float a0 = 0.f, a1 = 0.f, a2 = 0.f, a3 = 0.f;
    #pragma unroll 4
    for (int c = 0; c < 256; c += 4){
      a0 += (xln[c+0] * g_off[c+0] + b_off[c+0]) * w_off[(c+0) * 72 + j];
      a1 += (xln[c+1] * g_off[c+1] + b_off[c+1]) * w_off[(c+1) * 72 + j];
      a2 += (xln[c+2] * g_off[c+2] + b_off[c+2]) * w_off[(c+2) * 72 + j];
      a3 += (xln[c+3] * g_off[c+3] + b_off[c+3]) * w_off[(c+3) * 72 + j];
    }
    offs[j] = (a0 + a1) + (a2 + a3) + off_bias[j];
  } else if (tid < 140){
    int j = tid - 76;
    float a0 = 0.f, a1 = 0.f, a2 = 0.f, a3 = 0.f;
    #pragma unroll 4
    for (int c = 0; c < 256; c += 4){
      a0 += (xln[c+0] * g_pg[c+0] + b_pg[c+0]) * w_pg1[(c+0) * 64 + j];
      a1 += (xln[c+1] * g_pg[c+1] + b_pg[c+1]) * w_pg1[(c+1) * 64 + j];
      a2 += (xln[c+2] * g_pg[c+2] + b_pg[c+2]) * w_pg1[(c+2) * 64 + j];
      a3 += (xln[c+3] * g_pg[c+3] + b_pg[c+3]) * w_pg1[(c+3) * 64 + j];
    }
    hbuf[t * 64 + j] = f2bf((a0 + a1) + (a2 + a3) + b_pg1[j]);
  }
  __syncthreads();
  if (tid == 0){
    float x0 = roi[t*4+0], y0 = roi[t*4+1], x1 = roi[t*4+2], y1 = roi[t*4+3];
    float cx = (x0 + x1) * 0.5f, cy = (y0 + y1) * 0.5f;
    float w = fabsf(x1 - x0), hh = fabsf(y1 - y0);
    cx += lg[0] * w; cy += lg[1] * hh;
    w *= expf(lg[2]); hh *= expf(lg[3]);
    stat[0] = cx; stat[1] = cy; stat[2] = w; stat[3] = hh;
  }
  if (tid < 2){
    float mu = 0.f;
    for (int p = 0; p < 36; ++p) mu += offs[p*2 + tid];
    mu *= (1.f / 36.f);
    float v2 = 0.f;
    for (int p = 0; p < 36; ++p){ float d = offs[p*2 + tid] - mu; v2 += d * d; }
    float sd = sqrtf(v2 * (1.f / 35.f)) + 1e-7f;   // ddof=1
    stat[4 + tid] = mu; stat[6 + tid] = 1.f / (3.f * sd);
  }
  __syncthreads();
  if (tid < 72){
    int c = tid & 1;
    pts[t * 72 + tid] = stat[c] + (offs[tid] - stat[4 + c]) * stat[6 + c] * stat[2 + c];
  }
}

// ---------------- kernel 2: img [B,C,H,W] f32 -> [B,H,W,C] bf16 ----------------
__global__ __launch_bounds__(256) void k_transpose(const float* __restrict__ img,
                                                   unsigned short* __restrict__ imgT)
{
  __shared__ float tile[128][65];
  const int blk = blockIdx.x, tid = threadIdx.x;
  const int b = blk >> 6, y = blk & 63;
  for (int half = 0; half < 2; ++half){
    int c_loc = tid >> 1, x0 = (tid & 1) * 32;
    const float* src = img + (((size_t)(b * 256 + half * 128 + c_loc)) * 64 + y) * 64 + x0;
    #pragma unroll
    for (int i = 0; i < 32; ++i) tile[c_loc][x0 + i] = src[i];
    __syncthreads();
    {
      int x = tid >> 2, c0 = (tid & 3) * 32;
      size_t obase = (((size_t)(b * 64 + y)) * 64 + x) * 256 + half * 128 + c0;
      #pragma unroll
      for (int cb = 0; cb < 32; cb += 8){
        unsigned short tmp[8];
        #pragma unroll
        for (int j = 0; j < 8; ++j) tmp[j] = f2bf(tile[c0 + cb + j][x]);
        *(bf16x8*)(imgT + obase + cb) = *(const bf16x8*)tmp;
      }
    }
    __syncthreads();
  }
}

// ---------------- kernel 4: params = h @ pg_w2 + pg_b2 (M=1024,K=64,N=66832)
// cm chunks (nc<1024) -> fp8 e4m3 via HW cvt_pk; sm tail (nc>=1024) -> f16.
__global__ __launch_bounds__(256) void k_params(
    const unsigned short* __restrict__ hbuf, const float* __restrict__ w2,
    const float* __restrict__ b2, unsigned char* __restrict__ params8,
    unsigned short* __restrict__ sm16)
{
  __shared__ __align__(16) unsigned short Bs[64][72];  // [n][k^swz]
  __shared__ __align__(16) unsigned short As[64][72];  // [m][k]
  __shared__ __align__(16) unsigned short Os[64][72];  // f16 staging (sm path)
  __shared__ __align__(16) unsigned char  Os8[64][72]; // fp8 staging (cm path)
  const int tid = threadIdx.x, lane = tid & 63, wave = tid >> 6;
  const int wm = wave >> 1, wn = wave & 1;
  const int nc = blockIdx.x, n0 = nc * 64;
  const bool cm = (nc < 1024);
  {
    int k = tid >> 2, nb = (tid & 3) * 16;
    #pragma unroll
    for (int i = 0; i < 16; ++i){
      int n = nb + i, gn = n0 + n;
      float v = (gn < 66832) ? w2[(size_t)k * 66832 + gn] : 0.f;
      Bs[n][k ^ (((n >> 3) & 7) << 3)] = f2bf(v);
    }
  }
  float bv[2];
  #pragma unroll
  for (int j = 0; j < 2; ++j){
    int col = n0 + wn*32 + j*16 + (lane & 15);
    bv[j] = (col < 66832) ? b2[col] : 0.f;
  }
  __syncthreads();
  for (int mt = 0; mt < 16; ++mt){
    int m0 = mt * 64;
    { int m = tid >> 2, kb4 = (tid & 3) * 16;
      const unsigned short* hp = hbuf + (m0 + m) * 64 + kb4;
      *(bf16x8*)&As[m][kb4]     = *(const bf16x8*)hp;
      *(bf16x8*)&As[m][kb4 + 8] = *(const bf16x8*)(hp + 8);
    }
    __syncthreads();
    f32x4 acc[2][2] = {};
    #pragma unroll
    for (int ks = 0; ks < 2; ++ks){
      int kb = ks * 32 + (lane >> 4) * 8;
      bf16x8 a[2], bb[2];
      #pragma unroll
      for (int i = 0; i < 2; ++i) a[i] = *(const bf16x8*)&As[wm*32 + i*16 + (lane & 15)][kb];
      #pragma unroll
      for (int j = 0; j < 2; ++j){
        int n = wn*32 + j*16 + (lane & 15);
        bb[j] = *(const bf16x8*)&Bs[n][kb ^ (((n >> 3) & 7) << 3)];
      }
      #pragma unroll
      for (int i = 0; i < 2; ++i)
        #pragma unroll
        for (int j = 0; j < 2; ++j) acc[i][j] = mfma16(a[i], bb[j], acc[i][j]);
    }
    if (cm){
      #pragma unroll
      for (int i = 0; i < 2; ++i)
        #pragma unroll
        for (int j = 0; j < 2; ++j){
          int cl = wn*32 + j*16 + (lane & 15);
          int rl = wm*32 + i*16 + (lane >> 4) * 4;
          unsigned p01 = pk_fp8(acc[i][j][0] + bv[j], acc[i][j][1] + bv[j]);
          unsigned p23 = pk_fp8(acc[i][j][2] + bv[j], acc[i][j][3] + bv[j]);
          Os8[rl + 0][cl] = (unsigned char)(p01 & 0xFFu);
          Os8[rl + 1][cl] = (unsigned char)((p01 >> 8) & 0xFFu);
          Os8[rl + 2][cl] = (unsigned char)(p23 & 0xFFu);
          Os8[rl + 3][cl] = (unsigned char)((p23 >> 8) & 0xFFu);
        }
      __syncthreads();
      {
        int rl = tid >> 2, c0 = (tid & 3) * 16;
        uint2 lo = *(const uint2*)&Os8[rl][c0];
        uint2 hi = *(const uint2*)&Os8[rl][c0 + 8];
        uint4 val; val.x = lo.x; val.y = lo.y; val.z = hi.x; val.w = hi.y;
        *(uint4*)(params8 + ((size_t)nc * 1024 + m0 + rl) * 64 + c0) = val;
      }
    } else {
      #pragma unroll
      for (int i = 0; i < 2; ++i)
        #pragma unroll
        for (int j = 0; j < 2; ++j){
          int cl = wn*32 + j*16 + (lane & 15);
          #pragma unroll
          for (int r = 0; r < 4; ++r){
            int rl = wm*32 + i*16 + (lane >> 4) * 4 + r;
            Os[rl][cl] = f2h(acc[i][j][r] + bv[j]);
          }
        }
      __syncthreads();
      {
        int rl = tid >> 2, c0 = (tid & 3) * 16;
        size_t gbase = ((size_t)(nc - 1024) * 1024 + m0 + rl) * 64 + c0;
        *(bf16x8*)(sm16 + gbase)     = *(const bf16x8*)&Os[rl][c0];
        *(bf16x8*)(sm16 + gbase + 8) = *(const bf16x8*)&Os[rl][c0 + 8];
      }
    }
    __syncthreads();
  }
}

// ---------------- kernel 5: fused sample + per-token adaptive mixing ----------
// S gathered directly from imgT (bilinear, fused k_sample); cm fp8, f16 pipeline.
__global__ __launch_bounds__(256) void k_mixtoken(
    const unsigned short* __restrict__ imgT,      // bf16 [B,H,W,C]
    const float* __restrict__ pts,                // [T,36,2]
    const unsigned char*  __restrict__ params8,   // fp8 cm
    const unsigned short* __restrict__ sm16,      // f16 sm tail
    const float* __restrict__ m_beta, const float* __restrict__ s_beta,
    unsigned short* __restrict__ out2)            // bf16
{
  __shared__ __align__(16) unsigned short smem[29984];
  __shared__ float lpts[72];
  const int t = blockIdx.x, tid = threadIdx.x, lane = tid & 63, wave = tid >> 6;
  const int l15 = lane & 15, kb = (lane >> 4) * 8;
  unsigned short (*Ss)[264] = (unsigned short (*)[264])smem;
  const int c31  = tid & 31;
  const int g    = tid >> 5;
  const int goff = (g & 1) * 32;
  const int colw = c31 ^ ((g & 3) << 3);
  const unsigned char* ptok8 = params8 + (size_t)t * 64;
  uint4 rv8[2];
  {
    const unsigned char* src = ptok8 + ((size_t)(c31 * 4 + (g >> 1)) << 16) + goff;
    rv8[0] = *(const uint4*)src;
    rv8[1] = *(const uint4*)(src + 16);
  }
  unsigned short rSm[14];
  #pragma unroll
  for (int k = 0; k < 14; ++k){
    int idx = tid + k * 256;
    unsigned short v = 0;
    if (idx < 3456){
      int o = idx / 72, p = idx % 72;
      if (o < 36 && p < 36){
        int n = 65536 + o * 36 + p;
        v = sm16[(size_t)((n >> 6) - 1024) * 65536 + (size_t)t * 64 + (n & 63)];
      }
    }
    rSm[k] = v;
  }
  // ---- fused sample: gather S[36][256] from imgT ----
  if (tid < 72) lpts[tid] = pts[t * 72 + tid];
  __syncthreads();
  {
    const int b = t >> 6;
    #pragma unroll 4
    for (int p = 0; p < 36; ++p){
      float fx = lpts[p*2]   * 64.f - 0.5f;
      float fy = lpts[p*2+1] * 64.f - 0.5f;
      float x0f = floorf(fx), y0f = floorf(fy);
      float wx = fx - x0f, wy = fy - y0f;
      int x0 = (int)x0f, y0 = (int)y0f;
      float acc_s = 0.f;
      #pragma unroll
      for (int dy = 0; dy < 2; ++dy){
        #pragma unroll
        for (int dx = 0; dx < 2; ++dx){
          int xi = x0 + dx, yi = y0 + dy;
          bool valid = (xi >= 0) & (xi < 64) & (yi >= 0) & (yi < 64);
          int xc = min(max(xi, 0), 63), yc = min(max(yi, 0), 63);
          float w = (dx ? wx : 1.f - wx) * (dy ? wy : 1.f - wy);
          float v = bf2f(imgT[(((size_t)(b * 64 + yc)) * 64 + xc) * 256 + tid]);
          acc_s += v * (valid ? w : 0.f);
        }
      }
      Ss[p][tid] = f2h(acc_s);
    }
  }
  __syncthreads();
  f32x4 acc[3][4] = {};
  int cur = 0;
  for (int cc = 0; cc < 8; ++cc){
    unsigned short (*C)[40] = (unsigned short (*)[40])(smem + 9504 + cur * 10240);
    #pragma unroll
    for (int v = 0; v < 2; ++v){
      #pragma unroll
      for (int w = 0; w < 4; ++w){
        unsigned dw = ((const unsigned*)&rv8[v])[w];
        int d0 = g * 32 + v * 16 + w * 4;
        unsigned short r[4];
        dec4_fp8(dw, r);
        C[d0 + 0][colw] = r[0];
        C[d0 + 1][colw] = r[1];
        C[d0 + 2][colw] = r[2];
        C[d0 + 3][colw] = r[3];
      }
    }
    __syncthreads();   // C[cur] ready
    if (cc < 7){
      const unsigned char* src = ptok8 + ((size_t)((cc + 1) * 128 + c31 * 4 + (g >> 1)) << 16) + goff;
      rv8[0] = *(const uint4*)src;
      rv8[1] = *(const uint4*)(src + 16);
    }
    f16x8 a[3], bfr[4];
    a[0] = *(const f16x8*)&Ss[l15][cc * 32 + kb];
    a[1] = *(const f16x8*)&Ss[16 + l15][cc * 32 + kb];
    a[2] = f16x8{};
    if (l15 < 4) a[2] = *(const f16x8*)&Ss[32 + l15][cc * 32 + kb];
    #pragma unroll
    for (int j = 0; j < 4; ++j){
      int d = wave * 64 + j * 16 + l15;
      bfr[j] = *(const f16x8*)&C[d][kb ^ (((d >> 5) & 3) << 3)];
    }
    #pragma unroll
    for (int i = 0; i < 3; ++i)
      #pragma unroll
      for (int j = 0; j < 4; ++j) acc[i][j] = mfma16h(a[i], bfr[j], acc[i][j]);
    cur ^= 1;
  }
  __syncthreads();
  {
    const bf16x8 z = {};
    #pragma unroll
    for (int i = 0; i < 9; ++i)
      *(bf16x8*)&smem[(i * 256 + tid) * 8] = z;
    #pragma unroll
    for (int k = 0; k < 14; ++k){
      int idx = tid + k * 256;
      if (idx < 3456) smem[18432 + idx] = rSm[k];
    }
  }
  __syncthreads();
  unsigned short (*O1T)[72] = (unsigned short (*)[72])smem;
  unsigned short (*Sm)[72]  = (unsigned short (*)[72])(smem + 18432);
  #pragma unroll
  for (int i = 0; i < 3; ++i){
    int p = i * 16 + ((lane >> 4) << 2);
    if (p < 36){
      #pragma unroll
      for (int j = 0; j < 4; ++j){
        int d = wave * 64 + j * 16 + l15;
        float mb = m_beta[d];
        unsigned short* dst = &O1T[d][p];
        #pragma unroll
        for (int r = 0; r < 4; ++r) dst[r] = f2h(gelu_f(acc[i][j][r] + mb));
      }
    }
  }
  __syncthreads();
  f32x4 acc2[3][4] = {};
  #pragma unroll
  for (int ks = 0; ks < 2; ++ks){
    int kb2 = ks * 32 + (lane >> 4) * 8;
    f16x8 a2[3], bf2[4];
    #pragma unroll
    for (int i = 0; i < 3; ++i) a2[i] = *(const f16x8*)&Sm[i*16 + l15][kb2];
    #pragma unroll
    for (int j = 0; j < 4; ++j) bf2[j] = *(const f16x8*)&O1T[wave*64 + j*16 + l15][kb2];
    #pragma unroll
    for (int i = 0; i < 3; ++i)
      #pragma unroll
      for (int j = 0; j < 4; ++j) acc2[i][j] = mfma16h(a2[i], bf2[j], acc2[i][j]);
  }
  unsigned short* o2 = out2 + (size_t)t * 9216;
  #pragma unroll
  for (int i = 0; i < 3; ++i){
    int ob = i*16 + ((lane >> 4) << 2);
    #pragma unroll
    for (int j = 0; j < 4; ++j){
      int d = wave*64 + j*16 + l15;
      #pragma unroll
      for (int r = 0; r < 4; ++r){
        int o = ob + r;
        if (o < 36) o2[o * 256 + d] = f2bf(gelu_f(acc2[i][j][r] + s_beta[o]));
      }
    }
  }
}

// ---------------- generic GEMM: C = act(A @ W + bias) (+resid) ----------------
template<int AK, int ACT, int RES, int OUTB>
__global__ __launch_bounds__(256) void k_gemm(
    const void* __restrict__ Ap, const float* __restrict__ W,
    const float* __restrict__ bias, const float* __restrict__ resid,
    void* __restrict__ Cp, int M, int N, int K)
{
  __shared__ __align__(16) unsigned short As[64][40];  // [m][k]
  __shared__ __align__(16) unsigned short Bs[64][40];  // [n][k^swz]
  const int tid = threadIdx.x, lane = tid & 63, wave = tid >> 6;
  const int wm = wave >> 1, wn = wave & 1;
  const int n0 = blockIdx.x * 64, m0 = blockIdx.y * 64;
  f32x4 acc[2][2] = {};
  for (int kk = 0; kk < K; kk += 32){
    { int m = tid >> 2, k4 = (tid & 3) * 8;
      if (AK == 0){
        const float* ap = (const float*)Ap + (size_t)(m0 + m) * K + kk + k4;
        #pragma unroll
        for (int i = 0; i < 8; ++i) As[m][k4 + i] = f2bf(ap[i]);
      } else {
        const unsigned short* ap = (const unsigned short*)Ap + (size_t)(m0 + m) * K + kk + k4;
        *(bf16x8*)&As[m][k4] = *(const bf16x8*)ap;
      }
    }
    { int kq = tid >> 3, n8 = (tid & 7) * 8;
      const float* wp = W + (size_t)(kk + kq) * N + n0 + n8;
      #pragma unroll
      for (int i = 0; i < 8; ++i){
        int n = n8 + i;
        Bs[n][kq ^ (((n >> 3) & 3) << 3)] = f2bf(wp[i]);
      }
    }
    __syncthreads();
    const int kb = (lane >> 4) * 8;
    bf16x8 a[2], bfr[2];
    #pragma unroll
    for (int i = 0; i < 2; ++i) a[i] = *(const bf16x8*)&As[wm*32 + i*16 + (lane & 15)][kb];
    #pragma unroll
    for (int j = 0; j < 2; ++j){
      int n = wn*32 + j*16 + (lane & 15);
      bfr[j] = *(const bf16x8*)&Bs[n][kb ^ (((n >> 3) & 3) << 3)];
    }
    #pragma unroll
    for (int i = 0; i < 2; ++i)
      #pragma unroll
      for (int j = 0; j < 2; ++j) acc[i][j] = mfma16(a[i], bfr[j], acc[i][j]);
    __syncthreads();
  }
  #pragma unroll
  for (int i = 0; i < 2; ++i)
    #pragma unroll
    for (int j = 0; j < 2; ++j){
      int col = n0 + wn*32 + j*16 + (lane & 15);
      float bv = bias[col];
      #pragma unroll
      for (int r = 0; r < 4; ++r){
        int row = m0 + wm*32 + i*16 + (lane >> 4) * 4 + r;
        float v = acc[i][j][r] + bv;
        if (ACT == 1) v = gelu_f(v);
        if (RES) v += resid[(size_t)row * N + col];
        if (OUTB) ((unsigned short*)Cp)[(size_t)row * N + col] = f2bf(v);
        else      ((float*)Cp)[(size_t)row * N + col] = v;
      }
    }
}

// ---------------- split-K GEMM: part[z][M][N] = A[:, z*KS:(z+1)*KS] @ W[z*KS:...] ----
template<int AK>
__global__ __launch_bounds__(256) void k_gemm_sk(
    const void* __restrict__ Ap, const float* __restrict__ W,
    float* __restrict__ part, int M, int N, int K, int KS)
{
  __shared__ __align__(16) unsigned short As[64][40];  // [m][k]
  __shared__ __align__(16) unsigned short Bs[64][40];  // [n][k^swz]
  const int tid = threadIdx.x, lane = tid & 63, wave = tid >> 6;
  const int wm = wave >> 1, wn = wave & 1;
  const int n0 = blockIdx.x * 64, m0 = blockIdx.y * 64;
  const int kbase = blockIdx.z * KS;
  f32x4 acc[2][2] = {};
  for (int kq = 0; kq < KS; kq += 32){
    int kk = kbase + kq;
    { int m = tid >> 2, k4 = (tid & 3) * 8;
      if (AK == 0){
        const float* ap = (const float*)Ap + (size_t)(m0 + m) * K + kk + k4;
        #pragma unroll
        for (int i = 0; i < 8; ++i) As[m][k4 + i] = f2bf(ap[i]);
      } else {
        const unsigned short* ap = (const unsigned short*)Ap + (size_t)(m0 + m) * K + kk + k4;
        *(bf16x8*)&As[m][k4] = *(const bf16x8*)ap;
      }
    }
    { int kr = tid >> 3, n8 = (tid & 7) * 8;
      const float* wp = W + (size_t)(kk + kr) * N + n0 + n8;
      #pragma unroll
      for (int i = 0; i < 8; ++i){
        int n = n8 + i;
        Bs[n][kr ^ (((n >> 3) & 3) << 3)] = f2bf(wp[i]);
      }
    }
    __syncthreads();
    const int kb = (lane >> 4) * 8;
    bf16x8 a[2], bfr[2];
    #pragma unroll
    for (int i = 0; i < 2; ++i) a[i] = *(const bf16x8*)&As[wm*32 + i*16 + (lane & 15)][kb];
    #pragma unroll
    for (int j = 0; j < 2; ++j){
      int n = wn*32 + j*16 + (lane & 15);
      bfr[j] = *(const bf16x8*)&Bs[n][kb ^ (((n >> 3) & 3) << 3)];
    }
    #pragma unroll
    for (int i = 0; i < 2; ++i)
      #pragma unroll
      for (int j = 0; j < 2; ++j) acc[i][j] = mfma16(a[i], bfr[j], acc[i][j]);
    __syncthreads();
  }
  float* pz = part + (size_t)blockIdx.z * M * N;
  #pragma unroll
  for (int i = 0; i < 2; ++i)
    #pragma unroll
    for (int j = 0; j < 2; ++j){
      int col = n0 + wn*32 + j*16 + (lane & 15);
      #pragma unroll
      for (int r = 0; r < 4; ++r){
        int row = m0 + wm*32 + i*16 + (lane >> 4) * 4 + r;
        pz[(size_t)row * N + col] = acc[i][j][r];
      }
    }
}

// ---------------- split-K reduce: out = sum_z part[z] + bias (+resid) ----------------
template<int RES>
__global__ __launch_bounds__(256) void k_reduce(
    const float* __restrict__ part, const float* __restrict__ bias,
    const float* __restrict__ resid, float* __restrict__ out,
    int total, int N, int SK)
{
  int i = blockIdx.x * 256 + threadIdx.x;
  if (i >= total) return;
  float s = 0.f;
  for (int z = 0; z < SK; ++z) s += part[(size_t)z * total + i];
  s += bias[i % N];
  if (RES) s += resid[i];
  out[i] = s;
}

// ---------------- fused split-K reduce + residual + LayerNorm ----------------
__global__ __launch_bounds__(256) void k_reduce_ln(
    const float* __restrict__ part, const float* __restrict__ bias,
    const float* __restrict__ resid,
    const float* __restrict__ g, const float* __restrict__ bb,
    float* __restrict__ emb_out, unsigned short* __restrict__ ln_out, int SK)
{
  __shared__ float red[4];
  const int t = blockIdx.x, tid = threadIdx.x;
  const int i = t * 256 + tid;
  float s = 0.f;
  for (int z = 0; z < SK; ++z) s += part[(size_t)z * 262144 + i];
  s += bias[tid] + resid[i];
  emb_out[i] = s;
  float mean = block_sum(s, red, tid) * (1.f / 256.f);
  float d = s - mean;
  float var = block_sum(d * d, red, tid) * (1.f / 256.f);
  ln_out[i] = f2bf(d * rsqrtf(var + 1e-5f) * g[tid] + bb[tid]);
}

// ---------------- attention: one (b,h) per block ----------------
__global__ __launch_bounds__(64) void k_attn(const float* __restrict__ qkv,
                                             float* __restrict__ attno)
{
  __shared__ float qs[64][33], ksm[64][33], vsm[64][33];
  const int blk = blockIdx.x, lane = threadIdx.x;
  const int b = blk >> 3, h = blk & 7;
  for (int idx = lane; idx < 2048; idx += 64){
    int row = idx >> 5, d = idx & 31;
    const float* base = qkv + (size_t)(b * 64 + row) * 768 + h * 32 + d;
    qs[row][d] = base[0]; ksm[row][d] = base[256]; vsm[row][d] = base[512];
  }
  __syncthreads();
  float qr[32];
  #pragma unroll
  for (int d = 0; d < 32; ++d) qr[d] = qs[lane][d];
  float s[64]; float mx = -1e30f;
  for (int m = 0; m < 64; ++m){
    float dot = 0.f;
    #pragma unroll
    for (int d = 0; d < 32; ++d) dot += qr[d] * ksm[m][d];
    dot *= 0.17677669529663687f;  // 32^-0.5
    s[m] = dot; mx = fmaxf(mx, dot);
  }
  float sum = 0.f;
  for (int m = 0; m < 64; ++m){ s[m] = expf(s[m] - mx); sum += s[m]; }
  float inv = 1.f / sum;
  float o[32] = {};
  for (int m = 0; m < 64; ++m){
    float p = s[m] * inv;
    #pragma unroll
    for (int d = 0; d < 32; ++d) o[d] += p * vsm[m][d];
  }
  float* dst = attno + (size_t)(b * 64 + lane) * 256 + h * 32;
  #pragma unroll
  for (int d = 0; d < 32; ++d) dst[d] = o[d];
}

__global__ void k_fill(float* p, int n, float v){
  int i = blockIdx.x * 256 + threadIdx.x;
  if (i < n) p[i] = v;
}

// ---------------- launch ----------------
extern "C" void kernel_launch(void* const* d_in, const int* in_sizes, int n_in,
                              void* d_out, int out_size, void* d_ws, size_t ws_size,
                              hipStream_t stream)
{
  const float* img      = (const float*)d_in[0];
  const float* embed    = (const float*)d_in[1];
  const float* roi      = (const float*)d_in[2];
  const float* ln_adj_g = (const float*)d_in[3];
  const float* ln_adj_b = (const float*)d_in[4];
  const float* w_adj    = (const float*)d_in[5];
  const float* ln_off_g = (const float*)d_in[6];
  const float* ln_off_b = (const float*)d_in[7];
  const float* w_off    = (const float*)d_in[8];
  const float* off_bias = (const float*)d_in[9];
  const float* pg_ln_g  = (const float*)d_in[10];
  const float* pg_ln_b  = (const float*)d_in[11];
  const float* pg_w1    = (const float*)d_in[12];
  const float* pg_b1    = (const float*)d_in[13];
  const float* pg_w2    = (const float*)d_in[14];
  const float* pg_b2    = (const float*)d_in[15];
  const float* m_beta   = (const float*)d_in[16];
  const float* s_beta   = (const float*)d_in[17];
  const float* mix_w    = (const float*)d_in[18];
  const float* mix_b    = (const float*)d_in[19];
  const float* ln1_g    = (const float*)d_in[20];
  const float* ln1_b    = (const float*)d_in[21];
  const float* qkv_w    = (const float*)d_in[22];
  const float* qkv_b    = (const float*)d_in[23];
  const float* proj_w   = (const float*)d_in[24];
  const float* proj_b   = (const float*)d_in[25];
  const float* ln2_g    = (const float*)d_in[26];
  const float* ln2_b    = (const float*)d_in[27];
  const float* fc1_w    = (const float*)d_in[28];
  const float* fc1_b    = (const float*)d_in[29];
  const float* fc2_w    = (const float*)d_in[30];
  const float* fc2_b    = (const float*)d_in[31];

  char* ws = (char*)d_ws;
  float*          pts     = (float*)         (ws + 0);          //   294912
  unsigned short* hbuf    = (unsigned short*)(ws + 294912);     //   131072 (bf16)
  unsigned short* imgT    = (unsigned short*)(ws + 557056);     // 33554432
  unsigned char*  params8 = (unsigned char*) (ws + 52985856);   // 67108864 (fp8 cm)
  unsigned short* sm16    = (unsigned short*)(ws + 120094720);  //  2752512 (f16 sm)
  unsigned short* out2    = (unsigned short*)(ws + 122847232);  // 18874368 (bf16)
  float*          embed1  = (float*)         (ws + 141721600);  //  1048576
  float*          embed2  = (float*)         (ws + 142770176);  //  1048576
  unsigned short* xln1    = (unsigned short*)(ws + 143818752);  //   524288
  unsigned short* xln2    = (unsigned short*)(ws + 144343040);  //   524288
  float*          qkvb    = (float*)         (ws + 144867328);  //  3145728
  float*          attno   = (float*)         (ws + 148013056);  //  1048576
  // aliased into the params8 region (dead after k_mixtoken):
  float*          part_mix  = (float*)(ws + 52985856);             // 16 MB (16 slabs)
  float*          part_smll = (float*)(ws + 52985856 + 16777216);  //  4 MB (4 slabs)
  unsigned short* h1        = (unsigned short*)(ws + 52985856 + 20971520); // 2 MB
  const size_t WS_NEEDED = 149061632;
  if (ws_size < WS_NEEDED){
    k_fill<<<(out_size + 255) / 256, 256, 0, stream>>>((float*)d_out, out_size, 12345.0f);
    return;
  }

  float* out = (float*)d_out;

  k_prep<<<1024, 256, 0, stream>>>(embed, roi, ln_adj_g, ln_adj_b, w_adj,
                                   ln_off_g, ln_off_b, w_off, off_bias,
                                   pg_ln_g, pg_ln_b, pg_w1, pg_b1, pts, hbuf);
  k_transpose<<<1024, 256, 0, stream>>>(img, imgT);
  k_params<<<1045, 256, 0, stream>>>(hbuf, pg_w2, pg_b2, params8, sm16);
  k_mixtoken<<<1024, 256, 0, stream>>>(imgT, pts, params8, sm16, m_beta, s_beta, out2);
  // embed1 = embed + out2 @ mix_w + mix_b   (split-K: 9216 = 16 x 576), fused LN1
  k_gemm_sk<1><<<dim3(4,16,16), 256, 0, stream>>>(out2, mix_w, part_mix, 1024, 256, 9216, 576);
  k_reduce_ln<<<1024, 256, 0, stream>>>(part_mix, mix_b, embed, ln1_g, ln1_b, embed1, xln1, 16);
  k_gemm<1,0,0,0><<<dim3(12,16), 256, 0, stream>>>(xln1, qkv_w, qkv_b, nullptr, qkvb, 1024, 768, 256);
  k_attn<<<128, 64, 0, stream>>>(qkvb, attno);
  // embed2 = embed1 + attno @ proj_w + proj_b (split-K: 256 = 4 x 64), fused LN2
  k_gemm_sk<0><<<dim3(4,16,4), 256, 0, stream>>>(attno, proj_w, part_smll, 1024, 256, 256, 64);
  k_reduce_ln<<<1024, 256, 0, stream>>>(part_smll, proj_b, embed1, ln2_g, ln2_b, embed2, xln2, 4);
  k_gemm<1,1,0,1><<<dim3(16,16), 256, 0, stream>>>(xln2, fc1_w, fc1_b, nullptr, h1, 1024, 1024, 256);
  // out = embed2 + h1 @ fc2_w + fc2_b   (split-K: 1024 = 4 x 256)
  k_gemm_sk<1><<<dim3(4,16,4), 256, 0, stream>>>(h1, fc2_w, part_smll, 1024, 256, 1024, 256);
  k_reduce<1><<<1024, 256, 0, stream>>>(part_smll, fc2_b, embed2, out, 262144, 256, 4);
}

// Round 15
// 246.444 us; speedup vs baseline: 1.7150x; 1.0018x over previous
//
#include <hip/hip_runtime.h>
#include <cstdint>

#define DEV __device__ __forceinline__

typedef __attribute__((ext_vector_type(8))) short bf16x8;
typedef __attribute__((ext_vector_type(8))) _Float16 f16x8;
typedef __attribute__((ext_vector_type(2))) __fp16 fp16x2;
typedef __attribute__((ext_vector_type(2))) float f32x2;
typedef __attribute__((ext_vector_type(4))) float f32x4;

DEV unsigned short f2bf(float x){
  union { float f; unsigned u; } c; c.f = x;
  unsigned r = c.u + 0x7fffu + ((c.u >> 16) & 1u);
  return (unsigned short)(r >> 16);
}
DEV float bf2f(unsigned short h){
  union { unsigned u; float f; } c; c.u = ((unsigned)h) << 16;
  return c.f;
}
DEV unsigned short f2h(float x){
  union { unsigned short u; _Float16 h; } c;
  c.h = (_Float16)x;
  return c.u;
}
// f32 -> e4m3 (OCP), RNE, saturate to +-448. Software fallback path.
DEV unsigned char f2fp8(float x){
  union { float f; unsigned u; } c; c.f = x;
  unsigned s = (c.u >> 24) & 0x80u;
  float a = fabsf(x);
  a = fminf(a, 448.f);
  unsigned n;
  if (a < 0.015625f){
    n = (unsigned)(int)rintf(a * 512.f);       // 0..8, RNE; 8 == 2^-6 normal
  } else {
    union { float f; unsigned u; } d; d.f = a;
    unsigned u2 = d.u + 0x7FFFFu + ((d.u >> 20) & 1u);
    n = (((u2 >> 23) - 120u) << 3) | ((u2 >> 20) & 7u);
  }
  return (unsigned char)(s | n);
}
// pack 2 f32 -> 2 e4m3 bytes (byte0 = a, byte1 = b); HW instr on gfx950
DEV unsigned pk_fp8(float a, float b){
#if defined(__has_builtin)
#if __has_builtin(__builtin_amdgcn_cvt_pk_fp8_f32)
  return (unsigned)__builtin_amdgcn_cvt_pk_fp8_f32(a, b, 0, false);
#else
  return (unsigned)f2fp8(a) | ((unsigned)f2fp8(b) << 8);
#endif
#else
  return (unsigned)f2fp8(a) | ((unsigned)f2fp8(b) << 8);
#endif
}
// e4m3 -> f16 bits, exact (software fallback).
DEV unsigned short fp82h(unsigned b){
  union { unsigned short u; _Float16 h; } c;
  c.u = (unsigned short)(((b & 0x80u) << 8) | ((b & 0x7Fu) << 7));
  c.h = c.h * (_Float16)256.0f;
  return c.u;
}
// decode 4 fp8 bytes (one dword, consecutive elements) -> 4 f16 (exact)
DEV void dec4_fp8(unsigned dw, unsigned short r[4]){
#if defined(__has_builtin)
#if __has_builtin(__builtin_amdgcn_cvt_pk_f32_fp8)
  f32x2 lo = __builtin_amdgcn_cvt_pk_f32_fp8((int)dw, false);
  f32x2 hi = __builtin_amdgcn_cvt_pk_f32_fp8((int)dw, true);
  union { fp16x2 h; unsigned short u[2]; } a, b;
  a.h = __builtin_amdgcn_cvt_pkrtz(lo.x, lo.y);   // fp8 values exact in f16 -> RTZ lossless
  b.h = __builtin_amdgcn_cvt_pkrtz(hi.x, hi.y);
  r[0] = a.u[0]; r[1] = a.u[1]; r[2] = b.u[0]; r[3] = b.u[1];
#else
  r[0] = fp82h(dw & 0xFFu); r[1] = fp82h((dw >> 8) & 0xFFu);
  r[2] = fp82h((dw >> 16) & 0xFFu); r[3] = fp82h(dw >> 24);
#endif
#else
  r[0] = fp82h(dw & 0xFFu); r[1] = fp82h((dw >> 8) & 0xFFu);
  r[2] = fp82h((dw >> 16) & 0xFFu); r[3] = fp82h(dw >> 24);
#endif
}

DEV float gelu_f(float x){ return 0.5f * x * (1.f + erff(x * 0.70710678118654752440f)); }

DEV f32x4 mfma16(bf16x8 a, bf16x8 b, f32x4 c){
  return __builtin_amdgcn_mfma_f32_16x16x32_bf16(a, b, c, 0, 0, 0);
}
DEV f32x4 mfma16h(f16x8 a, f16x8 b, f32x4 c){
  return __builtin_amdgcn_mfma_f32_16x16x32_f16(a, b, c, 0, 0, 0);
}

// block_sum: 256 threads (4 waves)
DEV float block_sum(float v, float* red, int tid){
  #pragma unroll
  for (int o = 32; o > 0; o >>= 1) v += __shfl_down(v, o);
  if ((tid & 63) == 0) red[tid >> 6] = v;
  __syncthreads();
  float s = red[0] + red[1] + red[2] + red[3];
  __syncthreads();
  return s;
}

// ---------------- constants ----------------
// B=16 N=64 D=256 CI=256 H=W=64 P=36 HEADS=8 HD=32 HID=1024 TOTAL=66832 T=1024
// cm (n<65536) stored fp8 e4m3, blocked: params8[(n>>6)*65536 + t*64 + (n&63)] bytes
// sm tail (n>=65536) stored f16, blocked: sm16[((n>>6)-1024)*65536 + t*64 + (n&63)]
// hbuf is stored bf16. k_sample fused into k_mixtoken (per-point coeffs hoisted to LDS).

// ---------------- kernel 1: per-token prep ----------------
__global__ __launch_bounds__(256) void k_prep(
    const float* __restrict__ embed, const float* __restrict__ roi,
    const float* __restrict__ g_adj, const float* __restrict__ b_adj, const float* __restrict__ w_adj,
    const float* __restrict__ g_off, const float* __restrict__ b_off, const float* __restrict__ w_off,
    const float* __restrict__ off_bias,
    const float* __restrict__ g_pg, const float* __restrict__ b_pg,
    const float* __restrict__ w_pg1, const float* __restrict__ b_pg1,
    float* __restrict__ pts, unsigned short* __restrict__ hbuf)
{
  __shared__ float red[4];
  __shared__ float xln[256];
  __shared__ float offs[72];
  __shared__ float lg[4];
  __shared__ float stat[8];
  const int t = blockIdx.x, tid = threadIdx.x;
  float e = embed[t * 256 + tid];
  float mean = block_sum(e, red, tid) * (1.f / 256.f);
  float dv = e - mean;
  float var = block_sum(dv * dv, red, tid) * (1.f / 256.f);
  xln[tid] = dv * rsqrtf(var + 1e-5f);
  __syncthreads();
  if (tid < 4){
    float a0 = 0.f, a1 = 0.f, a2 = 0.f, a3 = 0.f;
    #pragma unroll 4
    for (int c = 0; c < 256; c += 4){
      a0 += (xln[c+0] * g_adj[c+0] + b_adj[c+0]) * w_adj[(c+0) * 4 + tid];
      a1 += (xln[c+1] * g_adj[c+1] + b_adj[c+1]) * w_adj[(c+1) * 4 + tid];
      a2 += (xln[c+2] * g_adj[c+2] + b_adj[c+2]) * w_adj[(c+2) * 4 + tid];
      a3 += (xln[c+3] * g_adj[c+3] + b_adj[c+3]) * w_adj[(c+3) * 4 + tid];
    }
    lg[tid] = (a0 + a1) + (a2 + a3);
  } else if (tid < 76){
    int j = tid - 4;
    float a0 = 0.f, a1 = 0.f, a2 = 0.f, a3 = 0.f;
    #pragma unroll 4
    for (int c = 0; c < 256; c += 4){
      a0 += (xln[c+0] * g_off[c+0] + b_off[c+0]) * w_off[(c+0) * 72 + j];
      a1 += (xln[c+1] * g_off[c+1] + b_off[c+1]) * w_off[(c+1) * 72 + j];
      a2 += (xln[c+2] * g_off[c+2] + b_off[c+2]) * w_off[(c+2) * 72 + j];
      a3 += (xln[c+3] * g_off[c+3] + b_off[c+3]) * w_off[(c+3) * 72 + j];
    }
    offs[j] = (a0 + a1) + (a2 + a3) + off_bias[j];
  } else if (tid < 140){
    int j = tid - 76;
    float a0 = 0.f, a1 = 0.f, a2 = 0.f, a3 = 0.f;
    #pragma unroll 4
    for (int c = 0; c < 256; c += 4){
      a0 += (xln[c+0] * g_pg[c+0] + b_pg[c+0]) * w_pg1[(c+0) * 64 + j];
      a1 += (xln[c+1] * g_pg[c+1] + b_pg[c+1]) * w_pg1[(c+1) * 64 + j];
      a2 += (xln[c+2] * g_pg[c+2] + b_pg[c+2]) * w_pg1[(c+2) * 64 + j];
      a3 += (xln[c+3] * g_pg[c+3] + b_pg[c+3]) * w_pg1[(c+3) * 64 + j];
    }
    hbuf[t * 64 + j] = f2bf((a0 + a1) + (a2 + a3) + b_pg1[j]);
  }
  __syncthreads();
  if (tid == 0){
    float x0 = roi[t*4+0], y0 = roi[t*4+1], x1 = roi[t*4+2], y1 = roi[t*4+3];
    float cx = (x0 + x1) * 0.5f, cy = (y0 + y1) * 0.5f;
    float w = fabsf(x1 - x0), hh = fabsf(y1 - y0);
    cx += lg[0] * w; cy += lg[1] * hh;
    w *= expf(lg[2]); hh *= expf(lg[3]);
    stat[0] = cx; stat[1] = cy; stat[2] = w; stat[3] = hh;
  }
  if (tid < 2){
    float mu = 0.f;
    for (int p = 0; p < 36; ++p) mu += offs[p*2 + tid];
    mu *= (1.f / 36.f);
    float v2 = 0.f;
    for (int p = 0; p < 36; ++p){ float d = offs[p*2 + tid] - mu; v2 += d * d; }
    float sd = sqrtf(v2 * (1.f / 35.f)) + 1e-7f;   // ddof=1
    stat[4 + tid] = mu; stat[6 + tid] = 1.f / (3.f * sd);
  }
  __syncthreads();
  if (tid < 72){
    int c = tid & 1;
    pts[t * 72 + tid] = stat[c] + (offs[tid] - stat[4 + c]) * stat[6 + c] * stat[2 + c];
  }
}

// ---------------- kernel 2: img [B,C,H,W] f32 -> [B,H,W,C] bf16 ----------------
__global__ __launch_bounds__(256) void k_transpose(const float* __restrict__ img,
                                                   unsigned short* __restrict__ imgT)
{
  __shared__ float tile[128][65];
  const int blk = blockIdx.x, tid = threadIdx.x;
  const int b = blk >> 6, y = blk & 63;
  for (int half = 0; half < 2; ++half){
    int c_loc = tid >> 1, x0 = (tid & 1) * 32;
    const float* src = img + (((size_t)(b * 256 + half * 128 + c_loc)) * 64 + y) * 64 + x0;
    #pragma unroll
    for (int i = 0; i < 32; ++i) tile[c_loc][x0 + i] = src[i];
    __syncthreads();
    {
      int x = tid >> 2, c0 = (tid & 3) * 32;
      size_t obase = (((size_t)(b * 64 + y)) * 64 + x) * 256 + half * 128 + c0;
      #pragma unroll
      for (int cb = 0; cb < 32; cb += 8){
        unsigned short tmp[8];
        #pragma unroll
        for (int j = 0; j < 8; ++j) tmp[j] = f2bf(tile[c0 + cb + j][x]);
        *(bf16x8*)(imgT + obase + cb) = *(const bf16x8*)tmp;
      }
    }
    __syncthreads();
  }
}

// ---------------- kernel 4: params = h @ pg_w2 + pg_b2 (M=1024,K=64,N=66832)
// cm chunks (nc<1024) -> fp8 e4m3 via HW cvt_pk; sm tail (nc>=1024) -> f16.
__global__ __launch_bounds__(256) void k_params(
    const unsigned short* __restrict__ hbuf, const float* __restrict__ w2,
    const float* __restrict__ b2, unsigned char* __restrict__ params8,
    unsigned short* __restrict__ sm16)
{
  __shared__ __align__(16) unsigned short Bs[64][72];  // [n][k^swz]
  __shared__ __align__(16) unsigned short As[64][72];  // [m][k]
  __shared__ __align__(16) unsigned short Os[64][72];  // f16 staging (sm path)
  __shared__ __align__(16) unsigned char  Os8[64][72]; // fp8 staging (cm path)
  const int tid = threadIdx.x, lane = tid & 63, wave = tid >> 6;
  const int wm = wave >> 1, wn = wave & 1;
  const int nc = blockIdx.x, n0 = nc * 64;
  const bool cm = (nc < 1024);
  {
    int k = tid >> 2, nb = (tid & 3) * 16;
    #pragma unroll
    for (int i = 0; i < 16; ++i){
      int n = nb + i, gn = n0 + n;
      float v = (gn < 66832) ? w2[(size_t)k * 66832 + gn] : 0.f;
      Bs[n][k ^ (((n >> 3) & 7) << 3)] = f2bf(v);
    }
  }
  float bv[2];
  #pragma unroll
  for (int j = 0; j < 2; ++j){
    int col = n0 + wn*32 + j*16 + (lane & 15);
    bv[j] = (col < 66832) ? b2[col] : 0.f;
  }
  __syncthreads();
  for (int mt = 0; mt < 16; ++mt){
    int m0 = mt * 64;
    { int m = tid >> 2, kb4 = (tid & 3) * 16;
      const unsigned short* hp = hbuf + (m0 + m) * 64 + kb4;
      *(bf16x8*)&As[m][kb4]     = *(const bf16x8*)hp;
      *(bf16x8*)&As[m][kb4 + 8] = *(const bf16x8*)(hp + 8);
    }
    __syncthreads();
    f32x4 acc[2][2] = {};
    #pragma unroll
    for (int ks = 0; ks < 2; ++ks){
      int kb = ks * 32 + (lane >> 4) * 8;
      bf16x8 a[2], bb[2];
      #pragma unroll
      for (int i = 0; i < 2; ++i) a[i] = *(const bf16x8*)&As[wm*32 + i*16 + (lane & 15)][kb];
      #pragma unroll
      for (int j = 0; j < 2; ++j){
        int n = wn*32 + j*16 + (lane & 15);
        bb[j] = *(const bf16x8*)&Bs[n][kb ^ (((n >> 3) & 7) << 3)];
      }
      #pragma unroll
      for (int i = 0; i < 2; ++i)
        #pragma unroll
        for (int j = 0; j < 2; ++j) acc[i][j] = mfma16(a[i], bb[j], acc[i][j]);
    }
    if (cm){
      #pragma unroll
      for (int i = 0; i < 2; ++i)
        #pragma unroll
        for (int j = 0; j < 2; ++j){
          int cl = wn*32 + j*16 + (lane & 15);
          int rl = wm*32 + i*16 + (lane >> 4) * 4;
          unsigned p01 = pk_fp8(acc[i][j][0] + bv[j], acc[i][j][1] + bv[j]);
          unsigned p23 = pk_fp8(acc[i][j][2] + bv[j], acc[i][j][3] + bv[j]);
          Os8[rl + 0][cl] = (unsigned char)(p01 & 0xFFu);
          Os8[rl + 1][cl] = (unsigned char)((p01 >> 8) & 0xFFu);
          Os8[rl + 2][cl] = (unsigned char)(p23 & 0xFFu);
          Os8[rl + 3][cl] = (unsigned char)((p23 >> 8) & 0xFFu);
        }
      __syncthreads();
      {
        int rl = tid >> 2, c0 = (tid & 3) * 16;
        uint2 lo = *(const uint2*)&Os8[rl][c0];
        uint2 hi = *(const uint2*)&Os8[rl][c0 + 8];
        uint4 val; val.x = lo.x; val.y = lo.y; val.z = hi.x; val.w = hi.y;
        *(uint4*)(params8 + ((size_t)nc * 1024 + m0 + rl) * 64 + c0) = val;
      }
    } else {
      #pragma unroll
      for (int i = 0; i < 2; ++i)
        #pragma unroll
        for (int j = 0; j < 2; ++j){
          int cl = wn*32 + j*16 + (lane & 15);
          #pragma unroll
          for (int r = 0; r < 4; ++r){
            int rl = wm*32 + i*16 + (lane >> 4) * 4 + r;
            Os[rl][cl] = f2h(acc[i][j][r] + bv[j]);
          }
        }
      __syncthreads();
      {
        int rl = tid >> 2, c0 = (tid & 3) * 16;
        size_t gbase = ((size_t)(nc - 1024) * 1024 + m0 + rl) * 64 + c0;
        *(bf16x8*)(sm16 + gbase)     = *(const bf16x8*)&Os[rl][c0];
        *(bf16x8*)(sm16 + gbase + 8) = *(const bf16x8*)&Os[rl][c0 + 8];
      }
    }
    __syncthreads();
  }
}

// ---------------- kernel 5: fused sample + per-token adaptive mixing ----------
// Gather coefficients (offsets/weights) hoisted: computed once by 36 threads,
// broadcast via LDS; inner loop is pure load+fma. cm fp8, f16 pipeline.
__global__ __launch_bounds__(256) void k_mixtoken(
    const unsigned short* __restrict__ imgT,      // bf16 [B,H,W,C]
    const float* __restrict__ pts,                // [T,36,2]
    const unsigned char*  __restrict__ params8,   // fp8 cm
    const unsigned short* __restrict__ sm16,      // f16 sm tail
    const float* __restrict__ m_beta, const float* __restrict__ s_beta,
    unsigned short* __restrict__ out2)            // bf16
{
  __shared__ __align__(16) unsigned short smem[29984];
  __shared__ float lpts[72];
  __shared__ float gw[36][4];   // per-point tap weights (masked)
  __shared__ int   gofs[36][4]; // per-point tap element offsets (sans tid)
  const int t = blockIdx.x, tid = threadIdx.x, lane = tid & 63, wave = tid >> 6;
  const int l15 = lane & 15, kb = (lane >> 4) * 8;
  unsigned short (*Ss)[264] = (unsigned short (*)[264])smem;
  const int c31  = tid & 31;
  const int g    = tid >> 5;
  const int goff = (g & 1) * 32;
  const int colw = c31 ^ ((g & 3) << 3);
  const unsigned char* ptok8 = params8 + (size_t)t * 64;
  uint4 rv8[2];
  {
    const unsigned char* src = ptok8 + ((size_t)(c31 * 4 + (g >> 1)) << 16) + goff;
    rv8[0] = *(const uint4*)src;
    rv8[1] = *(const uint4*)(src + 16);
  }
  unsigned short rSm[14];
  #pragma unroll
  for (int k = 0; k < 14; ++k){
    int idx = tid + k * 256;
    unsigned short v = 0;
    if (idx < 3456){
      int o = idx / 72, p = idx % 72;
      if (o < 36 && p < 36){
        int n = 65536 + o * 36 + p;
        v = sm16[(size_t)((n >> 6) - 1024) * 65536 + (size_t)t * 64 + (n & 63)];
      }
    }
    rSm[k] = v;
  }
  // ---- fused sample: coefficients once, then pure load+fma gather ----
  if (tid < 72) lpts[tid] = pts[t * 72 + tid];
  __syncthreads();
  if (tid < 36){
    const int b = t >> 6;
    int p = tid;
    float fx = lpts[p*2]   * 64.f - 0.5f;
    float fy = lpts[p*2+1] * 64.f - 0.5f;
    float x0f = floorf(fx), y0f = floorf(fy);
    float wx = fx - x0f, wy = fy - y0f;
    int x0 = (int)x0f, y0 = (int)y0f;
    #pragma unroll
    for (int dy = 0; dy < 2; ++dy){
      #pragma unroll
      for (int dx = 0; dx < 2; ++dx){
        int xi = x0 + dx, yi = y0 + dy;
        bool valid = (xi >= 0) & (xi < 64) & (yi >= 0) & (yi < 64);
        int xc = min(max(xi, 0), 63), yc = min(max(yi, 0), 63);
        float w = (dx ? wx : 1.f - wx) * (dy ? wy : 1.f - wy);
        gw[p][dy*2 + dx]   = valid ? w : 0.f;
        gofs[p][dy*2 + dx] = ((b * 64 + yc) * 64 + xc) * 256;
      }
    }
  }
  __syncthreads();
  #pragma unroll 4
  for (int p = 0; p < 36; ++p){
    float acc_s = 0.f;
    #pragma unroll
    for (int q = 0; q < 4; ++q)
      acc_s += bf2f(imgT[(size_t)gofs[p][q] + tid]) * gw[p][q];
    Ss[p][tid] = f2h(acc_s);
  }
  __syncthreads();
  f32x4 acc[3][4] = {};
  int cur = 0;
  for (int cc = 0; cc < 8; ++cc){
    unsigned short (*C)[40] = (unsigned short (*)[40])(smem + 9504 + cur * 10240);
    #pragma unroll
    for (int v = 0; v < 2; ++v){
      #pragma unroll
      for (int w = 0; w < 4; ++w){
        unsigned dw = ((const unsigned*)&rv8[v])[w];
        int d0 = g * 32 + v * 16 + w * 4;
        unsigned short r[4];
        dec4_fp8(dw, r);
        C[d0 + 0][colw] = r[0];
        C[d0 + 1][colw] = r[1];
        C[d0 + 2][colw] = r[2];
        C[d0 + 3][colw] = r[3];
      }
    }
    __syncthreads();   // C[cur] ready
    if (cc < 7){
      const unsigned char* src = ptok8 + ((size_t)((cc + 1) * 128 + c31 * 4 + (g >> 1)) << 16) + goff;
      rv8[0] = *(const uint4*)src;
      rv8[1] = *(const uint4*)(src + 16);
    }
    f16x8 a[3], bfr[4];
    a[0] = *(const f16x8*)&Ss[l15][cc * 32 + kb];
    a[1] = *(const f16x8*)&Ss[16 + l15][cc * 32 + kb];
    a[2] = f16x8{};
    if (l15 < 4) a[2] = *(const f16x8*)&Ss[32 + l15][cc * 32 + kb];
    #pragma unroll
    for (int j = 0; j < 4; ++j){
      int d = wave * 64 + j * 16 + l15;
      bfr[j] = *(const f16x8*)&C[d][kb ^ (((d >> 5) & 3) << 3)];
    }
    #pragma unroll
    for (int i = 0; i < 3; ++i)
      #pragma unroll
      for (int j = 0; j < 4; ++j) acc[i][j] = mfma16h(a[i], bfr[j], acc[i][j]);
    cur ^= 1;
  }
  __syncthreads();
  {
    const bf16x8 z = {};
    #pragma unroll
    for (int i = 0; i < 9; ++i)
      *(bf16x8*)&smem[(i * 256 + tid) * 8] = z;
    #pragma unroll
    for (int k = 0; k < 14; ++k){
      int idx = tid + k * 256;
      if (idx < 3456) smem[18432 + idx] = rSm[k];
    }
  }
  __syncthreads();
  unsigned short (*O1T)[72] = (unsigned short (*)[72])smem;
  unsigned short (*Sm)[72]  = (unsigned short (*)[72])(smem + 18432);
  #pragma unroll
  for (int i = 0; i < 3; ++i){
    int p = i * 16 + ((lane >> 4) << 2);
    if (p < 36){
      #pragma unroll
      for (int j = 0; j < 4; ++j){
        int d = wave * 64 + j * 16 + l15;
        float mb = m_beta[d];
        unsigned short* dst = &O1T[d][p];
        #pragma unroll
        for (int r = 0; r < 4; ++r) dst[r] = f2h(gelu_f(acc[i][j][r] + mb));
      }
    }
  }
  __syncthreads();
  f32x4 acc2[3][4] = {};
  #pragma unroll
  for (int ks = 0; ks < 2; ++ks){
    int kb2 = ks * 32 + (lane >> 4) * 8;
    f16x8 a2[3], bf2[4];
    #pragma unroll
    for (int i = 0; i < 3; ++i) a2[i] = *(const f16x8*)&Sm[i*16 + l15][kb2];
    #pragma unroll
    for (int j = 0; j < 4; ++j) bf2[j] = *(const f16x8*)&O1T[wave*64 + j*16 + l15][kb2];
    #pragma unroll
    for (int i = 0; i < 3; ++i)
      #pragma unroll
      for (int j = 0; j < 4; ++j) acc2[i][j] = mfma16h(a2[i], bf2[j], acc2[i][j]);
  }
  unsigned short* o2 = out2 + (size_t)t * 9216;
  #pragma unroll
  for (int i = 0; i < 3; ++i){
    int ob = i*16 + ((lane >> 4) << 2);
    #pragma unroll
    for (int j = 0; j < 4; ++j){
      int d = wave*64 + j*16 + l15;
      #pragma unroll
      for (int r = 0; r < 4; ++r){
        int o = ob + r;
        if (o < 36) o2[o * 256 + d] = f2bf(gelu_f(acc2[i][j][r] + s_beta[o]));
      }
    }
  }
}

// ---------------- generic GEMM: C = act(A @ W + bias) (+resid) ----------------
template<int AK, int ACT, int RES, int OUTB>
__global__ __launch_bounds__(256) void k_gemm(
    const void* __restrict__ Ap, const float* __restrict__ W,
    const float* __restrict__ bias, const float* __restrict__ resid,
    void* __restrict__ Cp, int M, int N, int K)
{
  __shared__ __align__(16) unsigned short As[64][40];  // [m][k]
  __shared__ __align__(16) unsigned short Bs[64][40];  // [n][k^swz]
  const int tid = threadIdx.x, lane = tid & 63, wave = tid >> 6;
  const int wm = wave >> 1, wn = wave & 1;
  const int n0 = blockIdx.x * 64, m0 = blockIdx.y * 64;
  f32x4 acc[2][2] = {};
  for (int kk = 0; kk < K; kk += 32){
    { int m = tid >> 2, k4 = (tid & 3) * 8;
      if (AK == 0){
        const float* ap = (const float*)Ap + (size_t)(m0 + m) * K + kk + k4;
        #pragma unroll
        for (int i = 0; i < 8; ++i) As[m][k4 + i] = f2bf(ap[i]);
      } else {
        const unsigned short* ap = (const unsigned short*)Ap + (size_t)(m0 + m) * K + kk + k4;
        *(bf16x8*)&As[m][k4] = *(const bf16x8*)ap;
      }
    }
    { int kq = tid >> 3, n8 = (tid & 7) * 8;
      const float* wp = W + (size_t)(kk + kq) * N + n0 + n8;
      #pragma unroll
      for (int i = 0; i < 8; ++i){
        int n = n8 + i;
        Bs[n][kq ^ (((n >> 3) & 3) << 3)] = f2bf(wp[i]);
      }
    }
    __syncthreads();
    const int kb = (lane >> 4) * 8;
    bf16x8 a[2], bfr[2];
    #pragma unroll
    for (int i = 0; i < 2; ++i) a[i] = *(const bf16x8*)&As[wm*32 + i*16 + (lane & 15)][kb];
    #pragma unroll
    for (int j = 0; j < 2; ++j){
      int n = wn*32 + j*16 + (lane & 15);
      bfr[j] = *(const bf16x8*)&Bs[n][kb ^ (((n >> 3) & 3) << 3)];
    }
    #pragma unroll
    for (int i = 0; i < 2; ++i)
      #pragma unroll
      for (int j = 0; j < 2; ++j) acc[i][j] = mfma16(a[i], bfr[j], acc[i][j]);
    __syncthreads();
  }
  #pragma unroll
  for (int i = 0; i < 2; ++i)
    #pragma unroll
    for (int j = 0; j < 2; ++j){
      int col = n0 + wn*32 + j*16 + (lane & 15);
      float bv = bias[col];
      #pragma unroll
      for (int r = 0; r < 4; ++r){
        int row = m0 + wm*32 + i*16 + (lane >> 4) * 4 + r;
        float v = acc[i][j][r] + bv;
        if (ACT == 1) v = gelu_f(v);
        if (RES) v += resid[(size_t)row * N + col];
        if (OUTB) ((unsigned short*)Cp)[(size_t)row * N + col] = f2bf(v);
        else      ((float*)Cp)[(size_t)row * N + col] = v;
      }
    }
}

// ---------------- split-K GEMM: part[z][M][N] = A[:, z*KS:(z+1)*KS] @ W[z*KS:...] ----
template<int AK>
__global__ __launch_bounds__(256) void k_gemm_sk(
    const void* __restrict__ Ap, const float* __restrict__ W,
    float* __restrict__ part, int M, int N, int K, int KS)
{
  __shared__ __align__(16) unsigned short As[64][40];  // [m][k]
  __shared__ __align__(16) unsigned short Bs[64][40];  // [n][k^swz]
  const int tid = threadIdx.x, lane = tid & 63, wave = tid >> 6;
  const int wm = wave >> 1, wn = wave & 1;
  const int n0 = blockIdx.x * 64, m0 = blockIdx.y * 64;
  const int kbase = blockIdx.z * KS;
  f32x4 acc[2][2] = {};
  for (int kq = 0; kq < KS; kq += 32){
    int kk = kbase + kq;
    { int m = tid >> 2, k4 = (tid & 3) * 8;
      if (AK == 0){
        const float* ap = (const float*)Ap + (size_t)(m0 + m) * K + kk + k4;
        #pragma unroll
        for (int i = 0; i < 8; ++i) As[m][k4 + i] = f2bf(ap[i]);
      } else {
        const unsigned short* ap = (const unsigned short*)Ap + (size_t)(m0 + m) * K + kk + k4;
        *(bf16x8*)&As[m][k4] = *(const bf16x8*)ap;
      }
    }
    { int kr = tid >> 3, n8 = (tid & 7) * 8;
      const float* wp = W + (size_t)(kk + kr) * N + n0 + n8;
      #pragma unroll
      for (int i = 0; i < 8; ++i){
        int n = n8 + i;
        Bs[n][kr ^ (((n >> 3) & 3) << 3)] = f2bf(wp[i]);
      }
    }
    __syncthreads();
    const int kb = (lane >> 4) * 8;
    bf16x8 a[2], bfr[2];
    #pragma unroll
    for (int i = 0; i < 2; ++i) a[i] = *(const bf16x8*)&As[wm*32 + i*16 + (lane & 15)][kb];
    #pragma unroll
    for (int j = 0; j < 2; ++j){
      int n = wn*32 + j*16 + (lane & 15);
      bfr[j] = *(const bf16x8*)&Bs[n][kb ^ (((n >> 3) & 3) << 3)];
    }
    #pragma unroll
    for (int i = 0; i < 2; ++i)
      #pragma unroll
      for (int j = 0; j < 2; ++j) acc[i][j] = mfma16(a[i], bfr[j], acc[i][j]);
    __syncthreads();
  }
  float* pz = part + (size_t)blockIdx.z * M * N;
  #pragma unroll
  for (int i = 0; i < 2; ++i)
    #pragma unroll
    for (int j = 0; j < 2; ++j){
      int col = n0 + wn*32 + j*16 + (lane & 15);
      #pragma unroll
      for (int r = 0; r < 4; ++r){
        int row = m0 + wm*32 + i*16 + (lane >> 4) * 4 + r;
        pz[(size_t)row * N + col] = acc[i][j][r];
      }
    }
}

// ---------------- split-K reduce: out = sum_z part[z] + bias (+resid) ----------------
template<int RES>
__global__ __launch_bounds__(256) void k_reduce(
    const float* __restrict__ part, const float* __restrict__ bias,
    const float* __restrict__ resid, float* __restrict__ out,
    int total, int N, int SK)
{
  int i = blockIdx.x * 256 + threadIdx.x;
  if (i >= total) return;
  float s = 0.f;
  for (int z = 0; z < SK; ++z) s += part[(size_t)z * total + i];
  s += bias[i % N];
  if (RES) s += resid[i];
  out[i] = s;
}

// ---------------- fused split-K reduce + residual + LayerNorm ----------------
__global__ __launch_bounds__(256) void k_reduce_ln(
    const float* __restrict__ part, const float* __restrict__ bias,
    const float* __restrict__ resid,
    const float* __restrict__ g, const float* __restrict__ bb,
    float* __restrict__ emb_out, unsigned short* __restrict__ ln_out, int SK)
{
  __shared__ float red[4];
  const int t = blockIdx.x, tid = threadIdx.x;
  const int i = t * 256 + tid;
  float s = 0.f;
  for (int z = 0; z < SK; ++z) s += part[(size_t)z * 262144 + i];
  s += bias[tid] + resid[i];
  emb_out[i] = s;
  float mean = block_sum(s, red, tid) * (1.f / 256.f);
  float d = s - mean;
  float var = block_sum(d * d, red, tid) * (1.f / 256.f);
  ln_out[i] = f2bf(d * rsqrtf(var + 1e-5f) * g[tid] + bb[tid]);
}

// ---------------- attention: one (b,h) per block ----------------
__global__ __launch_bounds__(64) void k_attn(const float* __restrict__ qkv,
                                             float* __restrict__ attno)
{
  __shared__ float qs[64][33], ksm[64][33], vsm[64][33];
  const int blk = blockIdx.x, lane = threadIdx.x;
  const int b = blk >> 3, h = blk & 7;
  for (int idx = lane; idx < 2048; idx += 64){
    int row = idx >> 5, d = idx & 31;
    const float* base = qkv + (size_t)(b * 64 + row) * 768 + h * 32 + d;
    qs[row][d] = base[0]; ksm[row][d] = base[256]; vsm[row][d] = base[512];
  }
  __syncthreads();
  float qr[32];
  #pragma unroll
  for (int d = 0; d < 32; ++d) qr[d] = qs[lane][d];
  float s[64]; float mx = -1e30f;
  for (int m = 0; m < 64; ++m){
    float dot = 0.f;
    #pragma unroll
    for (int d = 0; d < 32; ++d) dot += qr[d] * ksm[m][d];
    dot *= 0.17677669529663687f;  // 32^-0.5
    s[m] = dot; mx = fmaxf(mx, dot);
  }
  float sum = 0.f;
  for (int m = 0; m < 64; ++m){ s[m] = expf(s[m] - mx); sum += s[m]; }
  float inv = 1.f / sum;
  float o[32] = {};
  for (int m = 0; m < 64; ++m){
    float p = s[m] * inv;
    #pragma unroll
    for (int d = 0; d < 32; ++d) o[d] += p * vsm[m][d];
  }
  float* dst = attno + (size_t)(b * 64 + lane) * 256 + h * 32;
  #pragma unroll
  for (int d = 0; d < 32; ++d) dst[d] = o[d];
}

__global__ void k_fill(float* p, int n, float v){
  int i = blockIdx.x * 256 + threadIdx.x;
  if (i < n) p[i] = v;
}

// ---------------- launch ----------------
extern "C" void kernel_launch(void* const* d_in, const int* in_sizes, int n_in,
                              void* d_out, int out_size, void* d_ws, size_t ws_size,
                              hipStream_t stream)
{
  const float* img      = (const float*)d_in[0];
  const float* embed    = (const float*)d_in[1];
  const float* roi      = (const float*)d_in[2];
  const float* ln_adj_g = (const float*)d_in[3];
  const float* ln_adj_b = (const float*)d_in[4];
  const float* w_adj    = (const float*)d_in[5];
  const float* ln_off_g = (const float*)d_in[6];
  const float* ln_off_b = (const float*)d_in[7];
  const float* w_off    = (const float*)d_in[8];
  const float* off_bias = (const float*)d_in[9];
  const float* pg_ln_g  = (const float*)d_in[10];
  const float* pg_ln_b  = (const float*)d_in[11];
  const float* pg_w1    = (const float*)d_in[12];
  const float* pg_b1    = (const float*)d_in[13];
  const float* pg_w2    = (const float*)d_in[14];
  const float* pg_b2    = (const float*)d_in[15];
  const float* m_beta   = (const float*)d_in[16];
  const float* s_beta   = (const float*)d_in[17];
  const float* mix_w    = (const float*)d_in[18];
  const float* mix_b    = (const float*)d_in[19];
  const float* ln1_g    = (const float*)d_in[20];
  const float* ln1_b    = (const float*)d_in[21];
  const float* qkv_w    = (const float*)d_in[22];
  const float* qkv_b    = (const float*)d_in[23];
  const float* proj_w   = (const float*)d_in[24];
  const float* proj_b   = (const float*)d_in[25];
  const float* ln2_g    = (const float*)d_in[26];
  const float* ln2_b    = (const float*)d_in[27];
  const float* fc1_w    = (const float*)d_in[28];
  const float* fc1_b    = (const float*)d_in[29];
  const float* fc2_w    = (const float*)d_in[30];
  const float* fc2_b    = (const float*)d_in[31];

  char* ws = (char*)d_ws;
  float*          pts     = (float*)         (ws + 0);          //   294912
  unsigned short* hbuf    = (unsigned short*)(ws + 294912);     //   131072 (bf16)
  unsigned short* imgT    = (unsigned short*)(ws + 557056);     // 33554432
  unsigned char*  params8 = (unsigned char*) (ws + 52985856);   // 67108864 (fp8 cm)
  unsigned short* sm16    = (unsigned short*)(ws + 120094720);  //  2752512 (f16 sm)
  unsigned short* out2    = (unsigned short*)(ws + 122847232);  // 18874368 (bf16)
  float*          embed1  = (float*)         (ws + 141721600);  //  1048576
  float*          embed2  = (float*)         (ws + 142770176);  //  1048576
  unsigned short* xln1    = (unsigned short*)(ws + 143818752);  //   524288
  unsigned short* xln2    = (unsigned short*)(ws + 144343040);  //   524288
  float*          qkvb    = (float*)         (ws + 144867328);  //  3145728
  float*          attno   = (float*)         (ws + 148013056);  //  1048576
  // aliased into the params8 region (dead after k_mixtoken):
  float*          part_mix  = (float*)(ws + 52985856);             // 16 MB (16 slabs)
  float*          part_smll = (float*)(ws + 52985856 + 16777216);  //  4 MB (4 slabs)
  unsigned short* h1        = (unsigned short*)(ws + 52985856 + 20971520); // 2 MB
  const size_t WS_NEEDED = 149061632;
  if (ws_size < WS_NEEDED){
    k_fill<<<(out_size + 255) / 256, 256, 0, stream>>>((float*)d_out, out_size, 12345.0f);
    return;
  }

  float* out = (float*)d_out;

  k_prep<<<1024, 256, 0, stream>>>(embed, roi, ln_adj_g, ln_adj_b, w_adj,
                                   ln_off_g, ln_off_b, w_off, off_bias,
                                   pg_ln_g, pg_ln_b, pg_w1, pg_b1, pts, hbuf);
  k_transpose<<<1024, 256, 0, stream>>>(img, imgT);
  k_params<<<1045, 256, 0, stream>>>(hbuf, pg_w2, pg_b2, params8, sm16);
  k_mixtoken<<<1024, 256, 0, stream>>>(imgT, pts, params8, sm16, m_beta, s_beta, out2);
  // embed1 = embed + out2 @ mix_w + mix_b   (split-K: 9216 = 16 x 576), fused LN1
  k_gemm_sk<1><<<dim3(4,16,16), 256, 0, stream>>>(out2, mix_w, part_mix, 1024, 256, 9216, 576);
  k_reduce_ln<<<1024, 256, 0, stream>>>(part_mix, mix_b, embed, ln1_g, ln1_b, embed1, xln1, 16);
  k_gemm<1,0,0,0><<<dim3(12,16), 256, 0, stream>>>(xln1, qkv_w, qkv_b, nullptr, qkvb, 1024, 768, 256);
  k_attn<<<128, 64, 0, stream>>>(qkvb, attno);
  // embed2 = embed1 + attno @ proj_w + proj_b (split-K: 256 = 4 x 64), fused LN2
  k_gemm_sk<0><<<dim3(4,16,4), 256, 0, stream>>>(attno, proj_w, part_smll, 1024, 256, 256, 64);
  k_reduce_ln<<<1024, 256, 0, stream>>>(part_smll, proj_b, embed1, ln2_g, ln2_b, embed2, xln2, 4);
  k_gemm<1,1,0,1><<<dim3(16,16), 256, 0, stream>>>(xln2, fc1_w, fc1_b, nullptr, h1, 1024, 1024, 256);
  // out = embed2 + h1 @ fc2_w + fc2_b   (split-K: 1024 = 4 x 256)
  k_gemm_sk<1><<<dim3(4,16,4), 256, 0, stream>>>(h1, fc2_w, part_smll, 1024, 256, 1024, 256);
  k_reduce<1><<<1024, 256, 0, stream>>>(part_smll, fc2_b, embed2, out, 262144, 256, 4);
}

// Round 16
// 241.820 us; speedup vs baseline: 1.7478x; 1.0191x over previous
//
#include <hip/hip_runtime.h>
#include <cstdint>

#define DEV __device__ __forceinline__

typedef __attribute__((ext_vector_type(8))) short bf16x8;
typedef __attribute__((ext_vector_type(8))) _Float16 f16x8;
typedef __attribute__((ext_vector_type(2))) __fp16 fp16x2;
typedef __attribute__((ext_vector_type(2))) float f32x2;
typedef __attribute__((ext_vector_type(4))) float f32x4;

DEV unsigned short f2bf(float x){
  union { float f; unsigned u; } c; c.f = x;
  unsigned r = c.u + 0x7fffu + ((c.u >> 16) & 1u);
  return (unsigned short)(r >> 16);
}
DEV float bf2f(unsigned short h){
  union { unsigned u; float f; } c; c.u = ((unsigned)h) << 16;
  return c.f;
}
DEV unsigned short f2h(float x){
  union { unsigned short u; _Float16 h; } c;
  c.h = (_Float16)x;
  return c.u;
}
// f32 -> e4m3 (OCP), RNE, saturate to +-448. Software fallback path.
DEV unsigned char f2fp8(float x){
  union { float f; unsigned u; } c; c.f = x;
  unsigned s = (c.u >> 24) & 0x80u;
  float a = fabsf(x);
  a = fminf(a, 448.f);
  unsigned n;
  if (a < 0.015625f){
    n = (unsigned)(int)rintf(a * 512.f);       // 0..8, RNE; 8 == 2^-6 normal
  } else {
    union { float f; unsigned u; } d; d.f = a;
    unsigned u2 = d.u + 0x7FFFFu + ((d.u >> 20) & 1u);
    n = (((u2 >> 23) - 120u) << 3) | ((u2 >> 20) & 7u);
  }
  return (unsigned char)(s | n);
}
// pack 2 f32 -> 2 e4m3 bytes (byte0 = a, byte1 = b); HW instr on gfx950
DEV unsigned pk_fp8(float a, float b){
#if defined(__has_builtin)
#if __has_builtin(__builtin_amdgcn_cvt_pk_fp8_f32)
  return (unsigned)__builtin_amdgcn_cvt_pk_fp8_f32(a, b, 0, false);
#else
  return (unsigned)f2fp8(a) | ((unsigned)f2fp8(b) << 8);
#endif
#else
  return (unsigned)f2fp8(a) | ((unsigned)f2fp8(b) << 8);
#endif
}
// e4m3 -> f16 bits, exact (software fallback).
DEV unsigned short fp82h(unsigned b){
  union { unsigned short u; _Float16 h; } c;
  c.u = (unsigned short)(((b & 0x80u) << 8) | ((b & 0x7Fu) << 7));
  c.h = c.h * (_Float16)256.0f;
  return c.u;
}
// decode 4 fp8 bytes (one dword, consecutive elements) -> 4 f16 (exact)
DEV void dec4_fp8(unsigned dw, unsigned short r[4]){
#if defined(__has_builtin)
#if __has_builtin(__builtin_amdgcn_cvt_pk_f32_fp8)
  f32x2 lo = __builtin_amdgcn_cvt_pk_f32_fp8((int)dw, false);
  f32x2 hi = __builtin_amdgcn_cvt_pk_f32_fp8((int)dw, true);
  union { fp16x2 h; unsigned short u[2]; } a, b;
  a.h = __builtin_amdgcn_cvt_pkrtz(lo.x, lo.y);   // fp8 values exact in f16 -> RTZ lossless
  b.h = __builtin_amdgcn_cvt_pkrtz(hi.x, hi.y);
  r[0] = a.u[0]; r[1] = a.u[1]; r[2] = b.u[0]; r[3] = b.u[1];
#else
  r[0] = fp82h(dw & 0xFFu); r[1] = fp82h((dw >> 8) & 0xFFu);
  r[2] = fp82h((dw >> 16) & 0xFFu); r[3] = fp82h(dw >> 24);
#endif
#else
  r[0] = fp82h(dw & 0xFFu); r[1] = fp82h((dw >> 8) & 0xFFu);
  r[2] = fp82h((dw >> 16) & 0xFFu); r[3] = fp82h(dw >> 24);
#endif
}

DEV float gelu_f(float x){ return 0.5f * x * (1.f + erff(x * 0.70710678118654752440f)); }

DEV f32x4 mfma16(bf16x8 a, bf16x8 b, f32x4 c){
  return __builtin_amdgcn_mfma_f32_16x16x32_bf16(a, b, c, 0, 0, 0);
}
DEV f32x4 mfma16h(f16x8 a, f16x8 b, f32x4 c){
  return __builtin_amdgcn_mfma_f32_16x16x32_f16(a, b, c, 0, 0, 0);
}

// block_sum: 256 threads (4 waves)
DEV float block_sum(float v, float* red, int tid){
  #pragma unroll
  for (int o = 32; o > 0; o >>= 1) v += __shfl_down(v, o);
  if ((tid & 63) == 0) red[tid >> 6] = v;
  __syncthreads();
  float s = red[0] + red[1] + red[2] + red[3];
  __syncthreads();
  return s;
}

// ---------------- constants ----------------
// B=16 N=64 D=256 CI=256 H=W=64 P=36 HEADS=8 HD=32 HID=1024 TOTAL=66832 T=1024
// cm (n<65536) stored fp8 e4m3, blocked: params8[(n>>6)*65536 + t*64 + (n&63)] bytes
// sm tail (n>=65536) stored f16, blocked: sm16[((n>>6)-1024)*65536 + t*64 + (n&63)]
// hbuf is stored bf16. k_sample fused into k_mixtoken.
// k_mixtoken cc-loop is barrier-free: staging is wave-local (wave w stages and
// consumes d in [w*64, w*64+64)); single Cs buffer -> 45KB LDS, 3 blocks/CU.

// ---------------- kernel 1: per-token prep ----------------
__global__ __launch_bounds__(256) void k_prep(
    const float* __restrict__ embed, const float* __restrict__ roi,
    const float* __restrict__ g_adj, const float* __restrict__ b_adj, const float* __restrict__ w_adj,
    const float* __restrict__ g_off, const float* __restrict__ b_off, const float* __restrict__ w_off,
    const float* __restrict__ off_bias,
    const float* __restrict__ g_pg, const float* __restrict__ b_pg,
    const float* __restrict__ w_pg1, const float* __restrict__ b_pg1,
    float* __restrict__ pts, unsigned short* __restrict__ hbuf)
{
  __shared__ float red[4];
  __shared__ float xln[256];
  __shared__ float offs[72];
  __shared__ float lg[4];
  __shared__ float stat[8];
  const int t = blockIdx.x, tid = threadIdx.x;
  float e = embed[t * 256 + tid];
  float mean = block_sum(e, red, tid) * (1.f / 256.f);
  float dv = e - mean;
  float var = block_sum(dv * dv, red, tid) * (1.f / 256.f);
  xln[tid] = dv * rsqrtf(var + 1e-5f);
  __syncthreads();
  if (tid < 4){
    float a0 = 0.f, a1 = 0.f, a2 = 0.f, a3 = 0.f;
    #pragma unroll 4
    for (int c = 0; c < 256; c += 4){
      a0 += (xln[c+0] * g_adj[c+0] + b_adj[c+0]) * w_adj[(c+0) * 4 + tid];
      a1 += (xln[c+1] * g_adj[c+1] + b_adj[c+1]) * w_adj[(c+1) * 4 + tid];
      a2 += (xln[c+2] * g_adj[c+2] + b_adj[c+2]) * w_adj[(c+2) * 4 + tid];
      a3 += (xln[c+3] * g_adj[c+3] + b_adj[c+3]) * w_adj[(c+3) * 4 + tid];
    }
    lg[tid] = (a0 + a1) + (a2 + a3);
  } else if (tid < 76){
    int j = tid - 4;
    float a0 = 0.f, a1 = 0.f, a2 = 0.f, a3 = 0.f;
    #pragma unroll 4
    for (int c = 0; c < 256; c += 4){
      a0 += (xln[c+0] * g_off[c+0] + b_off[c+0]) * w_off[(c+0) * 72 + j];
      a1 += (xln[c+1] * g_off[c+1] + b_off[c+1]) * w_off[(c+1) * 72 + j];
      a2 += (xln[c+2] * g_off[c+2] + b_off[c+2]) * w_off[(c+2) * 72 + j];
      a3 += (xln[c+3] * g_off[c+3] + b_off[c+3]) * w_off[(c+3) * 72 + j];
    }
    offs[j] = (a0 + a1) + (a2 + a3) + off_bias[j];
  } else if (tid < 140){
    int j = tid - 76;
    float a0 = 0.f, a1 = 0.f, a2 = 0.f, a3 = 0.f;
    #pragma unroll 4
    for (int c = 0; c < 256; c += 4){
      a0 += (xln[c+0] * g_pg[c+0] + b_pg[c+0]) * w_pg1[(c+0) * 64 + j];
      a1 += (xln[c+1] * g_pg[c+1] + b_pg[c+1]) * w_pg1[(c+1) * 64 + j];
      a2 += (xln[c+2] * g_pg[c+2] + b_pg[c+2]) * w_pg1[(c+2) * 64 + j];
      a3 += (xln[c+3] * g_pg[c+3] + b_pg[c+3]) * w_pg1[(c+3) * 64 + j];
    }
    hbuf[t * 64 + j] = f2bf((a0 + a1) + (a2 + a3) + b_pg1[j]);
  }
  __syncthreads();
  if (tid == 0){
    float x0 = roi[t*4+0], y0 = roi[t*4+1], x1 = roi[t*4+2], y1 = roi[t*4+3];
    float cx = (x0 + x1) * 0.5f, cy = (y0 + y1) * 0.5f;
    float w = fabsf(x1 - x0), hh = fabsf(y1 - y0);
    cx += lg[0] * w; cy += lg[1] * hh;
    w *= expf(lg[2]); hh *= expf(lg[3]);
    stat[0] = cx; stat[1] = cy; stat[2] = w; stat[3] = hh;
  }
  if (tid < 2){
    float mu = 0.f;
    for (int p = 0; p < 36; ++p) mu += offs[p*2 + tid];
    mu *= (1.f / 36.f);
    float v2 = 0.f;
    for (int p = 0; p < 36; ++p){ float d = offs[p*2 + tid] - mu; v2 += d * d; }
    float sd = sqrtf(v2 * (1.f / 35.f)) + 1e-7f;   // ddof=1
    stat[4 + tid] = mu; stat[6 + tid] = 1.f / (3.f * sd);
  }
  __syncthreads();
  if (tid < 72){
    int c = tid & 1;
    pts[t * 72 + tid] = stat[c] + (offs[tid] - stat[4 + c]) * stat[6 + c] * stat[2 + c];
  }
}

// ---------------- kernel 2: img [B,C,H,W] f32 -> [B,H,W,C] bf16 ----------------
__global__ __launch_bounds__(256) void k_transpose(const float* __restrict__ img,
                                                   unsigned short* __restrict__ imgT)
{
  __shared__ float tile[128][65];
  const int blk = blockIdx.x, tid = threadIdx.x;
  const int b = blk >> 6, y = blk & 63;
  for (int half = 0; half < 2; ++half){
    int c_loc = tid >> 1, x0 = (tid & 1) * 32;
    const float* src = img + (((size_t)(b * 256 + half * 128 + c_loc)) * 64 + y) * 64 + x0;
    #pragma unroll
    for (int i = 0; i < 32; ++i) tile[c_loc][x0 + i] = src[i];
    __syncthreads();
    {
      int x = tid >> 2, c0 = (tid & 3) * 32;
      size_t obase = (((size_t)(b * 64 + y)) * 64 + x) * 256 + half * 128 + c0;
      #pragma unroll
      for (int cb = 0; cb < 32; cb += 8){
        unsigned short tmp[8];
        #pragma unroll
        for (int j = 0; j < 8; ++j) tmp[j] = f2bf(tile[c0 + cb + j][x]);
        *(bf16x8*)(imgT + obase + cb) = *(const bf16x8*)tmp;
      }
    }
    __syncthreads();
  }
}

// ---------------- kernel 4: params = h @ pg_w2 + pg_b2 (M=1024,K=64,N=66832)
// cm chunks (nc<1024) -> fp8 e4m3 via HW cvt_pk; sm tail (nc>=1024) -> f16.
__global__ __launch_bounds__(256) void k_params(
    const unsigned short* __restrict__ hbuf, const float* __restrict__ w2,
    const float* __restrict__ b2, unsigned char* __restrict__ params8,
    unsigned short* __restrict__ sm16)
{
  __shared__ __align__(16) unsigned short Bs[64][72];  // [n][k^swz]
  __shared__ __align__(16) unsigned short As[64][72];  // [m][k]
  __shared__ __align__(16) unsigned short Os[64][72];  // f16 staging (sm path)
  __shared__ __align__(16) unsigned char  Os8[64][72]; // fp8 staging (cm path)
  const int tid = threadIdx.x, lane = tid & 63, wave = tid >> 6;
  const int wm = wave >> 1, wn = wave & 1;
  const int nc = blockIdx.x, n0 = nc * 64;
  const bool cm = (nc < 1024);
  {
    int k = tid >> 2, nb = (tid & 3) * 16;
    #pragma unroll
    for (int i = 0; i < 16; ++i){
      int n = nb + i, gn = n0 + n;
      float v = (gn < 66832) ? w2[(size_t)k * 66832 + gn] : 0.f;
      Bs[n][k ^ (((n >> 3) & 7) << 3)] = f2bf(v);
    }
  }
  float bv[2];
  #pragma unroll
  for (int j = 0; j < 2; ++j){
    int col = n0 + wn*32 + j*16 + (lane & 15);
    bv[j] = (col < 66832) ? b2[col] : 0.f;
  }
  __syncthreads();
  for (int mt = 0; mt < 16; ++mt){
    int m0 = mt * 64;
    { int m = tid >> 2, kb4 = (tid & 3) * 16;
      const unsigned short* hp = hbuf + (m0 + m) * 64 + kb4;
      *(bf16x8*)&As[m][kb4]     = *(const bf16x8*)hp;
      *(bf16x8*)&As[m][kb4 + 8] = *(const bf16x8*)(hp + 8);
    }
    __syncthreads();
    f32x4 acc[2][2] = {};
    #pragma unroll
    for (int ks = 0; ks < 2; ++ks){
      int kb = ks * 32 + (lane >> 4) * 8;
      bf16x8 a[2], bb[2];
      #pragma unroll
      for (int i = 0; i < 2; ++i) a[i] = *(const bf16x8*)&As[wm*32 + i*16 + (lane & 15)][kb];
      #pragma unroll
      for (int j = 0; j < 2; ++j){
        int n = wn*32 + j*16 + (lane & 15);
        bb[j] = *(const bf16x8*)&Bs[n][kb ^ (((n >> 3) & 7) << 3)];
      }
      #pragma unroll
      for (int i = 0; i < 2; ++i)
        #pragma unroll
        for (int j = 0; j < 2; ++j) acc[i][j] = mfma16(a[i], bb[j], acc[i][j]);
    }
    if (cm){
      #pragma unroll
      for (int i = 0; i < 2; ++i)
        #pragma unroll
        for (int j = 0; j < 2; ++j){
          int cl = wn*32 + j*16 + (lane & 15);
          int rl = wm*32 + i*16 + (lane >> 4) * 4;
          unsigned p01 = pk_fp8(acc[i][j][0] + bv[j], acc[i][j][1] + bv[j]);
          unsigned p23 = pk_fp8(acc[i][j][2] + bv[j], acc[i][j][3] + bv[j]);
          Os8[rl + 0][cl] = (unsigned char)(p01 & 0xFFu);
          Os8[rl + 1][cl] = (unsigned char)((p01 >> 8) & 0xFFu);
          Os8[rl + 2][cl] = (unsigned char)(p23 & 0xFFu);
          Os8[rl + 3][cl] = (unsigned char)((p23 >> 8) & 0xFFu);
        }
      __syncthreads();
      {
        int rl = tid >> 2, c0 = (tid & 3) * 16;
        uint2 lo = *(const uint2*)&Os8[rl][c0];
        uint2 hi = *(const uint2*)&Os8[rl][c0 + 8];
        uint4 val; val.x = lo.x; val.y = lo.y; val.z = hi.x; val.w = hi.y;
        *(uint4*)(params8 + ((size_t)nc * 1024 + m0 + rl) * 64 + c0) = val;
      }
    } else {
      #pragma unroll
      for (int i = 0; i < 2; ++i)
        #pragma unroll
        for (int j = 0; j < 2; ++j){
          int cl = wn*32 + j*16 + (lane & 15);
          #pragma unroll
          for (int r = 0; r < 4; ++r){
            int rl = wm*32 + i*16 + (lane >> 4) * 4 + r;
            Os[rl][cl] = f2h(acc[i][j][r] + bv[j]);
          }
        }
      __syncthreads();
      {
        int rl = tid >> 2, c0 = (tid & 3) * 16;
        size_t gbase = ((size_t)(nc - 1024) * 1024 + m0 + rl) * 64 + c0;
        *(bf16x8*)(sm16 + gbase)     = *(const bf16x8*)&Os[rl][c0];
        *(bf16x8*)(sm16 + gbase + 8) = *(const bf16x8*)&Os[rl][c0 + 8];
      }
    }
    __syncthreads();
  }
}

// ---------------- kernel 5: fused sample + per-token adaptive mixing ----------
// cc-loop barrier-free (wave-local staging, single Cs buffer, 45KB LDS).
__global__ __launch_bounds__(256) void k_mixtoken(
    const unsigned short* __restrict__ imgT,      // bf16 [B,H,W,C]
    const float* __restrict__ pts,                // [T,36,2]
    const unsigned char*  __restrict__ params8,   // fp8 cm
    const unsigned short* __restrict__ sm16,      // f16 sm tail
    const float* __restrict__ m_beta, const float* __restrict__ s_beta,
    unsigned short* __restrict__ out2)            // bf16
{
  __shared__ __align__(16) unsigned short smem[21888];
  __shared__ float lpts[72];
  __shared__ float gw[36][4];   // per-point tap weights (masked)
  __shared__ int   gofs[36][4]; // per-point tap element offsets (sans tid)
  const int t = blockIdx.x, tid = threadIdx.x, lane = tid & 63, wave = tid >> 6;
  const int l15 = lane & 15, kb = (lane >> 4) * 8;
  unsigned short (*Ss)[264] = (unsigned short (*)[264])smem;
  unsigned short (*C)[40]   = (unsigned short (*)[40])(smem + 9504); // single buffer
  const int c31  = tid & 31;
  const int g    = tid >> 5;
  const int goff = (g & 1) * 32;
  const int colw = c31 ^ ((g & 3) << 3);
  const unsigned char* ptok8 = params8 + (size_t)t * 64;
  uint4 rv8[2];
  {
    const unsigned char* src = ptok8 + ((size_t)(c31 * 4 + (g >> 1)) << 16) + goff;
    rv8[0] = *(const uint4*)src;
    rv8[1] = *(const uint4*)(src + 16);
  }
  unsigned short rSm[14];
  #pragma unroll
  for (int k = 0; k < 14; ++k){
    int idx = tid + k * 256;
    unsigned short v = 0;
    if (idx < 3456){
      int o = idx / 72, p = idx % 72;
      if (o < 36 && p < 36){
        int n = 65536 + o * 36 + p;
        v = sm16[(size_t)((n >> 6) - 1024) * 65536 + (size_t)t * 64 + (n & 63)];
      }
    }
    rSm[k] = v;
  }
  // ---- fused sample: coefficients once, then pure load+fma gather ----
  if (tid < 72) lpts[tid] = pts[t * 72 + tid];
  __syncthreads();
  if (tid < 36){
    const int b = t >> 6;
    int p = tid;
    float fx = lpts[p*2]   * 64.f - 0.5f;
    float fy = lpts[p*2+1] * 64.f - 0.5f;
    float x0f = floorf(fx), y0f = floorf(fy);
    float wx = fx - x0f, wy = fy - y0f;
    int x0 = (int)x0f, y0 = (int)y0f;
    #pragma unroll
    for (int dy = 0; dy < 2; ++dy){
      #pragma unroll
      for (int dx = 0; dx < 2; ++dx){
        int xi = x0 + dx, yi = y0 + dy;
        bool valid = (xi >= 0) & (xi < 64) & (yi >= 0) & (yi < 64);
        int xc = min(max(xi, 0), 63), yc = min(max(yi, 0), 63);
        float w = (dx ? wx : 1.f - wx) * (dy ? wy : 1.f - wy);
        gw[p][dy*2 + dx]   = valid ? w : 0.f;
        gofs[p][dy*2 + dx] = ((b * 64 + yc) * 64 + xc) * 256;
      }
    }
  }
  __syncthreads();
  #pragma unroll 4
  for (int p = 0; p < 36; ++p){
    float acc_s = 0.f;
    #pragma unroll
    for (int q = 0; q < 4; ++q)
      acc_s += bf2f(imgT[(size_t)gofs[p][q] + tid]) * gw[p][q];
    Ss[p][tid] = f2h(acc_s);
  }
  __syncthreads();
  // ---- phase 1: barrier-free cc loop (wave-local staging) ----
  f32x4 acc[3][4] = {};
  for (int cc = 0; cc < 8; ++cc){
    #pragma unroll
    for (int v = 0; v < 2; ++v){
      #pragma unroll
      for (int w = 0; w < 4; ++w){
        unsigned dw = ((const unsigned*)&rv8[v])[w];
        int d0 = g * 32 + v * 16 + w * 4;
        unsigned short r[4];
        dec4_fp8(dw, r);
        C[d0 + 0][colw] = r[0];
        C[d0 + 1][colw] = r[1];
        C[d0 + 2][colw] = r[2];
        C[d0 + 3][colw] = r[3];
      }
    }
    if (cc < 7){
      const unsigned char* src = ptok8 + ((size_t)((cc + 1) * 128 + c31 * 4 + (g >> 1)) << 16) + goff;
      rv8[0] = *(const uint4*)src;
      rv8[1] = *(const uint4*)(src + 16);
    }
    f16x8 a[3], bfr[4];
    a[0] = *(const f16x8*)&Ss[l15][cc * 32 + kb];
    a[1] = *(const f16x8*)&Ss[16 + l15][cc * 32 + kb];
    a[2] = f16x8{};
    if (l15 < 4) a[2] = *(const f16x8*)&Ss[32 + l15][cc * 32 + kb];
    #pragma unroll
    for (int j = 0; j < 4; ++j){
      int d = wave * 64 + j * 16 + l15;   // within this wave's staged d-range
      bfr[j] = *(const f16x8*)&C[d][kb ^ (((d >> 5) & 3) << 3)];
    }
    #pragma unroll
    for (int i = 0; i < 3; ++i)
      #pragma unroll
      for (int j = 0; j < 4; ++j) acc[i][j] = mfma16h(a[i], bfr[j], acc[i][j]);
  }
  __syncthreads();
  {
    const bf16x8 z = {};
    #pragma unroll
    for (int i = 0; i < 9; ++i)
      *(bf16x8*)&smem[(i * 256 + tid) * 8] = z;
    #pragma unroll
    for (int k = 0; k < 14; ++k){
      int idx = tid + k * 256;
      if (idx < 3456) smem[18432 + idx] = rSm[k];
    }
  }
  __syncthreads();
  unsigned short (*O1T)[72] = (unsigned short (*)[72])smem;
  unsigned short (*Sm)[72]  = (unsigned short (*)[72])(smem + 18432);
  #pragma unroll
  for (int i = 0; i < 3; ++i){
    int p = i * 16 + ((lane >> 4) << 2);
    if (p < 36){
      #pragma unroll
      for (int j = 0; j < 4; ++j){
        int d = wave * 64 + j * 16 + l15;
        float mb = m_beta[d];
        unsigned short* dst = &O1T[d][p];
        #pragma unroll
        for (int r = 0; r < 4; ++r) dst[r] = f2h(gelu_f(acc[i][j][r] + mb));
      }
    }
  }
  __syncthreads();
  f32x4 acc2[3][4] = {};
  #pragma unroll
  for (int ks = 0; ks < 2; ++ks){
    int kb2 = ks * 32 + (lane >> 4) * 8;
    f16x8 a2[3], bf2[4];
    #pragma unroll
    for (int i = 0; i < 3; ++i) a2[i] = *(const f16x8*)&Sm[i*16 + l15][kb2];
    #pragma unroll
    for (int j = 0; j < 4; ++j) bf2[j] = *(const f16x8*)&O1T[wave*64 + j*16 + l15][kb2];
    #pragma unroll
    for (int i = 0; i < 3; ++i)
      #pragma unroll
      for (int j = 0; j < 4; ++j) acc2[i][j] = mfma16h(a2[i], bf2[j], acc2[i][j]);
  }
  unsigned short* o2 = out2 + (size_t)t * 9216;
  #pragma unroll
  for (int i = 0; i < 3; ++i){
    int ob = i*16 + ((lane >> 4) << 2);
    #pragma unroll
    for (int j = 0; j < 4; ++j){
      int d = wave*64 + j*16 + l15;
      #pragma unroll
      for (int r = 0; r < 4; ++r){
        int o = ob + r;
        if (o < 36) o2[o * 256 + d] = f2bf(gelu_f(acc2[i][j][r] + s_beta[o]));
      }
    }
  }
}

// ---------------- generic GEMM: C = act(A @ W + bias) (+resid) ----------------
template<int AK, int ACT, int RES, int OUTB>
__global__ __launch_bounds__(256) void k_gemm(
    const void* __restrict__ Ap, const float* __restrict__ W,
    const float* __restrict__ bias, const float* __restrict__ resid,
    void* __restrict__ Cp, int M, int N, int K)
{
  __shared__ __align__(16) unsigned short As[64][40];  // [m][k]
  __shared__ __align__(16) unsigned short Bs[64][40];  // [n][k^swz]
  const int tid = threadIdx.x, lane = tid & 63, wave = tid >> 6;
  const int wm = wave >> 1, wn = wave & 1;
  const int n0 = blockIdx.x * 64, m0 = blockIdx.y * 64;
  f32x4 acc[2][2] = {};
  for (int kk = 0; kk < K; kk += 32){
    { int m = tid >> 2, k4 = (tid & 3) * 8;
      if (AK == 0){
        const float* ap = (const float*)Ap + (size_t)(m0 + m) * K + kk + k4;
        #pragma unroll
        for (int i = 0; i < 8; ++i) As[m][k4 + i] = f2bf(ap[i]);
      } else {
        const unsigned short* ap = (const unsigned short*)Ap + (size_t)(m0 + m) * K + kk + k4;
        *(bf16x8*)&As[m][k4] = *(const bf16x8*)ap;
      }
    }
    { int kq = tid >> 3, n8 = (tid & 7) * 8;
      const float* wp = W + (size_t)(kk + kq) * N + n0 + n8;
      #pragma unroll
      for (int i = 0; i < 8; ++i){
        int n = n8 + i;
        Bs[n][kq ^ (((n >> 3) & 3) << 3)] = f2bf(wp[i]);
      }
    }
    __syncthreads();
    const int kb = (lane >> 4) * 8;
    bf16x8 a[2], bfr[2];
    #pragma unroll
    for (int i = 0; i < 2; ++i) a[i] = *(const bf16x8*)&As[wm*32 + i*16 + (lane & 15)][kb];
    #pragma unroll
    for (int j = 0; j < 2; ++j){
      int n = wn*32 + j*16 + (lane & 15);
      bfr[j] = *(const bf16x8*)&Bs[n][kb ^ (((n >> 3) & 3) << 3)];
    }
    #pragma unroll
    for (int i = 0; i < 2; ++i)
      #pragma unroll
      for (int j = 0; j < 2; ++j) acc[i][j] = mfma16(a[i], bfr[j], acc[i][j]);
    __syncthreads();
  }
  #pragma unroll
  for (int i = 0; i < 2; ++i)
    #pragma unroll
    for (int j = 0; j < 2; ++j){
      int col = n0 + wn*32 + j*16 + (lane & 15);
      float bv = bias[col];
      #pragma unroll
      for (int r = 0; r < 4; ++r){
        int row = m0 + wm*32 + i*16 + (lane >> 4) * 4 + r;
        float v = acc[i][j][r] + bv;
        if (ACT == 1) v = gelu_f(v);
        if (RES) v += resid[(size_t)row * N + col];
        if (OUTB) ((unsigned short*)Cp)[(size_t)row * N + col] = f2bf(v);
        else      ((float*)Cp)[(size_t)row * N + col] = v;
      }
    }
}

// ---------------- split-K GEMM: part[z][M][N] = A[:, z*KS:(z+1)*KS] @ W[z*KS:...] ----
template<int AK>
__global__ __launch_bounds__(256) void k_gemm_sk(
    const void* __restrict__ Ap, const float* __restrict__ W,
    float* __restrict__ part, int M, int N, int K, int KS)
{
  __shared__ __align__(16) unsigned short As[64][40];  // [m][k]
  __shared__ __align__(16) unsigned short Bs[64][40];  // [n][k^swz]
  const int tid = threadIdx.x, lane = tid & 63, wave = tid >> 6;
  const int wm = wave >> 1, wn = wave & 1;
  const int n0 = blockIdx.x * 64, m0 = blockIdx.y * 64;
  const int kbase = blockIdx.z * KS;
  f32x4 acc[2][2] = {};
  for (int kq = 0; kq < KS; kq += 32){
    int kk = kbase + kq;
    { int m = tid >> 2, k4 = (tid & 3) * 8;
      if (AK == 0){
        const float* ap = (const float*)Ap + (size_t)(m0 + m) * K + kk + k4;
        #pragma unroll
        for (int i = 0; i < 8; ++i) As[m][k4 + i] = f2bf(ap[i]);
      } else {
        const unsigned short* ap = (const unsigned short*)Ap + (size_t)(m0 + m) * K + kk + k4;
        *(bf16x8*)&As[m][k4] = *(const bf16x8*)ap;
      }
    }
    { int kr = tid >> 3, n8 = (tid & 7) * 8;
      const float* wp = W + (size_t)(kk + kr) * N + n0 + n8;
      #pragma unroll
      for (int i = 0; i < 8; ++i){
        int n = n8 + i;
        Bs[n][kr ^ (((n >> 3) & 3) << 3)] = f2bf(wp[i]);
      }
    }
    __syncthreads();
    const int kb = (lane >> 4) * 8;
    bf16x8 a[2], bfr[2];
    #pragma unroll
    for (int i = 0; i < 2; ++i) a[i] = *(const bf16x8*)&As[wm*32 + i*16 + (lane & 15)][kb];
    #pragma unroll
    for (int j = 0; j < 2; ++j){
      int n = wn*32 + j*16 + (lane & 15);
      bfr[j] = *(const bf16x8*)&Bs[n][kb ^ (((n >> 3) & 3) << 3)];
    }
    #pragma unroll
    for (int i = 0; i < 2; ++i)
      #pragma unroll
      for (int j = 0; j < 2; ++j) acc[i][j] = mfma16(a[i], bfr[j], acc[i][j]);
    __syncthreads();
  }
  float* pz = part + (size_t)blockIdx.z * M * N;
  #pragma unroll
  for (int i = 0; i < 2; ++i)
    #pragma unroll
    for (int j = 0; j < 2; ++j){
      int col = n0 + wn*32 + j*16 + (lane & 15);
      #pragma unroll
      for (int r = 0; r < 4; ++r){
        int row = m0 + wm*32 + i*16 + (lane >> 4) * 4 + r;
        pz[(size_t)row * N + col] = acc[i][j][r];
      }
    }
}

// ---------------- split-K reduce: out = sum_z part[z] + bias (+resid) ----------------
template<int RES>
__global__ __launch_bounds__(256) void k_reduce(
    const float* __restrict__ part, const float* __restrict__ bias,
    const float* __restrict__ resid, float* __restrict__ out,
    int total, int N, int SK)
{
  int i = blockIdx.x * 256 + threadIdx.x;
  if (i >= total) return;
  float s = 0.f;
  for (int z = 0; z < SK; ++z) s += part[(size_t)z * total + i];
  s += bias[i % N];
  if (RES) s += resid[i];
  out[i] = s;
}

// ---------------- fused split-K reduce + residual + LayerNorm ----------------
__global__ __launch_bounds__(256) void k_reduce_ln(
    const float* __restrict__ part, const float* __restrict__ bias,
    const float* __restrict__ resid,
    const float* __restrict__ g, const float* __restrict__ bb,
    float* __restrict__ emb_out, unsigned short* __restrict__ ln_out, int SK)
{
  __shared__ float red[4];
  const int t = blockIdx.x, tid = threadIdx.x;
  const int i = t * 256 + tid;
  float s = 0.f;
  for (int z = 0; z < SK; ++z) s += part[(size_t)z * 262144 + i];
  s += bias[tid] + resid[i];
  emb_out[i] = s;
  float mean = block_sum(s, red, tid) * (1.f / 256.f);
  float d = s - mean;
  float var = block_sum(d * d, red, tid) * (1.f / 256.f);
  ln_out[i] = f2bf(d * rsqrtf(var + 1e-5f) * g[tid] + bb[tid]);
}

// ---------------- attention: one (b,h) per block ----------------
__global__ __launch_bounds__(64) void k_attn(const float* __restrict__ qkv,
                                             float* __restrict__ attno)
{
  __shared__ float qs[64][33], ksm[64][33], vsm[64][33];
  const int blk = blockIdx.x, lane = threadIdx.x;
  const int b = blk >> 3, h = blk & 7;
  for (int idx = lane; idx < 2048; idx += 64){
    int row = idx >> 5, d = idx & 31;
    const float* base = qkv + (size_t)(b * 64 + row) * 768 + h * 32 + d;
    qs[row][d] = base[0]; ksm[row][d] = base[256]; vsm[row][d] = base[512];
  }
  __syncthreads();
  float qr[32];
  #pragma unroll
  for (int d = 0; d < 32; ++d) qr[d] = qs[lane][d];
  float s[64]; float mx = -1e30f;
  for (int m = 0; m < 64; ++m){
    float dot = 0.f;
    #pragma unroll
    for (int d = 0; d < 32; ++d) dot += qr[d] * ksm[m][d];
    dot *= 0.17677669529663687f;  // 32^-0.5
    s[m] = dot; mx = fmaxf(mx, dot);
  }
  float sum = 0.f;
  for (int m = 0; m < 64; ++m){ s[m] = expf(s[m] - mx); sum += s[m]; }
  float inv = 1.f / sum;
  float o[32] = {};
  for (int m = 0; m < 64; ++m){
    float p = s[m] * inv;
    #pragma unroll
    for (int d = 0; d < 32; ++d) o[d] += p * vsm[m][d];
  }
  float* dst = attno + (size_t)(b * 64 + lane) * 256 + h * 32;
  #pragma unroll
  for (int d = 0; d < 32; ++d) dst[d] = o[d];
}

__global__ void k_fill(float* p, int n, float v){
  int i = blockIdx.x * 256 + threadIdx.x;
  if (i < n) p[i] = v;
}

// ---------------- launch ----------------
extern "C" void kernel_launch(void* const* d_in, const int* in_sizes, int n_in,
                              void* d_out, int out_size, void* d_ws, size_t ws_size,
                              hipStream_t stream)
{
  const float* img      = (const float*)d_in[0];
  const float* embed    = (const float*)d_in[1];
  const float* roi      = (const float*)d_in[2];
  const float* ln_adj_g = (const float*)d_in[3];
  const float* ln_adj_b = (const float*)d_in[4];
  const float* w_adj    = (const float*)d_in[5];
  const float* ln_off_g = (const float*)d_in[6];
  const float* ln_off_b = (const float*)d_in[7];
  const float* w_off    = (const float*)d_in[8];
  const float* off_bias = (const float*)d_in[9];
  const float* pg_ln_g  = (const float*)d_in[10];
  const float* pg_ln_b  = (const float*)d_in[11];
  const float* pg_w1    = (const float*)d_in[12];
  const float* pg_b1    = (const float*)d_in[13];
  const float* pg_w2    = (const float*)d_in[14];
  const float* pg_b2    = (const float*)d_in[15];
  const float* m_beta   = (const float*)d_in[16];
  const float* s_beta   = (const float*)d_in[17];
  const float* mix_w    = (const float*)d_in[18];
  const float* mix_b    = (const float*)d_in[19];
  const float* ln1_g    = (const float*)d_in[20];
  const float* ln1_b    = (const float*)d_in[21];
  const float* qkv_w    = (const float*)d_in[22];
  const float* qkv_b    = (const float*)d_in[23];
  const float* proj_w   = (const float*)d_in[24];
  const float* proj_b   = (const float*)d_in[25];
  const float* ln2_g    = (const float*)d_in[26];
  const float* ln2_b    = (const float*)d_in[27];
  const float* fc1_w    = (const float*)d_in[28];
  const float* fc1_b    = (const float*)d_in[29];
  const float* fc2_w    = (const float*)d_in[30];
  const float* fc2_b    = (const float*)d_in[31];

  char* ws = (char*)d_ws;
  float*          pts     = (float*)         (ws + 0);          //   294912
  unsigned short* hbuf    = (unsigned short*)(ws + 294912);     //   131072 (bf16)
  unsigned short* imgT    = (unsigned short*)(ws + 557056);     // 33554432
  unsigned char*  params8 = (unsigned char*) (ws + 52985856);   // 67108864 (fp8 cm)
  unsigned short* sm16    = (unsigned short*)(ws + 120094720);  //  2752512 (f16 sm)
  unsigned short* out2    = (unsigned short*)(ws + 122847232);  // 18874368 (bf16)
  float*          embed1  = (float*)         (ws + 141721600);  //  1048576
  float*          embed2  = (float*)         (ws + 142770176);  //  1048576
  unsigned short* xln1    = (unsigned short*)(ws + 143818752);  //   524288
  unsigned short* xln2    = (unsigned short*)(ws + 144343040);  //   524288
  float*          qkvb    = (float*)         (ws + 144867328);  //  3145728
  float*          attno   = (float*)         (ws + 148013056);  //  1048576
  // aliased into the params8 region (dead after k_mixtoken):
  float*          part_mix  = (float*)(ws + 52985856);             // 16 MB (16 slabs)
  float*          part_smll = (float*)(ws + 52985856 + 16777216);  //  4 MB (4 slabs)
  unsigned short* h1        = (unsigned short*)(ws + 52985856 + 20971520); // 2 MB
  const size_t WS_NEEDED = 149061632;
  if (ws_size < WS_NEEDED){
    k_fill<<<(out_size + 255) / 256, 256, 0, stream>>>((float*)d_out, out_size, 12345.0f);
    return;
  }

  float* out = (float*)d_out;

  k_prep<<<1024, 256, 0, stream>>>(embed, roi, ln_adj_g, ln_adj_b, w_adj,
                                   ln_off_g, ln_off_b, w_off, off_bias,
                                   pg_ln_g, pg_ln_b, pg_w1, pg_b1, pts, hbuf);
  k_transpose<<<1024, 256, 0, stream>>>(img, imgT);
  k_params<<<1045, 256, 0, stream>>>(hbuf, pg_w2, pg_b2, params8, sm16);
  k_mixtoken<<<1024, 256, 0, stream>>>(imgT, pts, params8, sm16, m_beta, s_beta, out2);
  // embed1 = embed + out2 @ mix_w + mix_b   (split-K: 9216 = 16 x 576), fused LN1
  k_gemm_sk<1><<<dim3(4,16,16), 256, 0, stream>>>(out2, mix_w, part_mix, 1024, 256, 9216, 576);
  k_reduce_ln<<<1024, 256, 0, stream>>>(part_mix, mix_b, embed, ln1_g, ln1_b, embed1, xln1, 16);
  k_gemm<1,0,0,0><<<dim3(12,16), 256, 0, stream>>>(xln1, qkv_w, qkv_b, nullptr, qkvb, 1024, 768, 256);
  k_attn<<<128, 64, 0, stream>>>(qkvb, attno);
  // embed2 = embed1 + attno @ proj_w + proj_b (split-K: 256 = 4 x 64), fused LN2
  k_gemm_sk<0><<<dim3(4,16,4), 256, 0, stream>>>(attno, proj_w, part_smll, 1024, 256, 256, 64);
  k_reduce_ln<<<1024, 256, 0, stream>>>(part_smll, proj_b, embed1, ln2_g, ln2_b, embed2, xln2, 4);
  k_gemm<1,1,0,1><<<dim3(16,16), 256, 0, stream>>>(xln2, fc1_w, fc1_b, nullptr, h1, 1024, 1024, 256);
  // out = embed2 + h1 @ fc2_w + fc2_b   (split-K: 1024 = 4 x 256)
  k_gemm_sk<1><<<dim3(4,16,4), 256, 0, stream>>>(h1, fc2_w, part_smll, 1024, 256, 1024, 256);
  k_reduce<1><<<1024, 256, 0, stream>>>(part_smll, fc2_b, embed2, out, 262144, 256, 4);
}

// Round 17
// 237.485 us; speedup vs baseline: 1.7797x; 1.0183x over previous
//
#include <hip/hip_runtime.h>
#include <cstdint>

#define DEV __device__ __forceinline__

typedef __attribute__((ext_vector_type(8))) short bf16x8;
typedef __attribute__((ext_vector_type(8))) _Float16 f16x8;
typedef __attribute__((ext_vector_type(2))) __fp16 fp16x2;
typedef __attribute__((ext_vector_type(2))) float f32x2;
typedef __attribute__((ext_vector_type(4))) float f32x4;

DEV unsigned short f2bf(float x){
  union { float f; unsigned u; } c; c.f = x;
  unsigned r = c.u + 0x7fffu + ((c.u >> 16) & 1u);
  return (unsigned short)(r >> 16);
}
DEV float bf2f(unsigned short h){
  union { unsigned u; float f; } c; c.u = ((unsigned)h) << 16;
  return c.f;
}
DEV unsigned short f2h(float x){
  union { unsigned short u; _Float16 h; } c;
  c.h = (_Float16)x;
  return c.u;
}
// f32 -> e4m3 (OCP), RNE, saturate to +-448. Software fallback path.
DEV unsigned char f2fp8(float x){
  union { float f; unsigned u; } c; c.f = x;
  unsigned s = (c.u >> 24) & 0x80u;
  float a = fabsf(x);
  a = fminf(a, 448.f);
  unsigned n;
  if (a < 0.015625f){
    n = (unsigned)(int)rintf(a * 512.f);       // 0..8, RNE; 8 == 2^-6 normal
  } else {
    union { float f; unsigned u; } d; d.f = a;
    unsigned u2 = d.u + 0x7FFFFu + ((d.u >> 20) & 1u);
    n = (((u2 >> 23) - 120u) << 3) | ((u2 >> 20) & 7u);
  }
  return (unsigned char)(s | n);
}
// pack 2 f32 -> 2 e4m3 bytes (byte0 = a, byte1 = b); HW instr on gfx950
DEV unsigned pk_fp8(float a, float b){
#if defined(__has_builtin)
#if __has_builtin(__builtin_amdgcn_cvt_pk_fp8_f32)
  return (unsigned)__builtin_amdgcn_cvt_pk_fp8_f32(a, b, 0, false);
#else
  return (unsigned)f2fp8(a) | ((unsigned)f2fp8(b) << 8);
#endif
#else
  return (unsigned)f2fp8(a) | ((unsigned)f2fp8(b) << 8);
#endif
}
// e4m3 -> f16 bits, exact (software fallback).
DEV unsigned short fp82h(unsigned b){
  union { unsigned short u; _Float16 h; } c;
  c.u = (unsigned short)(((b & 0x80u) << 8) | ((b & 0x7Fu) << 7));
  c.h = c.h * (_Float16)256.0f;
  return c.u;
}
// single fp8 byte -> f32 (exact)
DEV float fp82f(unsigned b){
#if defined(__has_builtin)
#if __has_builtin(__builtin_amdgcn_cvt_f32_fp8)
  return __builtin_amdgcn_cvt_f32_fp8((int)b, 0);
#else
  union { unsigned short u; _Float16 h; } c; c.u = fp82h(b);
  return (float)c.h;
#endif
#else
  union { unsigned short u; _Float16 h; } c; c.u = fp82h(b);
  return (float)c.h;
#endif
}
// decode 4 fp8 bytes (one dword, consecutive elements) -> 4 f16 (exact)
DEV void dec4_fp8(unsigned dw, unsigned short r[4]){
#if defined(__has_builtin)
#if __has_builtin(__builtin_amdgcn_cvt_pk_f32_fp8)
  f32x2 lo = __builtin_amdgcn_cvt_pk_f32_fp8((int)dw, false);
  f32x2 hi = __builtin_amdgcn_cvt_pk_f32_fp8((int)dw, true);
  union { fp16x2 h; unsigned short u[2]; } a, b;
  a.h = __builtin_amdgcn_cvt_pkrtz(lo.x, lo.y);   // fp8 values exact in f16 -> RTZ lossless
  b.h = __builtin_amdgcn_cvt_pkrtz(hi.x, hi.y);
  r[0] = a.u[0]; r[1] = a.u[1]; r[2] = b.u[0]; r[3] = b.u[1];
#else
  r[0] = fp82h(dw & 0xFFu); r[1] = fp82h((dw >> 8) & 0xFFu);
  r[2] = fp82h((dw >> 16) & 0xFFu); r[3] = fp82h(dw >> 24);
#endif
#else
  r[0] = fp82h(dw & 0xFFu); r[1] = fp82h((dw >> 8) & 0xFFu);
  r[2] = fp82h((dw >> 16) & 0xFFu); r[3] = fp82h(dw >> 24);
#endif
}

DEV float gelu_f(float x){ return 0.5f * x * (1.f + erff(x * 0.70710678118654752440f)); }

DEV f32x4 mfma16(bf16x8 a, bf16x8 b, f32x4 c){
  return __builtin_amdgcn_mfma_f32_16x16x32_bf16(a, b, c, 0, 0, 0);
}
DEV f32x4 mfma16h(f16x8 a, f16x8 b, f32x4 c){
  return __builtin_amdgcn_mfma_f32_16x16x32_f16(a, b, c, 0, 0, 0);
}

// block_sum: 256 threads (4 waves)
DEV float block_sum(float v, float* red, int tid){
  #pragma unroll
  for (int o = 32; o > 0; o >>= 1) v += __shfl_down(v, o);
  if ((tid & 63) == 0) red[tid >> 6] = v;
  __syncthreads();
  float s = red[0] + red[1] + red[2] + red[3];
  __syncthreads();
  return s;
}

// ---------------- constants ----------------
// B=16 N=64 D=256 CI=256 H=W=64 P=36 HEADS=8 HD=32 HID=1024 TOTAL=66832 T=1024
// cm (n<65536) stored fp8 e4m3, blocked: params8[(n>>6)*65536 + t*64 + (n&63)] bytes
// sm tail (n>=65536) stored f16, blocked: sm16[((n>>6)-1024)*65536 + t*64 + (n&63)]
// imgT stored fp8 e4m3 [B,H,W,C] (17MB). hbuf bf16. k_sample fused into k_mixtoken.
// k_mixtoken cc-loop barrier-free (wave-local staging, single Cs buffer, 45KB LDS).

// ---------------- kernel 1: per-token prep ----------------
__global__ __launch_bounds__(256) void k_prep(
    const float* __restrict__ embed, const float* __restrict__ roi,
    const float* __restrict__ g_adj, const float* __restrict__ b_adj, const float* __restrict__ w_adj,
    const float* __restrict__ g_off, const float* __restrict__ b_off, const float* __restrict__ w_off,
    const float* __restrict__ off_bias,
    const float* __restrict__ g_pg, const float* __restrict__ b_pg,
    const float* __restrict__ w_pg1, const float* __restrict__ b_pg1,
    float* __restrict__ pts, unsigned short* __restrict__ hbuf)
{
  __shared__ float red[4];
  __shared__ float xln[256];
  __shared__ float offs[72];
  __shared__ float lg[4];
  __shared__ float stat[8];
  const int t = blockIdx.x, tid = threadIdx.x;
  float e = embed[t * 256 + tid];
  float mean = block_sum(e, red, tid) * (1.f / 256.f);
  float dv = e - mean;
  float var = block_sum(dv * dv, red, tid) * (1.f / 256.f);
  xln[tid] = dv * rsqrtf(var + 1e-5f);
  __syncthreads();
  if (tid < 4){
    float a0 = 0.f, a1 = 0.f, a2 = 0.f, a3 = 0.f;
    #pragma unroll 4
    for (int c = 0; c < 256; c += 4){
      a0 += (xln[c+0] * g_adj[c+0] + b_adj[c+0]) * w_adj[(c+0) * 4 + tid];
      a1 += (xln[c+1] * g_adj[c+1] + b_adj[c+1]) * w_adj[(c+1) * 4 + tid];
      a2 += (xln[c+2] * g_adj[c+2] + b_adj[c+2]) * w_adj[(c+2) * 4 + tid];
      a3 += (xln[c+3] * g_adj[c+3] + b_adj[c+3]) * w_adj[(c+3) * 4 + tid];
    }
    lg[tid] = (a0 + a1) + (a2 + a3);
  } else if (tid < 76){
    int j = tid - 4;
    float a0 = 0.f, a1 = 0.f, a2 = 0.f, a3 = 0.f;
    #pragma unroll 4
    for (int c = 0; c < 256; c += 4){
      a0 += (xln[c+0] * g_off[c+0] + b_off[c+0]) * w_off[(c+0) * 72 + j];
      a1 += (xln[c+1] * g_off[c+1] + b_off[c+1]) * w_off[(c+1) * 72 + j];
      a2 += (xln[c+2] * g_off[c+2] + b_off[c+2]) * w_off[(c+2) * 72 + j];
      a3 += (xln[c+3] * g_off[c+3] + b_off[c+3]) * w_off[(c+3) * 72 + j];
    }
    offs[j] = (a0 + a1) + (a2 + a3) + off_bias[j];
  } else if (tid < 140){
    int j = tid - 76;
    float a0 = 0.f, a1 = 0.f, a2 = 0.f, a3 = 0.f;
    #pragma unroll 4
    for (int c = 0; c < 256; c += 4){
      a0 += (xln[c+0] * g_pg[c+0] + b_pg[c+0]) * w_pg1[(c+0) * 64 + j];
      a1 += (xln[c+1] * g_pg[c+1] + b_pg[c+1]) * w_pg1[(c+1) * 64 + j];
      a2 += (xln[c+2] * g_pg[c+2] + b_pg[c+2]) * w_pg1[(c+2) * 64 + j];
      a3 += (xln[c+3] * g_pg[c+3] + b_pg[c+3]) * w_pg1[(c+3) * 64 + j];
    }
    hbuf[t * 64 + j] = f2bf((a0 + a1) + (a2 + a3) + b_pg1[j]);
  }
  __syncthreads();
  if (tid == 0){
    float x0 = roi[t*4+0], y0 = roi[t*4+1], x1 = roi[t*4+2], y1 = roi[t*4+3];
    float cx = (x0 + x1) * 0.5f, cy = (y0 + y1) * 0.5f;
    float w = fabsf(x1 - x0), hh = fabsf(y1 - y0);
    cx += lg[0] * w; cy += lg[1] * hh;
    w *= expf(lg[2]); hh *= expf(lg[3]);
    stat[0] = cx; stat[1] = cy; stat[2] = w; stat[3] = hh;
  }
  if (tid < 2){
    float mu = 0.f;
    for (int p = 0; p < 36; ++p) mu += offs[p*2 + tid];
    mu *= (1.f / 36.f);
    float v2 = 0.f;
    for (int p = 0; p < 36; ++p){ float d = offs[p*2 + tid] - mu; v2 += d * d; }
    float sd = sqrtf(v2 * (1.f / 35.f)) + 1e-7f;   // ddof=1
    stat[4 + tid] = mu; stat[6 + tid] = 1.f / (3.f * sd);
  }
  __syncthreads();
  if (tid < 72){
    int c = tid & 1;
    pts[t * 72 + tid] = stat[c] + (offs[tid] - stat[4 + c]) * stat[6 + c] * stat[2 + c];
  }
}

// ---------------- kernel 2: img [B,C,H,W] f32 -> [B,H,W,C] fp8 e4m3 ----------------
__global__ __launch_bounds__(256) void k_transpose(const float* __restrict__ img,
                                                   unsigned char* __restrict__ imgT8)
{
  __shared__ float tile[128][65];
  const int blk = blockIdx.x, tid = threadIdx.x;
  const int b = blk >> 6, y = blk & 63;
  for (int half = 0; half < 2; ++half){
    int c_loc = tid >> 1, x0 = (tid & 1) * 32;
    const float* src = img + (((size_t)(b * 256 + half * 128 + c_loc)) * 64 + y) * 64 + x0;
    #pragma unroll
    for (int i = 0; i < 32; ++i) tile[c_loc][x0 + i] = src[i];
    __syncthreads();
    {
      int x = tid >> 2, c0 = (tid & 3) * 32;
      size_t obase = (((size_t)(b * 64 + y)) * 64 + x) * 256 + half * 128 + c0;
      unsigned char tmp[32];
      #pragma unroll
      for (int cb = 0; cb < 32; cb += 2){
        unsigned pp = pk_fp8(tile[c0 + cb][x], tile[c0 + cb + 1][x]);
        tmp[cb]     = (unsigned char)(pp & 0xFFu);
        tmp[cb + 1] = (unsigned char)((pp >> 8) & 0xFFu);
      }
      *(uint4*)(imgT8 + obase)      = *(const uint4*)tmp;
      *(uint4*)(imgT8 + obase + 16) = *(const uint4*)(tmp + 16);
    }
    __syncthreads();
  }
}

// ---------------- kernel 4: params = h @ pg_w2 + pg_b2 (M=1024,K=64,N=66832)
// cm chunks (nc<1024) -> fp8 e4m3 via HW cvt_pk; sm tail (nc>=1024) -> f16.
__global__ __launch_bounds__(256) void k_params(
    const unsigned short* __restrict__ hbuf, const float* __restrict__ w2,
    const float* __restrict__ b2, unsigned char* __restrict__ params8,
    unsigned short* __restrict__ sm16)
{
  __shared__ __align__(16) unsigned short Bs[64][72];  // [n][k^swz]
  __shared__ __align__(16) unsigned short As[64][72];  // [m][k]
  __shared__ __align__(16) unsigned short Os[64][72];  // f16 staging (sm path)
  __shared__ __align__(16) unsigned char  Os8[64][72]; // fp8 staging (cm path)
  const int tid = threadIdx.x, lane = tid & 63, wave = tid >> 6;
  const int wm = wave >> 1, wn = wave & 1;
  const int nc = blockIdx.x, n0 = nc * 64;
  const bool cm = (nc < 1024);
  {
    int k = tid >> 2, nb = (tid & 3) * 16;
    #pragma unroll
    for (int i = 0; i < 16; ++i){
      int n = nb + i, gn = n0 + n;
      float v = (gn < 66832) ? w2[(size_t)k * 66832 + gn] : 0.f;
      Bs[n][k ^ (((n >> 3) & 7) << 3)] = f2bf(v);
    }
  }
  float bv[2];
  #pragma unroll
  for (int j = 0; j < 2; ++j){
    int col = n0 + wn*32 + j*16 + (lane & 15);
    bv[j] = (col < 66832) ? b2[col] : 0.f;
  }
  __syncthreads();
  for (int mt = 0; mt < 16; ++mt){
    int m0 = mt * 64;
    { int m = tid >> 2, kb4 = (tid & 3) * 16;
      const unsigned short* hp = hbuf + (m0 + m) * 64 + kb4;
      *(bf16x8*)&As[m][kb4]     = *(const bf16x8*)hp;
      *(bf16x8*)&As[m][kb4 + 8] = *(const bf16x8*)(hp + 8);
    }
    __syncthreads();
    f32x4 acc[2][2] = {};
    #pragma unroll
    for (int ks = 0; ks < 2; ++ks){
      int kb = ks * 32 + (lane >> 4) * 8;
      bf16x8 a[2], bb[2];
      #pragma unroll
      for (int i = 0; i < 2; ++i) a[i] = *(const bf16x8*)&As[wm*32 + i*16 + (lane & 15)][kb];
      #pragma unroll
      for (int j = 0; j < 2; ++j){
        int n = wn*32 + j*16 + (lane & 15);
        bb[j] = *(const bf16x8*)&Bs[n][kb ^ (((n >> 3) & 7) << 3)];
      }
      #pragma unroll
      for (int i = 0; i < 2; ++i)
        #pragma unroll
        for (int j = 0; j < 2; ++j) acc[i][j] = mfma16(a[i], bb[j], acc[i][j]);
    }
    if (cm){
      #pragma unroll
      for (int i = 0; i < 2; ++i)
        #pragma unroll
        for (int j = 0; j < 2; ++j){
          int cl = wn*32 + j*16 + (lane & 15);
          int rl = wm*32 + i*16 + (lane >> 4) * 4;
          unsigned p01 = pk_fp8(acc[i][j][0] + bv[j], acc[i][j][1] + bv[j]);
          unsigned p23 = pk_fp8(acc[i][j][2] + bv[j], acc[i][j][3] + bv[j]);
          Os8[rl + 0][cl] = (unsigned char)(p01 & 0xFFu);
          Os8[rl + 1][cl] = (unsigned char)((p01 >> 8) & 0xFFu);
          Os8[rl + 2][cl] = (unsigned char)(p23 & 0xFFu);
          Os8[rl + 3][cl] = (unsigned char)((p23 >> 8) & 0xFFu);
        }
      __syncthreads();
      {
        int rl = tid >> 2, c0 = (tid & 3) * 16;
        uint2 lo = *(const uint2*)&Os8[rl][c0];
        uint2 hi = *(const uint2*)&Os8[rl][c0 + 8];
        uint4 val; val.x = lo.x; val.y = lo.y; val.z = hi.x; val.w = hi.y;
        *(uint4*)(params8 + ((size_t)nc * 1024 + m0 + rl) * 64 + c0) = val;
      }
    } else {
      #pragma unroll
      for (int i = 0; i < 2; ++i)
        #pragma unroll
        for (int j = 0; j < 2; ++j){
          int cl = wn*32 + j*16 + (lane & 15);
          #pragma unroll
          for (int r = 0; r < 4; ++r){
            int rl = wm*32 + i*16 + (lane >> 4) * 4 + r;
            Os[rl][cl] = f2h(acc[i][j][r] + bv[j]);
          }
        }
      __syncthreads();
      {
        int rl = tid >> 2, c0 = (tid & 3) * 16;
        size_t gbase = ((size_t)(nc - 1024) * 1024 + m0 + rl) * 64 + c0;
        *(bf16x8*)(sm16 + gbase)     = *(const bf16x8*)&Os[rl][c0];
        *(bf16x8*)(sm16 + gbase + 8) = *(const bf16x8*)&Os[rl][c0 + 8];
      }
    }
    __syncthreads();
  }
}

// ---------------- kernel 5: fused sample + per-token adaptive mixing ----------
// cc-loop barrier-free (wave-local staging, single Cs buffer, 45KB LDS).
__global__ __launch_bounds__(256) void k_mixtoken(
    const unsigned char* __restrict__ imgT8,      // fp8 [B,H,W,C]
    const float* __restrict__ pts,                // [T,36,2]
    const unsigned char*  __restrict__ params8,   // fp8 cm
    const unsigned short* __restrict__ sm16,      // f16 sm tail
    const float* __restrict__ m_beta, const float* __restrict__ s_beta,
    unsigned short* __restrict__ out2)            // bf16
{
  __shared__ __align__(16) unsigned short smem[21888];
  __shared__ float lpts[72];
  __shared__ float gw[36][4];   // per-point tap weights (masked)
  __shared__ int   gofs[36][4]; // per-point tap element offsets (sans tid)
  const int t = blockIdx.x, tid = threadIdx.x, lane = tid & 63, wave = tid >> 6;
  const int l15 = lane & 15, kb = (lane >> 4) * 8;
  unsigned short (*Ss)[264] = (unsigned short (*)[264])smem;
  unsigned short (*C)[40]   = (unsigned short (*)[40])(smem + 9504); // single buffer
  const int c31  = tid & 31;
  const int g    = tid >> 5;
  const int goff = (g & 1) * 32;
  const int colw = c31 ^ ((g & 3) << 3);
  const unsigned char* ptok8 = params8 + (size_t)t * 64;
  uint4 rv8[2];
  {
    const unsigned char* src = ptok8 + ((size_t)(c31 * 4 + (g >> 1)) << 16) + goff;
    rv8[0] = *(const uint4*)src;
    rv8[1] = *(const uint4*)(src + 16);
  }
  unsigned short rSm[14];
  #pragma unroll
  for (int k = 0; k < 14; ++k){
    int idx = tid + k * 256;
    unsigned short v = 0;
    if (idx < 3456){
      int o = idx / 72, p = idx % 72;
      if (o < 36 && p < 36){
        int n = 65536 + o * 36 + p;
        v = sm16[(size_t)((n >> 6) - 1024) * 65536 + (size_t)t * 64 + (n & 63)];
      }
    }
    rSm[k] = v;
  }
  // ---- fused sample: coefficients once, then pure load+fma gather ----
  if (tid < 72) lpts[tid] = pts[t * 72 + tid];
  __syncthreads();
  if (tid < 36){
    const int b = t >> 6;
    int p = tid;
    float fx = lpts[p*2]   * 64.f - 0.5f;
    float fy = lpts[p*2+1] * 64.f - 0.5f;
    float x0f = floorf(fx), y0f = floorf(fy);
    float wx = fx - x0f, wy = fy - y0f;
    int x0 = (int)x0f, y0 = (int)y0f;
    #pragma unroll
    for (int dy = 0; dy < 2; ++dy){
      #pragma unroll
      for (int dx = 0; dx < 2; ++dx){
        int xi = x0 + dx, yi = y0 + dy;
        bool valid = (xi >= 0) & (xi < 64) & (yi >= 0) & (yi < 64);
        int xc = min(max(xi, 0), 63), yc = min(max(yi, 0), 63);
        float w = (dx ? wx : 1.f - wx) * (dy ? wy : 1.f - wy);
        gw[p][dy*2 + dx]   = valid ? w : 0.f;
        gofs[p][dy*2 + dx] = ((b * 64 + yc) * 64 + xc) * 256;
      }
    }
  }
  __syncthreads();
  #pragma unroll 4
  for (int p = 0; p < 36; ++p){
    float acc_s = 0.f;
    #pragma unroll
    for (int q = 0; q < 4; ++q)
      acc_s += fp82f(imgT8[(size_t)gofs[p][q] + tid]) * gw[p][q];
    Ss[p][tid] = f2h(acc_s);
  }
  __syncthreads();
  // ---- phase 1: barrier-free cc loop (wave-local staging) ----
  f32x4 acc[3][4] = {};
  for (int cc = 0; cc < 8; ++cc){
    #pragma unroll
    for (int v = 0; v < 2; ++v){
      #pragma unroll
      for (int w = 0; w < 4; ++w){
        unsigned dw = ((const unsigned*)&rv8[v])[w];
        int d0 = g * 32 + v * 16 + w * 4;
        unsigned short r[4];
        dec4_fp8(dw, r);
        C[d0 + 0][colw] = r[0];
        C[d0 + 1][colw] = r[1];
        C[d0 + 2][colw] = r[2];
        C[d0 + 3][colw] = r[3];
      }
    }
    if (cc < 7){
      const unsigned char* src = ptok8 + ((size_t)((cc + 1) * 128 + c31 * 4 + (g >> 1)) << 16) + goff;
      rv8[0] = *(const uint4*)src;
      rv8[1] = *(const uint4*)(src + 16);
    }
    f16x8 a[3], bfr[4];
    a[0] = *(const f16x8*)&Ss[l15][cc * 32 + kb];
    a[1] = *(const f16x8*)&Ss[16 + l15][cc * 32 + kb];
    a[2] = f16x8{};
    if (l15 < 4) a[2] = *(const f16x8*)&Ss[32 + l15][cc * 32 + kb];
    #pragma unroll
    for (int j = 0; j < 4; ++j){
      int d = wave * 64 + j * 16 + l15;   // within this wave's staged d-range
      bfr[j] = *(const f16x8*)&C[d][kb ^ (((d >> 5) & 3) << 3)];
    }
    #pragma unroll
    for (int i = 0; i < 3; ++i)
      #pragma unroll
      for (int j = 0; j < 4; ++j) acc[i][j] = mfma16h(a[i], bfr[j], acc[i][j]);
  }
  __syncthreads();
  {
    const bf16x8 z = {};
    #pragma unroll
    for (int i = 0; i < 9; ++i)
      *(bf16x8*)&smem[(i * 256 + tid) * 8] = z;
    #pragma unroll
    for (int k = 0; k < 14; ++k){
      int idx = tid + k * 256;
      if (idx < 3456) smem[18432 + idx] = rSm[k];
    }
  }
  __syncthreads();
  unsigned short (*O1T)[72] = (unsigned short (*)[72])smem;
  unsigned short (*Sm)[72]  = (unsigned short (*)[72])(smem + 18432);
  #pragma unroll
  for (int i = 0; i < 3; ++i){
    int p = i * 16 + ((lane >> 4) << 2);
    if (p < 36){
      #pragma unroll
      for (int j = 0; j < 4; ++j){
        int d = wave * 64 + j * 16 + l15;
        float mb = m_beta[d];
        unsigned short* dst = &O1T[d][p];
        #pragma unroll
        for (int r = 0; r < 4; ++r) dst[r] = f2h(gelu_f(acc[i][j][r] + mb));
      }
    }
  }
  __syncthreads();
  f32x4 acc2[3][4] = {};
  #pragma unroll
  for (int ks = 0; ks < 2; ++ks){
    int kb2 = ks * 32 + (lane >> 4) * 8;
    f16x8 a2[3], bf2[4];
    #pragma unroll
    for (int i = 0; i < 3; ++i) a2[i] = *(const f16x8*)&Sm[i*16 + l15][kb2];
    #pragma unroll
    for (int j = 0; j < 4; ++j) bf2[j] = *(const f16x8*)&O1T[wave*64 + j*16 + l15][kb2];
    #pragma unroll
    for (int i = 0; i < 3; ++i)
      #pragma unroll
      for (int j = 0; j < 4; ++j) acc2[i][j] = mfma16h(a2[i], bf2[j], acc2[i][j]);
  }
  unsigned short* o2 = out2 + (size_t)t * 9216;
  #pragma unroll
  for (int i = 0; i < 3; ++i){
    int ob = i*16 + ((lane >> 4) << 2);
    #pragma unroll
    for (int j = 0; j < 4; ++j){
      int d = wave*64 + j*16 + l15;
      #pragma unroll
      for (int r = 0; r < 4; ++r){
        int o = ob + r;
        if (o < 36) o2[o * 256 + d] = f2bf(gelu_f(acc2[i][j][r] + s_beta[o]));
      }
    }
  }
}

// ---------------- generic GEMM: C = act(A @ W + bias) (+resid) ----------------
template<int AK, int ACT, int RES, int OUTB>
__global__ __launch_bounds__(256) void k_gemm(
    const void* __restrict__ Ap, const float* __restrict__ W,
    const float* __restrict__ bias, const float* __restrict__ resid,
    void* __restrict__ Cp, int M, int N, int K)
{
  __shared__ __align__(16) unsigned short As[64][40];  // [m][k]
  __shared__ __align__(16) unsigned short Bs[64][40];  // [n][k^swz]
  const int tid = threadIdx.x, lane = tid & 63, wave = tid >> 6;
  const int wm = wave >> 1, wn = wave & 1;
  const int n0 = blockIdx.x * 64, m0 = blockIdx.y * 64;
  f32x4 acc[2][2] = {};
  for (int kk = 0; kk < K; kk += 32){
    { int m = tid >> 2, k4 = (tid & 3) * 8;
      if (AK == 0){
        const float* ap = (const float*)Ap + (size_t)(m0 + m) * K + kk + k4;
        #pragma unroll
        for (int i = 0; i < 8; ++i) As[m][k4 + i] = f2bf(ap[i]);
      } else {
        const unsigned short* ap = (const unsigned short*)Ap + (size_t)(m0 + m) * K + kk + k4;
        *(bf16x8*)&As[m][k4] = *(const bf16x8*)ap;
      }
    }
    { int kq = tid >> 3, n8 = (tid & 7) * 8;
      const float* wp = W + (size_t)(kk + kq) * N + n0 + n8;
      #pragma unroll
      for (int i = 0; i < 8; ++i){
        int n = n8 + i;
        Bs[n][kq ^ (((n >> 3) & 3) << 3)] = f2bf(wp[i]);
      }
    }
    __syncthreads();
    const int kb = (lane >> 4) * 8;
    bf16x8 a[2], bfr[2];
    #pragma unroll
    for (int i = 0; i < 2; ++i) a[i] = *(const bf16x8*)&As[wm*32 + i*16 + (lane & 15)][kb];
    #pragma unroll
    for (int j = 0; j < 2; ++j){
      int n = wn*32 + j*16 + (lane & 15);
      bfr[j] = *(const bf16x8*)&Bs[n][kb ^ (((n >> 3) & 3) << 3)];
    }
    #pragma unroll
    for (int i = 0; i < 2; ++i)
      #pragma unroll
      for (int j = 0; j < 2; ++j) acc[i][j] = mfma16(a[i], bfr[j], acc[i][j]);
    __syncthreads();
  }
  #pragma unroll
  for (int i = 0; i < 2; ++i)
    #pragma unroll
    for (int j = 0; j < 2; ++j){
      int col = n0 + wn*32 + j*16 + (lane & 15);
      float bv = bias[col];
      #pragma unroll
      for (int r = 0; r < 4; ++r){
        int row = m0 + wm*32 + i*16 + (lane >> 4) * 4 + r;
        float v = acc[i][j][r] + bv;
        if (ACT == 1) v = gelu_f(v);
        if (RES) v += resid[(size_t)row * N + col];
        if (OUTB) ((unsigned short*)Cp)[(size_t)row * N + col] = f2bf(v);
        else      ((float*)Cp)[(size_t)row * N + col] = v;
      }
    }
}

// ---------------- split-K GEMM: part[z][M][N] = A[:, z*KS:(z+1)*KS] @ W[z*KS:...] ----
template<int AK>
__global__ __launch_bounds__(256) void k_gemm_sk(
    const void* __restrict__ Ap, const float* __restrict__ W,
    float* __restrict__ part, int M, int N, int K, int KS)
{
  __shared__ __align__(16) unsigned short As[64][40];  // [m][k]
  __shared__ __align__(16) unsigned short Bs[64][40];  // [n][k^swz]
  const int tid = threadIdx.x, lane = tid & 63, wave = tid >> 6;
  const int wm = wave >> 1, wn = wave & 1;
  const int n0 = blockIdx.x * 64, m0 = blockIdx.y * 64;
  const int kbase = blockIdx.z * KS;
  f32x4 acc[2][2] = {};
  for (int kq = 0; kq < KS; kq += 32){
    int kk = kbase + kq;
    { int m = tid >> 2, k4 = (tid & 3) * 8;
      if (AK == 0){
        const float* ap = (const float*)Ap + (size_t)(m0 + m) * K + kk + k4;
        #pragma unroll
        for (int i = 0; i < 8; ++i) As[m][k4 + i] = f2bf(ap[i]);
      } else {
        const unsigned short* ap = (const unsigned short*)Ap + (size_t)(m0 + m) * K + kk + k4;
        *(bf16x8*)&As[m][k4] = *(const bf16x8*)ap;
      }
    }
    { int kr = tid >> 3, n8 = (tid & 7) * 8;
      const float* wp = W + (size_t)(kk + kr) * N + n0 + n8;
      #pragma unroll
      for (int i = 0; i < 8; ++i){
        int n = n8 + i;
        Bs[n][kr ^ (((n >> 3) & 3) << 3)] = f2bf(wp[i]);
      }
    }
    __syncthreads();
    const int kb = (lane >> 4) * 8;
    bf16x8 a[2], bfr[2];
    #pragma unroll
    for (int i = 0; i < 2; ++i) a[i] = *(const bf16x8*)&As[wm*32 + i*16 + (lane & 15)][kb];
    #pragma unroll
    for (int j = 0; j < 2; ++j){
      int n = wn*32 + j*16 + (lane & 15);
      bfr[j] = *(const bf16x8*)&Bs[n][kb ^ (((n >> 3) & 3) << 3)];
    }
    #pragma unroll
    for (int i = 0; i < 2; ++i)
      #pragma unroll
      for (int j = 0; j < 2; ++j) acc[i][j] = mfma16(a[i], bfr[j], acc[i][j]);
    __syncthreads();
  }
  float* pz = part + (size_t)blockIdx.z * M * N;
  #pragma unroll
  for (int i = 0; i < 2; ++i)
    #pragma unroll
    for (int j = 0; j < 2; ++j){
      int col = n0 + wn*32 + j*16 + (lane & 15);
      #pragma unroll
      for (int r = 0; r < 4; ++r){
        int row = m0 + wm*32 + i*16 + (lane >> 4) * 4 + r;
        pz[(size_t)row * N + col] = acc[i][j][r];
      }
    }
}

// ---------------- split-K reduce: out = sum_z part[z] + bias (+resid) ----------------
template<int RES>
__global__ __launch_bounds__(256) void k_reduce(
    const float* __restrict__ part, const float* __restrict__ bias,
    const float* __restrict__ resid, float* __restrict__ out,
    int total, int N, int SK)
{
  int i = blockIdx.x * 256 + threadIdx.x;
  if (i >= total) return;
  float s = 0.f;
  for (int z = 0; z < SK; ++z) s += part[(size_t)z * total + i];
  s += bias[i % N];
  if (RES) s += resid[i];
  out[i] = s;
}

// ---------------- fused split-K reduce + residual + LayerNorm ----------------
__global__ __launch_bounds__(256) void k_reduce_ln(
    const float* __restrict__ part, const float* __restrict__ bias,
    const float* __restrict__ resid,
    const float* __restrict__ g, const float* __restrict__ bb,
    float* __restrict__ emb_out, unsigned short* __restrict__ ln_out, int SK)
{
  __shared__ float red[4];
  const int t = blockIdx.x, tid = threadIdx.x;
  const int i = t * 256 + tid;
  float s = 0.f;
  for (int z = 0; z < SK; ++z) s += part[(size_t)z * 262144 + i];
  s += bias[tid] + resid[i];
  emb_out[i] = s;
  float mean = block_sum(s, red, tid) * (1.f / 256.f);
  float d = s - mean;
  float var = block_sum(d * d, red, tid) * (1.f / 256.f);
  ln_out[i] = f2bf(d * rsqrtf(var + 1e-5f) * g[tid] + bb[tid]);
}

// ---------------- attention: one (b,h) per block ----------------
__global__ __launch_bounds__(64) void k_attn(const float* __restrict__ qkv,
                                             float* __restrict__ attno)
{
  __shared__ float qs[64][33], ksm[64][33], vsm[64][33];
  const int blk = blockIdx.x, lane = threadIdx.x;
  const int b = blk >> 3, h = blk & 7;
  for (int idx = lane; idx < 2048; idx += 64){
    int row = idx >> 5, d = idx & 31;
    const float* base = qkv + (size_t)(b * 64 + row) * 768 + h * 32 + d;
    qs[row][d] = base[0]; ksm[row][d] = base[256]; vsm[row][d] = base[512];
  }
  __syncthreads();
  float qr[32];
  #pragma unroll
  for (int d = 0; d < 32; ++d) qr[d] = qs[lane][d];
  float s[64]; float mx = -1e30f;
  for (int m = 0; m < 64; ++m){
    float dot = 0.f;
    #pragma unroll
    for (int d = 0; d < 32; ++d) dot += qr[d] * ksm[m][d];
    dot *= 0.17677669529663687f;  // 32^-0.5
    s[m] = dot; mx = fmaxf(mx, dot);
  }
  float sum = 0.f;
  for (int m = 0; m < 64; ++m){ s[m] = expf(s[m] - mx); sum += s[m]; }
  float inv = 1.f / sum;
  float o[32] = {};
  for (int m = 0; m < 64; ++m){
    float p = s[m] * inv;
    #pragma unroll
    for (int d = 0; d < 32; ++d) o[d] += p * vsm[m][d];
  }
  float* dst = attno + (size_t)(b * 64 + lane) * 256 + h * 32;
  #pragma unroll
  for (int d = 0; d < 32; ++d) dst[d] = o[d];
}

__global__ void k_fill(float* p, int n, float v){
  int i = blockIdx.x * 256 + threadIdx.x;
  if (i < n) p[i] = v;
}

// ---------------- launch ----------------
extern "C" void kernel_launch(void* const* d_in, const int* in_sizes, int n_in,
                              void* d_out, int out_size, void* d_ws, size_t ws_size,
                              hipStream_t stream)
{
  const float* img      = (const float*)d_in[0];
  const float* embed    = (const float*)d_in[1];
  const float* roi      = (const float*)d_in[2];
  const float* ln_adj_g = (const float*)d_in[3];
  const float* ln_adj_b = (const float*)d_in[4];
  const float* w_adj    = (const float*)d_in[5];
  const float* ln_off_g = (const float*)d_in[6];
  const float* ln_off_b = (const float*)d_in[7];
  const float* w_off    = (const float*)d_in[8];
  const float* off_bias = (const float*)d_in[9];
  const float* pg_ln_g  = (const float*)d_in[10];
  const float* pg_ln_b  = (const float*)d_in[11];
  const float* pg_w1    = (const float*)d_in[12];
  const float* pg_b1    = (const float*)d_in[13];
  const float* pg_w2    = (const float*)d_in[14];
  const float* pg_b2    = (const float*)d_in[15];
  const float* m_beta   = (const float*)d_in[16];
  const float* s_beta   = (const float*)d_in[17];
  const float* mix_w    = (const float*)d_in[18];
  const float* mix_b    = (const float*)d_in[19];
  const float* ln1_g    = (const float*)d_in[20];
  const float* ln1_b    = (const float*)d_in[21];
  const float* qkv_w    = (const float*)d_in[22];
  const float* qkv_b    = (const float*)d_in[23];
  const float* proj_w   = (const float*)d_in[24];
  const float* proj_b   = (const float*)d_in[25];
  const float* ln2_g    = (const float*)d_in[26];
  const float* ln2_b    = (const float*)d_in[27];
  const float* fc1_w    = (const float*)d_in[28];
  const float* fc1_b    = (const float*)d_in[29];
  const float* fc2_w    = (const float*)d_in[30];
  const float* fc2_b    = (const float*)d_in[31];

  char* ws = (char*)d_ws;
  float*          pts     = (float*)         (ws + 0);          //   294912
  unsigned short* hbuf    = (unsigned short*)(ws + 294912);     //   131072 (bf16)
  unsigned char*  imgT8   = (unsigned char*) (ws + 557056);     // 16777216 (fp8)
  unsigned char*  params8 = (unsigned char*) (ws + 52985856);   // 67108864 (fp8 cm)
  unsigned short* sm16    = (unsigned short*)(ws + 120094720);  //  2752512 (f16 sm)
  unsigned short* out2    = (unsigned short*)(ws + 122847232);  // 18874368 (bf16)
  float*          embed1  = (float*)         (ws + 141721600);  //  1048576
  float*          embed2  = (float*)         (ws + 142770176);  //  1048576
  unsigned short* xln1    = (unsigned short*)(ws + 143818752);  //   524288
  unsigned short* xln2    = (unsigned short*)(ws + 144343040);  //   524288
  float*          qkvb    = (float*)         (ws + 144867328);  //  3145728
  float*          attno   = (float*)         (ws + 148013056);  //  1048576
  // aliased into the params8 region (dead after k_mixtoken):
  float*          part_mix  = (float*)(ws + 52985856);             // 16 MB (16 slabs)
  float*          part_smll = (float*)(ws + 52985856 + 16777216);  //  4 MB (4 slabs)
  unsigned short* h1        = (unsigned short*)(ws + 52985856 + 20971520); // 2 MB
  const size_t WS_NEEDED = 149061632;
  if (ws_size < WS_NEEDED){
    k_fill<<<(out_size + 255) / 256, 256, 0, stream>>>((float*)d_out, out_size, 12345.0f);
    return;
  }

  float* out = (float*)d_out;

  k_prep<<<1024, 256, 0, stream>>>(embed, roi, ln_adj_g, ln_adj_b, w_adj,
                                   ln_off_g, ln_off_b, w_off, off_bias,
                                   pg_ln_g, pg_ln_b, pg_w1, pg_b1, pts, hbuf);
  k_transpose<<<1024, 256, 0, stream>>>(img, imgT8);
  k_params<<<1045, 256, 0, stream>>>(hbuf, pg_w2, pg_b2, params8, sm16);
  k_mixtoken<<<1024, 256, 0, stream>>>(imgT8, pts, params8, sm16, m_beta, s_beta, out2);
  // embed1 = embed + out2 @ mix_w + mix_b   (split-K: 9216 = 16 x 576), fused LN1
  k_gemm_sk<1><<<dim3(4,16,16), 256, 0, stream>>>(out2, mix_w, part_mix, 1024, 256, 9216, 576);
  k_reduce_ln<<<1024, 256, 0, stream>>>(part_mix, mix_b, embed, ln1_g, ln1_b, embed1, xln1, 16);
  k_gemm<1,0,0,0><<<dim3(12,16), 256, 0, stream>>>(xln1, qkv_w, qkv_b, nullptr, qkvb, 1024, 768, 256);
  k_attn<<<128, 64, 0, stream>>>(qkvb, attno);
  // embed2 = embed1 + attno @ proj_w + proj_b (split-K: 256 = 4 x 64), fused LN2
  k_gemm_sk<0><<<dim3(4,16,4), 256, 0, stream>>>(attno, proj_w, part_smll, 1024, 256, 256, 64);
  k_reduce_ln<<<1024, 256, 0, stream>>>(part_smll, proj_b, embed1, ln2_g, ln2_b, embed2, xln2, 4);
  k_gemm<1,1,0,1><<<dim3(16,16), 256, 0, stream>>>(xln2, fc1_w, fc1_b, nullptr, h1, 1024, 1024, 256);
  // out = embed2 + h1 @ fc2_w + fc2_b   (split-K: 1024 = 4 x 256)
  k_gemm_sk<1><<<dim3(4,16,4), 256, 0, stream>>>(h1, fc2_w, part_smll, 1024, 256, 1024, 256);
  k_reduce<1><<<1024, 256, 0, stream>>>(part_smll, fc2_b, embed2, out, 262144, 256, 4);
}

// Round 18
// 233.059 us; speedup vs baseline: 1.8135x; 1.0190x over previous
//
#include <hip/hip_runtime.h>
#include <cstdint>

#define DEV __device__ __forceinline__

typedef __attribute__((ext_vector_type(8))) short bf16x8;
typedef __attribute__((ext_vector_type(8))) _Float16 f16x8;
typedef __attribute__((ext_vector_type(2))) __fp16 fp16x2;
typedef __attribute__((ext_vector_type(2))) float f32x2;
typedef __attribute__((ext_vector_type(4))) float f32x4;

DEV unsigned short f2bf(float x){
  union { float f; unsigned u; } c; c.f = x;
  unsigned r = c.u + 0x7fffu + ((c.u >> 16) & 1u);
  return (unsigned short)(r >> 16);
}
DEV float bf2f(unsigned short h){
  union { unsigned u; float f; } c; c.u = ((unsigned)h) << 16;
  return c.f;
}
DEV unsigned short f2h(float x){
  union { unsigned short u; _Float16 h; } c;
  c.h = (_Float16)x;
  return c.u;
}
// f32 -> e4m3 (OCP), RNE, saturate to +-448. Software fallback path.
DEV unsigned char f2fp8(float x){
  union { float f; unsigned u; } c; c.f = x;
  unsigned s = (c.u >> 24) & 0x80u;
  float a = fabsf(x);
  a = fminf(a, 448.f);
  unsigned n;
  if (a < 0.015625f){
    n = (unsigned)(int)rintf(a * 512.f);       // 0..8, RNE; 8 == 2^-6 normal
  } else {
    union { float f; unsigned u; } d; d.f = a;
    unsigned u2 = d.u + 0x7FFFFu + ((d.u >> 20) & 1u);
    n = (((u2 >> 23) - 120u) << 3) | ((u2 >> 20) & 7u);
  }
  return (unsigned char)(s | n);
}
// pack 2 f32 -> 2 e4m3 bytes (byte0 = a, byte1 = b); HW instr on gfx950
DEV unsigned pk_fp8(float a, float b){
#if defined(__has_builtin)
#if __has_builtin(__builtin_amdgcn_cvt_pk_fp8_f32)
  return (unsigned)__builtin_amdgcn_cvt_pk_fp8_f32(a, b, 0, false);
#else
  return (unsigned)f2fp8(a) | ((unsigned)f2fp8(b) << 8);
#endif
#else
  return (unsigned)f2fp8(a) | ((unsigned)f2fp8(b) << 8);
#endif
}
// e4m3 -> f16 bits, exact (software fallback).
DEV unsigned short fp82h(unsigned b){
  union { unsigned short u; _Float16 h; } c;
  c.u = (unsigned short)(((b & 0x80u) << 8) | ((b & 0x7Fu) << 7));
  c.h = c.h * (_Float16)256.0f;
  return c.u;
}
// single fp8 byte -> f32 (exact)
DEV float fp82f(unsigned b){
#if defined(__has_builtin)
#if __has_builtin(__builtin_amdgcn_cvt_f32_fp8)
  return __builtin_amdgcn_cvt_f32_fp8((int)b, 0);
#else
  union { unsigned short u; _Float16 h; } c; c.u = fp82h(b);
  return (float)c.h;
#endif
#else
  union { unsigned short u; _Float16 h; } c; c.u = fp82h(b);
  return (float)c.h;
#endif
}
// decode 4 fp8 bytes (one dword) -> 4 f32 (exact)
DEV void fp8x4_to_f32(unsigned dw, float r[4]){
#if defined(__has_builtin)
#if __has_builtin(__builtin_amdgcn_cvt_pk_f32_fp8)
  f32x2 lo = __builtin_amdgcn_cvt_pk_f32_fp8((int)dw, false);
  f32x2 hi = __builtin_amdgcn_cvt_pk_f32_fp8((int)dw, true);
  r[0] = lo.x; r[1] = lo.y; r[2] = hi.x; r[3] = hi.y;
#else
  r[0] = fp82f(dw & 0xFFu); r[1] = fp82f((dw >> 8) & 0xFFu);
  r[2] = fp82f((dw >> 16) & 0xFFu); r[3] = fp82f(dw >> 24);
#endif
#else
  r[0] = fp82f(dw & 0xFFu); r[1] = fp82f((dw >> 8) & 0xFFu);
  r[2] = fp82f((dw >> 16) & 0xFFu); r[3] = fp82f(dw >> 24);
#endif
}
// decode 4 fp8 bytes (one dword, consecutive elements) -> 4 f16 (exact)
DEV void dec4_fp8(unsigned dw, unsigned short r[4]){
#if defined(__has_builtin)
#if __has_builtin(__builtin_amdgcn_cvt_pk_f32_fp8)
  f32x2 lo = __builtin_amdgcn_cvt_pk_f32_fp8((int)dw, false);
  f32x2 hi = __builtin_amdgcn_cvt_pk_f32_fp8((int)dw, true);
  union { fp16x2 h; unsigned short u[2]; } a, b;
  a.h = __builtin_amdgcn_cvt_pkrtz(lo.x, lo.y);   // fp8 values exact in f16 -> RTZ lossless
  b.h = __builtin_amdgcn_cvt_pkrtz(hi.x, hi.y);
  r[0] = a.u[0]; r[1] = a.u[1]; r[2] = b.u[0]; r[3] = b.u[1];
#else
  r[0] = fp82h(dw & 0xFFu); r[1] = fp82h((dw >> 8) & 0xFFu);
  r[2] = fp82h((dw >> 16) & 0xFFu); r[3] = fp82h(dw >> 24);
#endif
#else
  r[0] = fp82h(dw & 0xFFu); r[1] = fp82h((dw >> 8) & 0xFFu);
  r[2] = fp82h((dw >> 16) & 0xFFu); r[3] = fp82h(dw >> 24);
#endif
}

DEV float gelu_f(float x){ return 0.5f * x * (1.f + erff(x * 0.70710678118654752440f)); }

DEV f32x4 mfma16(bf16x8 a, bf16x8 b, f32x4 c){
  return __builtin_amdgcn_mfma_f32_16x16x32_bf16(a, b, c, 0, 0, 0);
}
DEV f32x4 mfma16h(f16x8 a, f16x8 b, f32x4 c){
  return __builtin_amdgcn_mfma_f32_16x16x32_f16(a, b, c, 0, 0, 0);
}

// block_sum: 256 threads (4 waves)
DEV float block_sum(float v, float* red, int tid){
  #pragma unroll
  for (int o = 32; o > 0; o >>= 1) v += __shfl_down(v, o);
  if ((tid & 63) == 0) red[tid >> 6] = v;
  __syncthreads();
  float s = red[0] + red[1] + red[2] + red[3];
  __syncthreads();
  return s;
}

// ---------------- constants ----------------
// B=16 N=64 D=256 CI=256 H=W=64 P=36 HEADS=8 HD=32 HID=1024 TOTAL=66832 T=1024
// cm (n<65536) stored fp8 e4m3, blocked: params8[(n>>6)*65536 + t*64 + (n&63)] bytes
// sm tail (n>=65536) stored f16, blocked: sm16[((n>>6)-1024)*65536 + t*64 + (n&63)]
// imgT stored fp8 e4m3 [B,H,W,C] (17MB). hbuf bf16. k_sample fused into k_mixtoken
// (gather vectorized: dword per tap, 4 channels/thread).
// k_mixtoken cc-loop barrier-free (wave-local staging, single Cs buffer, 45KB LDS).

// ---------------- kernel 1: per-token prep ----------------
__global__ __launch_bounds__(256) void k_prep(
    const float* __restrict__ embed, const float* __restrict__ roi,
    const float* __restrict__ g_adj, const float* __restrict__ b_adj, const float* __restrict__ w_adj,
    const float* __restrict__ g_off, const float* __restrict__ b_off, const float* __restrict__ w_off,
    const float* __restrict__ off_bias,
    const float* __restrict__ g_pg, const float* __restrict__ b_pg,
    const float* __restrict__ w_pg1, const float* __restrict__ b_pg1,
    float* __restrict__ pts, unsigned short* __restrict__ hbuf)
{
  __shared__ float red[4];
  __shared__ float xln[256];
  __shared__ float offs[72];
  __shared__ float lg[4];
  __shared__ float stat[8];
  const int t = blockIdx.x, tid = threadIdx.x;
  float e = embed[t * 256 + tid];
  float mean = block_sum(e, red, tid) * (1.f / 256.f);
  float dv = e - mean;
  float var = block_sum(dv * dv, red, tid) * (1.f / 256.f);
  xln[tid] = dv * rsqrtf(var + 1e-5f);
  __syncthreads();
  if (tid < 4){
    float a0 = 0.f, a1 = 0.f, a2 = 0.f, a3 = 0.f;
    #pragma unroll 4
    for (int c = 0; c < 256; c += 4){
      a0 += (xln[c+0] * g_adj[c+0] + b_adj[c+0]) * w_adj[(c+0) * 4 + tid];
      a1 += (xln[c+1] * g_adj[c+1] + b_adj[c+1]) * w_adj[(c+1) * 4 + tid];
      a2 += (xln[c+2] * g_adj[c+2] + b_adj[c+2]) * w_adj[(c+2) * 4 + tid];
      a3 += (xln[c+3] * g_adj[c+3] + b_adj[c+3]) * w_adj[(c+3) * 4 + tid];
    }
    lg[tid] = (a0 + a1) + (a2 + a3);
  } else if (tid < 76){
    int j = tid - 4;
    float a0 = 0.f, a1 = 0.f, a2 = 0.f, a3 = 0.f;
    #pragma unroll 4
    for (int c = 0; c < 256; c += 4){
      a0 += (xln[c+0] * g_off[c+0] + b_off[c+0]) * w_off[(c+0) * 72 + j];
      a1 += (xln[c+1] * g_off[c+1] + b_off[c+1]) * w_off[(c+1) * 72 + j];
      a2 += (xln[c+2] * g_off[c+2] + b_off[c+2]) * w_off[(c+2) * 72 + j];
      a3 += (xln[c+3] * g_off[c+3] + b_off[c+3]) * w_off[(c+3) * 72 + j];
    }
    offs[j] = (a0 + a1) + (a2 + a3) + off_bias[j];
  } else if (tid < 140){
    int j = tid - 76;
    float a0 = 0.f, a1 = 0.f, a2 = 0.f, a3 = 0.f;
    #pragma unroll 4
    for (int c = 0; c < 256; c += 4){
      a0 += (xln[c+0] * g_pg[c+0] + b_pg[c+0]) * w_pg1[(c+0) * 64 + j];
      a1 += (xln[c+1] * g_pg[c+1] + b_pg[c+1]) * w_pg1[(c+1) * 64 + j];
      a2 += (xln[c+2] * g_pg[c+2] + b_pg[c+2]) * w_pg1[(c+2) * 64 + j];
      a3 += (xln[c+3] * g_pg[c+3] + b_pg[c+3]) * w_pg1[(c+3) * 64 + j];
    }
    hbuf[t * 64 + j] = f2bf((a0 + a1) + (a2 + a3) + b_pg1[j]);
  }
  __syncthreads();
  if (tid == 0){
    float x0 = roi[t*4+0], y0 = roi[t*4+1], x1 = roi[t*4+2], y1 = roi[t*4+3];
    float cx = (x0 + x1) * 0.5f, cy = (y0 + y1) * 0.5f;
    float w = fabsf(x1 - x0), hh = fabsf(y1 - y0);
    cx += lg[0] * w; cy += lg[1] * hh;
    w *= expf(lg[2]); hh *= expf(lg[3]);
    stat[0] = cx; stat[1] = cy; stat[2] = w; stat[3] = hh;
  }
  if (tid < 2){
    float mu = 0.f;
    for (int p = 0; p < 36; ++p) mu += offs[p*2 + tid];
    mu *= (1.f / 36.f);
    float v2 = 0.f;
    for (int p = 0; p < 36; ++p){ float d = offs[p*2 + tid] - mu; v2 += d * d; }
    float sd = sqrtf(v2 * (1.f / 35.f)) + 1e-7f;   // ddof=1
    stat[4 + tid] = mu; stat[6 + tid] = 1.f / (3.f * sd);
  }
  __syncthreads();
  if (tid < 72){
    int c = tid & 1;
    pts[t * 72 + tid] = stat[c] + (offs[tid] - stat[4 + c]) * stat[6 + c] * stat[2 + c];
  }
}

// ---------------- kernel 2: img [B,C,H,W] f32 -> [B,H,W,C] fp8 e4m3 ----------------
__global__ __launch_bounds__(256) void k_transpose(const float* __restrict__ img,
                                                   unsigned char* __restrict__ imgT8)
{
  __shared__ float tile[128][65];
  const int blk = blockIdx.x, tid = threadIdx.x;
  const int b = blk >> 6, y = blk & 63;
  for (int half = 0; half < 2; ++half){
    int c_loc = tid >> 1, x0 = (tid & 1) * 32;
    const float* src = img + (((size_t)(b * 256 + half * 128 + c_loc)) * 64 + y) * 64 + x0;
    #pragma unroll
    for (int i = 0; i < 32; ++i) tile[c_loc][x0 + i] = src[i];
    __syncthreads();
    {
      int x = tid >> 2, c0 = (tid & 3) * 32;
      size_t obase = (((size_t)(b * 64 + y)) * 64 + x) * 256 + half * 128 + c0;
      unsigned char tmp[32];
      #pragma unroll
      for (int cb = 0; cb < 32; cb += 2){
        unsigned pp = pk_fp8(tile[c0 + cb][x], tile[c0 + cb + 1][x]);
        tmp[cb]     = (unsigned char)(pp & 0xFFu);
        tmp[cb + 1] = (unsigned char)((pp >> 8) & 0xFFu);
      }
      *(uint4*)(imgT8 + obase)      = *(const uint4*)tmp;
      *(uint4*)(imgT8 + obase + 16) = *(const uint4*)(tmp + 16);
    }
    __syncthreads();
  }
}

// ---------------- kernel 4: params = h @ pg_w2 + pg_b2 (M=1024,K=64,N=66832)
// cm chunks (nc<1024) -> fp8 e4m3 via HW cvt_pk; sm tail (nc>=1024) -> f16.
__global__ __launch_bounds__(256) void k_params(
    const unsigned short* __restrict__ hbuf, const float* __restrict__ w2,
    const float* __restrict__ b2, unsigned char* __restrict__ params8,
    unsigned short* __restrict__ sm16)
{
  __shared__ __align__(16) unsigned short Bs[64][72];  // [n][k^swz]
  __shared__ __align__(16) unsigned short As[64][72];  // [m][k]
  __shared__ __align__(16) unsigned short Os[64][72];  // f16 staging (sm path)
  __shared__ __align__(16) unsigned char  Os8[64][72]; // fp8 staging (cm path)
  const int tid = threadIdx.x, lane = tid & 63, wave = tid >> 6;
  const int wm = wave >> 1, wn = wave & 1;
  const int nc = blockIdx.x, n0 = nc * 64;
  const bool cm = (nc < 1024);
  {
    int k = tid >> 2, nb = (tid & 3) * 16;
    #pragma unroll
    for (int i = 0; i < 16; ++i){
      int n = nb + i, gn = n0 + n;
      float v = (gn < 66832) ? w2[(size_t)k * 66832 + gn] : 0.f;
      Bs[n][k ^ (((n >> 3) & 7) << 3)] = f2bf(v);
    }
  }
  float bv[2];
  #pragma unroll
  for (int j = 0; j < 2; ++j){
    int col = n0 + wn*32 + j*16 + (lane & 15);
    bv[j] = (col < 66832) ? b2[col] : 0.f;
  }
  __syncthreads();
  for (int mt = 0; mt < 16; ++mt){
    int m0 = mt * 64;
    { int m = tid >> 2, kb4 = (tid & 3) * 16;
      const unsigned short* hp = hbuf + (m0 + m) * 64 + kb4;
      *(bf16x8*)&As[m][kb4]     = *(const bf16x8*)hp;
      *(bf16x8*)&As[m][kb4 + 8] = *(const bf16x8*)(hp + 8);
    }
    __syncthreads();
    f32x4 acc[2][2] = {};
    #pragma unroll
    for (int ks = 0; ks < 2; ++ks){
      int kb = ks * 32 + (lane >> 4) * 8;
      bf16x8 a[2], bb[2];
      #pragma unroll
      for (int i = 0; i < 2; ++i) a[i] = *(const bf16x8*)&As[wm*32 + i*16 + (lane & 15)][kb];
      #pragma unroll
      for (int j = 0; j < 2; ++j){
        int n = wn*32 + j*16 + (lane & 15);
        bb[j] = *(const bf16x8*)&Bs[n][kb ^ (((n >> 3) & 7) << 3)];
      }
      #pragma unroll
      for (int i = 0; i < 2; ++i)
        #pragma unroll
        for (int j = 0; j < 2; ++j) acc[i][j] = mfma16(a[i], bb[j], acc[i][j]);
    }
    if (cm){
      #pragma unroll
      for (int i = 0; i < 2; ++i)
        #pragma unroll
        for (int j = 0; j < 2; ++j){
          int cl = wn*32 + j*16 + (lane & 15);
          int rl = wm*32 + i*16 + (lane >> 4) * 4;
          unsigned p01 = pk_fp8(acc[i][j][0] + bv[j], acc[i][j][1] + bv[j]);
          unsigned p23 = pk_fp8(acc[i][j][2] + bv[j], acc[i][j][3] + bv[j]);
          Os8[rl + 0][cl] = (unsigned char)(p01 & 0xFFu);
          Os8[rl + 1][cl] = (unsigned char)((p01 >> 8) & 0xFFu);
          Os8[rl + 2][cl] = (unsigned char)(p23 & 0xFFu);
          Os8[rl + 3][cl] = (unsigned char)((p23 >> 8) & 0xFFu);
        }
      __syncthreads();
      {
        int rl = tid >> 2, c0 = (tid & 3) * 16;
        uint2 lo = *(const uint2*)&Os8[rl][c0];
        uint2 hi = *(const uint2*)&Os8[rl][c0 + 8];
        uint4 val; val.x = lo.x; val.y = lo.y; val.z = hi.x; val.w = hi.y;
        *(uint4*)(params8 + ((size_t)nc * 1024 + m0 + rl) * 64 + c0) = val;
      }
    } else {
      #pragma unroll
      for (int i = 0; i < 2; ++i)
        #pragma unroll
        for (int j = 0; j < 2; ++j){
          int cl = wn*32 + j*16 + (lane & 15);
          #pragma unroll
          for (int r = 0; r < 4; ++r){
            int rl = wm*32 + i*16 + (lane >> 4) * 4 + r;
            Os[rl][cl] = f2h(acc[i][j][r] + bv[j]);
          }
        }
      __syncthreads();
      {
        int rl = tid >> 2, c0 = (tid & 3) * 16;
        size_t gbase = ((size_t)(nc - 1024) * 1024 + m0 + rl) * 64 + c0;
        *(bf16x8*)(sm16 + gbase)     = *(const bf16x8*)&Os[rl][c0];
        *(bf16x8*)(sm16 + gbase + 8) = *(const bf16x8*)&Os[rl][c0 + 8];
      }
    }
    __syncthreads();
  }
}

// ---------------- kernel 5: fused sample + per-token adaptive mixing ----------
// Gather vectorized: thread = (c-group, point-lane); dword loads (4 channels/tap).
// cc-loop barrier-free (wave-local staging, single Cs buffer, 45KB LDS).
__global__ __launch_bounds__(256) void k_mixtoken(
    const unsigned char* __restrict__ imgT8,      // fp8 [B,H,W,C]
    const float* __restrict__ pts,                // [T,36,2]
    const unsigned char*  __restrict__ params8,   // fp8 cm
    const unsigned short* __restrict__ sm16,      // f16 sm tail
    const float* __restrict__ m_beta, const float* __restrict__ s_beta,
    unsigned short* __restrict__ out2)            // bf16
{
  __shared__ __align__(16) unsigned short smem[21888];
  __shared__ float lpts[72];
  __shared__ float gw[36][4];   // per-point tap weights (masked)
  __shared__ int   gofs[36][4]; // per-point tap element offsets (sans channel)
  const int t = blockIdx.x, tid = threadIdx.x, lane = tid & 63, wave = tid >> 6;
  const int l15 = lane & 15, kb = (lane >> 4) * 8;
  unsigned short (*Ss)[264] = (unsigned short (*)[264])smem;
  unsigned short (*C)[40]   = (unsigned short (*)[40])(smem + 9504); // single buffer
  const int c31  = tid & 31;
  const int g    = tid >> 5;
  const int goff = (g & 1) * 32;
  const int colw = c31 ^ ((g & 3) << 3);
  const unsigned char* ptok8 = params8 + (size_t)t * 64;
  uint4 rv8[2];
  {
    const unsigned char* src = ptok8 + ((size_t)(c31 * 4 + (g >> 1)) << 16) + goff;
    rv8[0] = *(const uint4*)src;
    rv8[1] = *(const uint4*)(src + 16);
  }
  unsigned short rSm[14];
  #pragma unroll
  for (int k = 0; k < 14; ++k){
    int idx = tid + k * 256;
    unsigned short v = 0;
    if (idx < 3456){
      int o = idx / 72, p = idx % 72;
      if (o < 36 && p < 36){
        int n = 65536 + o * 36 + p;
        v = sm16[(size_t)((n >> 6) - 1024) * 65536 + (size_t)t * 64 + (n & 63)];
      }
    }
    rSm[k] = v;
  }
  // ---- fused sample: coefficients once, vectorized dword gather ----
  if (tid < 72) lpts[tid] = pts[t * 72 + tid];
  __syncthreads();
  if (tid < 36){
    const int b = t >> 6;
    int p = tid;
    float fx = lpts[p*2]   * 64.f - 0.5f;
    float fy = lpts[p*2+1] * 64.f - 0.5f;
    float x0f = floorf(fx), y0f = floorf(fy);
    float wx = fx - x0f, wy = fy - y0f;
    int x0 = (int)x0f, y0 = (int)y0f;
    #pragma unroll
    for (int dy = 0; dy < 2; ++dy){
      #pragma unroll
      for (int dx = 0; dx < 2; ++dx){
        int xi = x0 + dx, yi = y0 + dy;
        bool valid = (xi >= 0) & (xi < 64) & (yi >= 0) & (yi < 64);
        int xc = min(max(xi, 0), 63), yc = min(max(yi, 0), 63);
        float w = (dx ? wx : 1.f - wx) * (dy ? wy : 1.f - wy);
        gw[p][dy*2 + dx]   = valid ? w : 0.f;
        gofs[p][dy*2 + dx] = ((b * 64 + yc) * 64 + xc) * 256;
      }
    }
  }
  __syncthreads();
  {
    const int cl4 = (tid & 63) * 4;   // channel base (4 channels/thread)
    const int pl  = tid >> 6;         // point lane (4 points concurrent)
    #pragma unroll
    for (int it = 0; it < 9; ++it){
      int p = pl + it * 4;
      float a0 = 0.f, a1 = 0.f, a2 = 0.f, a3 = 0.f;
      #pragma unroll
      for (int q = 0; q < 4; ++q){
        unsigned dw = *(const unsigned*)(imgT8 + (size_t)gofs[p][q] + cl4);
        float wt = gw[p][q];
        float r[4];
        fp8x4_to_f32(dw, r);
        a0 += r[0] * wt; a1 += r[1] * wt; a2 += r[2] * wt; a3 += r[3] * wt;
      }
      unsigned short tmp[4] = { f2h(a0), f2h(a1), f2h(a2), f2h(a3) };
      *(uint2*)&Ss[p][cl4] = *(const uint2*)tmp;
    }
  }
  __syncthreads();
  // ---- phase 1: barrier-free cc loop (wave-local staging) ----
  f32x4 acc[3][4] = {};
  for (int cc = 0; cc < 8; ++cc){
    #pragma unroll
    for (int v = 0; v < 2; ++v){
      #pragma unroll
      for (int w = 0; w < 4; ++w){
        unsigned dw = ((const unsigned*)&rv8[v])[w];
        int d0 = g * 32 + v * 16 + w * 4;
        unsigned short r[4];
        dec4_fp8(dw, r);
        C[d0 + 0][colw] = r[0];
        C[d0 + 1][colw] = r[1];
        C[d0 + 2][colw] = r[2];
        C[d0 + 3][colw] = r[3];
      }
    }
    if (cc < 7){
      const unsigned char* src = ptok8 + ((size_t)((cc + 1) * 128 + c31 * 4 + (g >> 1)) << 16) + goff;
      rv8[0] = *(const uint4*)src;
      rv8[1] = *(const uint4*)(src + 16);
    }
    f16x8 a[3], bfr[4];
    a[0] = *(const f16x8*)&Ss[l15][cc * 32 + kb];
    a[1] = *(const f16x8*)&Ss[16 + l15][cc * 32 + kb];
    a[2] = f16x8{};
    if (l15 < 4) a[2] = *(const f16x8*)&Ss[32 + l15][cc * 32 + kb];
    #pragma unroll
    for (int j = 0; j < 4; ++j){
      int d = wave * 64 + j * 16 + l15;   // within this wave's staged d-range
      bfr[j] = *(const f16x8*)&C[d][kb ^ (((d >> 5) & 3) << 3)];
    }
    #pragma unroll
    for (int i = 0; i < 3; ++i)
      #pragma unroll
      for (int j = 0; j < 4; ++j) acc[i][j] = mfma16h(a[i], bfr[j], acc[i][j]);
  }
  __syncthreads();
  {
    const bf16x8 z = {};
    #pragma unroll
    for (int i = 0; i < 9; ++i)
      *(bf16x8*)&smem[(i * 256 + tid) * 8] = z;
    #pragma unroll
    for (int k = 0; k < 14; ++k){
      int idx = tid + k * 256;
      if (idx < 3456) smem[18432 + idx] = rSm[k];
    }
  }
  __syncthreads();
  unsigned short (*O1T)[72] = (unsigned short (*)[72])smem;
  unsigned short (*Sm)[72]  = (unsigned short (*)[72])(smem + 18432);
  #pragma unroll
  for (int i = 0; i < 3; ++i){
    int p = i * 16 + ((lane >> 4) << 2);
    if (p < 36){
      #pragma unroll
      for (int j = 0; j < 4; ++j){
        int d = wave * 64 + j * 16 + l15;
        float mb = m_beta[d];
        unsigned short* dst = &O1T[d][p];
        #pragma unroll
        for (int r = 0; r < 4; ++r) dst[r] = f2h(gelu_f(acc[i][j][r] + mb));
      }
    }
  }
  __syncthreads();
  f32x4 acc2[3][4] = {};
  #pragma unroll
  for (int ks = 0; ks < 2; ++ks){
    int kb2 = ks * 32 + (lane >> 4) * 8;
    f16x8 a2[3], bf2[4];
    #pragma unroll
    for (int i = 0; i < 3; ++i) a2[i] = *(const f16x8*)&Sm[i*16 + l15][kb2];
    #pragma unroll
    for (int j = 0; j < 4; ++j) bf2[j] = *(const f16x8*)&O1T[wave*64 + j*16 + l15][kb2];
    #pragma unroll
    for (int i = 0; i < 3; ++i)
      #pragma unroll
      for (int j = 0; j < 4; ++j) acc2[i][j] = mfma16h(a2[i], bf2[j], acc2[i][j]);
  }
  unsigned short* o2 = out2 + (size_t)t * 9216;
  #pragma unroll
  for (int i = 0; i < 3; ++i){
    int ob = i*16 + ((lane >> 4) << 2);
    #pragma unroll
    for (int j = 0; j < 4; ++j){
      int d = wave*64 + j*16 + l15;
      #pragma unroll
      for (int r = 0; r < 4; ++r){
        int o = ob + r;
        if (o < 36) o2[o * 256 + d] = f2bf(gelu_f(acc2[i][j][r] + s_beta[o]));
      }
    }
  }
}

// ---------------- generic GEMM: C = act(A @ W + bias) (+resid) ----------------
template<int AK, int ACT, int RES, int OUTB>
__global__ __launch_bounds__(256) void k_gemm(
    const void* __restrict__ Ap, const float* __restrict__ W,
    const float* __restrict__ bias, const float* __restrict__ resid,
    void* __restrict__ Cp, int M, int N, int K)
{
  __shared__ __align__(16) unsigned short As[64][40];  // [m][k]
  __shared__ __align__(16) unsigned short Bs[64][40];  // [n][k^swz]
  const int tid = threadIdx.x, lane = tid & 63, wave = tid >> 6;
  const int wm = wave >> 1, wn = wave & 1;
  const int n0 = blockIdx.x * 64, m0 = blockIdx.y * 64;
  f32x4 acc[2][2] = {};
  for (int kk = 0; kk < K; kk += 32){
    { int m = tid >> 2, k4 = (tid & 3) * 8;
      if (AK == 0){
        const float* ap = (const float*)Ap + (size_t)(m0 + m) * K + kk + k4;
        #pragma unroll
        for (int i = 0; i < 8; ++i) As[m][k4 + i] = f2bf(ap[i]);
      } else {
        const unsigned short* ap = (const unsigned short*)Ap + (size_t)(m0 + m) * K + kk + k4;
        *(bf16x8*)&As[m][k4] = *(const bf16x8*)ap;
      }
    }
    { int kq = tid >> 3, n8 = (tid & 7) * 8;
      const float* wp = W + (size_t)(kk + kq) * N + n0 + n8;
      #pragma unroll
      for (int i = 0; i < 8; ++i){
        int n = n8 + i;
        Bs[n][kq ^ (((n >> 3) & 3) << 3)] = f2bf(wp[i]);
      }
    }
    __syncthreads();
    const int kb = (lane >> 4) * 8;
    bf16x8 a[2], bfr[2];
    #pragma unroll
    for (int i = 0; i < 2; ++i) a[i] = *(const bf16x8*)&As[wm*32 + i*16 + (lane & 15)][kb];
    #pragma unroll
    for (int j = 0; j < 2; ++j){
      int n = wn*32 + j*16 + (lane & 15);
      bfr[j] = *(const bf16x8*)&Bs[n][kb ^ (((n >> 3) & 3) << 3)];
    }
    #pragma unroll
    for (int i = 0; i < 2; ++i)
      #pragma unroll
      for (int j = 0; j < 2; ++j) acc[i][j] = mfma16(a[i], bfr[j], acc[i][j]);
    __syncthreads();
  }
  #pragma unroll
  for (int i = 0; i < 2; ++i)
    #pragma unroll
    for (int j = 0; j < 2; ++j){
      int col = n0 + wn*32 + j*16 + (lane & 15);
      float bv = bias[col];
      #pragma unroll
      for (int r = 0; r < 4; ++r){
        int row = m0 + wm*32 + i*16 + (lane >> 4) * 4 + r;
        float v = acc[i][j][r] + bv;
        if (ACT == 1) v = gelu_f(v);
        if (RES) v += resid[(size_t)row * N + col];
        if (OUTB) ((unsigned short*)Cp)[(size_t)row * N + col] = f2bf(v);
        else      ((float*)Cp)[(size_t)row * N + col] = v;
      }
    }
}

// ---------------- split-K GEMM: part[z][M][N] = A[:, z*KS:(z+1)*KS] @ W[z*KS:...] ----
template<int AK>
__global__ __launch_bounds__(256) void k_gemm_sk(
    const void* __restrict__ Ap, const float* __restrict__ W,
    float* __restrict__ part, int M, int N, int K, int KS)
{
  __shared__ __align__(16) unsigned short As[64][40];  // [m][k]
  __shared__ __align__(16) unsigned short Bs[64][40];  // [n][k^swz]
  const int tid = threadIdx.x, lane = tid & 63, wave = tid >> 6;
  const int wm = wave >> 1, wn = wave & 1;
  const int n0 = blockIdx.x * 64, m0 = blockIdx.y * 64;
  const int kbase = blockIdx.z * KS;
  f32x4 acc[2][2] = {};
  for (int kq = 0; kq < KS; kq += 32){
    int kk = kbase + kq;
    { int m = tid >> 2, k4 = (tid & 3) * 8;
      if (AK == 0){
        const float* ap = (const float*)Ap + (size_t)(m0 + m) * K + kk + k4;
        #pragma unroll
        for (int i = 0; i < 8; ++i) As[m][k4 + i] = f2bf(ap[i]);
      } else {
        const unsigned short* ap = (const unsigned short*)Ap + (size_t)(m0 + m) * K + kk + k4;
        *(bf16x8*)&As[m][k4] = *(const bf16x8*)ap;
      }
    }
    { int kr = tid >> 3, n8 = (tid & 7) * 8;
      const float* wp = W + (size_t)(kk + kr) * N + n0 + n8;
      #pragma unroll
      for (int i = 0; i < 8; ++i){
        int n = n8 + i;
        Bs[n][kr ^ (((n >> 3) & 3) << 3)] = f2bf(wp[i]);
      }
    }
    __syncthreads();
    const int kb = (lane >> 4) * 8;
    bf16x8 a[2], bfr[2];
    #pragma unroll
    for (int i = 0; i < 2; ++i) a[i] = *(const bf16x8*)&As[wm*32 + i*16 + (lane & 15)][kb];
    #pragma unroll
    for (int j = 0; j < 2; ++j){
      int n = wn*32 + j*16 + (lane & 15);
      bfr[j] = *(const bf16x8*)&Bs[n][kb ^ (((n >> 3) & 3) << 3)];
    }
    #pragma unroll
    for (int i = 0; i < 2; ++i)
      #pragma unroll
      for (int j = 0; j < 2; ++j) acc[i][j] = mfma16(a[i], bfr[j], acc[i][j]);
    __syncthreads();
  }
  float* pz = part + (size_t)blockIdx.z * M * N;
  #pragma unroll
  for (int i = 0; i < 2; ++i)
    #pragma unroll
    for (int j = 0; j < 2; ++j){
      int col = n0 + wn*32 + j*16 + (lane & 15);
      #pragma unroll
      for (int r = 0; r < 4; ++r){
        int row = m0 + wm*32 + i*16 + (lane >> 4) * 4 + r;
        pz[(size_t)row * N + col] = acc[i][j][r];
      }
    }
}

// ---------------- split-K reduce: out = sum_z part[z] + bias (+resid) ----------------
template<int RES>
__global__ __launch_bounds__(256) void k_reduce(
    const float* __restrict__ part, const float* __restrict__ bias,
    const float* __restrict__ resid, float* __restrict__ out,
    int total, int N, int SK)
{
  int i = blockIdx.x * 256 + threadIdx.x;
  if (i >= total) return;
  float s = 0.f;
  for (int z = 0; z < SK; ++z) s += part[(size_t)z * total + i];
  s += bias[i % N];
  if (RES) s += resid[i];
  out[i] = s;
}

// ---------------- fused split-K reduce + residual + LayerNorm ----------------
__global__ __launch_bounds__(256) void k_reduce_ln(
    const float* __restrict__ part, const float* __restrict__ bias,
    const float* __restrict__ resid,
    const float* __restrict__ g, const float* __restrict__ bb,
    float* __restrict__ emb_out, unsigned short* __restrict__ ln_out, int SK)
{
  __shared__ float red[4];
  const int t = blockIdx.x, tid = threadIdx.x;
  const int i = t * 256 + tid;
  float s = 0.f;
  for (int z = 0; z < SK; ++z) s += part[(size_t)z * 262144 + i];
  s += bias[tid] + resid[i];
  emb_out[i] = s;
  float mean = block_sum(s, red, tid) * (1.f / 256.f);
  float d = s - mean;
  float var = block_sum(d * d, red, tid) * (1.f / 256.f);
  ln_out[i] = f2bf(d * rsqrtf(var + 1e-5f) * g[tid] + bb[tid]);
}

// ---------------- attention: one (b,h) per block ----------------
__global__ __launch_bounds__(64) void k_attn(const float* __restrict__ qkv,
                                             float* __restrict__ attno)
{
  __shared__ float qs[64][33], ksm[64][33], vsm[64][33];
  const int blk = blockIdx.x, lane = threadIdx.x;
  const int b = blk >> 3, h = blk & 7;
  for (int idx = lane; idx < 2048; idx += 64){
    int row = idx >> 5, d = idx & 31;
    const float* base = qkv + (size_t)(b * 64 + row) * 768 + h * 32 + d;
    qs[row][d] = base[0]; ksm[row][d] = base[256]; vsm[row][d] = base[512];
  }
  __syncthreads();
  float qr[32];
  #pragma unroll
  for (int d = 0; d < 32; ++d) qr[d] = qs[lane][d];
  float s[64]; float mx = -1e30f;
  for (int m = 0; m < 64; ++m){
    float dot = 0.f;
    #pragma unroll
    for (int d = 0; d < 32; ++d) dot += qr[d] * ksm[m][d];
    dot *= 0.17677669529663687f;  // 32^-0.5
    s[m] = dot; mx = fmaxf(mx, dot);
  }
  float sum = 0.f;
  for (int m = 0; m < 64; ++m){ s[m] = expf(s[m] - mx); sum += s[m]; }
  float inv = 1.f / sum;
  float o[32] = {};
  for (int m = 0; m < 64; ++m){
    float p = s[m] * inv;
    #pragma unroll
    for (int d = 0; d < 32; ++d) o[d] += p * vsm[m][d];
  }
  float* dst = attno + (size_t)(b * 64 + lane) * 256 + h * 32;
  #pragma unroll
  for (int d = 0; d < 32; ++d) dst[d] = o[d];
}

__global__ void k_fill(float* p, int n, float v){
  int i = blockIdx.x * 256 + threadIdx.x;
  if (i < n) p[i] = v;
}

// ---------------- launch ----------------
extern "C" void kernel_launch(void* const* d_in, const int* in_sizes, int n_in,
                              void* d_out, int out_size, void* d_ws, size_t ws_size,
                              hipStream_t stream)
{
  const float* img      = (const float*)d_in[0];
  const float* embed    = (const float*)d_in[1];
  const float* roi      = (const float*)d_in[2];
  const float* ln_adj_g = (const float*)d_in[3];
  const float* ln_adj_b = (const float*)d_in[4];
  const float* w_adj    = (const float*)d_in[5];
  const float* ln_off_g = (const float*)d_in[6];
  const float* ln_off_b = (const float*)d_in[7];
  const float* w_off    = (const float*)d_in[8];
  const float* off_bias = (const float*)d_in[9];
  const float* pg_ln_g  = (const float*)d_in[10];
  const float* pg_ln_b  = (const float*)d_in[11];
  const float* pg_w1    = (const float*)d_in[12];
  const float* pg_b1    = (const float*)d_in[13];
  const float* pg_w2    = (const float*)d_in[14];
  const float* pg_b2    = (const float*)d_in[15];
  const float* m_beta   = (const float*)d_in[16];
  const float* s_beta   = (const float*)d_in[17];
  const float* mix_w    = (const float*)d_in[18];
  const float* mix_b    = (const float*)d_in[19];
  const float* ln1_g    = (const float*)d_in[20];
  const float* ln1_b    = (const float*)d_in[21];
  const float* qkv_w    = (const float*)d_in[22];
  const float* qkv_b    = (const float*)d_in[23];
  const float* proj_w   = (const float*)d_in[24];
  const float* proj_b   = (const float*)d_in[25];
  const float* ln2_g    = (const float*)d_in[26];
  const float* ln2_b    = (const float*)d_in[27];
  const float* fc1_w    = (const float*)d_in[28];
  const float* fc1_b    = (const float*)d_in[29];
  const float* fc2_w    = (const float*)d_in[30];
  const float* fc2_b    = (const float*)d_in[31];

  char* ws = (char*)d_ws;
  float*          pts     = (float*)         (ws + 0);          //   294912
  unsigned short* hbuf    = (unsigned short*)(ws + 294912);     //   131072 (bf16)
  unsigned char*  imgT8   = (unsigned char*) (ws + 557056);     // 16777216 (fp8)
  unsigned char*  params8 = (unsigned char*) (ws + 52985856);   // 67108864 (fp8 cm)
  unsigned short* sm16    = (unsigned short*)(ws + 120094720);  //  2752512 (f16 sm)
  unsigned short* out2    = (unsigned short*)(ws + 122847232);  // 18874368 (bf16)
  float*          embed1  = (float*)         (ws + 141721600);  //  1048576
  float*          embed2  = (float*)         (ws + 142770176);  //  1048576
  unsigned short* xln1    = (unsigned short*)(ws + 143818752);  //   524288
  unsigned short* xln2    = (unsigned short*)(ws + 144343040);  //   524288
  float*          qkvb    = (float*)         (ws + 144867328);  //  3145728
  float*          attno   = (float*)         (ws + 148013056);  //  1048576
  // aliased into the params8 region (dead after k_mixtoken):
  float*          part_mix  = (float*)(ws + 52985856);             // 16 MB (16 slabs)
  float*          part_smll = (float*)(ws + 52985856 + 16777216);  //  4 MB (4 slabs)
  unsigned short* h1        = (unsigned short*)(ws + 52985856 + 20971520); // 2 MB
  const size_t WS_NEEDED = 149061632;
  if (ws_size < WS_NEEDED){
    k_fill<<<(out_size + 255) / 256, 256, 0, stream>>>((float*)d_out, out_size, 12345.0f);
    return;
  }

  float* out = (float*)d_out;

  k_prep<<<1024, 256, 0, stream>>>(embed, roi, ln_adj_g, ln_adj_b, w_adj,
                                   ln_off_g, ln_off_b, w_off, off_bias,
                                   pg_ln_g, pg_ln_b, pg_w1, pg_b1, pts, hbuf);
  k_transpose<<<1024, 256, 0, stream>>>(img, imgT8);
  k_params<<<1045, 256, 0, stream>>>(hbuf, pg_w2, pg_b2, params8, sm16);
  k_mixtoken<<<1024, 256, 0, stream>>>(imgT8, pts, params8, sm16, m_beta, s_beta, out2);
  // embed1 = embed + out2 @ mix_w + mix_b   (split-K: 9216 = 16 x 576), fused LN1
  k_gemm_sk<1><<<dim3(4,16,16), 256, 0, stream>>>(out2, mix_w, part_mix, 1024, 256, 9216, 576);
  k_reduce_ln<<<1024, 256, 0, stream>>>(part_mix, mix_b, embed, ln1_g, ln1_b, embed1, xln1, 16);
  k_gemm<1,0,0,0><<<dim3(12,16), 256, 0, stream>>>(xln1, qkv_w, qkv_b, nullptr, qkvb, 1024, 768, 256);
  k_attn<<<128, 64, 0, stream>>>(qkvb, attno);
  // embed2 = embed1 + attno @ proj_w + proj_b (split-K: 256 = 4 x 64), fused LN2
  k_gemm_sk<0><<<dim3(4,16,4), 256, 0, stream>>>(attno, proj_w, part_smll, 1024, 256, 256, 64);
  k_reduce_ln<<<1024, 256, 0, stream>>>(part_smll, proj_b, embed1, ln2_g, ln2_b, embed2, xln2, 4);
  k_gemm<1,1,0,1><<<dim3(16,16), 256, 0, stream>>>(xln2, fc1_w, fc1_b, nullptr, h1, 1024, 1024, 256);
  // out = embed2 + h1 @ fc2_w + fc2_b   (split-K: 1024 = 4 x 256)
  k_gemm_sk<1><<<dim3(4,16,4), 256, 0, stream>>>(h1, fc2_w, part_smll, 1024, 256, 1024, 256);
  k_reduce<1><<<1024, 256, 0, stream>>>(part_smll, fc2_b, embed2, out, 262144, 256, 4);
}

// Round 19
// 228.620 us; speedup vs baseline: 1.8487x; 1.0194x over previous
//
#include <hip/hip_runtime.h>
#include <cstdint>

#define DEV __device__ __forceinline__

typedef __attribute__((ext_vector_type(8))) short bf16x8;
typedef __attribute__((ext_vector_type(8))) _Float16 f16x8;
typedef __attribute__((ext_vector_type(2))) __fp16 fp16x2;
typedef __attribute__((ext_vector_type(2))) float f32x2;
typedef __attribute__((ext_vector_type(4))) float f32x4;

DEV unsigned short f2bf(float x){
  union { float f; unsigned u; } c; c.f = x;
  unsigned r = c.u + 0x7fffu + ((c.u >> 16) & 1u);
  return (unsigned short)(r >> 16);
}
DEV float bf2f(unsigned short h){
  union { unsigned u; float f; } c; c.u = ((unsigned)h) << 16;
  return c.f;
}
DEV unsigned short f2h(float x){
  union { unsigned short u; _Float16 h; } c;
  c.h = (_Float16)x;
  return c.u;
}
// f32 -> e4m3 (OCP), RNE, saturate to +-448. Software fallback path.
DEV unsigned char f2fp8(float x){
  union { float f; unsigned u; } c; c.f = x;
  unsigned s = (c.u >> 24) & 0x80u;
  float a = fabsf(x);
  a = fminf(a, 448.f);
  unsigned n;
  if (a < 0.015625f){
    n = (unsigned)(int)rintf(a * 512.f);       // 0..8, RNE; 8 == 2^-6 normal
  } else {
    union { float f; unsigned u; } d; d.f = a;
    unsigned u2 = d.u + 0x7FFFFu + ((d.u >> 20) & 1u);
    n = (((u2 >> 23) - 120u) << 3) | ((u2 >> 20) & 7u);
  }
  return (unsigned char)(s | n);
}
// pack 2 f32 -> 2 e4m3 bytes (byte0 = a, byte1 = b); HW instr on gfx950
DEV unsigned pk_fp8(float a, float b){
#if defined(__has_builtin)
#if __has_builtin(__builtin_amdgcn_cvt_pk_fp8_f32)
  return (unsigned)__builtin_amdgcn_cvt_pk_fp8_f32(a, b, 0, false);
#else
  return (unsigned)f2fp8(a) | ((unsigned)f2fp8(b) << 8);
#endif
#else
  return (unsigned)f2fp8(a) | ((unsigned)f2fp8(b) << 8);
#endif
}
// e4m3 -> f16 bits, exact (software fallback).
DEV unsigned short fp82h(unsigned b){
  union { unsigned short u; _Float16 h; } c;
  c.u = (unsigned short)(((b & 0x80u) << 8) | ((b & 0x7Fu) << 7));
  c.h = c.h * (_Float16)256.0f;
  return c.u;
}
// single fp8 byte -> f32 (exact)
DEV float fp82f(unsigned b){
#if defined(__has_builtin)
#if __has_builtin(__builtin_amdgcn_cvt_f32_fp8)
  return __builtin_amdgcn_cvt_f32_fp8((int)b, 0);
#else
  union { unsigned short u; _Float16 h; } c; c.u = fp82h(b);
  return (float)c.h;
#endif
#else
  union { unsigned short u; _Float16 h; } c; c.u = fp82h(b);
  return (float)c.h;
#endif
}
// decode 4 fp8 bytes (one dword) -> 4 f32 (exact)
DEV void fp8x4_to_f32(unsigned dw, float r[4]){
#if defined(__has_builtin)
#if __has_builtin(__builtin_amdgcn_cvt_pk_f32_fp8)
  f32x2 lo = __builtin_amdgcn_cvt_pk_f32_fp8((int)dw, false);
  f32x2 hi = __builtin_amdgcn_cvt_pk_f32_fp8((int)dw, true);
  r[0] = lo.x; r[1] = lo.y; r[2] = hi.x; r[3] = hi.y;
#else
  r[0] = fp82f(dw & 0xFFu); r[1] = fp82f((dw >> 8) & 0xFFu);
  r[2] = fp82f((dw >> 16) & 0xFFu); r[3] = fp82f(dw >> 24);
#endif
#else
  r[0] = fp82f(dw & 0xFFu); r[1] = fp82f((dw >> 8) & 0xFFu);
  r[2] = fp82f((dw >> 16) & 0xFFu); r[3] = fp82f(dw >> 24);
#endif
}
// decode 4 fp8 bytes (one dword, consecutive elements) -> 4 f16 (exact)
DEV void dec4_fp8(unsigned dw, unsigned short r[4]){
#if defined(__has_builtin)
#if __has_builtin(__builtin_amdgcn_cvt_pk_f32_fp8)
  f32x2 lo = __builtin_amdgcn_cvt_pk_f32_fp8((int)dw, false);
  f32x2 hi = __builtin_amdgcn_cvt_pk_f32_fp8((int)dw, true);
  union { fp16x2 h; unsigned short u[2]; } a, b;
  a.h = __builtin_amdgcn_cvt_pkrtz(lo.x, lo.y);   // fp8 values exact in f16 -> RTZ lossless
  b.h = __builtin_amdgcn_cvt_pkrtz(hi.x, hi.y);
  r[0] = a.u[0]; r[1] = a.u[1]; r[2] = b.u[0]; r[3] = b.u[1];
#else
  r[0] = fp82h(dw & 0xFFu); r[1] = fp82h((dw >> 8) & 0xFFu);
  r[2] = fp82h((dw >> 16) & 0xFFu); r[3] = fp82h(dw >> 24);
#endif
#else
  r[0] = fp82h(dw & 0xFFu); r[1] = fp82h((dw >> 8) & 0xFFu);
  r[2] = fp82h((dw >> 16) & 0xFFu); r[3] = fp82h(dw >> 24);
#endif
}

DEV float gelu_f(float x){ return 0.5f * x * (1.f + erff(x * 0.70710678118654752440f)); }

DEV f32x4 mfma16(bf16x8 a, bf16x8 b, f32x4 c){
  return __builtin_amdgcn_mfma_f32_16x16x32_bf16(a, b, c, 0, 0, 0);
}
DEV f32x4 mfma16h(f16x8 a, f16x8 b, f32x4 c){
  return __builtin_amdgcn_mfma_f32_16x16x32_f16(a, b, c, 0, 0, 0);
}

// block_sum: 256 threads (4 waves)
DEV float block_sum(float v, float* red, int tid){
  #pragma unroll
  for (int o = 32; o > 0; o >>= 1) v += __shfl_down(v, o);
  if ((tid & 63) == 0) red[tid >> 6] = v;
  __syncthreads();
  float s = red[0] + red[1] + red[2] + red[3];
  __syncthreads();
  return s;
}

// ---------------- constants ----------------
// B=16 N=64 D=256 CI=256 H=W=64 P=36 HEADS=8 HD=32 HID=1024 TOTAL=66832 T=1024
// cm (n<65536) stored fp8 e4m3, blocked: params8[(n>>6)*65536 + t*64 + (n&63)] bytes
// sm tail (n>=65536) stored f16, blocked: sm16[((n>>6)-1024)*65536 + t*64 + (n&63)]
// imgT stored fp8 e4m3 [B,H,W,C] (17MB). out2 stored fp8 e4m3 [T,36,256] (9.4MB).
// hbuf bf16. k_sample fused into k_mixtoken (dword gather, 4 channels/thread).
// k_mixtoken cc-loop barrier-free (wave-local staging, single Cs buffer, 45KB LDS).

// ---------------- kernel 1: per-token prep ----------------
__global__ __launch_bounds__(256) void k_prep(
    const float* __restrict__ embed, const float* __restrict__ roi,
    const float* __restrict__ g_adj, const float* __restrict__ b_adj, const float* __restrict__ w_adj,
    const float* __restrict__ g_off, const float* __restrict__ b_off, const float* __restrict__ w_off,
    const float* __restrict__ off_bias,
    const float* __restrict__ g_pg, const float* __restrict__ b_pg,
    const float* __restrict__ w_pg1, const float* __restrict__ b_pg1,
    float* __restrict__ pts, unsigned short* __restrict__ hbuf)
{
  __shared__ float red[4];
  __shared__ float xln[256];
  __shared__ float offs[72];
  __shared__ float lg[4];
  __shared__ float stat[8];
  const int t = blockIdx.x, tid = threadIdx.x;
  float e = embed[t * 256 + tid];
  float mean = block_sum(e, red, tid) * (1.f / 256.f);
  float dv = e - mean;
  float var = block_sum(dv * dv, red, tid) * (1.f / 256.f);
  xln[tid] = dv * rsqrtf(var + 1e-5f);
  __syncthreads();
  if (tid < 4){
    float a0 = 0.f, a1 = 0.f, a2 = 0.f, a3 = 0.f;
    #pragma unroll 4
    for (int c = 0; c < 256; c += 4){
      a0 += (xln[c+0] * g_adj[c+0] + b_adj[c+0]) * w_adj[(c+0) * 4 + tid];
      a1 += (xln[c+1] * g_adj[c+1] + b_adj[c+1]) * w_adj[(c+1) * 4 + tid];
      a2 += (xln[c+2] * g_adj[c+2] + b_adj[c+2]) * w_adj[(c+2) * 4 + tid];
      a3 += (xln[c+3] * g_adj[c+3] + b_adj[c+3]) * w_adj[(c+3) * 4 + tid];
    }
    lg[tid] = (a0 + a1) + (a2 + a3);
  } else if (tid < 76){
    int j = tid - 4;
    float a0 = 0.f, a1 = 0.f, a2 = 0.f, a3 = 0.f;
    #pragma unroll 4
    for (int c = 0; c < 256; c += 4){
      a0 += (xln[c+0] * g_off[c+0] + b_off[c+0]) * w_off[(c+0) * 72 + j];
      a1 += (xln[c+1] * g_off[c+1] + b_off[c+1]) * w_off[(c+1) * 72 + j];
      a2 += (xln[c+2] * g_off[c+2] + b_off[c+2]) * w_off[(c+2) * 72 + j];
      a3 += (xln[c+3] * g_off[c+3] + b_off[c+3]) * w_off[(c+3) * 72 + j];
    }
    offs[j] = (a0 + a1) + (a2 + a3) + off_bias[j];
  } else if (tid < 140){
    int j = tid - 76;
    float a0 = 0.f, a1 = 0.f, a2 = 0.f, a3 = 0.f;
    #pragma unroll 4
    for (int c = 0; c < 256; c += 4){
      a0 += (xln[c+0] * g_pg[c+0] + b_pg[c+0]) * w_pg1[(c+0) * 64 + j];
      a1 += (xln[c+1] * g_pg[c+1] + b_pg[c+1]) * w_pg1[(c+1) * 64 + j];
      a2 += (xln[c+2] * g_pg[c+2] + b_pg[c+2]) * w_pg1[(c+2) * 64 + j];
      a3 += (xln[c+3] * g_pg[c+3] + b_pg[c+3]) * w_pg1[(c+3) * 64 + j];
    }
    hbuf[t * 64 + j] = f2bf((a0 + a1) + (a2 + a3) + b_pg1[j]);
  }
  __syncthreads();
  if (tid == 0){
    float x0 = roi[t*4+0], y0 = roi[t*4+1], x1 = roi[t*4+2], y1 = roi[t*4+3];
    float cx = (x0 + x1) * 0.5f, cy = (y0 + y1) * 0.5f;
    float w = fabsf(x1 - x0), hh = fabsf(y1 - y0);
    cx += lg[0] * w; cy += lg[1] * hh;
    w *= expf(lg[2]); hh *= expf(lg[3]);
    stat[0] = cx; stat[1] = cy; stat[2] = w; stat[3] = hh;
  }
  if (tid < 2){
    float mu = 0.f;
    for (int p = 0; p < 36; ++p) mu += offs[p*2 + tid];
    mu *= (1.f / 36.f);
    float v2 = 0.f;
    for (int p = 0; p < 36; ++p){ float d = offs[p*2 + tid] - mu; v2 += d * d; }
    float sd = sqrtf(v2 * (1.f / 35.f)) + 1e-7f;   // ddof=1
    stat[4 + tid] = mu; stat[6 + tid] = 1.f / (3.f * sd);
  }
  __syncthreads();
  if (tid < 72){
    int c = tid & 1;
    pts[t * 72 + tid] = stat[c] + (offs[tid] - stat[4 + c]) * stat[6 + c] * stat[2 + c];
  }
}

// ---------------- kernel 2: img [B,C,H,W] f32 -> [B,H,W,C] fp8 e4m3 ----------------
__global__ __launch_bounds__(256) void k_transpose(const float* __restrict__ img,
                                                   unsigned char* __restrict__ imgT8)
{
  __shared__ float tile[128][65];
  const int blk = blockIdx.x, tid = threadIdx.x;
  const int b = blk >> 6, y = blk & 63;
  for (int half = 0; half < 2; ++half){
    int c_loc = tid >> 1, x0 = (tid & 1) * 32;
    const float* src = img + (((size_t)(b * 256 + half * 128 + c_loc)) * 64 + y) * 64 + x0;
    #pragma unroll
    for (int i = 0; i < 32; ++i) tile[c_loc][x0 + i] = src[i];
    __syncthreads();
    {
      int x = tid >> 2, c0 = (tid & 3) * 32;
      size_t obase = (((size_t)(b * 64 + y)) * 64 + x) * 256 + half * 128 + c0;
      unsigned char tmp[32];
      #pragma unroll
      for (int cb = 0; cb < 32; cb += 2){
        unsigned pp = pk_fp8(tile[c0 + cb][x], tile[c0 + cb + 1][x]);
        tmp[cb]     = (unsigned char)(pp & 0xFFu);
        tmp[cb + 1] = (unsigned char)((pp >> 8) & 0xFFu);
      }
      *(uint4*)(imgT8 + obase)      = *(const uint4*)tmp;
      *(uint4*)(imgT8 + obase + 16) = *(const uint4*)(tmp + 16);
    }
    __syncthreads();
  }
}

// ---------------- kernel 4: params = h @ pg_w2 + pg_b2 (M=1024,K=64,N=66832)
// cm chunks (nc<1024) -> fp8 e4m3 via HW cvt_pk; sm tail (nc>=1024) -> f16.
__global__ __launch_bounds__(256) void k_params(
    const unsigned short* __restrict__ hbuf, const float* __restrict__ w2,
    const float* __restrict__ b2, unsigned char* __restrict__ params8,
    unsigned short* __restrict__ sm16)
{
  __shared__ __align__(16) unsigned short Bs[64][72];  // [n][k^swz]
  __shared__ __align__(16) unsigned short As[64][72];  // [m][k]
  __shared__ __align__(16) unsigned short Os[64][72];  // f16 staging (sm path)
  __shared__ __align__(16) unsigned char  Os8[64][72]; // fp8 staging (cm path)
  const int tid = threadIdx.x, lane = tid & 63, wave = tid >> 6;
  const int wm = wave >> 1, wn = wave & 1;
  const int nc = blockIdx.x, n0 = nc * 64;
  const bool cm = (nc < 1024);
  {
    int k = tid >> 2, nb = (tid & 3) * 16;
    #pragma unroll
    for (int i = 0; i < 16; ++i){
      int n = nb + i, gn = n0 + n;
      float v = (gn < 66832) ? w2[(size_t)k * 66832 + gn] : 0.f;
      Bs[n][k ^ (((n >> 3) & 7) << 3)] = f2bf(v);
    }
  }
  float bv[2];
  #pragma unroll
  for (int j = 0; j < 2; ++j){
    int col = n0 + wn*32 + j*16 + (lane & 15);
    bv[j] = (col < 66832) ? b2[col] : 0.f;
  }
  __syncthreads();
  for (int mt = 0; mt < 16; ++mt){
    int m0 = mt * 64;
    { int m = tid >> 2, kb4 = (tid & 3) * 16;
      const unsigned short* hp = hbuf + (m0 + m) * 64 + kb4;
      *(bf16x8*)&As[m][kb4]     = *(const bf16x8*)hp;
      *(bf16x8*)&As[m][kb4 + 8] = *(const bf16x8*)(hp + 8);
    }
    __syncthreads();
    f32x4 acc[2][2] = {};
    #pragma unroll
    for (int ks = 0; ks < 2; ++ks){
      int kb = ks * 32 + (lane >> 4) * 8;
      bf16x8 a[2], bb[2];
      #pragma unroll
      for (int i = 0; i < 2; ++i) a[i] = *(const bf16x8*)&As[wm*32 + i*16 + (lane & 15)][kb];
      #pragma unroll
      for (int j = 0; j < 2; ++j){
        int n = wn*32 + j*16 + (lane & 15);
        bb[j] = *(const bf16x8*)&Bs[n][kb ^ (((n >> 3) & 7) << 3)];
      }
      #pragma unroll
      for (int i = 0; i < 2; ++i)
        #pragma unroll
        for (int j = 0; j < 2; ++j) acc[i][j] = mfma16(a[i], bb[j], acc[i][j]);
    }
    if (cm){
      #pragma unroll
      for (int i = 0; i < 2; ++i)
        #pragma unroll
        for (int j = 0; j < 2; ++j){
          int cl = wn*32 + j*16 + (lane & 15);
          int rl = wm*32 + i*16 + (lane >> 4) * 4;
          unsigned p01 = pk_fp8(acc[i][j][0] + bv[j], acc[i][j][1] + bv[j]);
          unsigned p23 = pk_fp8(acc[i][j][2] + bv[j], acc[i][j][3] + bv[j]);
          Os8[rl + 0][cl] = (unsigned char)(p01 & 0xFFu);
          Os8[rl + 1][cl] = (unsigned char)((p01 >> 8) & 0xFFu);
          Os8[rl + 2][cl] = (unsigned char)(p23 & 0xFFu);
          Os8[rl + 3][cl] = (unsigned char)((p23 >> 8) & 0xFFu);
        }
      __syncthreads();
      {
        int rl = tid >> 2, c0 = (tid & 3) * 16;
        uint2 lo = *(const uint2*)&Os8[rl][c0];
        uint2 hi = *(const uint2*)&Os8[rl][c0 + 8];
        uint4 val; val.x = lo.x; val.y = lo.y; val.z = hi.x; val.w = hi.y;
        *(uint4*)(params8 + ((size_t)nc * 1024 + m0 + rl) * 64 + c0) = val;
      }
    } else {
      #pragma unroll
      for (int i = 0; i < 2; ++i)
        #pragma unroll
        for (int j = 0; j < 2; ++j){
          int cl = wn*32 + j*16 + (lane & 15);
          #pragma unroll
          for (int r = 0; r < 4; ++r){
            int rl = wm*32 + i*16 + (lane >> 4) * 4 + r;
            Os[rl][cl] = f2h(acc[i][j][r] + bv[j]);
          }
        }
      __syncthreads();
      {
        int rl = tid >> 2, c0 = (tid & 3) * 16;
        size_t gbase = ((size_t)(nc - 1024) * 1024 + m0 + rl) * 64 + c0;
        *(bf16x8*)(sm16 + gbase)     = *(const bf16x8*)&Os[rl][c0];
        *(bf16x8*)(sm16 + gbase + 8) = *(const bf16x8*)&Os[rl][c0 + 8];
      }
    }
    __syncthreads();
  }
}

// ---------------- kernel 5: fused sample + per-token adaptive mixing ----------
// Gather vectorized (dword per tap); out2 written as fp8 e4m3.
// cc-loop barrier-free (wave-local staging, single Cs buffer, 45KB LDS).
__global__ __launch_bounds__(256) void k_mixtoken(
    const unsigned char* __restrict__ imgT8,      // fp8 [B,H,W,C]
    const float* __restrict__ pts,                // [T,36,2]
    const unsigned char*  __restrict__ params8,   // fp8 cm
    const unsigned short* __restrict__ sm16,      // f16 sm tail
    const float* __restrict__ m_beta, const float* __restrict__ s_beta,
    unsigned char* __restrict__ out28)            // fp8
{
  __shared__ __align__(16) unsigned short smem[21888];
  __shared__ float lpts[72];
  __shared__ float gw[36][4];   // per-point tap weights (masked)
  __shared__ int   gofs[36][4]; // per-point tap element offsets (sans channel)
  const int t = blockIdx.x, tid = threadIdx.x, lane = tid & 63, wave = tid >> 6;
  const int l15 = lane & 15, kb = (lane >> 4) * 8;
  unsigned short (*Ss)[264] = (unsigned short (*)[264])smem;
  unsigned short (*C)[40]   = (unsigned short (*)[40])(smem + 9504); // single buffer
  const int c31  = tid & 31;
  const int g    = tid >> 5;
  const int goff = (g & 1) * 32;
  const int colw = c31 ^ ((g & 3) << 3);
  const unsigned char* ptok8 = params8 + (size_t)t * 64;
  uint4 rv8[2];
  {
    const unsigned char* src = ptok8 + ((size_t)(c31 * 4 + (g >> 1)) << 16) + goff;
    rv8[0] = *(const uint4*)src;
    rv8[1] = *(const uint4*)(src + 16);
  }
  unsigned short rSm[14];
  #pragma unroll
  for (int k = 0; k < 14; ++k){
    int idx = tid + k * 256;
    unsigned short v = 0;
    if (idx < 3456){
      int o = idx / 72, p = idx % 72;
      if (o < 36 && p < 36){
        int n = 65536 + o * 36 + p;
        v = sm16[(size_t)((n >> 6) - 1024) * 65536 + (size_t)t * 64 + (n & 63)];
      }
    }
    rSm[k] = v;
  }
  // ---- fused sample: coefficients once, vectorized dword gather ----
  if (tid < 72) lpts[tid] = pts[t * 72 + tid];
  __syncthreads();
  if (tid < 36){
    const int b = t >> 6;
    int p = tid;
    float fx = lpts[p*2]   * 64.f - 0.5f;
    float fy = lpts[p*2+1] * 64.f - 0.5f;
    float x0f = floorf(fx), y0f = floorf(fy);
    float wx = fx - x0f, wy = fy - y0f;
    int x0 = (int)x0f, y0 = (int)y0f;
    #pragma unroll
    for (int dy = 0; dy < 2; ++dy){
      #pragma unroll
      for (int dx = 0; dx < 2; ++dx){
        int xi = x0 + dx, yi = y0 + dy;
        bool valid = (xi >= 0) & (xi < 64) & (yi >= 0) & (yi < 64);
        int xc = min(max(xi, 0), 63), yc = min(max(yi, 0), 63);
        float w = (dx ? wx : 1.f - wx) * (dy ? wy : 1.f - wy);
        gw[p][dy*2 + dx]   = valid ? w : 0.f;
        gofs[p][dy*2 + dx] = ((b * 64 + yc) * 64 + xc) * 256;
      }
    }
  }
  __syncthreads();
  {
    const int cl4 = (tid & 63) * 4;   // channel base (4 channels/thread)
    const int pl  = tid >> 6;         // point lane (4 points concurrent)
    #pragma unroll
    for (int it = 0; it < 9; ++it){
      int p = pl + it * 4;
      float a0 = 0.f, a1 = 0.f, a2 = 0.f, a3 = 0.f;
      #pragma unroll
      for (int q = 0; q < 4; ++q){
        unsigned dw = *(const unsigned*)(imgT8 + (size_t)gofs[p][q] + cl4);
        float wt = gw[p][q];
        float r[4];
        fp8x4_to_f32(dw, r);
        a0 += r[0] * wt; a1 += r[1] * wt; a2 += r[2] * wt; a3 += r[3] * wt;
      }
      unsigned short tmp[4] = { f2h(a0), f2h(a1), f2h(a2), f2h(a3) };
      *(uint2*)&Ss[p][cl4] = *(const uint2*)tmp;
    }
  }
  __syncthreads();
  // ---- phase 1: barrier-free cc loop (wave-local staging) ----
  f32x4 acc[3][4] = {};
  for (int cc = 0; cc < 8; ++cc){
    #pragma unroll
    for (int v = 0; v < 2; ++v){
      #pragma unroll
      for (int w = 0; w < 4; ++w){
        unsigned dw = ((const unsigned*)&rv8[v])[w];
        int d0 = g * 32 + v * 16 + w * 4;
        unsigned short r[4];
        dec4_fp8(dw, r);
        C[d0 + 0][colw] = r[0];
        C[d0 + 1][colw] = r[1];
        C[d0 + 2][colw] = r[2];
        C[d0 + 3][colw] = r[3];
      }
    }
    if (cc < 7){
      const unsigned char* src = ptok8 + ((size_t)((cc + 1) * 128 + c31 * 4 + (g >> 1)) << 16) + goff;
      rv8[0] = *(const uint4*)src;
      rv8[1] = *(const uint4*)(src + 16);
    }
    f16x8 a[3], bfr[4];
    a[0] = *(const f16x8*)&Ss[l15][cc * 32 + kb];
    a[1] = *(const f16x8*)&Ss[16 + l15][cc * 32 + kb];
    a[2] = f16x8{};
    if (l15 < 4) a[2] = *(const f16x8*)&Ss[32 + l15][cc * 32 + kb];
    #pragma unroll
    for (int j = 0; j < 4; ++j){
      int d = wave * 64 + j * 16 + l15;   // within this wave's staged d-range
      bfr[j] = *(const f16x8*)&C[d][kb ^ (((d >> 5) & 3) << 3)];
    }
    #pragma unroll
    for (int i = 0; i < 3; ++i)
      #pragma unroll
      for (int j = 0; j < 4; ++j) acc[i][j] = mfma16h(a[i], bfr[j], acc[i][j]);
  }
  __syncthreads();
  {
    const bf16x8 z = {};
    #pragma unroll
    for (int i = 0; i < 9; ++i)
      *(bf16x8*)&smem[(i * 256 + tid) * 8] = z;
    #pragma unroll
    for (int k = 0; k < 14; ++k){
      int idx = tid + k * 256;
      if (idx < 3456) smem[18432 + idx] = rSm[k];
    }
  }
  __syncthreads();
  unsigned short (*O1T)[72] = (unsigned short (*)[72])smem;
  unsigned short (*Sm)[72]  = (unsigned short (*)[72])(smem + 18432);
  #pragma unroll
  for (int i = 0; i < 3; ++i){
    int p = i * 16 + ((lane >> 4) << 2);
    if (p < 36){
      #pragma unroll
      for (int j = 0; j < 4; ++j){
        int d = wave * 64 + j * 16 + l15;
        float mb = m_beta[d];
        unsigned short* dst = &O1T[d][p];
        #pragma unroll
        for (int r = 0; r < 4; ++r) dst[r] = f2h(gelu_f(acc[i][j][r] + mb));
      }
    }
  }
  __syncthreads();
  f32x4 acc2[3][4] = {};
  #pragma unroll
  for (int ks = 0; ks < 2; ++ks){
    int kb2 = ks * 32 + (lane >> 4) * 8;
    f16x8 a2[3], bf2[4];
    #pragma unroll
    for (int i = 0; i < 3; ++i) a2[i] = *(const f16x8*)&Sm[i*16 + l15][kb2];
    #pragma unroll
    for (int j = 0; j < 4; ++j) bf2[j] = *(const f16x8*)&O1T[wave*64 + j*16 + l15][kb2];
    #pragma unroll
    for (int i = 0; i < 3; ++i)
      #pragma unroll
      for (int j = 0; j < 4; ++j) acc2[i][j] = mfma16h(a2[i], bf2[j], acc2[i][j]);
  }
  unsigned char* o2 = out28 + (size_t)t * 9216;
  #pragma unroll
  for (int i = 0; i < 3; ++i){
    int ob = i*16 + ((lane >> 4) << 2);
    #pragma unroll
    for (int j = 0; j < 4; ++j){
      int d = wave*64 + j*16 + l15;
      float v0 = (ob + 0 < 36) ? gelu_f(acc2[i][j][0] + s_beta[ob + 0]) : 0.f;
      float v1 = (ob + 1 < 36) ? gelu_f(acc2[i][j][1] + s_beta[ob + 1]) : 0.f;
      float v2 = (ob + 2 < 36) ? gelu_f(acc2[i][j][2] + s_beta[ob + 2]) : 0.f;
      float v3 = (ob + 3 < 36) ? gelu_f(acc2[i][j][3] + s_beta[ob + 3]) : 0.f;
      unsigned p01 = pk_fp8(v0, v1);
      unsigned p23 = pk_fp8(v2, v3);
      if (ob + 0 < 36) o2[(ob + 0) * 256 + d] = (unsigned char)(p01 & 0xFFu);
      if (ob + 1 < 36) o2[(ob + 1) * 256 + d] = (unsigned char)((p01 >> 8) & 0xFFu);
      if (ob + 2 < 36) o2[(ob + 2) * 256 + d] = (unsigned char)(p23 & 0xFFu);
      if (ob + 3 < 36) o2[(ob + 3) * 256 + d] = (unsigned char)((p23 >> 8) & 0xFFu);
    }
  }
}

// ---------------- generic GEMM: C = act(A @ W + bias) (+resid) ----------------
// AK: 0 = f32 A, 1 = bf16 A, 2 = fp8 e4m3 A (decoded exactly to bf16)
template<int AK, int ACT, int RES, int OUTB>
__global__ __launch_bounds__(256) void k_gemm(
    const void* __restrict__ Ap, const float* __restrict__ W,
    const float* __restrict__ bias, const float* __restrict__ resid,
    void* __restrict__ Cp, int M, int N, int K)
{
  __shared__ __align__(16) unsigned short As[64][40];  // [m][k]
  __shared__ __align__(16) unsigned short Bs[64][40];  // [n][k^swz]
  const int tid = threadIdx.x, lane = tid & 63, wave = tid >> 6;
  const int wm = wave >> 1, wn = wave & 1;
  const int n0 = blockIdx.x * 64, m0 = blockIdx.y * 64;
  f32x4 acc[2][2] = {};
  for (int kk = 0; kk < K; kk += 32){
    { int m = tid >> 2, k4 = (tid & 3) * 8;
      if (AK == 0){
        const float* ap = (const float*)Ap + (size_t)(m0 + m) * K + kk + k4;
        #pragma unroll
        for (int i = 0; i < 8; ++i) As[m][k4 + i] = f2bf(ap[i]);
      } else {
        const unsigned short* ap = (const unsigned short*)Ap + (size_t)(m0 + m) * K + kk + k4;
        *(bf16x8*)&As[m][k4] = *(const bf16x8*)ap;
      }
    }
    { int kq = tid >> 3, n8 = (tid & 7) * 8;
      const float* wp = W + (size_t)(kk + kq) * N + n0 + n8;
      #pragma unroll
      for (int i = 0; i < 8; ++i){
        int n = n8 + i;
        Bs[n][kq ^ (((n >> 3) & 3) << 3)] = f2bf(wp[i]);
      }
    }
    __syncthreads();
    const int kb = (lane >> 4) * 8;
    bf16x8 a[2], bfr[2];
    #pragma unroll
    for (int i = 0; i < 2; ++i) a[i] = *(const bf16x8*)&As[wm*32 + i*16 + (lane & 15)][kb];
    #pragma unroll
    for (int j = 0; j < 2; ++j){
      int n = wn*32 + j*16 + (lane & 15);
      bfr[j] = *(const bf16x8*)&Bs[n][kb ^ (((n >> 3) & 3) << 3)];
    }
    #pragma unroll
    for (int i = 0; i < 2; ++i)
      #pragma unroll
      for (int j = 0; j < 2; ++j) acc[i][j] = mfma16(a[i], bfr[j], acc[i][j]);
    __syncthreads();
  }
  #pragma unroll
  for (int i = 0; i < 2; ++i)
    #pragma unroll
    for (int j = 0; j < 2; ++j){
      int col = n0 + wn*32 + j*16 + (lane & 15);
      float bv = bias[col];
      #pragma unroll
      for (int r = 0; r < 4; ++r){
        int row = m0 + wm*32 + i*16 + (lane >> 4) * 4 + r;
        float v = acc[i][j][r] + bv;
        if (ACT == 1) v = gelu_f(v);
        if (RES) v += resid[(size_t)row * N + col];
        if (OUTB) ((unsigned short*)Cp)[(size_t)row * N + col] = f2bf(v);
        else      ((float*)Cp)[(size_t)row * N + col] = v;
      }
    }
}

// ---------------- split-K GEMM: part[z][M][N] = A[:, z*KS:(z+1)*KS] @ W[z*KS:...] ----
// AK: 0 = f32 A, 1 = bf16 A, 2 = fp8 e4m3 A (decoded exactly to bf16)
template<int AK>
__global__ __launch_bounds__(256) void k_gemm_sk(
    const void* __restrict__ Ap, const float* __restrict__ W,
    float* __restrict__ part, int M, int N, int K, int KS)
{
  __shared__ __align__(16) unsigned short As[64][40];  // [m][k]
  __shared__ __align__(16) unsigned short Bs[64][40];  // [n][k^swz]
  const int tid = threadIdx.x, lane = tid & 63, wave = tid >> 6;
  const int wm = wave >> 1, wn = wave & 1;
  const int n0 = blockIdx.x * 64, m0 = blockIdx.y * 64;
  const int kbase = blockIdx.z * KS;
  f32x4 acc[2][2] = {};
  for (int kq = 0; kq < KS; kq += 32){
    int kk = kbase + kq;
    { int m = tid >> 2, k4 = (tid & 3) * 8;
      if (AK == 0){
        const float* ap = (const float*)Ap + (size_t)(m0 + m) * K + kk + k4;
        #pragma unroll
        for (int i = 0; i < 8; ++i) As[m][k4 + i] = f2bf(ap[i]);
      } else if (AK == 1){
        const unsigned short* ap = (const unsigned short*)Ap + (size_t)(m0 + m) * K + kk + k4;
        *(bf16x8*)&As[m][k4] = *(const bf16x8*)ap;
      } else {
        const unsigned char* ap = (const unsigned char*)Ap + (size_t)(m0 + m) * K + kk + k4;
        uint2 dw2 = *(const uint2*)ap;
        float r0[4], r1[4];
        fp8x4_to_f32(dw2.x, r0);
        fp8x4_to_f32(dw2.y, r1);
        unsigned short tmp[8] = { f2bf(r0[0]), f2bf(r0[1]), f2bf(r0[2]), f2bf(r0[3]),
                                  f2bf(r1[0]), f2bf(r1[1]), f2bf(r1[2]), f2bf(r1[3]) };
        *(bf16x8*)&As[m][k4] = *(const bf16x8*)tmp;
      }
    }
    { int kr = tid >> 3, n8 = (tid & 7) * 8;
      const float* wp = W + (size_t)(kk + kr) * N + n0 + n8;
      #pragma unroll
      for (int i = 0; i < 8; ++i){
        int n = n8 + i;
        Bs[n][kr ^ (((n >> 3) & 3) << 3)] = f2bf(wp[i]);
      }
    }
    __syncthreads();
    const int kb = (lane >> 4) * 8;
    bf16x8 a[2], bfr[2];
    #pragma unroll
    for (int i = 0; i < 2; ++i) a[i] = *(const bf16x8*)&As[wm*32 + i*16 + (lane & 15)][kb];
    #pragma unroll
    for (int j = 0; j < 2; ++j){
      int n = wn*32 + j*16 + (lane & 15);
      bfr[j] = *(const bf16x8*)&Bs[n][kb ^ (((n >> 3) & 3) << 3)];
    }
    #pragma unroll
    for (int i = 0; i < 2; ++i)
      #pragma unroll
      for (int j = 0; j < 2; ++j) acc[i][j] = mfma16(a[i], bfr[j], acc[i][j]);
    __syncthreads();
  }
  float* pz = part + (size_t)blockIdx.z * M * N;
  #pragma unroll
  for (int i = 0; i < 2; ++i)
    #pragma unroll
    for (int j = 0; j < 2; ++j){
      int col = n0 + wn*32 + j*16 + (lane & 15);
      #pragma unroll
      for (int r = 0; r < 4; ++r){
        int row = m0 + wm*32 + i*16 + (lane >> 4) * 4 + r;
        pz[(size_t)row * N + col] = acc[i][j][r];
      }
    }
}

// ---------------- split-K reduce: out = sum_z part[z] + bias (+resid) ----------------
template<int RES>
__global__ __launch_bounds__(256) void k_reduce(
    const float* __restrict__ part, const float* __restrict__ bias,
    const float* __restrict__ resid, float* __restrict__ out,
    int total, int N, int SK)
{
  int i = blockIdx.x * 256 + threadIdx.x;
  if (i >= total) return;
  float s = 0.f;
  for (int z = 0; z < SK; ++z) s += part[(size_t)z * total + i];
  s += bias[i % N];
  if (RES) s += resid[i];
  out[i] = s;
}

// ---------------- fused split-K reduce + residual + LayerNorm ----------------
__global__ __launch_bounds__(256) void k_reduce_ln(
    const float* __restrict__ part, const float* __restrict__ bias,
    const float* __restrict__ resid,
    const float* __restrict__ g, const float* __restrict__ bb,
    float* __restrict__ emb_out, unsigned short* __restrict__ ln_out, int SK)
{
  __shared__ float red[4];
  const int t = blockIdx.x, tid = threadIdx.x;
  const int i = t * 256 + tid;
  float s = 0.f;
  for (int z = 0; z < SK; ++z) s += part[(size_t)z * 262144 + i];
  s += bias[tid] + resid[i];
  emb_out[i] = s;
  float mean = block_sum(s, red, tid) * (1.f / 256.f);
  float d = s - mean;
  float var = block_sum(d * d, red, tid) * (1.f / 256.f);
  ln_out[i] = f2bf(d * rsqrtf(var + 1e-5f) * g[tid] + bb[tid]);
}

// ---------------- attention: one (b,h) per block ----------------
__global__ __launch_bounds__(64) void k_attn(const float* __restrict__ qkv,
                                             float* __restrict__ attno)
{
  __shared__ float qs[64][33], ksm[64][33], vsm[64][33];
  const int blk = blockIdx.x, lane = threadIdx.x;
  const int b = blk >> 3, h = blk & 7;
  for (int idx = lane; idx < 2048; idx += 64){
    int row = idx >> 5, d = idx & 31;
    const float* base = qkv + (size_t)(b * 64 + row) * 768 + h * 32 + d;
    qs[row][d] = base[0]; ksm[row][d] = base[256]; vsm[row][d] = base[512];
  }
  __syncthreads();
  float qr[32];
  #pragma unroll
  for (int d = 0; d < 32; ++d) qr[d] = qs[lane][d];
  float s[64]; float mx = -1e30f;
  for (int m = 0; m < 64; ++m){
    float dot = 0.f;
    #pragma unroll
    for (int d = 0; d < 32; ++d) dot += qr[d] * ksm[m][d];
    dot *= 0.17677669529663687f;  // 32^-0.5
    s[m] = dot; mx = fmaxf(mx, dot);
  }
  float sum = 0.f;
  for (int m = 0; m < 64; ++m){ s[m] = expf(s[m] - mx); sum += s[m]; }
  float inv = 1.f / sum;
  float o[32] = {};
  for (int m = 0; m < 64; ++m){
    float p = s[m] * inv;
    #pragma unroll
    for (int d = 0; d < 32; ++d) o[d] += p * vsm[m][d];
  }
  float* dst = attno + (size_t)(b * 64 + lane) * 256 + h * 32;
  #pragma unroll
  for (int d = 0; d < 32; ++d) dst[d] = o[d];
}

__global__ void k_fill(float* p, int n, float v){
  int i = blockIdx.x * 256 + threadIdx.x;
  if (i < n) p[i] = v;
}

// ---------------- launch ----------------
extern "C" void kernel_launch(void* const* d_in, const int* in_sizes, int n_in,
                              void* d_out, int out_size, void* d_ws, size_t ws_size,
                              hipStream_t stream)
{
  const float* img      = (const float*)d_in[0];
  const float* embed    = (const float*)d_in[1];
  const float* roi      = (const float*)d_in[2];
  const float* ln_adj_g = (const float*)d_in[3];
  const float* ln_adj_b = (const float*)d_in[4];
  const float* w_adj    = (const float*)d_in[5];
  const float* ln_off_g = (const float*)d_in[6];
  const float* ln_off_b = (const float*)d_in[7];
  const float* w_off    = (const float*)d_in[8];
  const float* off_bias = (const float*)d_in[9];
  const float* pg_ln_g  = (const float*)d_in[10];
  const float* pg_ln_b  = (const float*)d_in[11];
  const float* pg_w1    = (const float*)d_in[12];
  const float* pg_b1    = (const float*)d_in[13];
  const float* pg_w2    = (const float*)d_in[14];
  const float* pg_b2    = (const float*)d_in[15];
  const float* m_beta   = (const float*)d_in[16];
  const float* s_beta   = (const float*)d_in[17];
  const float* mix_w    = (const float*)d_in[18];
  const float* mix_b    = (const float*)d_in[19];
  const float* ln1_g    = (const float*)d_in[20];
  const float* ln1_b    = (const float*)d_in[21];
  const float* qkv_w    = (const float*)d_in[22];
  const float* qkv_b    = (const float*)d_in[23];
  const float* proj_w   = (const float*)d_in[24];
  const float* proj_b   = (const float*)d_in[25];
  const float* ln2_g    = (const float*)d_in[26];
  const float* ln2_b    = (const float*)d_in[27];
  const float* fc1_w    = (const float*)d_in[28];
  const float* fc1_b    = (const float*)d_in[29];
  const float* fc2_w    = (const float*)d_in[30];
  const float* fc2_b    = (const float*)d_in[31];

  char* ws = (char*)d_ws;
  float*          pts     = (float*)         (ws + 0);          //   294912
  unsigned short* hbuf    = (unsigned short*)(ws + 294912);     //   131072 (bf16)
  unsigned char*  imgT8   = (unsigned char*) (ws + 557056);     // 16777216 (fp8)
  unsigned char*  params8 = (unsigned char*) (ws + 52985856);   // 67108864 (fp8 cm)
  unsigned short* sm16    = (unsigned short*)(ws + 120094720);  //  2752512 (f16 sm)
  unsigned char*  out28   = (unsigned char*) (ws + 122847232);  //  9437184 (fp8)
  float*          embed1  = (float*)         (ws + 141721600);  //  1048576
  float*          embed2  = (float*)         (ws + 142770176);  //  1048576
  unsigned short* xln1    = (unsigned short*)(ws + 143818752);  //   524288
  unsigned short* xln2    = (unsigned short*)(ws + 144343040);  //   524288
  float*          qkvb    = (float*)         (ws + 144867328);  //  3145728
  float*          attno   = (float*)         (ws + 148013056);  //  1048576
  // aliased into the params8 region (dead after k_mixtoken):
  float*          part_mix  = (float*)(ws + 52985856);             // 16 MB (16 slabs)
  float*          part_smll = (float*)(ws + 52985856 + 16777216);  //  4 MB (4 slabs)
  unsigned short* h1        = (unsigned short*)(ws + 52985856 + 20971520); // 2 MB
  const size_t WS_NEEDED = 149061632;
  if (ws_size < WS_NEEDED){
    k_fill<<<(out_size + 255) / 256, 256, 0, stream>>>((float*)d_out, out_size, 12345.0f);
    return;
  }

  float* out = (float*)d_out;

  k_prep<<<1024, 256, 0, stream>>>(embed, roi, ln_adj_g, ln_adj_b, w_adj,
                                   ln_off_g, ln_off_b, w_off, off_bias,
                                   pg_ln_g, pg_ln_b, pg_w1, pg_b1, pts, hbuf);
  k_transpose<<<1024, 256, 0, stream>>>(img, imgT8);
  k_params<<<1045, 256, 0, stream>>>(hbuf, pg_w2, pg_b2, params8, sm16);
  k_mixtoken<<<1024, 256, 0, stream>>>(imgT8, pts, params8, sm16, m_beta, s_beta, out28);
  // embed1 = embed + out2 @ mix_w + mix_b   (split-K: 9216 = 16 x 576), fused LN1
  k_gemm_sk<2><<<dim3(4,16,16), 256, 0, stream>>>(out28, mix_w, part_mix, 1024, 256, 9216, 576);
  k_reduce_ln<<<1024, 256, 0, stream>>>(part_mix, mix_b, embed, ln1_g, ln1_b, embed1, xln1, 16);
  k_gemm<1,0,0,0><<<dim3(12,16), 256, 0, stream>>>(xln1, qkv_w, qkv_b, nullptr, qkvb, 1024, 768, 256);
  k_attn<<<128, 64, 0, stream>>>(qkvb, attno);
  // embed2 = embed1 + attno @ proj_w + proj_b (split-K: 256 = 4 x 64), fused LN2
  k_gemm_sk<0><<<dim3(4,16,4), 256, 0, stream>>>(attno, proj_w, part_smll, 1024, 256, 256, 64);
  k_reduce_ln<<<1024, 256, 0, stream>>>(part_smll, proj_b, embed1, ln2_g, ln2_b, embed2, xln2, 4);
  k_gemm<1,1,0,1><<<dim3(16,16), 256, 0, stream>>>(xln2, fc1_w, fc1_b, nullptr, h1, 1024, 1024, 256);
  // out = embed2 + h1 @ fc2_w + fc2_b   (split-K: 1024 = 4 x 256)
  k_gemm_sk<1><<<dim3(4,16,4), 256, 0, stream>>>(h1, fc2_w, part_smll, 1024, 256, 1024, 256);
  k_reduce<1><<<1024, 256, 0, stream>>>(part_smll, fc2_b, embed2, out, 262144, 256, 4);
}

// Round 20
// 227.402 us; speedup vs baseline: 1.8586x; 1.0054x over previous
//
#include <hip/hip_runtime.h>
#include <cstdint>

#define DEV __device__ __forceinline__

typedef __attribute__((ext_vector_type(8))) short bf16x8;
typedef __attribute__((ext_vector_type(8))) _Float16 f16x8;
typedef __attribute__((ext_vector_type(2))) __fp16 fp16x2;
typedef __attribute__((ext_vector_type(2))) float f32x2;
typedef __attribute__((ext_vector_type(4))) float f32x4;

DEV unsigned short f2bf(float x){
  union { float f; unsigned u; } c; c.f = x;
  unsigned r = c.u + 0x7fffu + ((c.u >> 16) & 1u);
  return (unsigned short)(r >> 16);
}
DEV float bf2f(unsigned short h){
  union { unsigned u; float f; } c; c.u = ((unsigned)h) << 16;
  return c.f;
}
DEV unsigned short f2h(float x){
  union { unsigned short u; _Float16 h; } c;
  c.h = (_Float16)x;
  return c.u;
}
// f32 -> e4m3 (OCP), RNE, saturate to +-448. Software fallback path.
DEV unsigned char f2fp8(float x){
  union { float f; unsigned u; } c; c.f = x;
  unsigned s = (c.u >> 24) & 0x80u;
  float a = fabsf(x);
  a = fminf(a, 448.f);
  unsigned n;
  if (a < 0.015625f){
    n = (unsigned)(int)rintf(a * 512.f);       // 0..8, RNE; 8 == 2^-6 normal
  } else {
    union { float f; unsigned u; } d; d.f = a;
    unsigned u2 = d.u + 0x7FFFFu + ((d.u >> 20) & 1u);
    n = (((u2 >> 23) - 120u) << 3) | ((u2 >> 20) & 7u);
  }
  return (unsigned char)(s | n);
}
// pack 2 f32 -> 2 e4m3 bytes (byte0 = a, byte1 = b); HW instr on gfx950
DEV unsigned pk_fp8(float a, float b){
#if defined(__has_builtin)
#if __has_builtin(__builtin_amdgcn_cvt_pk_fp8_f32)
  return (unsigned)__builtin_amdgcn_cvt_pk_fp8_f32(a, b, 0, false);
#else
  return (unsigned)f2fp8(a) | ((unsigned)f2fp8(b) << 8);
#endif
#else
  return (unsigned)f2fp8(a) | ((unsigned)f2fp8(b) << 8);
#endif
}
// e4m3 -> f16 bits, exact (software fallback).
DEV unsigned short fp82h(unsigned b){
  union { unsigned short u; _Float16 h; } c;
  c.u = (unsigned short)(((b & 0x80u) << 8) | ((b & 0x7Fu) << 7));
  c.h = c.h * (_Float16)256.0f;
  return c.u;
}
// single fp8 byte -> f32 (exact)
DEV float fp82f(unsigned b){
#if defined(__has_builtin)
#if __has_builtin(__builtin_amdgcn_cvt_f32_fp8)
  return __builtin_amdgcn_cvt_f32_fp8((int)b, 0);
#else
  union { unsigned short u; _Float16 h; } c; c.u = fp82h(b);
  return (float)c.h;
#endif
#else
  union { unsigned short u; _Float16 h; } c; c.u = fp82h(b);
  return (float)c.h;
#endif
}
// decode 4 fp8 bytes (one dword) -> 4 f32 (exact)
DEV void fp8x4_to_f32(unsigned dw, float r[4]){
#if defined(__has_builtin)
#if __has_builtin(__builtin_amdgcn_cvt_pk_f32_fp8)
  f32x2 lo = __builtin_amdgcn_cvt_pk_f32_fp8((int)dw, false);
  f32x2 hi = __builtin_amdgcn_cvt_pk_f32_fp8((int)dw, true);
  r[0] = lo.x; r[1] = lo.y; r[2] = hi.x; r[3] = hi.y;
#else
  r[0] = fp82f(dw & 0xFFu); r[1] = fp82f((dw >> 8) & 0xFFu);
  r[2] = fp82f((dw >> 16) & 0xFFu); r[3] = fp82f(dw >> 24);
#endif
#else
  r[0] = fp82f(dw & 0xFFu); r[1] = fp82f((dw >> 8) & 0xFFu);
  r[2] = fp82f((dw >> 16) & 0xFFu); r[3] = fp82f(dw >> 24);
#endif
}
// decode 4 fp8 bytes (one dword, consecutive elements) -> 4 f16 (exact)
DEV void dec4_fp8(unsigned dw, unsigned short r[4]){
#if defined(__has_builtin)
#if __has_builtin(__builtin_amdgcn_cvt_pk_f32_fp8)
  f32x2 lo = __builtin_amdgcn_cvt_pk_f32_fp8((int)dw, false);
  f32x2 hi = __builtin_amdgcn_cvt_pk_f32_fp8((int)dw, true);
  union { fp16x2 h; unsigned short u[2]; } a, b;
  a.h = __builtin_amdgcn_cvt_pkrtz(lo.x, lo.y);   // fp8 values exact in f16 -> RTZ lossless
  b.h = __builtin_amdgcn_cvt_pkrtz(hi.x, hi.y);
  r[0] = a.u[0]; r[1] = a.u[1]; r[2] = b.u[0]; r[3] = b.u[1];
#else
  r[0] = fp82h(dw & 0xFFu); r[1] = fp82h((dw >> 8) & 0xFFu);
  r[2] = fp82h((dw >> 16) & 0xFFu); r[3] = fp82h(dw >> 24);
#endif
#else
  r[0] = fp82h(dw & 0xFFu); r[1] = fp82h((dw >> 8) & 0xFFu);
  r[2] = fp82h((dw >> 16) & 0xFFu); r[3] = fp82h(dw >> 24);
#endif
}

DEV float gelu_f(float x){ return 0.5f * x * (1.f + erff(x * 0.70710678118654752440f)); }

DEV f32x4 mfma16(bf16x8 a, bf16x8 b, f32x4 c){
  return __builtin_amdgcn_mfma_f32_16x16x32_bf16(a, b, c, 0, 0, 0);
}
DEV f32x4 mfma16h(f16x8 a, f16x8 b, f32x4 c){
  return __builtin_amdgcn_mfma_f32_16x16x32_f16(a, b, c, 0, 0, 0);
}

// block_sum: 256 threads (4 waves)
DEV float block_sum(float v, float* red, int tid){
  #pragma unroll
  for (int o = 32; o > 0; o >>= 1) v += __shfl_down(v, o);
  if ((tid & 63) == 0) red[tid >> 6] = v;
  __syncthreads();
  float s = red[0] + red[1] + red[2] + red[3];
  __syncthreads();
  return s;
}

// ---------------- constants ----------------
// B=16 N=64 D=256 CI=256 H=W=64 P=36 HEADS=8 HD=32 HID=1024 TOTAL=66832 T=1024
// cm (n<65536) stored fp8 e4m3, blocked: params8[(n>>6)*65536 + t*64 + (n&63)] bytes
// sm tail (n>=65536) stored f16, blocked: sm16[((n>>6)-1024)*65536 + t*64 + (n&63)]
// imgT stored fp8 e4m3 [B,H,W,C] (17MB). out2 stored fp8 e4m3 [T,36,256] (9.4MB).
// hbuf bf16. k_sample fused into k_mixtoken (dword gather, 4 channels/thread).
// k_mixtoken cc-loop barrier-free, 2-deep register prefetch pipeline (rvA/rvB).

// ---------------- kernel 1: per-token prep ----------------
__global__ __launch_bounds__(256) void k_prep(
    const float* __restrict__ embed, const float* __restrict__ roi,
    const float* __restrict__ g_adj, const float* __restrict__ b_adj, const float* __restrict__ w_adj,
    const float* __restrict__ g_off, const float* __restrict__ b_off, const float* __restrict__ w_off,
    const float* __restrict__ off_bias,
    const float* __restrict__ g_pg, const float* __restrict__ b_pg,
    const float* __restrict__ w_pg1, const float* __restrict__ b_pg1,
    float* __restrict__ pts, unsigned short* __restrict__ hbuf)
{
  __shared__ float red[4];
  __shared__ float xln[256];
  __shared__ float offs[72];
  __shared__ float lg[4];
  __shared__ float stat[8];
  const int t = blockIdx.x, tid = threadIdx.x;
  float e = embed[t * 256 + tid];
  float mean = block_sum(e, red, tid) * (1.f / 256.f);
  float dv = e - mean;
  float var = block_sum(dv * dv, red, tid) * (1.f / 256.f);
  xln[tid] = dv * rsqrtf(var + 1e-5f);
  __syncthreads();
  if (tid < 4){
    float a0 = 0.f, a1 = 0.f, a2 = 0.f, a3 = 0.f;
    #pragma unroll 4
    for (int c = 0; c < 256; c += 4){
      a0 += (xln[c+0] * g_adj[c+0] + b_adj[c+0]) * w_adj[(c+0) * 4 + tid];
      a1 += (xln[c+1] * g_adj[c+1] + b_adj[c+1]) * w_adj[(c+1) * 4 + tid];
      a2 += (xln[c+2] * g_adj[c+2] + b_adj[c+2]) * w_adj[(c+2) * 4 + tid];
      a3 += (xln[c+3] * g_adj[c+3] + b_adj[c+3]) * w_adj[(c+3) * 4 + tid];
    }
    lg[tid] = (a0 + a1) + (a2 + a3);
  } else if (tid < 76){
    int j = tid - 4;
    float a0 = 0.f, a1 = 0.f, a2 = 0.f, a3 = 0.f;
    #pragma unroll 4
    for (int c = 0; c < 256; c += 4){
      a0 += (xln[c+0] * g_off[c+0] + b_off[c+0]) * w_off[(c+0) * 72 + j];
      a1 += (xln[c+1] * g_off[c+1] + b_off[c+1]) * w_off[(c+1) * 72 + j];
      a2 += (xln[c+2] * g_off[c+2] + b_off[c+2]) * w_off[(c+2) * 72 + j];
      a3 += (xln[c+3] * g_off[c+3] + b_off[c+3]) * w_off[(c+3) * 72 + j];
    }
    offs[j] = (a0 + a1) + (a2 + a3) + off_bias[j];
  } else if (tid < 140){
    int j = tid - 76;
    float a0 = 0.f, a1 = 0.f, a2 = 0.f, a3 = 0.f;
    #pragma unroll 4
    for (int c = 0; c < 256; c += 4){
      a0 += (xln[c+0] * g_pg[c+0] + b_pg[c+0]) * w_pg1[(c+0) * 64 + j];
      a1 += (xln[c+1] * g_pg[c+1] + b_pg[c+1]) * w_pg1[(c+1) * 64 + j];
      a2 += (xln[c+2] * g_pg[c+2] + b_pg[c+2]) * w_pg1[(c+2) * 64 + j];
      a3 += (xln[c+3] * g_pg[c+3] + b_pg[c+3]) * w_pg1[(c+3) * 64 + j];
    }
    hbuf[t * 64 + j] = f2bf((a0 + a1) + (a2 + a3) + b_pg1[j]);
  }
  __syncthreads();
  if (tid == 0){
    float x0 = roi[t*4+0], y0 = roi[t*4+1], x1 = roi[t*4+2], y1 = roi[t*4+3];
    float cx = (x0 + x1) * 0.5f, cy = (y0 + y1) * 0.5f;
    float w = fabsf(x1 - x0), hh = fabsf(y1 - y0);
    cx += lg[0] * w; cy += lg[1] * hh;
    w *= expf(lg[2]); hh *= expf(lg[3]);
    stat[0] = cx; stat[1] = cy; stat[2] = w; stat[3] = hh;
  }
  if (tid < 2){
    float mu = 0.f;
    for (int p = 0; p < 36; ++p) mu += offs[p*2 + tid];
    mu *= (1.f / 36.f);
    float v2 = 0.f;
    for (int p = 0; p < 36; ++p){ float d = offs[p*2 + tid] - mu; v2 += d * d; }
    float sd = sqrtf(v2 * (1.f / 35.f)) + 1e-7f;   // ddof=1
    stat[4 + tid] = mu; stat[6 + tid] = 1.f / (3.f * sd);
  }
  __syncthreads();
  if (tid < 72){
    int c = tid & 1;
    pts[t * 72 + tid] = stat[c] + (offs[tid] - stat[4 + c]) * stat[6 + c] * stat[2 + c];
  }
}

// ---------------- kernel 2: img [B,C,H,W] f32 -> [B,H,W,C] fp8 e4m3 ----------------
__global__ __launch_bounds__(256) void k_transpose(const float* __restrict__ img,
                                                   unsigned char* __restrict__ imgT8)
{
  __shared__ float tile[128][65];
  const int blk = blockIdx.x, tid = threadIdx.x;
  const int b = blk >> 6, y = blk & 63;
  for (int half = 0; half < 2; ++half){
    int c_loc = tid >> 1, x0 = (tid & 1) * 32;
    const float* src = img + (((size_t)(b * 256 + half * 128 + c_loc)) * 64 + y) * 64 + x0;
    #pragma unroll
    for (int i = 0; i < 32; ++i) tile[c_loc][x0 + i] = src[i];
    __syncthreads();
    {
      int x = tid >> 2, c0 = (tid & 3) * 32;
      size_t obase = (((size_t)(b * 64 + y)) * 64 + x) * 256 + half * 128 + c0;
      unsigned char tmp[32];
      #pragma unroll
      for (int cb = 0; cb < 32; cb += 2){
        unsigned pp = pk_fp8(tile[c0 + cb][x], tile[c0 + cb + 1][x]);
        tmp[cb]     = (unsigned char)(pp & 0xFFu);
        tmp[cb + 1] = (unsigned char)((pp >> 8) & 0xFFu);
      }
      *(uint4*)(imgT8 + obase)      = *(const uint4*)tmp;
      *(uint4*)(imgT8 + obase + 16) = *(const uint4*)(tmp + 16);
    }
    __syncthreads();
  }
}

// ---------------- kernel 4: params = h @ pg_w2 + pg_b2 (M=1024,K=64,N=66832)
// cm chunks (nc<1024) -> fp8 e4m3 via HW cvt_pk; sm tail (nc>=1024) -> f16.
__global__ __launch_bounds__(256) void k_params(
    const unsigned short* __restrict__ hbuf, const float* __restrict__ w2,
    const float* __restrict__ b2, unsigned char* __restrict__ params8,
    unsigned short* __restrict__ sm16)
{
  __shared__ __align__(16) unsigned short Bs[64][72];  // [n][k^swz]
  __shared__ __align__(16) unsigned short As[64][72];  // [m][k]
  __shared__ __align__(16) unsigned short Os[64][72];  // f16 staging (sm path)
  __shared__ __align__(16) unsigned char  Os8[64][72]; // fp8 staging (cm path)
  const int tid = threadIdx.x, lane = tid & 63, wave = tid >> 6;
  const int wm = wave >> 1, wn = wave & 1;
  const int nc = blockIdx.x, n0 = nc * 64;
  const bool cm = (nc < 1024);
  {
    int k = tid >> 2, nb = (tid & 3) * 16;
    #pragma unroll
    for (int i = 0; i < 16; ++i){
      int n = nb + i, gn = n0 + n;
      float v = (gn < 66832) ? w2[(size_t)k * 66832 + gn] : 0.f;
      Bs[n][k ^ (((n >> 3) & 7) << 3)] = f2bf(v);
    }
  }
  float bv[2];
  #pragma unroll
  for (int j = 0; j < 2; ++j){
    int col = n0 + wn*32 + j*16 + (lane & 15);
    bv[j] = (col < 66832) ? b2[col] : 0.f;
  }
  __syncthreads();
  for (int mt = 0; mt < 16; ++mt){
    int m0 = mt * 64;
    { int m = tid >> 2, kb4 = (tid & 3) * 16;
      const unsigned short* hp = hbuf + (m0 + m) * 64 + kb4;
      *(bf16x8*)&As[m][kb4]     = *(const bf16x8*)hp;
      *(bf16x8*)&As[m][kb4 + 8] = *(const bf16x8*)(hp + 8);
    }
    __syncthreads();
    f32x4 acc[2][2] = {};
    #pragma unroll
    for (int ks = 0; ks < 2; ++ks){
      int kb = ks * 32 + (lane >> 4) * 8;
      bf16x8 a[2], bb[2];
      #pragma unroll
      for (int i = 0; i < 2; ++i) a[i] = *(const bf16x8*)&As[wm*32 + i*16 + (lane & 15)][kb];
      #pragma unroll
      for (int j = 0; j < 2; ++j){
        int n = wn*32 + j*16 + (lane & 15);
        bb[j] = *(const bf16x8*)&Bs[n][kb ^ (((n >> 3) & 7) << 3)];
      }
      #pragma unroll
      for (int i = 0; i < 2; ++i)
        #pragma unroll
        for (int j = 0; j < 2; ++j) acc[i][j] = mfma16(a[i], bb[j], acc[i][j]);
    }
    if (cm){
      #pragma unroll
      for (int i = 0; i < 2; ++i)
        #pragma unroll
        for (int j = 0; j < 2; ++j){
          int cl = wn*32 + j*16 + (lane & 15);
          int rl = wm*32 + i*16 + (lane >> 4) * 4;
          unsigned p01 = pk_fp8(acc[i][j][0] + bv[j], acc[i][j][1] + bv[j]);
          unsigned p23 = pk_fp8(acc[i][j][2] + bv[j], acc[i][j][3] + bv[j]);
          Os8[rl + 0][cl] = (unsigned char)(p01 & 0xFFu);
          Os8[rl + 1][cl] = (unsigned char)((p01 >> 8) & 0xFFu);
          Os8[rl + 2][cl] = (unsigned char)(p23 & 0xFFu);
          Os8[rl + 3][cl] = (unsigned char)((p23 >> 8) & 0xFFu);
        }
      __syncthreads();
      {
        int rl = tid >> 2, c0 = (tid & 3) * 16;
        uint2 lo = *(const uint2*)&Os8[rl][c0];
        uint2 hi = *(const uint2*)&Os8[rl][c0 + 8];
        uint4 val; val.x = lo.x; val.y = lo.y; val.z = hi.x; val.w = hi.y;
        *(uint4*)(params8 + ((size_t)nc * 1024 + m0 + rl) * 64 + c0) = val;
      }
    } else {
      #pragma unroll
      for (int i = 0; i < 2; ++i)
        #pragma unroll
        for (int j = 0; j < 2; ++j){
          int cl = wn*32 + j*16 + (lane & 15);
          #pragma unroll
          for (int r = 0; r < 4; ++r){
            int rl = wm*32 + i*16 + (lane >> 4) * 4 + r;
            Os[rl][cl] = f2h(acc[i][j][r] + bv[j]);
          }
        }
      __syncthreads();
      {
        int rl = tid >> 2, c0 = (tid & 3) * 16;
        size_t gbase = ((size_t)(nc - 1024) * 1024 + m0 + rl) * 64 + c0;
        *(bf16x8*)(sm16 + gbase)     = *(const bf16x8*)&Os[rl][c0];
        *(bf16x8*)(sm16 + gbase + 8) = *(const bf16x8*)&Os[rl][c0 + 8];
      }
    }
    __syncthreads();
  }
}

// ---------------- k_mixtoken helpers ----------------
DEV void load_chunk(uint4 rv[2], const unsigned char* __restrict__ ptok8,
                    int cc, int c31, int g, int goff){
  const unsigned char* src = ptok8 + ((size_t)(cc * 128 + c31 * 4 + (g >> 1)) << 16) + goff;
  rv[0] = *(const uint4*)src;
  rv[1] = *(const uint4*)(src + 16);
}
DEV void stage_chunk(unsigned short (*C)[40], const uint4 rv[2], int g, int colw){
  #pragma unroll
  for (int v = 0; v < 2; ++v){
    #pragma unroll
    for (int w = 0; w < 4; ++w){
      unsigned dw = ((const unsigned*)&rv[v])[w];
      int d0 = g * 32 + v * 16 + w * 4;
      unsigned short r[4];
      dec4_fp8(dw, r);
      C[d0 + 0][colw] = r[0];
      C[d0 + 1][colw] = r[1];
      C[d0 + 2][colw] = r[2];
      C[d0 + 3][colw] = r[3];
    }
  }
}
DEV void mfma_chunk(f32x4 acc[3][4], unsigned short (*Ss)[264], unsigned short (*C)[40],
                    int cc, int wave, int l15, int kb){
  f16x8 a[3], bfr[4];
  a[0] = *(const f16x8*)&Ss[l15][cc * 32 + kb];
  a[1] = *(const f16x8*)&Ss[16 + l15][cc * 32 + kb];
  a[2] = f16x8{};
  if (l15 < 4) a[2] = *(const f16x8*)&Ss[32 + l15][cc * 32 + kb];
  #pragma unroll
  for (int j = 0; j < 4; ++j){
    int d = wave * 64 + j * 16 + l15;
    bfr[j] = *(const f16x8*)&C[d][kb ^ (((d >> 5) & 3) << 3)];
  }
  #pragma unroll
  for (int i = 0; i < 3; ++i)
    #pragma unroll
    for (int j = 0; j < 4; ++j) acc[i][j] = mfma16h(a[i], bfr[j], acc[i][j]);
}

// ---------------- kernel 5: fused sample + per-token adaptive mixing ----------
// Gather vectorized (dword per tap); out2 written as fp8 e4m3.
// cc-loop barrier-free, 2-deep register prefetch pipeline (rvA/rvB).
__global__ __launch_bounds__(256) void k_mixtoken(
    const unsigned char* __restrict__ imgT8,      // fp8 [B,H,W,C]
    const float* __restrict__ pts,                // [T,36,2]
    const unsigned char*  __restrict__ params8,   // fp8 cm
    const unsigned short* __restrict__ sm16,      // f16 sm tail
    const float* __restrict__ m_beta, const float* __restrict__ s_beta,
    unsigned char* __restrict__ out28)            // fp8
{
  __shared__ __align__(16) unsigned short smem[21888];
  __shared__ float lpts[72];
  __shared__ float gw[36][4];   // per-point tap weights (masked)
  __shared__ int   gofs[36][4]; // per-point tap element offsets (sans channel)
  const int t = blockIdx.x, tid = threadIdx.x, lane = tid & 63, wave = tid >> 6;
  const int l15 = lane & 15, kb = (lane >> 4) * 8;
  unsigned short (*Ss)[264] = (unsigned short (*)[264])smem;
  unsigned short (*C)[40]   = (unsigned short (*)[40])(smem + 9504); // single buffer
  const int c31  = tid & 31;
  const int g    = tid >> 5;
  const int goff = (g & 1) * 32;
  const int colw = c31 ^ ((g & 3) << 3);
  const unsigned char* ptok8 = params8 + (size_t)t * 64;
  uint4 rvA[2], rvB[2];
  load_chunk(rvA, ptok8, 0, c31, g, goff);   // 2-deep prefetch issued up front;
  load_chunk(rvB, ptok8, 1, c31, g, goff);   // latency hides under rSm + gather
  unsigned short rSm[14];
  #pragma unroll
  for (int k = 0; k < 14; ++k){
    int idx = tid + k * 256;
    unsigned short v = 0;
    if (idx < 3456){
      int o = idx / 72, p = idx % 72;
      if (o < 36 && p < 36){
        int n = 65536 + o * 36 + p;
        v = sm16[(size_t)((n >> 6) - 1024) * 65536 + (size_t)t * 64 + (n & 63)];
      }
    }
    rSm[k] = v;
  }
  // ---- fused sample: coefficients once, vectorized dword gather ----
  if (tid < 72) lpts[tid] = pts[t * 72 + tid];
  __syncthreads();
  if (tid < 36){
    const int b = t >> 6;
    int p = tid;
    float fx = lpts[p*2]   * 64.f - 0.5f;
    float fy = lpts[p*2+1] * 64.f - 0.5f;
    float x0f = floorf(fx), y0f = floorf(fy);
    float wx = fx - x0f, wy = fy - y0f;
    int x0 = (int)x0f, y0 = (int)y0f;
    #pragma unroll
    for (int dy = 0; dy < 2; ++dy){
      #pragma unroll
      for (int dx = 0; dx < 2; ++dx){
        int xi = x0 + dx, yi = y0 + dy;
        bool valid = (xi >= 0) & (xi < 64) & (yi >= 0) & (yi < 64);
        int xc = min(max(xi, 0), 63), yc = min(max(yi, 0), 63);
        float w = (dx ? wx : 1.f - wx) * (dy ? wy : 1.f - wy);
        gw[p][dy*2 + dx]   = valid ? w : 0.f;
        gofs[p][dy*2 + dx] = ((b * 64 + yc) * 64 + xc) * 256;
      }
    }
  }
  __syncthreads();
  {
    const int cl4 = (tid & 63) * 4;   // channel base (4 channels/thread)
    const int pl  = tid >> 6;         // point lane (4 points concurrent)
    #pragma unroll
    for (int it = 0; it < 9; ++it){
      int p = pl + it * 4;
      float a0 = 0.f, a1 = 0.f, a2 = 0.f, a3 = 0.f;
      #pragma unroll
      for (int q = 0; q < 4; ++q){
        unsigned dw = *(const unsigned*)(imgT8 + (size_t)gofs[p][q] + cl4);
        float wt = gw[p][q];
        float r[4];
        fp8x4_to_f32(dw, r);
        a0 += r[0] * wt; a1 += r[1] * wt; a2 += r[2] * wt; a3 += r[3] * wt;
      }
      unsigned short tmp[4] = { f2h(a0), f2h(a1), f2h(a2), f2h(a3) };
      *(uint2*)&Ss[p][cl4] = *(const uint2*)tmp;
    }
  }
  __syncthreads();
  // ---- phase 1: barrier-free cc loop, 2-deep prefetch ----
  f32x4 acc[3][4] = {};
  #pragma unroll
  for (int cc = 0; cc < 8; cc += 2){
    stage_chunk(C, rvA, g, colw);
    if (cc + 2 < 8) load_chunk(rvA, ptok8, cc + 2, c31, g, goff);
    mfma_chunk(acc, Ss, C, cc, wave, l15, kb);
    stage_chunk(C, rvB, g, colw);
    if (cc + 3 < 8) load_chunk(rvB, ptok8, cc + 3, c31, g, goff);
    mfma_chunk(acc, Ss, C, cc + 1, wave, l15, kb);
  }
  __syncthreads();
  {
    const bf16x8 z = {};
    #pragma unroll
    for (int i = 0; i < 9; ++i)
      *(bf16x8*)&smem[(i * 256 + tid) * 8] = z;
    #pragma unroll
    for (int k = 0; k < 14; ++k){
      int idx = tid + k * 256;
      if (idx < 3456) smem[18432 + idx] = rSm[k];
    }
  }
  __syncthreads();
  unsigned short (*O1T)[72] = (unsigned short (*)[72])smem;
  unsigned short (*Sm)[72]  = (unsigned short (*)[72])(smem + 18432);
  #pragma unroll
  for (int i = 0; i < 3; ++i){
    int p = i * 16 + ((lane >> 4) << 2);
    if (p < 36){
      #pragma unroll
      for (int j = 0; j < 4; ++j){
        int d = wave * 64 + j * 16 + l15;
        float mb = m_beta[d];
        unsigned short* dst = &O1T[d][p];
        #pragma unroll
        for (int r = 0; r < 4; ++r) dst[r] = f2h(gelu_f(acc[i][j][r] + mb));
      }
    }
  }
  __syncthreads();
  f32x4 acc2[3][4] = {};
  #pragma unroll
  for (int ks = 0; ks < 2; ++ks){
    int kb2 = ks * 32 + (lane >> 4) * 8;
    f16x8 a2[3], bf2[4];
    #pragma unroll
    for (int i = 0; i < 3; ++i) a2[i] = *(const f16x8*)&Sm[i*16 + l15][kb2];
    #pragma unroll
    for (int j = 0; j < 4; ++j) bf2[j] = *(const f16x8*)&O1T[wave*64 + j*16 + l15][kb2];
    #pragma unroll
    for (int i = 0; i < 3; ++i)
      #pragma unroll
      for (int j = 0; j < 4; ++j) acc2[i][j] = mfma16h(a2[i], bf2[j], acc2[i][j]);
  }
  unsigned char* o2 = out28 + (size_t)t * 9216;
  #pragma unroll
  for (int i = 0; i < 3; ++i){
    int ob = i*16 + ((lane >> 4) << 2);
    #pragma unroll
    for (int j = 0; j < 4; ++j){
      int d = wave*64 + j*16 + l15;
      float v0 = (ob + 0 < 36) ? gelu_f(acc2[i][j][0] + s_beta[ob + 0]) : 0.f;
      float v1 = (ob + 1 < 36) ? gelu_f(acc2[i][j][1] + s_beta[ob + 1]) : 0.f;
      float v2 = (ob + 2 < 36) ? gelu_f(acc2[i][j][2] + s_beta[ob + 2]) : 0.f;
      float v3 = (ob + 3 < 36) ? gelu_f(acc2[i][j][3] + s_beta[ob + 3]) : 0.f;
      unsigned p01 = pk_fp8(v0, v1);
      unsigned p23 = pk_fp8(v2, v3);
      if (ob + 0 < 36) o2[(ob + 0) * 256 + d] = (unsigned char)(p01 & 0xFFu);
      if (ob + 1 < 36) o2[(ob + 1) * 256 + d] = (unsigned char)((p01 >> 8) & 0xFFu);
      if (ob + 2 < 36) o2[(ob + 2) * 256 + d] = (unsigned char)(p23 & 0xFFu);
      if (ob + 3 < 36) o2[(ob + 3) * 256 + d] = (unsigned char)((p23 >> 8) & 0xFFu);
    }
  }
}

// ---------------- generic GEMM: C = act(A @ W + bias) (+resid) ----------------
// AK: 0 = f32 A, 1 = bf16 A
template<int AK, int ACT, int RES, int OUTB>
__global__ __launch_bounds__(256) void k_gemm(
    const void* __restrict__ Ap, const float* __restrict__ W,
    const float* __restrict__ bias, const float* __restrict__ resid,
    void* __restrict__ Cp, int M, int N, int K)
{
  __shared__ __align__(16) unsigned short As[64][40];  // [m][k]
  __shared__ __align__(16) unsigned short Bs[64][40];  // [n][k^swz]
  const int tid = threadIdx.x, lane = tid & 63, wave = tid >> 6;
  const int wm = wave >> 1, wn = wave & 1;
  const int n0 = blockIdx.x * 64, m0 = blockIdx.y * 64;
  f32x4 acc[2][2] = {};
  for (int kk = 0; kk < K; kk += 32){
    { int m = tid >> 2, k4 = (tid & 3) * 8;
      if (AK == 0){
        const float* ap = (const float*)Ap + (size_t)(m0 + m) * K + kk + k4;
        #pragma unroll
        for (int i = 0; i < 8; ++i) As[m][k4 + i] = f2bf(ap[i]);
      } else {
        const unsigned short* ap = (const unsigned short*)Ap + (size_t)(m0 + m) * K + kk + k4;
        *(bf16x8*)&As[m][k4] = *(const bf16x8*)ap;
      }
    }
    { int kq = tid >> 3, n8 = (tid & 7) * 8;
      const float* wp = W + (size_t)(kk + kq) * N + n0 + n8;
      #pragma unroll
      for (int i = 0; i < 8; ++i){
        int n = n8 + i;
        Bs[n][kq ^ (((n >> 3) & 3) << 3)] = f2bf(wp[i]);
      }
    }
    __syncthreads();
    const int kb = (lane >> 4) * 8;
    bf16x8 a[2], bfr[2];
    #pragma unroll
    for (int i = 0; i < 2; ++i) a[i] = *(const bf16x8*)&As[wm*32 + i*16 + (lane & 15)][kb];
    #pragma unroll
    for (int j = 0; j < 2; ++j){
      int n = wn*32 + j*16 + (lane & 15);
      bfr[j] = *(const bf16x8*)&Bs[n][kb ^ (((n >> 3) & 3) << 3)];
    }
    #pragma unroll
    for (int i = 0; i < 2; ++i)
      #pragma unroll
      for (int j = 0; j < 2; ++j) acc[i][j] = mfma16(a[i], bfr[j], acc[i][j]);
    __syncthreads();
  }
  #pragma unroll
  for (int i = 0; i < 2; ++i)
    #pragma unroll
    for (int j = 0; j < 2; ++j){
      int col = n0 + wn*32 + j*16 + (lane & 15);
      float bv = bias[col];
      #pragma unroll
      for (int r = 0; r < 4; ++r){
        int row = m0 + wm*32 + i*16 + (lane >> 4) * 4 + r;
        float v = acc[i][j][r] + bv;
        if (ACT == 1) v = gelu_f(v);
        if (RES) v += resid[(size_t)row * N + col];
        if (OUTB) ((unsigned short*)Cp)[(size_t)row * N + col] = f2bf(v);
        else      ((float*)Cp)[(size_t)row * N + col] = v;
      }
    }
}

// ---------------- split-K GEMM: part[z][M][N] = A[:, z*KS:(z+1)*KS] @ W[z*KS:...] ----
// AK: 0 = f32 A, 1 = bf16 A, 2 = fp8 e4m3 A (decoded exactly to bf16)
template<int AK>
__global__ __launch_bounds__(256) void k_gemm_sk(
    const void* __restrict__ Ap, const float* __restrict__ W,
    float* __restrict__ part, int M, int N, int K, int KS)
{
  __shared__ __align__(16) unsigned short As[64][40];  // [m][k]
  __shared__ __align__(16) unsigned short Bs[64][40];  // [n][k^swz]
  const int tid = threadIdx.x, lane = tid & 63, wave = tid >> 6;
  const int wm = wave >> 1, wn = wave & 1;
  const int n0 = blockIdx.x * 64, m0 = blockIdx.y * 64;
  const int kbase = blockIdx.z * KS;
  f32x4 acc[2][2] = {};
  for (int kq = 0; kq < KS; kq += 32){
    int kk = kbase + kq;
    { int m = tid >> 2, k4 = (tid & 3) * 8;
      if (AK == 0){
        const float* ap = (const float*)Ap + (size_t)(m0 + m) * K + kk + k4;
        #pragma unroll
        for (int i = 0; i < 8; ++i) As[m][k4 + i] = f2bf(ap[i]);
      } else if (AK == 1){
        const unsigned short* ap = (const unsigned short*)Ap + (size_t)(m0 + m) * K + kk + k4;
        *(bf16x8*)&As[m][k4] = *(const bf16x8*)ap;
      } else {
        const unsigned char* ap = (const unsigned char*)Ap + (size_t)(m0 + m) * K + kk + k4;
        uint2 dw2 = *(const uint2*)ap;
        float r0[4], r1[4];
        fp8x4_to_f32(dw2.x, r0);
        fp8x4_to_f32(dw2.y, r1);
        unsigned short tmp[8] = { f2bf(r0[0]), f2bf(r0[1]), f2bf(r0[2]), f2bf(r0[3]),
                                  f2bf(r1[0]), f2bf(r1[1]), f2bf(r1[2]), f2bf(r1[3]) };
        *(bf16x8*)&As[m][k4] = *(const bf16x8*)tmp;
      }
    }
    { int kr = tid >> 3, n8 = (tid & 7) * 8;
      const float* wp = W + (size_t)(kk + kr) * N + n0 + n8;
      #pragma unroll
      for (int i = 0; i < 8; ++i){
        int n = n8 + i;
        Bs[n][kr ^ (((n >> 3) & 3) << 3)] = f2bf(wp[i]);
      }
    }
    __syncthreads();
    const int kb = (lane >> 4) * 8;
    bf16x8 a[2], bfr[2];
    #pragma unroll
    for (int i = 0; i < 2; ++i) a[i] = *(const bf16x8*)&As[wm*32 + i*16 + (lane & 15)][kb];
    #pragma unroll
    for (int j = 0; j < 2; ++j){
      int n = wn*32 + j*16 + (lane & 15);
      bfr[j] = *(const bf16x8*)&Bs[n][kb ^ (((n >> 3) & 3) << 3)];
    }
    #pragma unroll
    for (int i = 0; i < 2; ++i)
      #pragma unroll
      for (int j = 0; j < 2; ++j) acc[i][j] = mfma16(a[i], bfr[j], acc[i][j]);
    __syncthreads();
  }
  float* pz = part + (size_t)blockIdx.z * M * N;
  #pragma unroll
  for (int i = 0; i < 2; ++i)
    #pragma unroll
    for (int j = 0; j < 2; ++j){
      int col = n0 + wn*32 + j*16 + (lane & 15);
      #pragma unroll
      for (int r = 0; r < 4; ++r){
        int row = m0 + wm*32 + i*16 + (lane >> 4) * 4 + r;
        pz[(size_t)row * N + col] = acc[i][j][r];
      }
    }
}

// ---------------- split-K reduce: out = sum_z part[z] + bias (+resid) ----------------
template<int RES>
__global__ __launch_bounds__(256) void k_reduce(
    const float* __restrict__ part, const float* __restrict__ bias,
    const float* __restrict__ resid, float* __restrict__ out,
    int total, int N, int SK)
{
  int i = blockIdx.x * 256 + threadIdx.x;
  if (i >= total) return;
  float s = 0.f;
  for (int z = 0; z < SK; ++z) s += part[(size_t)z * total + i];
  s += bias[i % N];
  if (RES) s += resid[i];
  out[i] = s;
}

// ---------------- fused split-K reduce + residual + LayerNorm ----------------
__global__ __launch_bounds__(256) void k_reduce_ln(
    const float* __restrict__ part, const float* __restrict__ bias,
    const float* __restrict__ resid,
    const float* __restrict__ g, const float* __restrict__ bb,
    float* __restrict__ emb_out, unsigned short* __restrict__ ln_out, int SK)
{
  __shared__ float red[4];
  const int t = blockIdx.x, tid = threadIdx.x;
  const int i = t * 256 + tid;
  float s = 0.f;
  for (int z = 0; z < SK; ++z) s += part[(size_t)z * 262144 + i];
  s += bias[tid] + resid[i];
  emb_out[i] = s;
  float mean = block_sum(s, red, tid) * (1.f / 256.f);
  float d = s - mean;
  float var = block_sum(d * d, red, tid) * (1.f / 256.f);
  ln_out[i] = f2bf(d * rsqrtf(var + 1e-5f) * g[tid] + bb[tid]);
}

// ---------------- attention: one (b,h) per block ----------------
__global__ __launch_bounds__(64) void k_attn(const float* __restrict__ qkv,
                                             float* __restrict__ attno)
{
  __shared__ float qs[64][33], ksm[64][33], vsm[64][33];
  const int blk = blockIdx.x, lane = threadIdx.x;
  const int b = blk >> 3, h = blk & 7;
  for (int idx = lane; idx < 2048; idx += 64){
    int row = idx >> 5, d = idx & 31;
    const float* base = qkv + (size_t)(b * 64 + row) * 768 + h * 32 + d;
    qs[row][d] = base[0]; ksm[row][d] = base[256]; vsm[row][d] = base[512];
  }
  __syncthreads();
  float qr[32];
  #pragma unroll
  for (int d = 0; d < 32; ++d) qr[d] = qs[lane][d];
  float s[64]; float mx = -1e30f;
  for (int m = 0; m < 64; ++m){
    float dot = 0.f;
    #pragma unroll
    for (int d = 0; d < 32; ++d) dot += qr[d] * ksm[m][d];
    dot *= 0.17677669529663687f;  // 32^-0.5
    s[m] = dot; mx = fmaxf(mx, dot);
  }
  float sum = 0.f;
  for (int m = 0; m < 64; ++m){ s[m] = expf(s[m] - mx); sum += s[m]; }
  float inv = 1.f / sum;
  float o[32] = {};
  for (int m = 0; m < 64; ++m){
    float p = s[m] * inv;
    #pragma unroll
    for (int d = 0; d < 32; ++d) o[d] += p * vsm[m][d];
  }
  float* dst = attno + (size_t)(b * 64 + lane) * 256 + h * 32;
  #pragma unroll
  for (int d = 0; d < 32; ++d) dst[d] = o[d];
}

__global__ void k_fill(float* p, int n, float v){
  int i = blockIdx.x * 256 + threadIdx.x;
  if (i < n) p[i] = v;
}

// ---------------- launch ----------------
extern "C" void kernel_launch(void* const* d_in, const int* in_sizes, int n_in,
                              void* d_out, int out_size, void* d_ws, size_t ws_size,
                              hipStream_t stream)
{
  const float* img      = (const float*)d_in[0];
  const float* embed    = (const float*)d_in[1];
  const float* roi      = (const float*)d_in[2];
  const float* ln_adj_g = (const float*)d_in[3];
  const float* ln_adj_b = (const float*)d_in[4];
  const float* w_adj    = (const float*)d_in[5];
  const float* ln_off_g = (const float*)d_in[6];
  const float* ln_off_b = (const float*)d_in[7];
  const float* w_off    = (const float*)d_in[8];
  const float* off_bias = (const float*)d_in[9];
  const float* pg_ln_g  = (const float*)d_in[10];
  const float* pg_ln_b  = (const float*)d_in[11];
  const float* pg_w1    = (const float*)d_in[12];
  const float* pg_b1    = (const float*)d_in[13];
  const float* pg_w2    = (const float*)d_in[14];
  const float* pg_b2    = (const float*)d_in[15];
  const float* m_beta   = (const float*)d_in[16];
  const float* s_beta   = (const float*)d_in[17];
  const float* mix_w    = (const float*)d_in[18];
  const float* mix_b    = (const float*)d_in[19];
  const float* ln1_g    = (const float*)d_in[20];
  const float* ln1_b    = (const float*)d_in[21];
  const float* qkv_w    = (const float*)d_in[22];
  const float* qkv_b    = (const float*)d_in[23];
  const float* proj_w   = (const float*)d_in[24];
  const float* proj_b   = (const float*)d_in[25];
  const float* ln2_g    = (const float*)d_in[26];
  const float* ln2_b    = (const float*)d_in[27];
  const float* fc1_w    = (const float*)d_in[28];
  const float* fc1_b    = (const float*)d_in[29];
  const float* fc2_w    = (const float*)d_in[30];
  const float* fc2_b    = (const float*)d_in[31];

  char* ws = (char*)d_ws;
  float*          pts     = (float*)         (ws + 0);          //   294912
  unsigned short* hbuf    = (unsigned short*)(ws + 294912);     //   131072 (bf16)
  unsigned char*  imgT8   = (unsigned char*) (ws + 557056);     // 16777216 (fp8)
  unsigned char*  params8 = (unsigned char*) (ws + 52985856);   // 67108864 (fp8 cm)
  unsigned short* sm16    = (unsigned short*)(ws + 120094720);  //  2752512 (f16 sm)
  unsigned char*  out28   = (unsigned char*) (ws + 122847232);  //  9437184 (fp8)
  float*          embed1  = (float*)         (ws + 141721600);  //  1048576
  float*          embed2  = (float*)         (ws + 142770176);  //  1048576
  unsigned short* xln1    = (unsigned short*)(ws + 143818752);  //   524288
  unsigned short* xln2    = (unsigned short*)(ws + 144343040);  //   524288
  float*          qkvb    = (float*)         (ws + 144867328);  //  3145728
  float*          attno   = (float*)         (ws + 148013056);  //  1048576
  // aliased into the params8 region (dead after k_mixtoken):
  float*          part_mix  = (float*)(ws + 52985856);             // 16 MB (16 slabs)
  float*          part_smll = (float*)(ws + 52985856 + 16777216);  //  4 MB (4 slabs)
  unsigned short* h1        = (unsigned short*)(ws + 52985856 + 20971520); // 2 MB
  const size_t WS_NEEDED = 149061632;
  if (ws_size < WS_NEEDED){
    k_fill<<<(out_size + 255) / 256, 256, 0, stream>>>((float*)d_out, out_size, 12345.0f);
    return;
  }

  float* out = (float*)d_out;

  k_prep<<<1024, 256, 0, stream>>>(embed, roi, ln_adj_g, ln_adj_b, w_adj,
                                   ln_off_g, ln_off_b, w_off, off_bias,
                                   pg_ln_g, pg_ln_b, pg_w1, pg_b1, pts, hbuf);
  k_transpose<<<1024, 256, 0, stream>>>(img, imgT8);
  k_params<<<1045, 256, 0, stream>>>(hbuf, pg_w2, pg_b2, params8, sm16);
  k_mixtoken<<<1024, 256, 0, stream>>>(imgT8, pts, params8, sm16, m_beta, s_beta, out28);
  // embed1 = embed + out2 @ mix_w + mix_b   (split-K: 9216 = 16 x 576), fused LN1
  k_gemm_sk<2><<<dim3(4,16,16), 256, 0, stream>>>(out28, mix_w, part_mix, 1024, 256, 9216, 576);
  k_reduce_ln<<<1024, 256, 0, stream>>>(part_mix, mix_b, embed, ln1_g, ln1_b, embed1, xln1, 16);
  k_gemm<1,0,0,0><<<dim3(12,16), 256, 0, stream>>>(xln1, qkv_w, qkv_b, nullptr, qkvb, 1024, 768, 256);
  k_attn<<<128, 64, 0, stream>>>(qkvb, attno);
  // embed2 = embed1 + attno @ proj_w + proj_b (split-K: 256 = 4 x 64), fused LN2
  k_gemm_sk<0><<<dim3(4,16,4), 256, 0, stream>>>(attno, proj_w, part_smll, 1024, 256, 256, 64);
  k_reduce_ln<<<1024, 256, 0, stream>>>(part_smll, proj_b, embed1, ln2_g, ln2_b, embed2, xln2, 4);
  k_gemm<1,1,0,1><<<dim3(16,16), 256, 0, stream>>>(xln2, fc1_w, fc1_b, nullptr, h1, 1024, 1024, 256);
  // out = embed2 + h1 @ fc2_w + fc2_b   (split-K: 1024 = 4 x 256)
  k_gemm_sk<1><<<dim3(4,16,4), 256, 0, stream>>>(h1, fc2_w, part_smll, 1024, 256, 1024, 256);
  k_reduce<1><<<1024, 256, 0, stream>>>(part_smll, fc2_b, embed2, out, 262144, 256, 4);
}